// Round 1
// baseline (1442.307 us; speedup 1.0000x reference)
//
#include <hip/hip_runtime.h>
#include <math.h>

static constexpr int B  = 8;
static constexpr int T  = 256;
static constexpr int C  = 1024;
static constexpr int H  = 16;
static constexpr int HEAD = 64;
static constexpr int FF = 4096;
static constexpr int BT = B * T;

// ---------------- epilogue ids ----------------
#define EPI_NONE      0
#define EPI_TANH      1
#define EPI_SILU      2
#define EPI_BIAS      3
#define EPI_RELUSQ    4
#define EPI_RES       5
#define EPI_SIGMULRES 6

// ---------------- LayerNorm: one block per (b,t) row ----------------
__global__ __launch_bounds__(256) void ln_kernel(const float* __restrict__ x,
                                                 const float* __restrict__ g,
                                                 const float* __restrict__ b,
                                                 float* __restrict__ out)
{
    const int row = blockIdx.x;
    const int tid = threadIdx.x;
    const float4 v = reinterpret_cast<const float4*>(x + (size_t)row * C)[tid];
    float s = v.x + v.y + v.z + v.w;
#pragma unroll
    for (int off = 32; off > 0; off >>= 1) s += __shfl_xor(s, off);
    __shared__ float red[8];
    const int wave = tid >> 6, lane = tid & 63;
    if (lane == 0) red[wave] = s;
    __syncthreads();
    const float mean = (red[0] + red[1] + red[2] + red[3]) * (1.0f / C);
    const float d0 = v.x - mean, d1 = v.y - mean, d2 = v.z - mean, d3 = v.w - mean;
    float q = d0 * d0 + d1 * d1 + d2 * d2 + d3 * d3;
#pragma unroll
    for (int off = 32; off > 0; off >>= 1) q += __shfl_xor(q, off);
    if (lane == 0) red[4 + wave] = q;
    __syncthreads();
    const float var = (red[4] + red[5] + red[6] + red[7]) * (1.0f / C);
    const float rstd = rsqrtf(var + 1e-5f);
    const int c = tid * 4;
    float4 o;
    o.x = d0 * rstd * g[c + 0] + b[c + 0];
    o.y = d1 * rstd * g[c + 1] + b[c + 1];
    o.z = d2 * rstd * g[c + 2] + b[c + 2];
    o.w = d3 * rstd * g[c + 3] + b[c + 3];
    reinterpret_cast<float4*>(out + (size_t)row * C)[tid] = o;
}

// ---------------- bidirectional shift:  xx = bshift(xa) - xa ----------------
__global__ __launch_bounds__(256) void bshift_kernel(const float* __restrict__ xa,
                                                     float* __restrict__ xx)
{
    const int i = blockIdx.x * 256 + threadIdx.x;       // [0, BT*C)
    const int c = i & (C - 1);
    const int bt = i >> 10;
    const int t = bt & (T - 1);
    const int j = c & (HEAD - 1);
    float src = 0.f;
    if (j < HEAD / 2) { if (t > 0)     src = xa[i - C]; }
    else              { if (t < T - 1) src = xa[i + C]; }
    xx[i] = src - xa[i];
}

// ---------------- ax = xa + xx * maa_x ----------------
__global__ __launch_bounds__(256) void mixax_kernel(const float* __restrict__ xa,
                                                    const float* __restrict__ xx,
                                                    const float* __restrict__ maa,
                                                    float* __restrict__ out)
{
    const int i = blockIdx.x * 256 + threadIdx.x;
    const int c = i & (C - 1);
    out[i] = xa[i] + xx[i] * maa[c];
}

// -------- mix5: out = xa + xx * (maa_f + a5[bt, f,:] @ w2[f,:,:]) --------
__global__ __launch_bounds__(256) void mix5_kernel(const float* __restrict__ xa,
                                                   const float* __restrict__ xx,
                                                   const float* __restrict__ a5,
                                                   const float* __restrict__ w2,
                                                   const float* __restrict__ maa,
                                                   int f, float* __restrict__ out)
{
    const int bt = blockIdx.x;
    const int tid = threadIdx.x;
    __shared__ float al[32];
    if (tid < 32) al[tid] = a5[(size_t)bt * 160 + f * 32 + tid];
    __syncthreads();
    const float* __restrict__ w2f = w2 + (size_t)f * 32 * C;
    const size_t rb = (size_t)bt * C;
#pragma unroll
    for (int m = 0; m < 4; ++m) {
        const int c = tid + 256 * m;
        float acc = 0.f;
#pragma unroll 8
        for (int d = 0; d < 32; ++d) acc = fmaf(al[d], w2f[d * C + c], acc);
        out[rb + c] = xa[rb + c] + xx[rb + c] * (maa[c] + acc);
    }
}

// -------- cmix: two mixed inputs for the FFN --------
__global__ __launch_bounds__(256) void cmix_kernel(const float* __restrict__ xc,
                                                   const float* __restrict__ cxx,
                                                   const float* __restrict__ mk,
                                                   const float* __restrict__ mr,
                                                   float* __restrict__ ok,
                                                   float* __restrict__ orr)
{
    const int i = blockIdx.x * 256 + threadIdx.x;
    const int c = i & (C - 1);
    const float a = xc[i], d = cxx[i];
    ok[i]  = a + d * mk[c];
    orr[i] = a + d * mr[c];
}

// -------- GroupNorm(yf+yb) * lnx_g + lnx_b, then * gate --------
__global__ __launch_bounds__(1024) void gnmul_kernel(const float* __restrict__ yf,
                                                     const float* __restrict__ yb,
                                                     const float* __restrict__ g,
                                                     const float* __restrict__ b,
                                                     const float* __restrict__ gate,
                                                     float* __restrict__ out)
{
    const int row = blockIdx.x;
    const int tid = threadIdx.x;                 // 1024 threads; wave == head
    const size_t idx = (size_t)row * C + tid;
    const float v = yf[idx] + yb[idx];
    float s = v;
#pragma unroll
    for (int off = 32; off > 0; off >>= 1) s += __shfl_xor(s, off);
    const float m = s * (1.0f / HEAD);
    const float d = v - m;
    float q = d * d;
#pragma unroll
    for (int off = 32; off > 0; off >>= 1) q += __shfl_xor(q, off);
    const float rstd = rsqrtf(q * (1.0f / HEAD) + 6.4e-4f);   // 1e-5 * 8^2
    out[idx] = (d * rstd * g[tid] + b[tid]) * gate[idx];
}

// ---------------- bidirectional WKV6 ----------------
// grid (B*H, 2), 256 threads = 4 waves; wave w owns state rows j in [16w,16w+16)
__global__ __launch_bounds__(256) void wkv_kernel(const float* __restrict__ r,
                                                  const float* __restrict__ k,
                                                  const float* __restrict__ v,
                                                  const float* __restrict__ w,
                                                  const float* __restrict__ u,
                                                  float* __restrict__ yf,
                                                  float* __restrict__ yb)
{
    const int bh = blockIdx.x;
    const int dir = blockIdx.y;
    const int b = bh >> 4, h = bh & (H - 1);
    const int tid = threadIdx.x;
    const int wave = tid >> 6, lane = tid & 63;
    __shared__ __align__(16) float s_r[64], s_k[64], s_d[64], s_ru[64];
    __shared__ float psum[4][64];
    float S[16];
#pragma unroll
    for (int j = 0; j < 16; ++j) S[j] = 0.f;
    float* __restrict__ yo = dir ? yb : yf;
    const int j0 = wave * 16;

    for (int tt = 0; tt < T; ++tt) {
        const int t = dir ? (T - 1 - tt) : tt;
        const size_t base = ((size_t)(b * T + t) * H + h) * HEAD;
        if (tid < 64) {
            const float rr = r[base + tid];
            const float kk = k[base + tid];
            const float ww = w[base + tid];
            s_r[tid] = rr;
            s_k[tid] = kk;
            s_d[tid] = __expf(-__expf(ww));
            s_ru[tid] = rr * kk * u[h * HEAD + tid];
        }
        __syncthreads();
        const float vv = v[base + lane];
        float y = 0.f;
#pragma unroll
        for (int jj = 0; jj < 16; jj += 4) {
            const float4 r4 = *reinterpret_cast<const float4*>(&s_r[j0 + jj]);
            const float4 k4 = *reinterpret_cast<const float4*>(&s_k[j0 + jj]);
            const float4 d4 = *reinterpret_cast<const float4*>(&s_d[j0 + jj]);
            // y from OLD state (both directions)
            y = fmaf(r4.x, S[jj + 0], y);
            y = fmaf(r4.y, S[jj + 1], y);
            y = fmaf(r4.z, S[jj + 2], y);
            y = fmaf(r4.w, S[jj + 3], y);
            if (dir == 0) {   // forward adds the u-bonus term r_j * u_j * k_j * v_i
                const float4 ru4 = *reinterpret_cast<const float4*>(&s_ru[j0 + jj]);
                y = fmaf(ru4.x, vv, y);
                y = fmaf(ru4.y, vv, y);
                y = fmaf(ru4.z, vv, y);
                y = fmaf(ru4.w, vv, y);
            }
            S[jj + 0] = fmaf(d4.x, S[jj + 0], k4.x * vv);
            S[jj + 1] = fmaf(d4.y, S[jj + 1], k4.y * vv);
            S[jj + 2] = fmaf(d4.z, S[jj + 2], k4.z * vv);
            S[jj + 3] = fmaf(d4.w, S[jj + 3], k4.w * vv);
        }
        psum[wave][lane] = y;
        __syncthreads();
        if (wave == 0)
            yo[base + lane] = psum[0][lane] + psum[1][lane] + psum[2][lane] + psum[3][lane];
    }
}

// ---------------- generic fp32 GEMM: C = epi(A[M,K] @ B[K,N]) ----------------
// 64x64 tile, BK=16, 256 threads, 4x4 per thread.
template <int EPI>
__global__ __launch_bounds__(256) void gemm_kernel(const float* __restrict__ A,
                                                   const float* __restrict__ Bm,
                                                   float* __restrict__ Cm,
                                                   int M, int N, int K,
                                                   const float* __restrict__ aux1,
                                                   const float* __restrict__ aux2)
{
    __shared__ float As[16][68];
    __shared__ float Bs[16][68];
    const int tid = threadIdx.x;
    const int bm = blockIdx.y * 64, bn = blockIdx.x * 64;
    const int tn = tid & 15, tm = tid >> 4;
    const int ar = tid >> 2;            // 0..63 row within A tile
    const int ak = (tid & 3) * 4;       // 0,4,8,12
    const int bk = tid >> 4;            // 0..15 row within B tile
    const int bn4 = (tid & 15) * 4;     // 0..60
    float acc[4][4] = {{0.f, 0.f, 0.f, 0.f}, {0.f, 0.f, 0.f, 0.f},
                       {0.f, 0.f, 0.f, 0.f}, {0.f, 0.f, 0.f, 0.f}};

    for (int k0 = 0; k0 < K; k0 += 16) {
        const float4 a4 = *reinterpret_cast<const float4*>(&A[(size_t)(bm + ar) * K + k0 + ak]);
        As[ak + 0][ar] = a4.x;
        As[ak + 1][ar] = a4.y;
        As[ak + 2][ar] = a4.z;
        As[ak + 3][ar] = a4.w;
        float4 b4 = make_float4(0.f, 0.f, 0.f, 0.f);
        if (bn + bn4 < N)
            b4 = *reinterpret_cast<const float4*>(&Bm[(size_t)(k0 + bk) * N + bn + bn4]);
        *reinterpret_cast<float4*>(&Bs[bk][bn4]) = b4;
        __syncthreads();
#pragma unroll
        for (int kk = 0; kk < 16; ++kk) {
            const float4 av = *reinterpret_cast<const float4*>(&As[kk][tm * 4]);
            const float4 bv = *reinterpret_cast<const float4*>(&Bs[kk][tn * 4]);
            acc[0][0] = fmaf(av.x, bv.x, acc[0][0]);
            acc[0][1] = fmaf(av.x, bv.y, acc[0][1]);
            acc[0][2] = fmaf(av.x, bv.z, acc[0][2]);
            acc[0][3] = fmaf(av.x, bv.w, acc[0][3]);
            acc[1][0] = fmaf(av.y, bv.x, acc[1][0]);
            acc[1][1] = fmaf(av.y, bv.y, acc[1][1]);
            acc[1][2] = fmaf(av.y, bv.z, acc[1][2]);
            acc[1][3] = fmaf(av.y, bv.w, acc[1][3]);
            acc[2][0] = fmaf(av.z, bv.x, acc[2][0]);
            acc[2][1] = fmaf(av.z, bv.y, acc[2][1]);
            acc[2][2] = fmaf(av.z, bv.z, acc[2][2]);
            acc[2][3] = fmaf(av.z, bv.w, acc[2][3]);
            acc[3][0] = fmaf(av.w, bv.x, acc[3][0]);
            acc[3][1] = fmaf(av.w, bv.y, acc[3][1]);
            acc[3][2] = fmaf(av.w, bv.z, acc[3][2]);
            acc[3][3] = fmaf(av.w, bv.w, acc[3][3]);
        }
        __syncthreads();
    }

#pragma unroll
    for (int i = 0; i < 4; ++i) {
        const int row = bm + tm * 4 + i;
#pragma unroll
        for (int j = 0; j < 4; ++j) {
            const int col = bn + tn * 4 + j;
            if (col >= N) continue;
            const float a = acc[i][j];
            const size_t oi = (size_t)row * N + col;
            float o;
            if (EPI == EPI_NONE)            o = a;
            else if (EPI == EPI_TANH)       o = tanhf(a);
            else if (EPI == EPI_SILU)       o = a / (1.f + __expf(-a));
            else if (EPI == EPI_BIAS)       o = a + aux1[col];
            else if (EPI == EPI_RELUSQ)   { const float tpos = fmaxf(a, 0.f); o = tpos * tpos; }
            else if (EPI == EPI_RES)        o = aux1[oi] + a;
            else /* EPI_SIGMULRES */        o = aux1[oi] + aux2[oi] / (1.f + __expf(-a));
            Cm[oi] = o;
        }
    }
}

// ---------------- launch ----------------
extern "C" void kernel_launch(void* const* d_in, const int* in_sizes, int n_in,
                              void* d_out, int out_size, void* d_ws, size_t ws_size,
                              hipStream_t stream)
{
    const float* x        = (const float*)d_in[0];
    const float* ln1_g    = (const float*)d_in[1];
    const float* ln1_b    = (const float*)d_in[2];
    const float* ln2_g    = (const float*)d_in[3];
    const float* ln2_b    = (const float*)d_in[4];
    const float* maa_x    = (const float*)d_in[5];
    const float* maa_w    = (const float*)d_in[6];
    const float* maa_k    = (const float*)d_in[7];
    const float* maa_v    = (const float*)d_in[8];
    const float* maa_r    = (const float*)d_in[9];
    const float* maa_g    = (const float*)d_in[10];
    const float* maa_w1   = (const float*)d_in[11];
    const float* maa_w2   = (const float*)d_in[12];
    const float* time_dec = (const float*)d_in[13];
    const float* tdw1     = (const float*)d_in[14];
    const float* tdw2     = (const float*)d_in[15];
    const float* u        = (const float*)d_in[16];
    const float* Wr       = (const float*)d_in[17];
    const float* Wk       = (const float*)d_in[18];
    const float* Wv       = (const float*)d_in[19];
    const float* Wg       = (const float*)d_in[20];
    const float* Wo       = (const float*)d_in[21];
    const float* lnx_g    = (const float*)d_in[22];
    const float* lnx_b    = (const float*)d_in[23];
    const float* cmaa_k   = (const float*)d_in[24];
    const float* cmaa_r   = (const float*)d_in[25];
    const float* Wck      = (const float*)d_in[26];
    const float* Wcv      = (const float*)d_in[27];
    const float* Wcr      = (const float*)d_in[28];
    float* out = (float*)d_out;

    float* ws = (float*)d_ws;
    const size_t E = (size_t)BT * C;       // 2,097,152 floats
    float* bufA = ws + 0 * E;              // xa  -> yf
    float* bufB = ws + 1 * E;              // xx  -> yb
    float* bufC = ws + 2 * E;              // ax / mix scratch -> ya
    float* bufD = ws + 3 * E;              // r   -> xc
    float* bufE = ws + 4 * E;              // k   -> cxx -> kv
    float* bufF = ws + 5 * E;              // v   -> ckin
    float* bufG = ws + 6 * E;              // w   -> crin
    float* bufH = ws + 7 * E;              // g (silu)
    float* a5   = ws + 8 * E;              // BT*160
    float* t1   = a5 + (size_t)BT * 160;   // BT*64
    float* kkb  = ws;                      // BT*FF floats == 4*E, reuses bufA..bufD

    const dim3 blk(256);
    const int EW = (BT * C) / 256;         // elementwise grid

    // ---- attention branch ----
    ln_kernel<<<BT, blk, 0, stream>>>(x, ln1_g, ln1_b, bufA);
    bshift_kernel<<<EW, blk, 0, stream>>>(bufA, bufB);
    mixax_kernel<<<EW, blk, 0, stream>>>(bufA, bufB, maa_x, bufC);
    gemm_kernel<EPI_TANH><<<dim3(3, BT / 64), blk, 0, stream>>>(bufC, maa_w1, a5, BT, 160, C, nullptr, nullptr);

    // f=0 -> w
    mix5_kernel<<<BT, blk, 0, stream>>>(bufA, bufB, a5, maa_w2, maa_w, 0, bufC);
    gemm_kernel<EPI_TANH><<<dim3(1, BT / 64), blk, 0, stream>>>(bufC, tdw1, t1, BT, 64, C, nullptr, nullptr);
    gemm_kernel<EPI_BIAS><<<dim3(C / 64, BT / 64), blk, 0, stream>>>(t1, tdw2, bufG, BT, C, 64, time_dec, nullptr);
    // f=1 -> k
    mix5_kernel<<<BT, blk, 0, stream>>>(bufA, bufB, a5, maa_w2, maa_k, 1, bufC);
    gemm_kernel<EPI_NONE><<<dim3(C / 64, BT / 64), blk, 0, stream>>>(bufC, Wk, bufE, BT, C, C, nullptr, nullptr);
    // f=2 -> v
    mix5_kernel<<<BT, blk, 0, stream>>>(bufA, bufB, a5, maa_w2, maa_v, 2, bufC);
    gemm_kernel<EPI_NONE><<<dim3(C / 64, BT / 64), blk, 0, stream>>>(bufC, Wv, bufF, BT, C, C, nullptr, nullptr);
    // f=3 -> r
    mix5_kernel<<<BT, blk, 0, stream>>>(bufA, bufB, a5, maa_w2, maa_r, 3, bufC);
    gemm_kernel<EPI_NONE><<<dim3(C / 64, BT / 64), blk, 0, stream>>>(bufC, Wr, bufD, BT, C, C, nullptr, nullptr);
    // f=4 -> g
    mix5_kernel<<<BT, blk, 0, stream>>>(bufA, bufB, a5, maa_w2, maa_g, 4, bufC);
    gemm_kernel<EPI_SILU><<<dim3(C / 64, BT / 64), blk, 0, stream>>>(bufC, Wg, bufH, BT, C, C, nullptr, nullptr);

    // bidirectional WKV
    wkv_kernel<<<dim3(B * H, 2), blk, 0, stream>>>(bufD, bufE, bufF, bufG, u, bufA, bufB);

    // ya = groupnorm(yf+yb)*g ; x = x + ya @ Wo
    gnmul_kernel<<<BT, dim3(1024), 0, stream>>>(bufA, bufB, lnx_g, lnx_b, bufH, bufC);
    gemm_kernel<EPI_RES><<<dim3(C / 64, BT / 64), blk, 0, stream>>>(bufC, Wo, out, BT, C, C, x, nullptr);

    // ---- FFN branch ----
    ln_kernel<<<BT, blk, 0, stream>>>(out, ln2_g, ln2_b, bufD);
    bshift_kernel<<<EW, blk, 0, stream>>>(bufD, bufE);
    cmix_kernel<<<EW, blk, 0, stream>>>(bufD, bufE, cmaa_k, cmaa_r, bufF, bufG);
    gemm_kernel<EPI_RELUSQ><<<dim3(FF / 64, BT / 64), blk, 0, stream>>>(bufF, Wck, kkb, BT, FF, C, nullptr, nullptr);
    gemm_kernel<EPI_NONE><<<dim3(C / 64, BT / 64), blk, 0, stream>>>(kkb, Wcv, bufE, BT, C, FF, nullptr, nullptr);
    gemm_kernel<EPI_SIGMULRES><<<dim3(C / 64, BT / 64), blk, 0, stream>>>(bufG, Wcr, out, BT, C, C, out, bufE);

    (void)in_sizes; (void)n_in; (void)out_size; (void)ws_size;
}

// Round 3
// 721.736 us; speedup vs baseline: 1.9984x; 1.9984x over previous
//
#include <hip/hip_runtime.h>
#include <math.h>
#include <stdint.h>

static constexpr int B  = 8;
static constexpr int T  = 256;
static constexpr int C  = 1024;
static constexpr int H  = 16;
static constexpr int HEAD = 64;
static constexpr int FF = 4096;
static constexpr int BT = B * T;

typedef short short8  __attribute__((ext_vector_type(8)));
typedef float floatx4 __attribute__((ext_vector_type(4)));

// ---------------- bf16 helpers ----------------
__device__ __forceinline__ float bf2f(ushort u) {
    return __uint_as_float(((uint32_t)u) << 16);
}
__device__ __forceinline__ ushort f2bf(float x) {
    uint32_t u = __float_as_uint(x);
    u += 0x7fff + ((u >> 16) & 1);          // RNE
    return (ushort)(u >> 16);
}

__device__ __forceinline__ void gload16(const void* g, void* l) {
    __builtin_amdgcn_global_load_lds(
        (const __attribute__((address_space(1))) unsigned int*)g,
        (__attribute__((address_space(3))) unsigned int*)l, 16, 0, 0);
}

// ---------------- epilogue ids ----------------
#define EPI_TANH      1
#define EPI_BIAS      3

#define BEPI_NONE_BF   0   // bf16 out
#define BEPI_SILU_BF   1   // bf16 out
#define BEPI_RELUSQ_BF 2   // bf16 out
#define BEPI_NONE_F    3   // f32 out
#define BEPI_RES_F     4   // f32 out = aux1 + acc
#define BEPI_SIGRES_F  5   // f32 out = aux1 + aux2*sigmoid(acc)

// ---------------- LayerNorm: one block per (b,t) row ----------------
__global__ __launch_bounds__(256) void ln_kernel(const float* __restrict__ x,
                                                 const float* __restrict__ g,
                                                 const float* __restrict__ b,
                                                 float* __restrict__ out)
{
    const int row = blockIdx.x;
    const int tid = threadIdx.x;
    const float4 v = reinterpret_cast<const float4*>(x + (size_t)row * C)[tid];
    float s = v.x + v.y + v.z + v.w;
#pragma unroll
    for (int off = 32; off > 0; off >>= 1) s += __shfl_xor(s, off);
    __shared__ float red[8];
    const int wave = tid >> 6, lane = tid & 63;
    if (lane == 0) red[wave] = s;
    __syncthreads();
    const float mean = (red[0] + red[1] + red[2] + red[3]) * (1.0f / C);
    const float d0 = v.x - mean, d1 = v.y - mean, d2 = v.z - mean, d3 = v.w - mean;
    float q = d0 * d0 + d1 * d1 + d2 * d2 + d3 * d3;
#pragma unroll
    for (int off = 32; off > 0; off >>= 1) q += __shfl_xor(q, off);
    if (lane == 0) red[4 + wave] = q;
    __syncthreads();
    const float var = (red[4] + red[5] + red[6] + red[7]) * (1.0f / C);
    const float rstd = rsqrtf(var + 1e-5f);
    const int c = tid * 4;
    float4 o;
    o.x = d0 * rstd * g[c + 0] + b[c + 0];
    o.y = d1 * rstd * g[c + 1] + b[c + 1];
    o.z = d2 * rstd * g[c + 2] + b[c + 2];
    o.w = d3 * rstd * g[c + 3] + b[c + 3];
    reinterpret_cast<float4*>(out + (size_t)row * C)[tid] = o;
}

// ---------------- bidirectional shift:  xx = bshift(xa) - xa ----------------
__global__ __launch_bounds__(256) void bshift_kernel(const float* __restrict__ xa,
                                                     float* __restrict__ xx)
{
    const int i = blockIdx.x * 256 + threadIdx.x;       // [0, BT*C)
    const int c = i & (C - 1);
    const int bt = i >> 10;
    const int t = bt & (T - 1);
    const int j = c & (HEAD - 1);
    float src = 0.f;
    if (j < HEAD / 2) { if (t > 0)     src = xa[i - C]; }
    else              { if (t < T - 1) src = xa[i + C]; }
    xx[i] = src - xa[i];
}

// ---------------- ax = xa + xx * maa_x ----------------
__global__ __launch_bounds__(256) void mixax_kernel(const float* __restrict__ xa,
                                                    const float* __restrict__ xx,
                                                    const float* __restrict__ maa,
                                                    float* __restrict__ out)
{
    const int i = blockIdx.x * 256 + threadIdx.x;
    const int c = i & (C - 1);
    out[i] = xa[i] + xx[i] * maa[c];
}

// -------- mix5 fp32: out = xa + xx * (maa_f + a5[bt,f,:] @ w2[f,:,:]) --------
__global__ __launch_bounds__(256) void mix5_kernel(const float* __restrict__ xa,
                                                   const float* __restrict__ xx,
                                                   const float* __restrict__ a5,
                                                   const float* __restrict__ w2,
                                                   const float* __restrict__ maa,
                                                   int f, float* __restrict__ out)
{
    const int bt = blockIdx.x;
    const int tid = threadIdx.x;
    __shared__ float al[32];
    if (tid < 32) al[tid] = a5[(size_t)bt * 160 + f * 32 + tid];
    __syncthreads();
    const float* __restrict__ w2f = w2 + (size_t)f * 32 * C;
    const size_t rb = (size_t)bt * C;
#pragma unroll
    for (int m = 0; m < 4; ++m) {
        const int c = tid + 256 * m;
        float acc = 0.f;
#pragma unroll 8
        for (int d = 0; d < 32; ++d) acc = fmaf(al[d], w2f[d * C + c], acc);
        out[rb + c] = xa[rb + c] + xx[rb + c] * (maa[c] + acc);
    }
}

// -------- mix5 bf16 out --------
__global__ __launch_bounds__(256) void mix5bf_kernel(const float* __restrict__ xa,
                                                     const float* __restrict__ xx,
                                                     const float* __restrict__ a5,
                                                     const float* __restrict__ w2,
                                                     const float* __restrict__ maa,
                                                     int f, ushort* __restrict__ out)
{
    const int bt = blockIdx.x;
    const int tid = threadIdx.x;
    __shared__ float al[32];
    if (tid < 32) al[tid] = a5[(size_t)bt * 160 + f * 32 + tid];
    __syncthreads();
    const float* __restrict__ w2f = w2 + (size_t)f * 32 * C;
    const size_t rb = (size_t)bt * C;
#pragma unroll
    for (int m = 0; m < 4; ++m) {
        const int c = tid + 256 * m;
        float acc = 0.f;
#pragma unroll 8
        for (int d = 0; d < 32; ++d) acc = fmaf(al[d], w2f[d * C + c], acc);
        out[rb + c] = f2bf(xa[rb + c] + xx[rb + c] * (maa[c] + acc));
    }
}

// -------- cmix: two mixed bf16 inputs for the FFN --------
__global__ __launch_bounds__(256) void cmix_kernel(const float* __restrict__ xc,
                                                   const float* __restrict__ cxx,
                                                   const float* __restrict__ mk,
                                                   const float* __restrict__ mr,
                                                   ushort* __restrict__ ok,
                                                   ushort* __restrict__ orr)
{
    const int i = blockIdx.x * 256 + threadIdx.x;
    const int c = i & (C - 1);
    const float a = xc[i], d = cxx[i];
    ok[i]  = f2bf(a + d * mk[c]);
    orr[i] = f2bf(a + d * mr[c]);
}

// -------- GroupNorm(yf+yb)*lnx_g+lnx_b, * gate(bf16) -> ya(bf16) --------
__global__ __launch_bounds__(1024) void gnmul_kernel(const float* __restrict__ yf,
                                                     const float* __restrict__ yb,
                                                     const float* __restrict__ g,
                                                     const float* __restrict__ b,
                                                     const ushort* __restrict__ gate,
                                                     ushort* __restrict__ out)
{
    const int row = blockIdx.x;
    const int tid = threadIdx.x;                 // 1024 threads; wave == head
    const size_t idx = (size_t)row * C + tid;
    const float v = yf[idx] + yb[idx];
    float s = v;
#pragma unroll
    for (int off = 32; off > 0; off >>= 1) s += __shfl_xor(s, off);
    const float m = s * (1.0f / HEAD);
    const float d = v - m;
    float q = d * d;
#pragma unroll
    for (int off = 32; off > 0; off >>= 1) q += __shfl_xor(q, off);
    const float rstd = rsqrtf(q * (1.0f / HEAD) + 6.4e-4f);   // 1e-5 * 8^2
    out[idx] = f2bf((d * rstd * g[tid] + b[tid]) * bf2f(gate[idx]));
}

// -------- weight convert+transpose: W[Kd,Nd] f32 -> Wt[Nd,Kd] bf16 --------
__global__ __launch_bounds__(256) void wconv_kernel(const float* __restrict__ W,
                                                    ushort* __restrict__ Wt,
                                                    int Kd, int Nd)
{
    __shared__ float tile[32][33];
    const int n0 = blockIdx.x * 32, k0 = blockIdx.y * 32;
    const int tx = threadIdx.x, ty = threadIdx.y;   // 32 x 8
#pragma unroll
    for (int i = 0; i < 4; ++i)
        tile[ty * 4 + i][tx] = W[(size_t)(k0 + ty * 4 + i) * Nd + n0 + tx];
    __syncthreads();
#pragma unroll
    for (int i = 0; i < 4; ++i)
        Wt[(size_t)(n0 + ty * 4 + i) * Kd + k0 + tx] = f2bf(tile[tx][ty * 4 + i]);
}

// ---------------- bidirectional WKV6 (r,k,v bf16; w fp32) ----------------
__global__ __launch_bounds__(256) void wkv_kernel(const ushort* __restrict__ r,
                                                  const ushort* __restrict__ k,
                                                  const ushort* __restrict__ v,
                                                  const float* __restrict__ w,
                                                  const float* __restrict__ u,
                                                  float* __restrict__ yf,
                                                  float* __restrict__ yb)
{
    const int bh = blockIdx.x;
    const int dir = blockIdx.y;
    const int b = bh >> 4, h = bh & (H - 1);
    const int tid = threadIdx.x;
    const int wave = tid >> 6, lane = tid & 63;
    __shared__ __align__(16) float s_r[64], s_k[64], s_d[64], s_ru[64];
    __shared__ float psum[4][64];
    float S[16];
#pragma unroll
    for (int j = 0; j < 16; ++j) S[j] = 0.f;
    float* __restrict__ yo = dir ? yb : yf;
    const int j0 = wave * 16;

    for (int tt = 0; tt < T; ++tt) {
        const int t = dir ? (T - 1 - tt) : tt;
        const size_t base = ((size_t)(b * T + t) * H + h) * HEAD;
        if (tid < 64) {
            const float rr = bf2f(r[base + tid]);
            const float kk = bf2f(k[base + tid]);
            const float ww = w[base + tid];
            s_r[tid] = rr;
            s_k[tid] = kk;
            s_d[tid] = __expf(-__expf(ww));
            s_ru[tid] = rr * kk * u[h * HEAD + tid];
        }
        __syncthreads();
        const float vv = bf2f(v[base + lane]);
        float y = 0.f;
#pragma unroll
        for (int jj = 0; jj < 16; jj += 4) {
            const float4 r4 = *reinterpret_cast<const float4*>(&s_r[j0 + jj]);
            const float4 k4 = *reinterpret_cast<const float4*>(&s_k[j0 + jj]);
            const float4 d4 = *reinterpret_cast<const float4*>(&s_d[j0 + jj]);
            y = fmaf(r4.x, S[jj + 0], y);
            y = fmaf(r4.y, S[jj + 1], y);
            y = fmaf(r4.z, S[jj + 2], y);
            y = fmaf(r4.w, S[jj + 3], y);
            if (dir == 0) {
                const float4 ru4 = *reinterpret_cast<const float4*>(&s_ru[j0 + jj]);
                y = fmaf(ru4.x, vv, y);
                y = fmaf(ru4.y, vv, y);
                y = fmaf(ru4.z, vv, y);
                y = fmaf(ru4.w, vv, y);
            }
            S[jj + 0] = fmaf(d4.x, S[jj + 0], k4.x * vv);
            S[jj + 1] = fmaf(d4.y, S[jj + 1], k4.y * vv);
            S[jj + 2] = fmaf(d4.z, S[jj + 2], k4.z * vv);
            S[jj + 3] = fmaf(d4.w, S[jj + 3], k4.w * vv);
        }
        psum[wave][lane] = y;
        __syncthreads();
        if (wave == 0)
            yo[base + lane] = psum[0][lane] + psum[1][lane] + psum[2][lane] + psum[3][lane];
    }
}

// ======== bf16 MFMA GEMM: C = epi(A[M,K] @ Bt[N,K]^T), BM=128, BK=32 ========
// 256 threads = 4 waves (2x2); per wave 64 x (BN/2); 16x16x32 bf16 MFMA.
// LDS linear, global source pre-swizzled: slot ^= ((row>>1)&3)  (T2, rule #21)
template <int BN, int EPI>
__global__ __launch_bounds__(256) void bgemm_kernel(const ushort* __restrict__ A,
                                                    const ushort* __restrict__ Bt,
                                                    void* __restrict__ Cm,
                                                    int M, int N, int K,
                                                    const float* __restrict__ aux1,
                                                    const float* __restrict__ aux2)
{
    constexpr int NF = BN / 32;                 // n-frags per wave
    __shared__ __align__(16) ushort As[128 * 32];
    __shared__ __align__(16) ushort Bs[BN * 32];
    const int tid = threadIdx.x;
    const int wid = tid >> 6, lane = tid & 63;
    const int wr = wid >> 1, wc = wid & 1;
    const int bm = blockIdx.y * 128, bn = blockIdx.x * BN;
    const int l15 = lane & 15, lhi = lane >> 4;

    floatx4 acc[4][NF];
#pragma unroll
    for (int m = 0; m < 4; ++m)
#pragma unroll
        for (int n = 0; n < NF; ++n) acc[m][n] = (floatx4){0.f, 0.f, 0.f, 0.f};

    for (int k0 = 0; k0 < K; k0 += 32) {
        // stage A: 128x32 bf16 = 8KB, 2 passes of 256 lanes x 16B
#pragma unroll
        for (int p = 0; p < 2; ++p) {
            const int lin = p * 256 + tid;
            const int row = lin >> 2;
            const int sp = (lin & 3) ^ ((row >> 1) & 3);
            gload16(A + (size_t)(bm + row) * K + k0 + sp * 8, &As[lin * 8]);
        }
        // stage B: BNx32
#pragma unroll
        for (int p = 0; p < BN / 64; ++p) {
            const int lin = p * 256 + tid;
            const int n = lin >> 2;
            const int sp = (lin & 3) ^ ((n >> 1) & 3);
            gload16(Bt + (size_t)(bn + n) * K + k0 + sp * 8, &Bs[lin * 8]);
        }
        __syncthreads();

        short8 af[4], bfr[NF];
#pragma unroll
        for (int m = 0; m < 4; ++m) {
            const int row = wr * 64 + m * 16 + l15;
            const int sp = lhi ^ ((row >> 1) & 3);
            af[m] = *(const short8*)&As[row * 32 + sp * 8];
        }
#pragma unroll
        for (int n = 0; n < NF; ++n) {
            const int col = wc * (BN / 2) + n * 16 + l15;
            const int sp = lhi ^ ((col >> 1) & 3);
            bfr[n] = *(const short8*)&Bs[col * 32 + sp * 8];
        }
#pragma unroll
        for (int m = 0; m < 4; ++m)
#pragma unroll
            for (int n = 0; n < NF; ++n)
                acc[m][n] = __builtin_amdgcn_mfma_f32_16x16x32_bf16(af[m], bfr[n], acc[m][n], 0, 0, 0);
        __syncthreads();
    }

    // epilogue: C/D layout col = lane&15, row = (lane>>4)*4 + j
#pragma unroll
    for (int m = 0; m < 4; ++m) {
        const int row0 = bm + wr * 64 + m * 16 + lhi * 4;
#pragma unroll
        for (int n = 0; n < NF; ++n) {
            const int col = bn + wc * (BN / 2) + n * 16 + l15;
#pragma unroll
            for (int j = 0; j < 4; ++j) {
                const size_t oi = (size_t)(row0 + j) * N + col;
                const float a = acc[m][n][j];
                if constexpr (EPI == BEPI_NONE_BF) {
                    ((ushort*)Cm)[oi] = f2bf(a);
                } else if constexpr (EPI == BEPI_SILU_BF) {
                    ((ushort*)Cm)[oi] = f2bf(a / (1.f + __expf(-a)));
                } else if constexpr (EPI == BEPI_RELUSQ_BF) {
                    const float t = fmaxf(a, 0.f);
                    ((ushort*)Cm)[oi] = f2bf(t * t);
                } else if constexpr (EPI == BEPI_NONE_F) {
                    ((float*)Cm)[oi] = a;
                } else if constexpr (EPI == BEPI_RES_F) {
                    ((float*)Cm)[oi] = aux1[oi] + a;
                } else {  // BEPI_SIGRES_F
                    ((float*)Cm)[oi] = aux1[oi] + aux2[oi] / (1.f + __expf(-a));
                }
            }
        }
    }
}

// ---------------- small fp32 GEMM (w-path): 64x64 tile, BK=16 ----------------
template <int EPI>
__global__ __launch_bounds__(256) void gemm_kernel(const float* __restrict__ A,
                                                   const float* __restrict__ Bm,
                                                   float* __restrict__ Cm,
                                                   int M, int N, int K,
                                                   const float* __restrict__ aux1)
{
    __shared__ float As[16][68];
    __shared__ float Bs[16][68];
    const int tid = threadIdx.x;
    const int bm = blockIdx.y * 64, bn = blockIdx.x * 64;
    const int tn = tid & 15, tm = tid >> 4;
    const int ar = tid >> 2;
    const int ak = (tid & 3) * 4;
    const int bk = tid >> 4;
    const int bn4 = (tid & 15) * 4;
    float acc[4][4] = {{0.f}, {0.f}, {0.f}, {0.f}};

    for (int k0 = 0; k0 < K; k0 += 16) {
        const float4 a4 = *reinterpret_cast<const float4*>(&A[(size_t)(bm + ar) * K + k0 + ak]);
        As[ak + 0][ar] = a4.x;
        As[ak + 1][ar] = a4.y;
        As[ak + 2][ar] = a4.z;
        As[ak + 3][ar] = a4.w;
        float4 b4 = make_float4(0.f, 0.f, 0.f, 0.f);
        if (bn + bn4 < N)
            b4 = *reinterpret_cast<const float4*>(&Bm[(size_t)(k0 + bk) * N + bn + bn4]);
        *reinterpret_cast<float4*>(&Bs[bk][bn4]) = b4;
        __syncthreads();
#pragma unroll
        for (int kk = 0; kk < 16; ++kk) {
            const float4 av = *reinterpret_cast<const float4*>(&As[kk][tm * 4]);
            const float4 bv = *reinterpret_cast<const float4*>(&Bs[kk][tn * 4]);
#pragma unroll
            for (int i = 0; i < 4; ++i) {
                const float ai = (i == 0) ? av.x : (i == 1) ? av.y : (i == 2) ? av.z : av.w;
                acc[i][0] = fmaf(ai, bv.x, acc[i][0]);
                acc[i][1] = fmaf(ai, bv.y, acc[i][1]);
                acc[i][2] = fmaf(ai, bv.z, acc[i][2]);
                acc[i][3] = fmaf(ai, bv.w, acc[i][3]);
            }
        }
        __syncthreads();
    }

#pragma unroll
    for (int i = 0; i < 4; ++i) {
        const int row = bm + tm * 4 + i;
#pragma unroll
        for (int j = 0; j < 4; ++j) {
            const int col = bn + tn * 4 + j;
            if (col >= N) continue;
            const float a = acc[i][j];
            const size_t oi = (size_t)row * N + col;
            float o;
            if (EPI == EPI_TANH)      o = tanhf(a);
            else /* EPI_BIAS */       o = a + aux1[col];
            Cm[oi] = o;
        }
    }
}

// ---------------- launch ----------------
extern "C" void kernel_launch(void* const* d_in, const int* in_sizes, int n_in,
                              void* d_out, int out_size, void* d_ws, size_t ws_size,
                              hipStream_t stream)
{
    const float* x        = (const float*)d_in[0];
    const float* ln1_g    = (const float*)d_in[1];
    const float* ln1_b    = (const float*)d_in[2];
    const float* ln2_g    = (const float*)d_in[3];
    const float* ln2_b    = (const float*)d_in[4];
    const float* maa_x    = (const float*)d_in[5];
    const float* maa_w    = (const float*)d_in[6];
    const float* maa_k    = (const float*)d_in[7];
    const float* maa_v    = (const float*)d_in[8];
    const float* maa_r    = (const float*)d_in[9];
    const float* maa_g    = (const float*)d_in[10];
    const float* maa_w1   = (const float*)d_in[11];
    const float* maa_w2   = (const float*)d_in[12];
    const float* time_dec = (const float*)d_in[13];
    const float* tdw1     = (const float*)d_in[14];
    const float* tdw2     = (const float*)d_in[15];
    const float* u        = (const float*)d_in[16];
    const float* Wr       = (const float*)d_in[17];
    const float* Wk       = (const float*)d_in[18];
    const float* Wv       = (const float*)d_in[19];
    const float* Wg       = (const float*)d_in[20];
    const float* Wo       = (const float*)d_in[21];
    const float* lnx_g    = (const float*)d_in[22];
    const float* lnx_b    = (const float*)d_in[23];
    const float* cmaa_k   = (const float*)d_in[24];
    const float* cmaa_r   = (const float*)d_in[25];
    const float* Wck      = (const float*)d_in[26];
    const float* Wcv      = (const float*)d_in[27];
    const float* Wcr      = (const float*)d_in[28];
    float* out = (float*)d_out;

    // -------- workspace layout (~63 MB) --------
    float* fws = (float*)d_ws;
    const size_t E = (size_t)BT * C;            // 2,097,152
    float* xa = fws + 0 * E;                    // xa -> yf ; (FFN) kk low half
    float* xx = fws + 1 * E;                    // xx -> yb -> cxx ; kk high half
    float* fs = fws + 2 * E;                    // ax / xw / kv
    float* wd = fws + 3 * E;                    // w -> xc
    float* a5 = fws + 4 * E;                    // BT*160
    float* t1 = a5 + (size_t)BT * 160;          // BT*64
    ushort* wBuf = (ushort*)(t1 + (size_t)BT * 64);  // C*FF bf16 (weight staging)
    ushort* bf1  = wBuf + (size_t)C * FF;       // E bf16: xmix / ck_in
    ushort* rb   = bf1 + E;                     // r
    ushort* kb   = rb + E;                      // k
    ushort* vb   = kb + E;                      // v  -> ya
    ushort* gb   = vb + E;                      // g  -> cr_in
    ushort* kk   = (ushort*)xa;                 // BT*FF bf16 == xa..xx exactly

    const dim3 blk(256);
    const dim3 tblk(32, 8);
    const int EW = (BT * C) / 256;
    const dim3 gNN(C / 64, BT / 128);           // bgemm BN=64, N=C grids

    // ---- attention branch ----
    ln_kernel<<<BT, blk, 0, stream>>>(x, ln1_g, ln1_b, xa);
    bshift_kernel<<<EW, blk, 0, stream>>>(xa, xx);
    mixax_kernel<<<EW, blk, 0, stream>>>(xa, xx, maa_x, fs);
    gemm_kernel<EPI_TANH><<<dim3(3, BT / 64), blk, 0, stream>>>(fs, maa_w1, a5, BT, 160, C, nullptr);

    // w path (fp32)
    mix5_kernel<<<BT, blk, 0, stream>>>(xa, xx, a5, maa_w2, maa_w, 0, fs);
    gemm_kernel<EPI_TANH><<<dim3(1, BT / 64), blk, 0, stream>>>(fs, tdw1, t1, BT, 64, C, nullptr);
    gemm_kernel<EPI_BIAS><<<dim3(C / 64, BT / 64), blk, 0, stream>>>(t1, tdw2, wd, BT, C, 64, time_dec);

    // k
    mix5bf_kernel<<<BT, blk, 0, stream>>>(xa, xx, a5, maa_w2, maa_k, 1, bf1);
    wconv_kernel<<<dim3(C / 32, C / 32), tblk, 0, stream>>>(Wk, wBuf, C, C);
    bgemm_kernel<64, BEPI_NONE_BF><<<gNN, blk, 0, stream>>>(bf1, wBuf, kb, BT, C, C, nullptr, nullptr);
    // v
    mix5bf_kernel<<<BT, blk, 0, stream>>>(xa, xx, a5, maa_w2, maa_v, 2, bf1);
    wconv_kernel<<<dim3(C / 32, C / 32), tblk, 0, stream>>>(Wv, wBuf, C, C);
    bgemm_kernel<64, BEPI_NONE_BF><<<gNN, blk, 0, stream>>>(bf1, wBuf, vb, BT, C, C, nullptr, nullptr);
    // r
    mix5bf_kernel<<<BT, blk, 0, stream>>>(xa, xx, a5, maa_w2, maa_r, 3, bf1);
    wconv_kernel<<<dim3(C / 32, C / 32), tblk, 0, stream>>>(Wr, wBuf, C, C);
    bgemm_kernel<64, BEPI_NONE_BF><<<gNN, blk, 0, stream>>>(bf1, wBuf, rb, BT, C, C, nullptr, nullptr);
    // g
    mix5bf_kernel<<<BT, blk, 0, stream>>>(xa, xx, a5, maa_w2, maa_g, 4, bf1);
    wconv_kernel<<<dim3(C / 32, C / 32), tblk, 0, stream>>>(Wg, wBuf, C, C);
    bgemm_kernel<64, BEPI_SILU_BF><<<gNN, blk, 0, stream>>>(bf1, wBuf, gb, BT, C, C, nullptr, nullptr);

    // bidirectional WKV
    wkv_kernel<<<dim3(B * H, 2), blk, 0, stream>>>(rb, kb, vb, wd, u, xa, xx);

    // ya = groupnorm(yf+yb)*g (bf16); out = x + ya @ Wo^T
    gnmul_kernel<<<BT, dim3(1024), 0, stream>>>(xa, xx, lnx_g, lnx_b, gb, vb);
    wconv_kernel<<<dim3(C / 32, C / 32), tblk, 0, stream>>>(Wo, wBuf, C, C);
    bgemm_kernel<64, BEPI_RES_F><<<gNN, blk, 0, stream>>>(vb, wBuf, out, BT, C, C, x, nullptr);

    // ---- FFN branch ----
    ln_kernel<<<BT, blk, 0, stream>>>(out, ln2_g, ln2_b, wd);
    bshift_kernel<<<EW, blk, 0, stream>>>(wd, xx);
    cmix_kernel<<<EW, blk, 0, stream>>>(wd, xx, cmaa_k, cmaa_r, bf1, gb);
    // kk (BT x FF bf16) lives in xa..xx (dead after cmix)
    wconv_kernel<<<dim3(FF / 32, C / 32), tblk, 0, stream>>>(Wck, wBuf, C, FF);
    bgemm_kernel<128, BEPI_RELUSQ_BF><<<dim3(FF / 128, BT / 128), blk, 0, stream>>>(bf1, wBuf, kk, BT, FF, C, nullptr, nullptr);
    wconv_kernel<<<dim3(C / 32, FF / 32), tblk, 0, stream>>>(Wcv, wBuf, FF, C);
    bgemm_kernel<64, BEPI_NONE_F><<<gNN, blk, 0, stream>>>(kk, wBuf, fs, BT, C, FF, nullptr, nullptr);
    wconv_kernel<<<dim3(C / 32, C / 32), tblk, 0, stream>>>(Wcr, wBuf, C, C);
    bgemm_kernel<64, BEPI_SIGRES_F><<<gNN, blk, 0, stream>>>(gb, wBuf, out, BT, C, C, out, fs);

    (void)in_sizes; (void)n_in; (void)out_size; (void)ws_size;
}

// Round 4
// 627.339 us; speedup vs baseline: 2.2991x; 1.1505x over previous
//
#include <hip/hip_runtime.h>
#include <math.h>
#include <stdint.h>

static constexpr int B  = 8;
static constexpr int T  = 256;
static constexpr int C  = 1024;
static constexpr int H  = 16;
static constexpr int HEAD = 64;
static constexpr int FF = 4096;
static constexpr int BT = B * T;

typedef short short8  __attribute__((ext_vector_type(8)));
typedef float floatx4 __attribute__((ext_vector_type(4)));

// ---------------- bf16 helpers ----------------
__device__ __forceinline__ float bf2f(ushort u) {
    return __uint_as_float(((uint32_t)u) << 16);
}
__device__ __forceinline__ ushort f2bf(float x) {
    uint32_t u = __float_as_uint(x);
    u += 0x7fff + ((u >> 16) & 1);          // RNE
    return (ushort)(u >> 16);
}

__device__ __forceinline__ void gload16(const void* g, void* l) {
    __builtin_amdgcn_global_load_lds(
        (const __attribute__((address_space(1))) unsigned int*)g,
        (__attribute__((address_space(3))) unsigned int*)l, 16, 0, 0);
}

// ---------------- epilogue ids ----------------
#define BEPI_NONE_BF   0   // bf16 out
#define BEPI_SILU_BF   1   // bf16 out
#define BEPI_RELUSQ_BF 2   // bf16 out
#define BEPI_NONE_F    3   // f32 out
#define BEPI_RES_F     4   // f32 out = aux1 + acc
#define BEPI_SIGRES_F  5   // f32 out = aux1 + aux2*sigmoid(acc)
#define BEPI_TANH_F    6   // f32 out = tanh(acc)
#define BEPI_TANH_BF   7   // bf16 out = tanh(acc)
#define BEPI_BIAS_F    8   // f32 out = acc + aux1[col]

// ---------------- LayerNorm: one block per (b,t) row ----------------
__global__ __launch_bounds__(256) void ln_kernel(const float* __restrict__ x,
                                                 const float* __restrict__ g,
                                                 const float* __restrict__ b,
                                                 float* __restrict__ out)
{
    const int row = blockIdx.x;
    const int tid = threadIdx.x;
    const float4 v = reinterpret_cast<const float4*>(x + (size_t)row * C)[tid];
    float s = v.x + v.y + v.z + v.w;
#pragma unroll
    for (int off = 32; off > 0; off >>= 1) s += __shfl_xor(s, off);
    __shared__ float red[8];
    const int wave = tid >> 6, lane = tid & 63;
    if (lane == 0) red[wave] = s;
    __syncthreads();
    const float mean = (red[0] + red[1] + red[2] + red[3]) * (1.0f / C);
    const float d0 = v.x - mean, d1 = v.y - mean, d2 = v.z - mean, d3 = v.w - mean;
    float q = d0 * d0 + d1 * d1 + d2 * d2 + d3 * d3;
#pragma unroll
    for (int off = 32; off > 0; off >>= 1) q += __shfl_xor(q, off);
    if (lane == 0) red[4 + wave] = q;
    __syncthreads();
    const float var = (red[4] + red[5] + red[6] + red[7]) * (1.0f / C);
    const float rstd = rsqrtf(var + 1e-5f);
    const int c = tid * 4;
    float4 o;
    o.x = d0 * rstd * g[c + 0] + b[c + 0];
    o.y = d1 * rstd * g[c + 1] + b[c + 1];
    o.z = d2 * rstd * g[c + 2] + b[c + 2];
    o.w = d3 * rstd * g[c + 3] + b[c + 3];
    reinterpret_cast<float4*>(out + (size_t)row * C)[tid] = o;
}

// ---------------- bidirectional shift:  xx = bshift(xa) - xa ----------------
__global__ __launch_bounds__(256) void bshift_kernel(const float* __restrict__ xa,
                                                     float* __restrict__ xx)
{
    const int i = blockIdx.x * 256 + threadIdx.x;       // [0, BT*C)
    const int c = i & (C - 1);
    const int bt = i >> 10;
    const int t = bt & (T - 1);
    const int j = c & (HEAD - 1);
    float src = 0.f;
    if (j < HEAD / 2) { if (t > 0)     src = xa[i - C]; }
    else              { if (t < T - 1) src = xa[i + C]; }
    xx[i] = src - xa[i];
}

// ---------------- ax = xa + xx * maa_x  (bf16 out) ----------------
__global__ __launch_bounds__(256) void mixaxbf_kernel(const float* __restrict__ xa,
                                                      const float* __restrict__ xx,
                                                      const float* __restrict__ maa,
                                                      ushort* __restrict__ out)
{
    const int i = blockIdx.x * 256 + threadIdx.x;
    const int c = i & (C - 1);
    out[i] = f2bf(xa[i] + xx[i] * maa[c]);
}

// -------- mix5 bf16 out: out = xa + xx * (maa_f + a5[bt,f,:] @ w2[f,:,:]) ----
__global__ __launch_bounds__(256) void mix5bf_kernel(const float* __restrict__ xa,
                                                     const float* __restrict__ xx,
                                                     const float* __restrict__ a5,
                                                     const float* __restrict__ w2,
                                                     const float* __restrict__ maa,
                                                     int f, ushort* __restrict__ out)
{
    const int bt = blockIdx.x;
    const int tid = threadIdx.x;
    __shared__ float al[32];
    if (tid < 32) al[tid] = a5[(size_t)bt * 160 + f * 32 + tid];
    __syncthreads();
    const float* __restrict__ w2f = w2 + (size_t)f * 32 * C;
    const size_t rb = (size_t)bt * C;
#pragma unroll
    for (int m = 0; m < 4; ++m) {
        const int c = tid + 256 * m;
        float acc = 0.f;
#pragma unroll 8
        for (int d = 0; d < 32; ++d) acc = fmaf(al[d], w2f[d * C + c], acc);
        out[rb + c] = f2bf(xa[rb + c] + xx[rb + c] * (maa[c] + acc));
    }
}

// -------- cmix: two mixed bf16 inputs for the FFN --------
__global__ __launch_bounds__(256) void cmix_kernel(const float* __restrict__ xc,
                                                   const float* __restrict__ cxx,
                                                   const float* __restrict__ mk,
                                                   const float* __restrict__ mr,
                                                   ushort* __restrict__ ok,
                                                   ushort* __restrict__ orr)
{
    const int i = blockIdx.x * 256 + threadIdx.x;
    const int c = i & (C - 1);
    const float a = xc[i], d = cxx[i];
    ok[i]  = f2bf(a + d * mk[c]);
    orr[i] = f2bf(a + d * mr[c]);
}

// -------- sigma: sig[bt,h] = sum_j r*u*k  (the u-bonus scalar) --------
__global__ __launch_bounds__(256) void sigma_kernel(const ushort* __restrict__ r,
                                                    const ushort* __restrict__ k,
                                                    const float* __restrict__ u,
                                                    float* __restrict__ sig)
{
    const int bt = blockIdx.x;
    const int tid = threadIdx.x;
    const int c0 = tid * 4;
    const size_t base = (size_t)bt * C + c0;
    const uint2 rv = *reinterpret_cast<const uint2*>(r + base);
    const uint2 kv = *reinterpret_cast<const uint2*>(k + base);
    float p = 0.f;
    p += bf2f((ushort)(rv.x & 0xffff)) * bf2f((ushort)(kv.x & 0xffff)) * u[c0 + 0];
    p += bf2f((ushort)(rv.x >> 16))    * bf2f((ushort)(kv.x >> 16))    * u[c0 + 1];
    p += bf2f((ushort)(rv.y & 0xffff)) * bf2f((ushort)(kv.y & 0xffff)) * u[c0 + 2];
    p += bf2f((ushort)(rv.y >> 16))    * bf2f((ushort)(kv.y >> 16))    * u[c0 + 3];
    p += __shfl_xor(p, 1);
    p += __shfl_xor(p, 2);
    p += __shfl_xor(p, 4);
    p += __shfl_xor(p, 8);
    if ((tid & 15) == 0) sig[(size_t)bt * H + (tid >> 4)] = p;
}

// -------- GroupNorm(yf+yb+sig*v)*lnx_g+lnx_b, * gate(bf16) -> ya(bf16) -------
__global__ __launch_bounds__(1024) void gnmul_kernel(const float* __restrict__ yf,
                                                     const float* __restrict__ yb,
                                                     const float* __restrict__ g,
                                                     const float* __restrict__ b,
                                                     const ushort* __restrict__ gate,
                                                     const ushort* __restrict__ vin,
                                                     const float* __restrict__ sig,
                                                     ushort* __restrict__ out)
{
    const int row = blockIdx.x;
    const int tid = threadIdx.x;                 // 1024 threads; wave == head
    const size_t idx = (size_t)row * C + tid;
    const float sg = sig[(size_t)row * H + (tid >> 6)];
    const float v = yf[idx] + yb[idx] + sg * bf2f(vin[idx]);
    float s = v;
#pragma unroll
    for (int off = 32; off > 0; off >>= 1) s += __shfl_xor(s, off);
    const float m = s * (1.0f / HEAD);
    const float d = v - m;
    float q = d * d;
#pragma unroll
    for (int off = 32; off > 0; off >>= 1) q += __shfl_xor(q, off);
    const float rstd = rsqrtf(q * (1.0f / HEAD) + 6.4e-4f);   // 1e-5 * 8^2
    out[idx] = f2bf((d * rstd * g[tid] + b[tid]) * bf2f(gate[idx]));
}

// -------- weight convert+transpose: W[Kd,Nd] f32 -> Wt[Nd,Kd] bf16 --------
__global__ __launch_bounds__(256) void wconv_kernel(const float* __restrict__ W,
                                                    ushort* __restrict__ Wt,
                                                    int Kd, int Nd)
{
    __shared__ float tile[32][33];
    const int n0 = blockIdx.x * 32, k0 = blockIdx.y * 32;
    const int tx = threadIdx.x, ty = threadIdx.y;   // 32 x 8
#pragma unroll
    for (int i = 0; i < 4; ++i)
        tile[ty * 4 + i][tx] = W[(size_t)(k0 + ty * 4 + i) * Nd + n0 + tx];
    __syncthreads();
#pragma unroll
    for (int i = 0; i < 4; ++i)
        Wt[(size_t)(n0 + ty * 4 + i) * Kd + k0 + tx] = f2bf(tile[tx][ty * 4 + i]);
}

// ---------------- bidirectional WKV6: 1 wave per (b,h,dir) ----------------
// lane = state column i; S[j][i] in 64 VGPRs; r/k/d broadcast via LDS;
// no barriers (single wave), global loads prefetched 1 step ahead.
__global__ __launch_bounds__(64, 1) void wkv_kernel(const ushort* __restrict__ r,
                                                    const ushort* __restrict__ k,
                                                    const ushort* __restrict__ v,
                                                    const float* __restrict__ w,
                                                    float* __restrict__ yf,
                                                    float* __restrict__ yb)
{
    const int unit = blockIdx.x;            // 256 = B*H*2
    const int dir  = unit & 1;
    const int bh   = unit >> 1;
    const int lane = threadIdx.x;
    __shared__ __align__(16) float sbuf[2][3][64];   // [buf][{r,k,d}][64]

    float S[64];
#pragma unroll
    for (int j = 0; j < 64; ++j) S[j] = 0.f;
    float* __restrict__ yo = dir ? yb : yf;
    const size_t unit_off = ((size_t)(bh >> 4) * T * H + (bh & 15)) * HEAD;

    // prefetch t0
    {
        const int t0 = dir ? (T - 1) : 0;
        const size_t nb = unit_off + (size_t)t0 * (H * HEAD) + lane;
        (void)nb;
    }
    int t0 = dir ? (T - 1) : 0;
    size_t pb = unit_off + (size_t)t0 * (H * HEAD) + lane;
    float rr = bf2f(r[pb]);
    float kk = bf2f(k[pb]);
    float vn = bf2f(v[pb]);
    float ww = w[pb];

    int p = 0;
    for (int tt = 0; tt < T; ++tt) {
        const int t = dir ? (T - 1 - tt) : tt;
        const size_t obase = unit_off + (size_t)t * (H * HEAD) + lane;
        const float rc = rr, kc = kk, vv = vn, wc = ww;

        // prefetch next step (clamped; last-iter loads are unused)
        int tn = dir ? (T - 2 - tt) : (tt + 1);
        if (tn < 0 || tn >= T) tn = 0;
        const size_t nbase = unit_off + (size_t)tn * (H * HEAD) + lane;
        rr = bf2f(r[nbase]);
        kk = bf2f(k[nbase]);
        vn = bf2f(v[nbase]);
        ww = w[nbase];

        const float dd = __expf(-__expf(wc));
        sbuf[p][0][lane] = rc;
        sbuf[p][1][lane] = kc;
        sbuf[p][2][lane] = dd;
        asm volatile("s_waitcnt lgkmcnt(0)" ::: "memory");

        const float* __restrict__ sr = sbuf[p][0];
        const float* __restrict__ sk = sbuf[p][1];
        const float* __restrict__ sd = sbuf[p][2];
        float y0 = 0.f, y1 = 0.f, y2 = 0.f, y3 = 0.f;
#pragma unroll
        for (int jj = 0; jj < 64; jj += 4) {
            const float4 r4 = *reinterpret_cast<const float4*>(&sr[jj]);
            const float4 k4 = *reinterpret_cast<const float4*>(&sk[jj]);
            const float4 d4 = *reinterpret_cast<const float4*>(&sd[jj]);
            y0 = fmaf(r4.x, S[jj + 0], y0);
            S[jj + 0] = fmaf(d4.x, S[jj + 0], k4.x * vv);
            y1 = fmaf(r4.y, S[jj + 1], y1);
            S[jj + 1] = fmaf(d4.y, S[jj + 1], k4.y * vv);
            y2 = fmaf(r4.z, S[jj + 2], y2);
            S[jj + 2] = fmaf(d4.z, S[jj + 2], k4.z * vv);
            y3 = fmaf(r4.w, S[jj + 3], y3);
            S[jj + 3] = fmaf(d4.w, S[jj + 3], k4.w * vv);
        }
        yo[obase] = (y0 + y1) + (y2 + y3);
        p ^= 1;
    }
}

// ======== bf16 MFMA GEMM: C = epi(A[M,K] @ Bt[N,K]^T), BM=128, BK=32 ========
// 256 threads = 4 waves (2x2); per wave 64 x (BN/2); 16x16x32 bf16 MFMA.
// LDS linear, global source pre-swizzled: slot ^= ((row>>1)&3)  (T2, rule #21)
template <int BN, int EPI>
__global__ __launch_bounds__(256) void bgemm_kernel(const ushort* __restrict__ A,
                                                    const ushort* __restrict__ Bt,
                                                    void* __restrict__ Cm,
                                                    int M, int N, int K,
                                                    const float* __restrict__ aux1,
                                                    const float* __restrict__ aux2)
{
    constexpr int NF = BN / 32;                 // n-frags per wave
    __shared__ __align__(16) ushort As[128 * 32];
    __shared__ __align__(16) ushort Bs[BN * 32];
    const int tid = threadIdx.x;
    const int wid = tid >> 6, lane = tid & 63;
    const int wr = wid >> 1, wc = wid & 1;
    const int bm = blockIdx.y * 128, bn = blockIdx.x * BN;
    const int l15 = lane & 15, lhi = lane >> 4;

    floatx4 acc[4][NF];
#pragma unroll
    for (int m = 0; m < 4; ++m)
#pragma unroll
        for (int n = 0; n < NF; ++n) acc[m][n] = (floatx4){0.f, 0.f, 0.f, 0.f};

    for (int k0 = 0; k0 < K; k0 += 32) {
        // stage A: 128x32 bf16 = 8KB, 2 passes of 256 lanes x 16B
#pragma unroll
        for (int p = 0; p < 2; ++p) {
            const int lin = p * 256 + tid;
            const int row = lin >> 2;
            const int sp = (lin & 3) ^ ((row >> 1) & 3);
            gload16(A + (size_t)(bm + row) * K + k0 + sp * 8, &As[lin * 8]);
        }
        // stage B: BNx32
#pragma unroll
        for (int p = 0; p < BN / 64; ++p) {
            const int lin = p * 256 + tid;
            const int n = lin >> 2;
            const int sp = (lin & 3) ^ ((n >> 1) & 3);
            gload16(Bt + (size_t)(bn + n) * K + k0 + sp * 8, &Bs[lin * 8]);
        }
        __syncthreads();

        short8 af[4], bfr[NF];
#pragma unroll
        for (int m = 0; m < 4; ++m) {
            const int row = wr * 64 + m * 16 + l15;
            const int sp = lhi ^ ((row >> 1) & 3);
            af[m] = *(const short8*)&As[row * 32 + sp * 8];
        }
#pragma unroll
        for (int n = 0; n < NF; ++n) {
            const int col = wc * (BN / 2) + n * 16 + l15;
            const int sp = lhi ^ ((col >> 1) & 3);
            bfr[n] = *(const short8*)&Bs[col * 32 + sp * 8];
        }
#pragma unroll
        for (int m = 0; m < 4; ++m)
#pragma unroll
            for (int n = 0; n < NF; ++n)
                acc[m][n] = __builtin_amdgcn_mfma_f32_16x16x32_bf16(af[m], bfr[n], acc[m][n], 0, 0, 0);
        __syncthreads();
    }

    // epilogue: C/D layout col = lane&15, row = (lane>>4)*4 + j
#pragma unroll
    for (int m = 0; m < 4; ++m) {
        const int row0 = bm + wr * 64 + m * 16 + lhi * 4;
#pragma unroll
        for (int n = 0; n < NF; ++n) {
            const int col = bn + wc * (BN / 2) + n * 16 + l15;
            if (col >= N) continue;
#pragma unroll
            for (int j = 0; j < 4; ++j) {
                const size_t oi = (size_t)(row0 + j) * N + col;
                const float a = acc[m][n][j];
                if constexpr (EPI == BEPI_NONE_BF) {
                    ((ushort*)Cm)[oi] = f2bf(a);
                } else if constexpr (EPI == BEPI_SILU_BF) {
                    ((ushort*)Cm)[oi] = f2bf(a / (1.f + __expf(-a)));
                } else if constexpr (EPI == BEPI_RELUSQ_BF) {
                    const float t = fmaxf(a, 0.f);
                    ((ushort*)Cm)[oi] = f2bf(t * t);
                } else if constexpr (EPI == BEPI_NONE_F) {
                    ((float*)Cm)[oi] = a;
                } else if constexpr (EPI == BEPI_RES_F) {
                    ((float*)Cm)[oi] = aux1[oi] + a;
                } else if constexpr (EPI == BEPI_SIGRES_F) {
                    ((float*)Cm)[oi] = aux1[oi] + aux2[oi] / (1.f + __expf(-a));
                } else if constexpr (EPI == BEPI_TANH_F) {
                    ((float*)Cm)[oi] = tanhf(a);
                } else if constexpr (EPI == BEPI_TANH_BF) {
                    ((ushort*)Cm)[oi] = f2bf(tanhf(a));
                } else {  // BEPI_BIAS_F
                    ((float*)Cm)[oi] = a + aux1[col];
                }
            }
        }
    }
}

// ---------------- launch ----------------
extern "C" void kernel_launch(void* const* d_in, const int* in_sizes, int n_in,
                              void* d_out, int out_size, void* d_ws, size_t ws_size,
                              hipStream_t stream)
{
    const float* x        = (const float*)d_in[0];
    const float* ln1_g    = (const float*)d_in[1];
    const float* ln1_b    = (const float*)d_in[2];
    const float* ln2_g    = (const float*)d_in[3];
    const float* ln2_b    = (const float*)d_in[4];
    const float* maa_x    = (const float*)d_in[5];
    const float* maa_w    = (const float*)d_in[6];
    const float* maa_k    = (const float*)d_in[7];
    const float* maa_v    = (const float*)d_in[8];
    const float* maa_r    = (const float*)d_in[9];
    const float* maa_g    = (const float*)d_in[10];
    const float* maa_w1   = (const float*)d_in[11];
    const float* maa_w2   = (const float*)d_in[12];
    const float* time_dec = (const float*)d_in[13];
    const float* tdw1     = (const float*)d_in[14];
    const float* tdw2     = (const float*)d_in[15];
    const float* u        = (const float*)d_in[16];
    const float* Wr       = (const float*)d_in[17];
    const float* Wk       = (const float*)d_in[18];
    const float* Wv       = (const float*)d_in[19];
    const float* Wg       = (const float*)d_in[20];
    const float* Wo       = (const float*)d_in[21];
    const float* lnx_g    = (const float*)d_in[22];
    const float* lnx_b    = (const float*)d_in[23];
    const float* cmaa_k   = (const float*)d_in[24];
    const float* cmaa_r   = (const float*)d_in[25];
    const float* Wck      = (const float*)d_in[26];
    const float* Wcv      = (const float*)d_in[27];
    const float* Wcr      = (const float*)d_in[28];
    float* out = (float*)d_out;

    // -------- workspace layout (~64 MB) --------
    float* fws = (float*)d_ws;
    const size_t E = (size_t)BT * C;            // 2,097,152
    float* xa  = fws + 0 * E;                   // xa -> yf ; (FFN) kk low half
    float* xx  = fws + 1 * E;                   // xx -> yb -> cxx ; kk high half
    float* fs  = fws + 2 * E;                   // kv (f32)
    float* wd  = fws + 3 * E;                   // w -> xc
    float* a5  = fws + 4 * E;                   // BT*160 f32
    float* sig = a5 + (size_t)BT * 160;         // BT*16 f32
    ushort* wBuf = (ushort*)(sig + (size_t)BT * H);  // C*FF bf16 (weight staging)
    ushort* bf1  = wBuf + (size_t)C * FF;       // E bf16: mixed inputs / ck_in
    ushort* rb   = bf1 + E;                     // r
    ushort* kb   = rb + E;                      // k
    ushort* vb   = kb + E;                      // v  -> ya
    ushort* gb   = vb + E;                      // g  -> cr_in
    ushort* t1b  = gb + E;                      // BT*64 bf16 (tanh(xw@tdw1))
    ushort* kk   = (ushort*)xa;                 // BT*FF bf16 == xa..xx exactly

    const dim3 blk(256);
    const dim3 tblk(32, 8);
    const int EW = (BT * C) / 256;
    const dim3 gNN(C / 64, BT / 128);           // bgemm BN=64, N=C grids

    // ---- attention branch ----
    ln_kernel<<<BT, blk, 0, stream>>>(x, ln1_g, ln1_b, xa);
    bshift_kernel<<<EW, blk, 0, stream>>>(xa, xx);
    mixaxbf_kernel<<<EW, blk, 0, stream>>>(xa, xx, maa_x, bf1);
    wconv_kernel<<<dim3(160 / 32, C / 32), tblk, 0, stream>>>(maa_w1, wBuf, C, 160);
    bgemm_kernel<64, BEPI_TANH_F><<<dim3(3, BT / 128), blk, 0, stream>>>(bf1, wBuf, a5, BT, 160, C, nullptr, nullptr);

    // w path (bf16 MFMA): xw -> tanh(xw@tdw1) -> @tdw2 + time_decay
    mix5bf_kernel<<<BT, blk, 0, stream>>>(xa, xx, a5, maa_w2, maa_w, 0, bf1);
    wconv_kernel<<<dim3(64 / 32, C / 32), tblk, 0, stream>>>(tdw1, wBuf, C, 64);
    bgemm_kernel<64, BEPI_TANH_BF><<<dim3(1, BT / 128), blk, 0, stream>>>(bf1, wBuf, t1b, BT, 64, C, nullptr, nullptr);
    wconv_kernel<<<dim3(C / 32, 64 / 32), tblk, 0, stream>>>(tdw2, wBuf, 64, C);
    bgemm_kernel<64, BEPI_BIAS_F><<<gNN, blk, 0, stream>>>(t1b, wBuf, wd, BT, C, 64, time_dec, nullptr);

    // k
    mix5bf_kernel<<<BT, blk, 0, stream>>>(xa, xx, a5, maa_w2, maa_k, 1, bf1);
    wconv_kernel<<<dim3(C / 32, C / 32), tblk, 0, stream>>>(Wk, wBuf, C, C);
    bgemm_kernel<64, BEPI_NONE_BF><<<gNN, blk, 0, stream>>>(bf1, wBuf, kb, BT, C, C, nullptr, nullptr);
    // v
    mix5bf_kernel<<<BT, blk, 0, stream>>>(xa, xx, a5, maa_w2, maa_v, 2, bf1);
    wconv_kernel<<<dim3(C / 32, C / 32), tblk, 0, stream>>>(Wv, wBuf, C, C);
    bgemm_kernel<64, BEPI_NONE_BF><<<gNN, blk, 0, stream>>>(bf1, wBuf, vb, BT, C, C, nullptr, nullptr);
    // r
    mix5bf_kernel<<<BT, blk, 0, stream>>>(xa, xx, a5, maa_w2, maa_r, 3, bf1);
    wconv_kernel<<<dim3(C / 32, C / 32), tblk, 0, stream>>>(Wr, wBuf, C, C);
    bgemm_kernel<64, BEPI_NONE_BF><<<gNN, blk, 0, stream>>>(bf1, wBuf, rb, BT, C, C, nullptr, nullptr);
    // g
    mix5bf_kernel<<<BT, blk, 0, stream>>>(xa, xx, a5, maa_w2, maa_g, 4, bf1);
    wconv_kernel<<<dim3(C / 32, C / 32), tblk, 0, stream>>>(Wg, wBuf, C, C);
    bgemm_kernel<64, BEPI_SILU_BF><<<gNN, blk, 0, stream>>>(bf1, wBuf, gb, BT, C, C, nullptr, nullptr);

    // u-bonus scalar + bidirectional WKV (barrier-free, 1 wave/unit)
    sigma_kernel<<<BT, blk, 0, stream>>>(rb, kb, u, sig);
    wkv_kernel<<<dim3(2 * B * H), dim3(64), 0, stream>>>(rb, kb, vb, wd, xa, xx);

    // ya = groupnorm(yf+yb+sig*v)*g (bf16); out = x + ya @ Wo^T
    gnmul_kernel<<<BT, dim3(1024), 0, stream>>>(xa, xx, lnx_g, lnx_b, gb, vb, sig, vb);
    wconv_kernel<<<dim3(C / 32, C / 32), tblk, 0, stream>>>(Wo, wBuf, C, C);
    bgemm_kernel<64, BEPI_RES_F><<<gNN, blk, 0, stream>>>(vb, wBuf, out, BT, C, C, x, nullptr);

    // ---- FFN branch ----
    ln_kernel<<<BT, blk, 0, stream>>>(out, ln2_g, ln2_b, wd);
    bshift_kernel<<<EW, blk, 0, stream>>>(wd, xx);
    cmix_kernel<<<EW, blk, 0, stream>>>(wd, xx, cmaa_k, cmaa_r, bf1, gb);
    // kk (BT x FF bf16) lives in xa..xx (dead after cmix)
    wconv_kernel<<<dim3(FF / 32, C / 32), tblk, 0, stream>>>(Wck, wBuf, C, FF);
    bgemm_kernel<128, BEPI_RELUSQ_BF><<<dim3(FF / 128, BT / 128), blk, 0, stream>>>(bf1, wBuf, kk, BT, FF, C, nullptr, nullptr);
    wconv_kernel<<<dim3(C / 32, FF / 32), tblk, 0, stream>>>(Wcv, wBuf, FF, C);
    bgemm_kernel<64, BEPI_NONE_F><<<gNN, blk, 0, stream>>>(kk, wBuf, fs, BT, C, FF, nullptr, nullptr);
    wconv_kernel<<<dim3(C / 32, C / 32), tblk, 0, stream>>>(Wcr, wBuf, C, C);
    bgemm_kernel<64, BEPI_SIGRES_F><<<gNN, blk, 0, stream>>>(gb, wBuf, out, BT, C, C, out, fs);

    (void)in_sizes; (void)n_in; (void)out_size; (void)ws_size;
}

// Round 5
// 549.963 us; speedup vs baseline: 2.6226x; 1.1407x over previous
//
#include <hip/hip_runtime.h>
#include <math.h>
#include <stdint.h>

static constexpr int B  = 8;
static constexpr int T  = 256;
static constexpr int C  = 1024;
static constexpr int H  = 16;
static constexpr int HEAD = 64;
static constexpr int FF = 4096;
static constexpr int BT = B * T;
static constexpr int NCH = 8;       // time chunks
static constexpr int CS  = 32;      // chunk size (NCH*CS == T)

typedef short short8  __attribute__((ext_vector_type(8)));
typedef float floatx4 __attribute__((ext_vector_type(4)));

// ---------------- bf16 helpers ----------------
__device__ __forceinline__ float bf2f(ushort u) {
    return __uint_as_float(((uint32_t)u) << 16);
}
__device__ __forceinline__ ushort f2bf(float x) {
    uint32_t u = __float_as_uint(x);
    u += 0x7fff + ((u >> 16) & 1);          // RNE
    return (ushort)(u >> 16);
}

__device__ __forceinline__ void gload16(const void* g, void* l) {
    __builtin_amdgcn_global_load_lds(
        (const __attribute__((address_space(1))) unsigned int*)g,
        (__attribute__((address_space(3))) unsigned int*)l, 16, 0, 0);
}

// ---------------- epilogue ids ----------------
#define BEPI_NONE_BF   0   // bf16 out
#define BEPI_SILU_BF   1   // bf16 out
#define BEPI_RELUSQ_BF 2   // bf16 out
#define BEPI_NONE_F    3   // f32 out
#define BEPI_RES_F     4   // f32 out = aux1 + acc
#define BEPI_SIGRES_F  5   // f32 out = aux1 + aux2*sigmoid(acc)
#define BEPI_TANH_F    6   // f32 out = tanh(acc)
#define BEPI_TANH_BF   7   // bf16 out = tanh(acc)
#define BEPI_DECAY_F   8   // f32 out = exp(-exp(acc + aux1[col]))

// ---------------- LayerNorm: one block per (b,t) row ----------------
__global__ __launch_bounds__(256) void ln_kernel(const float* __restrict__ x,
                                                 const float* __restrict__ g,
                                                 const float* __restrict__ b,
                                                 float* __restrict__ out)
{
    const int row = blockIdx.x;
    const int tid = threadIdx.x;
    const float4 v = reinterpret_cast<const float4*>(x + (size_t)row * C)[tid];
    float s = v.x + v.y + v.z + v.w;
#pragma unroll
    for (int off = 32; off > 0; off >>= 1) s += __shfl_xor(s, off);
    __shared__ float red[8];
    const int wave = tid >> 6, lane = tid & 63;
    if (lane == 0) red[wave] = s;
    __syncthreads();
    const float mean = (red[0] + red[1] + red[2] + red[3]) * (1.0f / C);
    const float d0 = v.x - mean, d1 = v.y - mean, d2 = v.z - mean, d3 = v.w - mean;
    float q = d0 * d0 + d1 * d1 + d2 * d2 + d3 * d3;
#pragma unroll
    for (int off = 32; off > 0; off >>= 1) q += __shfl_xor(q, off);
    if (lane == 0) red[4 + wave] = q;
    __syncthreads();
    const float var = (red[4] + red[5] + red[6] + red[7]) * (1.0f / C);
    const float rstd = rsqrtf(var + 1e-5f);
    const int c = tid * 4;
    float4 o;
    o.x = d0 * rstd * g[c + 0] + b[c + 0];
    o.y = d1 * rstd * g[c + 1] + b[c + 1];
    o.z = d2 * rstd * g[c + 2] + b[c + 2];
    o.w = d3 * rstd * g[c + 3] + b[c + 3];
    reinterpret_cast<float4*>(out + (size_t)row * C)[tid] = o;
}

// ---------------- bidirectional shift:  xx = bshift(xa) - xa ----------------
__global__ __launch_bounds__(256) void bshift_kernel(const float* __restrict__ xa,
                                                     float* __restrict__ xx)
{
    const int i = blockIdx.x * 256 + threadIdx.x;       // [0, BT*C)
    const int c = i & (C - 1);
    const int bt = i >> 10;
    const int t = bt & (T - 1);
    const int j = c & (HEAD - 1);
    float src = 0.f;
    if (j < HEAD / 2) { if (t > 0)     src = xa[i - C]; }
    else              { if (t < T - 1) src = xa[i + C]; }
    xx[i] = src - xa[i];
}

// ---------------- ax = xa + xx * maa_x  (bf16 out) ----------------
__global__ __launch_bounds__(256) void mixaxbf_kernel(const float* __restrict__ xa,
                                                      const float* __restrict__ xx,
                                                      const float* __restrict__ maa,
                                                      ushort* __restrict__ out)
{
    const int i = blockIdx.x * 256 + threadIdx.x;
    const int c = i & (C - 1);
    out[i] = f2bf(xa[i] + xx[i] * maa[c]);
}

// -------- mix5 bf16 out: out = xa + xx * (maa_f + a5[bt,f,:] @ w2[f,:,:]) ----
__global__ __launch_bounds__(256) void mix5bf_kernel(const float* __restrict__ xa,
                                                     const float* __restrict__ xx,
                                                     const float* __restrict__ a5,
                                                     const float* __restrict__ w2,
                                                     const float* __restrict__ maa,
                                                     int f, ushort* __restrict__ out)
{
    const int bt = blockIdx.x;
    const int tid = threadIdx.x;
    __shared__ float al[32];
    if (tid < 32) al[tid] = a5[(size_t)bt * 160 + f * 32 + tid];
    __syncthreads();
    const float* __restrict__ w2f = w2 + (size_t)f * 32 * C;
    const size_t rb = (size_t)bt * C;
#pragma unroll
    for (int m = 0; m < 4; ++m) {
        const int c = tid + 256 * m;
        float acc = 0.f;
#pragma unroll 8
        for (int d = 0; d < 32; ++d) acc = fmaf(al[d], w2f[d * C + c], acc);
        out[rb + c] = f2bf(xa[rb + c] + xx[rb + c] * (maa[c] + acc));
    }
}

// -------- cmix: two mixed bf16 inputs for the FFN --------
__global__ __launch_bounds__(256) void cmix_kernel(const float* __restrict__ xc,
                                                   const float* __restrict__ cxx,
                                                   const float* __restrict__ mk,
                                                   const float* __restrict__ mr,
                                                   ushort* __restrict__ ok,
                                                   ushort* __restrict__ orr)
{
    const int i = blockIdx.x * 256 + threadIdx.x;
    const int c = i & (C - 1);
    const float a = xc[i], d = cxx[i];
    ok[i]  = f2bf(a + d * mk[c]);
    orr[i] = f2bf(a + d * mr[c]);
}

// -------- sigma: sig[bt,h] = sum_j r*u*k  (the u-bonus scalar) --------
__global__ __launch_bounds__(256) void sigma_kernel(const ushort* __restrict__ r,
                                                    const ushort* __restrict__ k,
                                                    const float* __restrict__ u,
                                                    float* __restrict__ sig)
{
    const int bt = blockIdx.x;
    const int tid = threadIdx.x;
    const int c0 = tid * 4;
    const size_t base = (size_t)bt * C + c0;
    const uint2 rv = *reinterpret_cast<const uint2*>(r + base);
    const uint2 kv = *reinterpret_cast<const uint2*>(k + base);
    float p = 0.f;
    p += bf2f((ushort)(rv.x & 0xffff)) * bf2f((ushort)(kv.x & 0xffff)) * u[c0 + 0];
    p += bf2f((ushort)(rv.x >> 16))    * bf2f((ushort)(kv.x >> 16))    * u[c0 + 1];
    p += bf2f((ushort)(rv.y & 0xffff)) * bf2f((ushort)(kv.y & 0xffff)) * u[c0 + 2];
    p += bf2f((ushort)(rv.y >> 16))    * bf2f((ushort)(kv.y >> 16))    * u[c0 + 3];
    p += __shfl_xor(p, 1);
    p += __shfl_xor(p, 2);
    p += __shfl_xor(p, 4);
    p += __shfl_xor(p, 8);
    if ((tid & 15) == 0) sig[(size_t)bt * H + (tid >> 4)] = p;
}

// -------- GroupNorm(yf+yb+sig*v)*lnx_g+lnx_b, * gate(bf16) -> ya(bf16) -------
__global__ __launch_bounds__(1024) void gnmul_kernel(const float* __restrict__ yf,
                                                     const float* __restrict__ yb,
                                                     const float* __restrict__ g,
                                                     const float* __restrict__ b,
                                                     const ushort* __restrict__ gate,
                                                     const ushort* __restrict__ vin,
                                                     const float* __restrict__ sig,
                                                     ushort* __restrict__ out)
{
    const int row = blockIdx.x;
    const int tid = threadIdx.x;                 // 1024 threads; wave == head
    const size_t idx = (size_t)row * C + tid;
    const float sg = sig[(size_t)row * H + (tid >> 6)];
    const float v = yf[idx] + yb[idx] + sg * bf2f(vin[idx]);
    float s = v;
#pragma unroll
    for (int off = 32; off > 0; off >>= 1) s += __shfl_xor(s, off);
    const float m = s * (1.0f / HEAD);
    const float d = v - m;
    float q = d * d;
#pragma unroll
    for (int off = 32; off > 0; off >>= 1) q += __shfl_xor(q, off);
    const float rstd = rsqrtf(q * (1.0f / HEAD) + 6.4e-4f);   // 1e-5 * 8^2
    out[idx] = f2bf((d * rstd * g[tid] + b[tid]) * bf2f(gate[idx]));
}

// -------- weight convert+transpose: W[Kd,Nd] f32 -> Wt[Nd,Kd] bf16 --------
__global__ __launch_bounds__(256) void wconv_kernel(const float* __restrict__ W,
                                                    ushort* __restrict__ Wt,
                                                    int Kd, int Nd)
{
    __shared__ float tile[32][33];
    const int n0 = blockIdx.x * 32, k0 = blockIdx.y * 32;
    const int tx = threadIdx.x, ty = threadIdx.y;   // 32 x 8
#pragma unroll
    for (int i = 0; i < 4; ++i)
        tile[ty * 4 + i][tx] = W[(size_t)(k0 + ty * 4 + i) * Nd + n0 + tx];
    __syncthreads();
#pragma unroll
    for (int i = 0; i < 4; ++i)
        Wt[(size_t)(n0 + ty * 4 + i) * Kd + k0 + tx] = f2bf(tile[tx][ty * 4 + i]);
}

// ================== chunked bidirectional WKV6 ==================
// unit u in [0,256): dir=u&1, bh=u>>1. uc = u*NCH + c. lane = state column i.
// pass1: local scan from 0 -> M_c (bf16), D_c (f32, per-j decay product)
__global__ __launch_bounds__(64) void wkv_pass1(const ushort* __restrict__ k,
                                                const ushort* __restrict__ v,
                                                const float* __restrict__ d,
                                                ushort* __restrict__ M,
                                                float* __restrict__ D)
{
    const int uc = blockIdx.x;
    const int c = uc & (NCH - 1), unit = uc >> 3;
    const int dir = unit & 1, bh = unit >> 1;
    const int lane = threadIdx.x;
    const size_t hb = ((size_t)(bh >> 4) * T * H + (bh & 15)) * HEAD + lane;
    __shared__ __align__(16) float sbuf[2][2][64];

    float S[64];
#pragma unroll
    for (int j = 0; j < 64; ++j) S[j] = 0.f;
    float PD = 1.f;

    // prefetch ss=0
    int s0 = c * CS;
    int t0 = dir ? (T - 1 - s0) : s0;
    size_t pb = hb + (size_t)t0 * (H * HEAD);
    float kk = bf2f(k[pb]);
    float vn = bf2f(v[pb]);
    float dd = d[pb];

    int p = 0;
    for (int ss = 0; ss < CS; ++ss) {
        const float kc = kk, vv = vn, dc = dd;
        const int sn = (ss + 1 < CS) ? (ss + 1) : 0;     // clamped (last unused)
        const int s = c * CS + sn;
        const int tn = dir ? (T - 1 - s) : s;
        const size_t nb = hb + (size_t)tn * (H * HEAD);
        kk = bf2f(k[nb]);
        vn = bf2f(v[nb]);
        dd = d[nb];

        PD *= dc;
        sbuf[p][0][lane] = kc;
        sbuf[p][1][lane] = dc;
        asm volatile("s_waitcnt lgkmcnt(0)" ::: "memory");
        const float* __restrict__ sk = sbuf[p][0];
        const float* __restrict__ sd = sbuf[p][1];
#pragma unroll
        for (int jj = 0; jj < 64; jj += 4) {
            const float4 k4 = *reinterpret_cast<const float4*>(&sk[jj]);
            const float4 d4 = *reinterpret_cast<const float4*>(&sd[jj]);
            S[jj + 0] = fmaf(d4.x, S[jj + 0], k4.x * vv);
            S[jj + 1] = fmaf(d4.y, S[jj + 1], k4.y * vv);
            S[jj + 2] = fmaf(d4.z, S[jj + 2], k4.z * vv);
            S[jj + 3] = fmaf(d4.w, S[jj + 3], k4.w * vv);
        }
        p ^= 1;
    }
    const size_t mb = (size_t)uc * 4096 + lane;
#pragma unroll
    for (int j = 0; j < 64; ++j) M[mb + j * 64] = f2bf(S[j]);
    D[(size_t)uc * 64 + lane] = PD;
}

// pass2: per unit, serial over chunks: write S_in(c) over M_c, S = D_c*S + M_c
__global__ __launch_bounds__(64) void wkv_pass2(ushort* __restrict__ M,
                                                const float* __restrict__ D)
{
    const int unit = blockIdx.x;
    const int lane = threadIdx.x;
    __shared__ float Dl[64];
    float S[64];
#pragma unroll
    for (int j = 0; j < 64; ++j) S[j] = 0.f;

    for (int c = 0; c < NCH; ++c) {
        const int uc = unit * NCH + c;
        __syncthreads();
        Dl[lane] = D[(size_t)uc * 64 + lane];
        __syncthreads();
        const size_t mb = (size_t)uc * 4096 + lane;
#pragma unroll
        for (int j = 0; j < 64; ++j) {
            const float m = bf2f(M[mb + j * 64]);
            M[mb + j * 64] = f2bf(S[j]);
            S[j] = fmaf(Dl[j], S[j], m);
        }
    }
}

// pass3: local scan from S_in(c), emit y
__global__ __launch_bounds__(64) void wkv_pass3(const ushort* __restrict__ r,
                                                const ushort* __restrict__ k,
                                                const ushort* __restrict__ v,
                                                const float* __restrict__ d,
                                                const ushort* __restrict__ Sin,
                                                float* __restrict__ yf,
                                                float* __restrict__ yb)
{
    const int uc = blockIdx.x;
    const int c = uc & (NCH - 1), unit = uc >> 3;
    const int dir = unit & 1, bh = unit >> 1;
    const int lane = threadIdx.x;
    const size_t hb = ((size_t)(bh >> 4) * T * H + (bh & 15)) * HEAD + lane;
    __shared__ __align__(16) float sbuf[2][3][64];

    float S[64];
    const size_t mb = (size_t)uc * 4096 + lane;
#pragma unroll
    for (int j = 0; j < 64; ++j) S[j] = bf2f(Sin[mb + j * 64]);
    float* __restrict__ yo = dir ? yb : yf;

    int s0 = c * CS;
    int t0 = dir ? (T - 1 - s0) : s0;
    size_t pb = hb + (size_t)t0 * (H * HEAD);
    float rr = bf2f(r[pb]);
    float kk = bf2f(k[pb]);
    float vn = bf2f(v[pb]);
    float dd = d[pb];

    int p = 0;
    for (int ss = 0; ss < CS; ++ss) {
        const int s = c * CS + ss;
        const int t = dir ? (T - 1 - s) : s;
        const size_t ob = hb + (size_t)t * (H * HEAD);
        const float rc = rr, kc = kk, vv = vn, dc = dd;

        const int sn2 = (ss + 1 < CS) ? (ss + 1) : 0;
        const int s2 = c * CS + sn2;
        const int tn = dir ? (T - 1 - s2) : s2;
        const size_t nb = hb + (size_t)tn * (H * HEAD);
        rr = bf2f(r[nb]);
        kk = bf2f(k[nb]);
        vn = bf2f(v[nb]);
        dd = d[nb];

        sbuf[p][0][lane] = rc;
        sbuf[p][1][lane] = kc;
        sbuf[p][2][lane] = dc;
        asm volatile("s_waitcnt lgkmcnt(0)" ::: "memory");
        const float* __restrict__ sr = sbuf[p][0];
        const float* __restrict__ sk = sbuf[p][1];
        const float* __restrict__ sd = sbuf[p][2];
        float y0 = 0.f, y1 = 0.f, y2 = 0.f, y3 = 0.f;
#pragma unroll
        for (int jj = 0; jj < 64; jj += 4) {
            const float4 r4 = *reinterpret_cast<const float4*>(&sr[jj]);
            const float4 k4 = *reinterpret_cast<const float4*>(&sk[jj]);
            const float4 d4 = *reinterpret_cast<const float4*>(&sd[jj]);
            y0 = fmaf(r4.x, S[jj + 0], y0);
            S[jj + 0] = fmaf(d4.x, S[jj + 0], k4.x * vv);
            y1 = fmaf(r4.y, S[jj + 1], y1);
            S[jj + 1] = fmaf(d4.y, S[jj + 1], k4.y * vv);
            y2 = fmaf(r4.z, S[jj + 2], y2);
            S[jj + 2] = fmaf(d4.z, S[jj + 2], k4.z * vv);
            y3 = fmaf(r4.w, S[jj + 3], y3);
            S[jj + 3] = fmaf(d4.w, S[jj + 3], k4.w * vv);
        }
        yo[ob] = (y0 + y1) + (y2 + y3);
        p ^= 1;
    }
}

// ======== bf16 MFMA GEMM: C = epi(A[M,K] @ Bt[N,K]^T), BM=128, BK=32 ========
// 256 threads = 4 waves (2x2); per wave 64 x (BN/2); 16x16x32 bf16 MFMA.
// LDS linear, global source pre-swizzled: slot ^= ((row>>1)&3)  (T2, rule #21)
template <int BN, int EPI>
__global__ __launch_bounds__(256) void bgemm_kernel(const ushort* __restrict__ A,
                                                    const ushort* __restrict__ Bt,
                                                    void* __restrict__ Cm,
                                                    int M, int N, int K,
                                                    const float* __restrict__ aux1,
                                                    const float* __restrict__ aux2)
{
    constexpr int NF = BN / 32;                 // n-frags per wave
    __shared__ __align__(16) ushort As[128 * 32];
    __shared__ __align__(16) ushort Bs[BN * 32];
    const int tid = threadIdx.x;
    const int wid = tid >> 6, lane = tid & 63;
    const int wr = wid >> 1, wc = wid & 1;
    const int bm = blockIdx.y * 128, bn = blockIdx.x * BN;
    const int l15 = lane & 15, lhi = lane >> 4;

    floatx4 acc[4][NF];
#pragma unroll
    for (int m = 0; m < 4; ++m)
#pragma unroll
        for (int n = 0; n < NF; ++n) acc[m][n] = (floatx4){0.f, 0.f, 0.f, 0.f};

    for (int k0 = 0; k0 < K; k0 += 32) {
        // stage A: 128x32 bf16 = 8KB, 2 passes of 256 lanes x 16B
#pragma unroll
        for (int p = 0; p < 2; ++p) {
            const int lin = p * 256 + tid;
            const int row = lin >> 2;
            const int sp = (lin & 3) ^ ((row >> 1) & 3);
            gload16(A + (size_t)(bm + row) * K + k0 + sp * 8, &As[lin * 8]);
        }
        // stage B: BNx32
#pragma unroll
        for (int p = 0; p < BN / 64; ++p) {
            const int lin = p * 256 + tid;
            const int n = lin >> 2;
            const int sp = (lin & 3) ^ ((n >> 1) & 3);
            gload16(Bt + (size_t)(bn + n) * K + k0 + sp * 8, &Bs[lin * 8]);
        }
        __syncthreads();

        short8 af[4], bfr[NF];
#pragma unroll
        for (int m = 0; m < 4; ++m) {
            const int row = wr * 64 + m * 16 + l15;
            const int sp = lhi ^ ((row >> 1) & 3);
            af[m] = *(const short8*)&As[row * 32 + sp * 8];
        }
#pragma unroll
        for (int n = 0; n < NF; ++n) {
            const int col = wc * (BN / 2) + n * 16 + l15;
            const int sp = lhi ^ ((col >> 1) & 3);
            bfr[n] = *(const short8*)&Bs[col * 32 + sp * 8];
        }
#pragma unroll
        for (int m = 0; m < 4; ++m)
#pragma unroll
            for (int n = 0; n < NF; ++n)
                acc[m][n] = __builtin_amdgcn_mfma_f32_16x16x32_bf16(af[m], bfr[n], acc[m][n], 0, 0, 0);
        __syncthreads();
    }

    // epilogue: C/D layout col = lane&15, row = (lane>>4)*4 + j
#pragma unroll
    for (int m = 0; m < 4; ++m) {
        const int row0 = bm + wr * 64 + m * 16 + lhi * 4;
#pragma unroll
        for (int n = 0; n < NF; ++n) {
            const int col = bn + wc * (BN / 2) + n * 16 + l15;
            if (col >= N) continue;
#pragma unroll
            for (int j = 0; j < 4; ++j) {
                const size_t oi = (size_t)(row0 + j) * N + col;
                const float a = acc[m][n][j];
                if constexpr (EPI == BEPI_NONE_BF) {
                    ((ushort*)Cm)[oi] = f2bf(a);
                } else if constexpr (EPI == BEPI_SILU_BF) {
                    ((ushort*)Cm)[oi] = f2bf(a / (1.f + __expf(-a)));
                } else if constexpr (EPI == BEPI_RELUSQ_BF) {
                    const float t = fmaxf(a, 0.f);
                    ((ushort*)Cm)[oi] = f2bf(t * t);
                } else if constexpr (EPI == BEPI_NONE_F) {
                    ((float*)Cm)[oi] = a;
                } else if constexpr (EPI == BEPI_RES_F) {
                    ((float*)Cm)[oi] = aux1[oi] + a;
                } else if constexpr (EPI == BEPI_SIGRES_F) {
                    ((float*)Cm)[oi] = aux1[oi] + aux2[oi] / (1.f + __expf(-a));
                } else if constexpr (EPI == BEPI_TANH_F) {
                    ((float*)Cm)[oi] = tanhf(a);
                } else if constexpr (EPI == BEPI_TANH_BF) {
                    ((ushort*)Cm)[oi] = f2bf(tanhf(a));
                } else {  // BEPI_DECAY_F
                    ((float*)Cm)[oi] = __expf(-__expf(a + aux1[col]));
                }
            }
        }
    }
}

// ---------------- launch ----------------
extern "C" void kernel_launch(void* const* d_in, const int* in_sizes, int n_in,
                              void* d_out, int out_size, void* d_ws, size_t ws_size,
                              hipStream_t stream)
{
    const float* x        = (const float*)d_in[0];
    const float* ln1_g    = (const float*)d_in[1];
    const float* ln1_b    = (const float*)d_in[2];
    const float* ln2_g    = (const float*)d_in[3];
    const float* ln2_b    = (const float*)d_in[4];
    const float* maa_x    = (const float*)d_in[5];
    const float* maa_w    = (const float*)d_in[6];
    const float* maa_k    = (const float*)d_in[7];
    const float* maa_v    = (const float*)d_in[8];
    const float* maa_r    = (const float*)d_in[9];
    const float* maa_g    = (const float*)d_in[10];
    const float* maa_w1   = (const float*)d_in[11];
    const float* maa_w2   = (const float*)d_in[12];
    const float* time_dec = (const float*)d_in[13];
    const float* tdw1     = (const float*)d_in[14];
    const float* tdw2     = (const float*)d_in[15];
    const float* u        = (const float*)d_in[16];
    const float* Wr       = (const float*)d_in[17];
    const float* Wk       = (const float*)d_in[18];
    const float* Wv       = (const float*)d_in[19];
    const float* Wg       = (const float*)d_in[20];
    const float* Wo       = (const float*)d_in[21];
    const float* lnx_g    = (const float*)d_in[22];
    const float* lnx_b    = (const float*)d_in[23];
    const float* cmaa_k   = (const float*)d_in[24];
    const float* cmaa_r   = (const float*)d_in[25];
    const float* Wck      = (const float*)d_in[26];
    const float* Wcv      = (const float*)d_in[27];
    const float* Wcr      = (const float*)d_in[28];
    float* out = (float*)d_out;

    // -------- workspace layout (~63 MB) --------
    float* fws = (float*)d_ws;
    const size_t E = (size_t)BT * C;            // 2,097,152
    float* xa  = fws + 0 * E;                   // xa -> yf ; (FFN) kk low half
    float* xx  = fws + 1 * E;                   // xx -> yb -> cxx ; kk high half
    float* wd  = fws + 2 * E;                   // decay d -> xc
    float* fs  = fws + 3 * E;                   // kv (FFN only); M low half (wkv)
    ushort* wBuf = (ushort*)(fws + 4 * E);      // C*FF bf16 weights; M high half
    ushort* Mbuf = (ushort*)fs;                 // 2048*4096 bf16 = fs..wBuf (16MB)
    ushort* bf1  = wBuf + (size_t)C * FF;       // E bf16: mixed inputs / ck_in
    ushort* rb   = bf1 + E;                     // r
    ushort* kb   = rb + E;                      // k
    ushort* vb   = kb + E;                      // v  -> ya
    ushort* gb   = vb + E;                      // g  -> cr_in
    ushort* t1b  = gb + E;                      // BT*64 bf16 (tanh(xw@tdw1))
    float* a5    = (float*)(t1b + (size_t)BT * 64);   // BT*160 f32
    float* sig   = a5 + (size_t)BT * 160;       // BT*16 f32
    float* Dbuf  = sig + (size_t)BT * H;        // 2048*64 f32
    ushort* kk   = (ushort*)xa;                 // BT*FF bf16 == xa..xx exactly

    const dim3 blk(256);
    const dim3 tblk(32, 8);
    const int EW = (BT * C) / 256;
    const dim3 gNN(C / 64, BT / 128);           // bgemm BN=64, N=C grids

    // ---- attention branch ----
    ln_kernel<<<BT, blk, 0, stream>>>(x, ln1_g, ln1_b, xa);
    bshift_kernel<<<EW, blk, 0, stream>>>(xa, xx);
    mixaxbf_kernel<<<EW, blk, 0, stream>>>(xa, xx, maa_x, bf1);
    wconv_kernel<<<dim3(160 / 32, C / 32), tblk, 0, stream>>>(maa_w1, wBuf, C, 160);
    bgemm_kernel<64, BEPI_TANH_F><<<dim3(3, BT / 128), blk, 0, stream>>>(bf1, wBuf, a5, BT, 160, C, nullptr, nullptr);

    // w path (bf16 MFMA): xw -> tanh(xw@tdw1) -> decay d = exp(-exp(@tdw2 + td))
    mix5bf_kernel<<<BT, blk, 0, stream>>>(xa, xx, a5, maa_w2, maa_w, 0, bf1);
    wconv_kernel<<<dim3(64 / 32, C / 32), tblk, 0, stream>>>(tdw1, wBuf, C, 64);
    bgemm_kernel<64, BEPI_TANH_BF><<<dim3(1, BT / 128), blk, 0, stream>>>(bf1, wBuf, t1b, BT, 64, C, nullptr, nullptr);
    wconv_kernel<<<dim3(C / 32, 64 / 32), tblk, 0, stream>>>(tdw2, wBuf, 64, C);
    bgemm_kernel<64, BEPI_DECAY_F><<<gNN, blk, 0, stream>>>(t1b, wBuf, wd, BT, C, 64, time_dec, nullptr);

    // k
    mix5bf_kernel<<<BT, blk, 0, stream>>>(xa, xx, a5, maa_w2, maa_k, 1, bf1);
    wconv_kernel<<<dim3(C / 32, C / 32), tblk, 0, stream>>>(Wk, wBuf, C, C);
    bgemm_kernel<64, BEPI_NONE_BF><<<gNN, blk, 0, stream>>>(bf1, wBuf, kb, BT, C, C, nullptr, nullptr);
    // v
    mix5bf_kernel<<<BT, blk, 0, stream>>>(xa, xx, a5, maa_w2, maa_v, 2, bf1);
    wconv_kernel<<<dim3(C / 32, C / 32), tblk, 0, stream>>>(Wv, wBuf, C, C);
    bgemm_kernel<64, BEPI_NONE_BF><<<gNN, blk, 0, stream>>>(bf1, wBuf, vb, BT, C, C, nullptr, nullptr);
    // r
    mix5bf_kernel<<<BT, blk, 0, stream>>>(xa, xx, a5, maa_w2, maa_r, 3, bf1);
    wconv_kernel<<<dim3(C / 32, C / 32), tblk, 0, stream>>>(Wr, wBuf, C, C);
    bgemm_kernel<64, BEPI_NONE_BF><<<gNN, blk, 0, stream>>>(bf1, wBuf, rb, BT, C, C, nullptr, nullptr);
    // g
    mix5bf_kernel<<<BT, blk, 0, stream>>>(xa, xx, a5, maa_w2, maa_g, 4, bf1);
    wconv_kernel<<<dim3(C / 32, C / 32), tblk, 0, stream>>>(Wg, wBuf, C, C);
    bgemm_kernel<64, BEPI_SILU_BF><<<gNN, blk, 0, stream>>>(bf1, wBuf, gb, BT, C, C, nullptr, nullptr);

    // u-bonus scalar + chunked bidirectional WKV (Mbuf overlays fs+wBuf)
    sigma_kernel<<<BT, blk, 0, stream>>>(rb, kb, u, sig);
    wkv_pass1<<<dim3(2 * B * H * NCH), dim3(64), 0, stream>>>(kb, vb, wd, Mbuf, Dbuf);
    wkv_pass2<<<dim3(2 * B * H), dim3(64), 0, stream>>>(Mbuf, Dbuf);
    wkv_pass3<<<dim3(2 * B * H * NCH), dim3(64), 0, stream>>>(rb, kb, vb, wd, Mbuf, xa, xx);

    // ya = groupnorm(yf+yb+sig*v)*g (bf16); out = x + ya @ Wo^T
    gnmul_kernel<<<BT, dim3(1024), 0, stream>>>(xa, xx, lnx_g, lnx_b, gb, vb, sig, vb);
    wconv_kernel<<<dim3(C / 32, C / 32), tblk, 0, stream>>>(Wo, wBuf, C, C);
    bgemm_kernel<64, BEPI_RES_F><<<gNN, blk, 0, stream>>>(vb, wBuf, out, BT, C, C, x, nullptr);

    // ---- FFN branch ----
    ln_kernel<<<BT, blk, 0, stream>>>(out, ln2_g, ln2_b, wd);
    bshift_kernel<<<EW, blk, 0, stream>>>(wd, xx);
    cmix_kernel<<<EW, blk, 0, stream>>>(wd, xx, cmaa_k, cmaa_r, bf1, gb);
    // kk (BT x FF bf16) lives in xa..xx (dead after cmix)
    wconv_kernel<<<dim3(FF / 32, C / 32), tblk, 0, stream>>>(Wck, wBuf, C, FF);
    bgemm_kernel<128, BEPI_RELUSQ_BF><<<dim3(FF / 128, BT / 128), blk, 0, stream>>>(bf1, wBuf, kk, BT, FF, C, nullptr, nullptr);
    wconv_kernel<<<dim3(C / 32, FF / 32), tblk, 0, stream>>>(Wcv, wBuf, FF, C);
    bgemm_kernel<64, BEPI_NONE_F><<<gNN, blk, 0, stream>>>(kk, wBuf, fs, BT, C, FF, nullptr, nullptr);
    wconv_kernel<<<dim3(C / 32, C / 32), tblk, 0, stream>>>(Wcr, wBuf, C, C);
    bgemm_kernel<64, BEPI_SIGRES_F><<<gNN, blk, 0, stream>>>(gb, wBuf, out, BT, C, C, out, fs);

    (void)in_sizes; (void)n_in; (void)out_size; (void)ws_size;
}

// Round 6
// 435.889 us; speedup vs baseline: 3.3089x; 1.2617x over previous
//
#include <hip/hip_runtime.h>
#include <math.h>
#include <stdint.h>

static constexpr int B  = 8;
static constexpr int T  = 256;
static constexpr int C  = 1024;
static constexpr int H  = 16;
static constexpr int HEAD = 64;
static constexpr int FF = 4096;
static constexpr int BT = B * T;
static constexpr int NCH = 8;       // time chunks
static constexpr int CS  = 32;      // chunk size (NCH*CS == T)

typedef short short8  __attribute__((ext_vector_type(8)));
typedef float floatx4 __attribute__((ext_vector_type(4)));

// ---------------- bf16 helpers ----------------
__device__ __forceinline__ float bf2f(ushort u) {
    return __uint_as_float(((uint32_t)u) << 16);
}
__device__ __forceinline__ ushort f2bf(float x) {
    uint32_t u = __float_as_uint(x);
    u += 0x7fff + ((u >> 16) & 1);          // RNE
    return (ushort)(u >> 16);
}

__device__ __forceinline__ void gload16(const void* g, void* l) {
    __builtin_amdgcn_global_load_lds(
        (const __attribute__((address_space(1))) unsigned int*)g,
        (__attribute__((address_space(3))) unsigned int*)l, 16, 0, 0);
}

// ---------------- epilogue ids ----------------
#define BEPI_NONE_BF   0
#define BEPI_SILU_BF   1
#define BEPI_RELUSQ_BF 2
#define BEPI_NONE_F    3
#define BEPI_RES_F     4
#define BEPI_SIGRES_F  5
#define BEPI_TANH_F    6
#define BEPI_TANH_BF   7
#define BEPI_DECAY_F   8

// ---------------- LayerNorm ----------------
__global__ __launch_bounds__(256) void ln_kernel(const float* __restrict__ x,
                                                 const float* __restrict__ g,
                                                 const float* __restrict__ b,
                                                 float* __restrict__ out)
{
    const int row = blockIdx.x;
    const int tid = threadIdx.x;
    const float4 v = reinterpret_cast<const float4*>(x + (size_t)row * C)[tid];
    float s = v.x + v.y + v.z + v.w;
#pragma unroll
    for (int off = 32; off > 0; off >>= 1) s += __shfl_xor(s, off);
    __shared__ float red[8];
    const int wave = tid >> 6, lane = tid & 63;
    if (lane == 0) red[wave] = s;
    __syncthreads();
    const float mean = (red[0] + red[1] + red[2] + red[3]) * (1.0f / C);
    const float d0 = v.x - mean, d1 = v.y - mean, d2 = v.z - mean, d3 = v.w - mean;
    float q = d0 * d0 + d1 * d1 + d2 * d2 + d3 * d3;
#pragma unroll
    for (int off = 32; off > 0; off >>= 1) q += __shfl_xor(q, off);
    if (lane == 0) red[4 + wave] = q;
    __syncthreads();
    const float var = (red[4] + red[5] + red[6] + red[7]) * (1.0f / C);
    const float rstd = rsqrtf(var + 1e-5f);
    const int c = tid * 4;
    float4 o;
    o.x = d0 * rstd * g[c + 0] + b[c + 0];
    o.y = d1 * rstd * g[c + 1] + b[c + 1];
    o.z = d2 * rstd * g[c + 2] + b[c + 2];
    o.w = d3 * rstd * g[c + 3] + b[c + 3];
    reinterpret_cast<float4*>(out + (size_t)row * C)[tid] = o;
}

// ---------------- bshift:  xx = bshift(xa) - xa ----------------
__global__ __launch_bounds__(256) void bshift_kernel(const float* __restrict__ xa,
                                                     float* __restrict__ xx)
{
    const int i = blockIdx.x * 256 + threadIdx.x;
    const int c = i & (C - 1);
    const int bt = i >> 10;
    const int t = bt & (T - 1);
    const int j = c & (HEAD - 1);
    float src = 0.f;
    if (j < HEAD / 2) { if (t > 0)     src = xa[i - C]; }
    else              { if (t < T - 1) src = xa[i + C]; }
    xx[i] = src - xa[i];
}

// ---------------- ax = xa + xx * maa_x  (bf16 out) ----------------
__global__ __launch_bounds__(256) void mixaxbf_kernel(const float* __restrict__ xa,
                                                      const float* __restrict__ xx,
                                                      const float* __restrict__ maa,
                                                      ushort* __restrict__ out)
{
    const int i = blockIdx.x * 256 + threadIdx.x;
    const int c = i & (C - 1);
    out[i] = f2bf(xa[i] + xx[i] * maa[c]);
}

// -------- batched mix5: 5 mixes in one launch (blockIdx.y = f) --------
struct Mix5Args { const float* maa[5]; ushort* out[5]; };
__global__ __launch_bounds__(256) void mix5b_kernel(const float* __restrict__ xa,
                                                    const float* __restrict__ xx,
                                                    const float* __restrict__ a5,
                                                    const float* __restrict__ w2,
                                                    Mix5Args args)
{
    const int bt = blockIdx.x;
    const int f  = blockIdx.y;
    const int tid = threadIdx.x;
    __shared__ float al[32];
    if (tid < 32) al[tid] = a5[(size_t)bt * 160 + f * 32 + tid];
    __syncthreads();
    const float* __restrict__ w2f = w2 + (size_t)f * 32 * C;
    const float* __restrict__ maa = args.maa[f];
    ushort* __restrict__ out = args.out[f];
    const size_t rb = (size_t)bt * C;
#pragma unroll
    for (int m = 0; m < 4; ++m) {
        const int c = tid + 256 * m;
        float acc = 0.f;
#pragma unroll 8
        for (int d = 0; d < 32; ++d) acc = fmaf(al[d], w2f[d * C + c], acc);
        out[rb + c] = f2bf(xa[rb + c] + xx[rb + c] * (maa[c] + acc));
    }
}

// -------- cmix --------
__global__ __launch_bounds__(256) void cmix_kernel(const float* __restrict__ xc,
                                                   const float* __restrict__ cxx,
                                                   const float* __restrict__ mk,
                                                   const float* __restrict__ mr,
                                                   ushort* __restrict__ ok,
                                                   ushort* __restrict__ orr)
{
    const int i = blockIdx.x * 256 + threadIdx.x;
    const int c = i & (C - 1);
    const float a = xc[i], d = cxx[i];
    ok[i]  = f2bf(a + d * mk[c]);
    orr[i] = f2bf(a + d * mr[c]);
}

// -------- sigma --------
__global__ __launch_bounds__(256) void sigma_kernel(const ushort* __restrict__ r,
                                                    const ushort* __restrict__ k,
                                                    const float* __restrict__ u,
                                                    float* __restrict__ sig)
{
    const int bt = blockIdx.x;
    const int tid = threadIdx.x;
    const int c0 = tid * 4;
    const size_t base = (size_t)bt * C + c0;
    const uint2 rv = *reinterpret_cast<const uint2*>(r + base);
    const uint2 kv = *reinterpret_cast<const uint2*>(k + base);
    float p = 0.f;
    p += bf2f((ushort)(rv.x & 0xffff)) * bf2f((ushort)(kv.x & 0xffff)) * u[c0 + 0];
    p += bf2f((ushort)(rv.x >> 16))    * bf2f((ushort)(kv.x >> 16))    * u[c0 + 1];
    p += bf2f((ushort)(rv.y & 0xffff)) * bf2f((ushort)(kv.y & 0xffff)) * u[c0 + 2];
    p += bf2f((ushort)(rv.y >> 16))    * bf2f((ushort)(kv.y >> 16))    * u[c0 + 3];
    p += __shfl_xor(p, 1);
    p += __shfl_xor(p, 2);
    p += __shfl_xor(p, 4);
    p += __shfl_xor(p, 8);
    if ((tid & 15) == 0) sig[(size_t)bt * H + (tid >> 4)] = p;
}

// -------- GroupNorm --------
__global__ __launch_bounds__(1024) void gnmul_kernel(const float* __restrict__ yf,
                                                     const float* __restrict__ yb,
                                                     const float* __restrict__ g,
                                                     const float* __restrict__ b,
                                                     const ushort* __restrict__ gate,
                                                     const ushort* __restrict__ vin,
                                                     const float* __restrict__ sig,
                                                     ushort* __restrict__ out)
{
    const int row = blockIdx.x;
    const int tid = threadIdx.x;
    const size_t idx = (size_t)row * C + tid;
    const float sg = sig[(size_t)row * H + (tid >> 6)];
    const float v = yf[idx] + yb[idx] + sg * bf2f(vin[idx]);
    float s = v;
#pragma unroll
    for (int off = 32; off > 0; off >>= 1) s += __shfl_xor(s, off);
    const float m = s * (1.0f / HEAD);
    const float d = v - m;
    float q = d * d;
#pragma unroll
    for (int off = 32; off > 0; off >>= 1) q += __shfl_xor(q, off);
    const float rstd = rsqrtf(q * (1.0f / HEAD) + 6.4e-4f);
    out[idx] = f2bf((d * rstd * g[tid] + b[tid]) * bf2f(gate[idx]));
}

// -------- weight convert+transpose: W[Kd,Nd] f32 -> Wt[Nd,Kd] bf16 --------
__global__ __launch_bounds__(256) void wconv_kernel(const float* __restrict__ W,
                                                    ushort* __restrict__ Wt,
                                                    int Kd, int Nd)
{
    __shared__ float tile[32][33];
    const int n0 = blockIdx.x * 32, k0 = blockIdx.y * 32;
    const int tx = threadIdx.x, ty = threadIdx.y;
#pragma unroll
    for (int i = 0; i < 4; ++i)
        tile[ty * 4 + i][tx] = W[(size_t)(k0 + ty * 4 + i) * Nd + n0 + tx];
    __syncthreads();
#pragma unroll
    for (int i = 0; i < 4; ++i)
        Wt[(size_t)(n0 + ty * 4 + i) * Kd + k0 + tx] = f2bf(tile[tx][ty * 4 + i]);
}

// -------- batched wconv: 4 C x C weights (blockIdx.z) --------
struct Wconv4Args { const float* W[4]; };
__global__ __launch_bounds__(256) void wconv4_kernel(Wconv4Args args, ushort* __restrict__ Wt)
{
    __shared__ float tile[32][33];
    const int z = blockIdx.z;
    const float* __restrict__ W = args.W[z];
    ushort* __restrict__ dst = Wt + (size_t)z * C * C;
    const int n0 = blockIdx.x * 32, k0 = blockIdx.y * 32;
    const int tx = threadIdx.x, ty = threadIdx.y;
#pragma unroll
    for (int i = 0; i < 4; ++i)
        tile[ty * 4 + i][tx] = W[(size_t)(k0 + ty * 4 + i) * C + n0 + tx];
    __syncthreads();
#pragma unroll
    for (int i = 0; i < 4; ++i)
        dst[(size_t)(n0 + ty * 4 + i) * C + k0 + tx] = f2bf(tile[tx][ty * 4 + i]);
}

// ================== chunked bidirectional WKV6 ==================
__global__ __launch_bounds__(64) void wkv_pass1(const ushort* __restrict__ k,
                                                const ushort* __restrict__ v,
                                                const float* __restrict__ d,
                                                ushort* __restrict__ M,
                                                float* __restrict__ D)
{
    const int uc = blockIdx.x;
    const int c = uc & (NCH - 1), unit = uc >> 3;
    const int dir = unit & 1, bh = unit >> 1;
    const int lane = threadIdx.x;
    const size_t hb = ((size_t)(bh >> 4) * T * H + (bh & 15)) * HEAD + lane;
    __shared__ __align__(16) float sbuf[2][2][64];

    float S[64];
#pragma unroll
    for (int j = 0; j < 64; ++j) S[j] = 0.f;
    float PD = 1.f;

    int s0 = c * CS;
    int t0 = dir ? (T - 1 - s0) : s0;
    size_t pb = hb + (size_t)t0 * (H * HEAD);
    float kk = bf2f(k[pb]);
    float vn = bf2f(v[pb]);
    float dd = d[pb];

    int p = 0;
    for (int ss = 0; ss < CS; ++ss) {
        const float kc = kk, vv = vn, dc = dd;
        const int sn = (ss + 1 < CS) ? (ss + 1) : 0;
        const int s = c * CS + sn;
        const int tn = dir ? (T - 1 - s) : s;
        const size_t nb = hb + (size_t)tn * (H * HEAD);
        kk = bf2f(k[nb]);
        vn = bf2f(v[nb]);
        dd = d[nb];

        PD *= dc;
        sbuf[p][0][lane] = kc;
        sbuf[p][1][lane] = dc;
        asm volatile("s_waitcnt lgkmcnt(0)" ::: "memory");
        const float* __restrict__ sk = sbuf[p][0];
        const float* __restrict__ sd = sbuf[p][1];
#pragma unroll
        for (int jj = 0; jj < 64; jj += 4) {
            const float4 k4 = *reinterpret_cast<const float4*>(&sk[jj]);
            const float4 d4 = *reinterpret_cast<const float4*>(&sd[jj]);
            S[jj + 0] = fmaf(d4.x, S[jj + 0], k4.x * vv);
            S[jj + 1] = fmaf(d4.y, S[jj + 1], k4.y * vv);
            S[jj + 2] = fmaf(d4.z, S[jj + 2], k4.z * vv);
            S[jj + 3] = fmaf(d4.w, S[jj + 3], k4.w * vv);
        }
        p ^= 1;
    }
    const size_t mb = (size_t)uc * 4096 + lane;
#pragma unroll
    for (int j = 0; j < 64; ++j) M[mb + j * 64] = f2bf(S[j]);
    D[(size_t)uc * 64 + lane] = PD;
}

__global__ __launch_bounds__(64) void wkv_pass2(ushort* __restrict__ M,
                                                const float* __restrict__ D)
{
    const int unit = blockIdx.x;
    const int lane = threadIdx.x;
    __shared__ float Dl[64];
    float S[64];
#pragma unroll
    for (int j = 0; j < 64; ++j) S[j] = 0.f;

    for (int c = 0; c < NCH; ++c) {
        const int uc = unit * NCH + c;
        __syncthreads();
        Dl[lane] = D[(size_t)uc * 64 + lane];
        __syncthreads();
        const size_t mb = (size_t)uc * 4096 + lane;
#pragma unroll
        for (int j = 0; j < 64; ++j) {
            const float m = bf2f(M[mb + j * 64]);
            M[mb + j * 64] = f2bf(S[j]);
            S[j] = fmaf(Dl[j], S[j], m);
        }
    }
}

__global__ __launch_bounds__(64) void wkv_pass3(const ushort* __restrict__ r,
                                                const ushort* __restrict__ k,
                                                const ushort* __restrict__ v,
                                                const float* __restrict__ d,
                                                const ushort* __restrict__ Sin,
                                                float* __restrict__ yf,
                                                float* __restrict__ yb)
{
    const int uc = blockIdx.x;
    const int c = uc & (NCH - 1), unit = uc >> 3;
    const int dir = unit & 1, bh = unit >> 1;
    const int lane = threadIdx.x;
    const size_t hb = ((size_t)(bh >> 4) * T * H + (bh & 15)) * HEAD + lane;
    __shared__ __align__(16) float sbuf[2][3][64];

    float S[64];
    const size_t mb = (size_t)uc * 4096 + lane;
#pragma unroll
    for (int j = 0; j < 64; ++j) S[j] = bf2f(Sin[mb + j * 64]);
    float* __restrict__ yo = dir ? yb : yf;

    int s0 = c * CS;
    int t0 = dir ? (T - 1 - s0) : s0;
    size_t pb = hb + (size_t)t0 * (H * HEAD);
    float rr = bf2f(r[pb]);
    float kk = bf2f(k[pb]);
    float vn = bf2f(v[pb]);
    float dd = d[pb];

    int p = 0;
    for (int ss = 0; ss < CS; ++ss) {
        const int s = c * CS + ss;
        const int t = dir ? (T - 1 - s) : s;
        const size_t ob = hb + (size_t)t * (H * HEAD);
        const float rc = rr, kc = kk, vv = vn, dc = dd;

        const int sn2 = (ss + 1 < CS) ? (ss + 1) : 0;
        const int s2 = c * CS + sn2;
        const int tn = dir ? (T - 1 - s2) : s2;
        const size_t nb = hb + (size_t)tn * (H * HEAD);
        rr = bf2f(r[nb]);
        kk = bf2f(k[nb]);
        vn = bf2f(v[nb]);
        dd = d[nb];

        sbuf[p][0][lane] = rc;
        sbuf[p][1][lane] = kc;
        sbuf[p][2][lane] = dc;
        asm volatile("s_waitcnt lgkmcnt(0)" ::: "memory");
        const float* __restrict__ sr = sbuf[p][0];
        const float* __restrict__ sk = sbuf[p][1];
        const float* __restrict__ sd = sbuf[p][2];
        float y0 = 0.f, y1 = 0.f, y2 = 0.f, y3 = 0.f;
#pragma unroll
        for (int jj = 0; jj < 64; jj += 4) {
            const float4 r4 = *reinterpret_cast<const float4*>(&sr[jj]);
            const float4 k4 = *reinterpret_cast<const float4*>(&sk[jj]);
            const float4 d4 = *reinterpret_cast<const float4*>(&sd[jj]);
            y0 = fmaf(r4.x, S[jj + 0], y0);
            S[jj + 0] = fmaf(d4.x, S[jj + 0], k4.x * vv);
            y1 = fmaf(r4.y, S[jj + 1], y1);
            S[jj + 1] = fmaf(d4.y, S[jj + 1], k4.y * vv);
            y2 = fmaf(r4.z, S[jj + 2], y2);
            S[jj + 2] = fmaf(d4.z, S[jj + 2], k4.z * vv);
            y3 = fmaf(r4.w, S[jj + 3], y3);
            S[jj + 3] = fmaf(d4.w, S[jj + 3], k4.w * vv);
        }
        yo[ob] = (y0 + y1) + (y2 + y3);
        p ^= 1;
    }
}

// ======== pipelined bf16 MFMA GEMM core: BM=128, BK=64, BN in {64,128} ========
// 2-phase: issue next-tile global_load_lds BEFORE computing current tile;
// one drain+barrier per K-step. LDS chunk-XOR swizzle (c ^= row&7), both sides.
template <int BN>
struct GemmLds {
    ushort As[2][128 * 64];
    ushort Bs[2][BN * 64];
};

template <int BN>
__device__ __forceinline__ void gemm_body(const ushort* __restrict__ A,
                                          const ushort* __restrict__ Bt,
                                          int bm, int bn, int K,
                                          GemmLds<BN>& lds,
                                          floatx4 (&acc)[4][BN / 32])
{
    constexpr int NF = BN / 32;
    const int tid = threadIdx.x;
    const int wid = tid >> 6, lane = tid & 63;
    const int wr = wid >> 1, wc = wid & 1;
    const int l15 = lane & 15, lhi = lane >> 4;
    const int NT = K >> 6;

    auto stage = [&](int buf, int k0) {
#pragma unroll
        for (int p = 0; p < 4; ++p) {
            const int lin = p * 256 + tid;
            const int row = lin >> 3;
            const int cs = (lin & 7) ^ (row & 7);
            gload16(A + (size_t)(bm + row) * K + k0 + cs * 8, &lds.As[buf][lin * 8]);
        }
#pragma unroll
        for (int p = 0; p < NF; ++p) {
            const int lin = p * 256 + tid;
            const int n = lin >> 3;
            const int cs = (lin & 7) ^ (n & 7);
            gload16(Bt + (size_t)(bn + n) * K + k0 + cs * 8, &lds.Bs[buf][lin * 8]);
        }
    };

    stage(0, 0);
    __syncthreads();                      // drains vmcnt
    for (int t = 0; t < NT; ++t) {
        const int cur = t & 1;
        if (t + 1 < NT) stage(cur ^ 1, (t + 1) << 6);

        short8 af[4][2];
#pragma unroll
        for (int m = 0; m < 4; ++m) {
            const int row = wr * 64 + m * 16 + l15;
#pragma unroll
            for (int s = 0; s < 2; ++s) {
                const int cc = (s * 4 + lhi) ^ (row & 7);
                af[m][s] = *(const short8*)&lds.As[cur][row * 64 + cc * 8];
            }
        }
        short8 bf[NF][2];
#pragma unroll
        for (int n = 0; n < NF; ++n) {
            const int col = wc * (BN / 2) + n * 16 + l15;
#pragma unroll
            for (int s = 0; s < 2; ++s) {
                const int cc = (s * 4 + lhi) ^ (col & 7);
                bf[n][s] = *(const short8*)&lds.Bs[cur][col * 64 + cc * 8];
            }
        }
#pragma unroll
        for (int m = 0; m < 4; ++m)
#pragma unroll
            for (int n = 0; n < NF; ++n) {
                acc[m][n] = __builtin_amdgcn_mfma_f32_16x16x32_bf16(af[m][0], bf[n][0], acc[m][n], 0, 0, 0);
                acc[m][n] = __builtin_amdgcn_mfma_f32_16x16x32_bf16(af[m][1], bf[n][1], acc[m][n], 0, 0, 0);
            }
        __syncthreads();                  // drains next-tile loads + protects cur buf
    }
}

template <int BN, int EPI>
__global__ __launch_bounds__(256) void bgemm_kernel(const ushort* __restrict__ A,
                                                    const ushort* __restrict__ Bt,
                                                    void* __restrict__ Cm,
                                                    int M, int N, int K,
                                                    const float* __restrict__ aux1,
                                                    const float* __restrict__ aux2)
{
    constexpr int NF = BN / 32;
    __shared__ GemmLds<BN> lds;
    int w = blockIdx.y * gridDim.x + blockIdx.x;
    const int nwg = gridDim.x * gridDim.y;
    if ((nwg & 7) == 0) w = (w & 7) * (nwg >> 3) + (w >> 3);   // XCD swizzle
    const int bn = (w % gridDim.x) * BN;
    const int bm = (w / gridDim.x) * 128;
    const int tid = threadIdx.x;
    const int wid = tid >> 6, lane = tid & 63;
    const int wr = wid >> 1, wc = wid & 1;
    const int l15 = lane & 15, lhi = lane >> 4;

    floatx4 acc[4][NF];
#pragma unroll
    for (int m = 0; m < 4; ++m)
#pragma unroll
        for (int n = 0; n < NF; ++n) acc[m][n] = (floatx4){0.f, 0.f, 0.f, 0.f};

    gemm_body<BN>(A, Bt, bm, bn, K, lds, acc);

#pragma unroll
    for (int m = 0; m < 4; ++m) {
        const int row0 = bm + wr * 64 + m * 16 + lhi * 4;
#pragma unroll
        for (int n = 0; n < NF; ++n) {
            const int col = bn + wc * (BN / 2) + n * 16 + l15;
            if (col >= N) continue;
#pragma unroll
            for (int j = 0; j < 4; ++j) {
                const size_t oi = (size_t)(row0 + j) * N + col;
                const float a = acc[m][n][j];
                if constexpr (EPI == BEPI_NONE_BF) {
                    ((ushort*)Cm)[oi] = f2bf(a);
                } else if constexpr (EPI == BEPI_SILU_BF) {
                    ((ushort*)Cm)[oi] = f2bf(a / (1.f + __expf(-a)));
                } else if constexpr (EPI == BEPI_RELUSQ_BF) {
                    const float t = fmaxf(a, 0.f);
                    ((ushort*)Cm)[oi] = f2bf(t * t);
                } else if constexpr (EPI == BEPI_NONE_F) {
                    ((float*)Cm)[oi] = a;
                } else if constexpr (EPI == BEPI_RES_F) {
                    ((float*)Cm)[oi] = aux1[oi] + a;
                } else if constexpr (EPI == BEPI_SIGRES_F) {
                    ((float*)Cm)[oi] = aux1[oi] + aux2[oi] / (1.f + __expf(-a));
                } else if constexpr (EPI == BEPI_TANH_F) {
                    ((float*)Cm)[oi] = tanhf(a);
                } else if constexpr (EPI == BEPI_TANH_BF) {
                    ((ushort*)Cm)[oi] = f2bf(tanhf(a));
                } else {  // BEPI_DECAY_F
                    ((float*)Cm)[oi] = __expf(-__expf(a + aux1[col]));
                }
            }
        }
    }
}

// -------- batched QKVG GEMM: blockIdx.z selects {k,v,r,g}; z==3 -> silu --------
struct QkvgArgs { const ushort* A[4]; ushort* O[4]; };
__global__ __launch_bounds__(256) void qkvg_kernel(QkvgArgs args,
                                                   const ushort* __restrict__ Wt)
{
    __shared__ GemmLds<64> lds;
    const int z = blockIdx.z;
    int w = blockIdx.y * gridDim.x + blockIdx.x;          // 16 x 16 grid
    w = (w & 7) * 32 + (w >> 3);                           // XCD swizzle (256/8)
    const int bn = (w & 15) * 64;
    const int bm = (w >> 4) * 128;
    const int tid = threadIdx.x;
    const int wid = tid >> 6, lane = tid & 63;
    const int wr = wid >> 1, wc = wid & 1;
    const int l15 = lane & 15, lhi = lane >> 4;

    floatx4 acc[4][2];
#pragma unroll
    for (int m = 0; m < 4; ++m)
#pragma unroll
        for (int n = 0; n < 2; ++n) acc[m][n] = (floatx4){0.f, 0.f, 0.f, 0.f};

    gemm_body<64>(args.A[z], Wt + (size_t)z * C * C, bm, bn, C, lds, acc);

    ushort* __restrict__ O = args.O[z];
    const bool silu = (z == 3);
#pragma unroll
    for (int m = 0; m < 4; ++m) {
        const int row0 = bm + wr * 64 + m * 16 + lhi * 4;
#pragma unroll
        for (int n = 0; n < 2; ++n) {
            const int col = bn + wc * 32 + n * 16 + l15;
#pragma unroll
            for (int j = 0; j < 4; ++j) {
                float a = acc[m][n][j];
                if (silu) a = a / (1.f + __expf(-a));
                O[(size_t)(row0 + j) * C + col] = f2bf(a);
            }
        }
    }
}

// ---------------- launch ----------------
extern "C" void kernel_launch(void* const* d_in, const int* in_sizes, int n_in,
                              void* d_out, int out_size, void* d_ws, size_t ws_size,
                              hipStream_t stream)
{
    const float* x        = (const float*)d_in[0];
    const float* ln1_g    = (const float*)d_in[1];
    const float* ln1_b    = (const float*)d_in[2];
    const float* ln2_g    = (const float*)d_in[3];
    const float* ln2_b    = (const float*)d_in[4];
    const float* maa_x    = (const float*)d_in[5];
    const float* maa_w    = (const float*)d_in[6];
    const float* maa_k    = (const float*)d_in[7];
    const float* maa_v    = (const float*)d_in[8];
    const float* maa_r    = (const float*)d_in[9];
    const float* maa_g    = (const float*)d_in[10];
    const float* maa_w1   = (const float*)d_in[11];
    const float* maa_w2   = (const float*)d_in[12];
    const float* time_dec = (const float*)d_in[13];
    const float* tdw1     = (const float*)d_in[14];
    const float* tdw2     = (const float*)d_in[15];
    const float* u        = (const float*)d_in[16];
    const float* Wr       = (const float*)d_in[17];
    const float* Wk       = (const float*)d_in[18];
    const float* Wv       = (const float*)d_in[19];
    const float* Wg       = (const float*)d_in[20];
    const float* Wo       = (const float*)d_in[21];
    const float* lnx_g    = (const float*)d_in[22];
    const float* lnx_b    = (const float*)d_in[23];
    const float* cmaa_k   = (const float*)d_in[24];
    const float* cmaa_r   = (const float*)d_in[25];
    const float* Wck      = (const float*)d_in[26];
    const float* Wcv      = (const float*)d_in[27];
    const float* Wcr      = (const float*)d_in[28];
    float* out = (float*)d_out;

    // -------- workspace layout (~63 MB) --------
    float* fws = (float*)d_ws;
    const size_t E = (size_t)BT * C;            // 2,097,152
    float* xa  = fws + 0 * E;                   // xa -> yf ; (FFN) kk low half
    float* xx  = fws + 1 * E;                   // xx -> yb -> cxx ; kk high half
    float* wd  = fws + 2 * E;                   // decay d -> xc
    float* fs  = fws + 3 * E;                   // xvb/xrb (mix) ; M low ; kv
    ushort* wBuf = (ushort*)(fws + 4 * E);      // 4M ushort: weights / M high
    ushort* Mbuf = (ushort*)fs;                 // 2048*4096 bf16 = fs..wBuf (16MB)
    ushort* bf1  = wBuf + (size_t)C * FF;       // E: mixax out / xkb / ck_in
    ushort* rb   = bf1 + E;                     // r
    ushort* kb   = rb + E;                      // k
    ushort* vb   = kb + E;                      // v  -> ya
    ushort* gb   = vb + E;                      // g  -> cr_in
    ushort* t1b  = gb + E;                      // BT*64 bf16
    float* a5    = (float*)(t1b + (size_t)BT * 64);   // BT*160 f32
    float* sig   = a5 + (size_t)BT * 160;       // BT*16 f32
    float* Dbuf  = sig + (size_t)BT * H;        // 2048*64 f32
    ushort* xvb  = (ushort*)fs;                 // E (mix v input)
    ushort* xrb  = (ushort*)fs + E;             // E (mix r input)
    ushort* xgb  = (ushort*)out;                // E (mix g input; out is scratch)
    ushort* xwb  = (ushort*)out + E;            // E (mix w input)
    ushort* kk   = (ushort*)xa;                 // BT*FF bf16 == xa..xx

    const dim3 blk(256);
    const dim3 tblk(32, 8);
    const int EW = (BT * C) / 256;
    const dim3 gNN(C / 64, BT / 128);

    // ---- attention branch ----
    ln_kernel<<<BT, blk, 0, stream>>>(x, ln1_g, ln1_b, xa);
    bshift_kernel<<<EW, blk, 0, stream>>>(xa, xx);
    mixaxbf_kernel<<<EW, blk, 0, stream>>>(xa, xx, maa_x, bf1);
    wconv_kernel<<<dim3(160 / 32, C / 32), tblk, 0, stream>>>(maa_w1, wBuf, C, 160);
    bgemm_kernel<64, BEPI_TANH_F><<<dim3(3, BT / 128), blk, 0, stream>>>(bf1, wBuf, a5, BT, 160, C, nullptr, nullptr);

    // all 5 mixes in one launch (bf1 consumed by a5 gemm above, then reused as xkb)
    Mix5Args margs;
    margs.maa[0] = maa_w; margs.maa[1] = maa_k; margs.maa[2] = maa_v;
    margs.maa[3] = maa_r; margs.maa[4] = maa_g;
    margs.out[0] = xwb; margs.out[1] = bf1; margs.out[2] = xvb;
    margs.out[3] = xrb; margs.out[4] = xgb;
    mix5b_kernel<<<dim3(BT, 5), blk, 0, stream>>>(xa, xx, a5, maa_w2, margs);

    // w path: tanh(xw@tdw1) -> decay d = exp(-exp(@tdw2 + time_decay))
    wconv_kernel<<<dim3(64 / 32, C / 32), tblk, 0, stream>>>(tdw1, wBuf, C, 64);
    bgemm_kernel<64, BEPI_TANH_BF><<<dim3(1, BT / 128), blk, 0, stream>>>(xwb, wBuf, t1b, BT, 64, C, nullptr, nullptr);
    wconv_kernel<<<dim3(C / 32, 64 / 32), tblk, 0, stream>>>(tdw2, wBuf, 64, C);
    bgemm_kernel<64, BEPI_DECAY_F><<<gNN, blk, 0, stream>>>(t1b, wBuf, wd, BT, C, 64, time_dec, nullptr);

    // batched QKVG: convert 4 weights, then one 4-slice GEMM launch
    Wconv4Args wargs;
    wargs.W[0] = Wk; wargs.W[1] = Wv; wargs.W[2] = Wr; wargs.W[3] = Wg;
    wconv4_kernel<<<dim3(C / 32, C / 32, 4), tblk, 0, stream>>>(wargs, wBuf);
    QkvgArgs qargs;
    qargs.A[0] = bf1; qargs.A[1] = xvb; qargs.A[2] = xrb; qargs.A[3] = xgb;
    qargs.O[0] = kb;  qargs.O[1] = vb;  qargs.O[2] = rb;  qargs.O[3] = gb;
    qkvg_kernel<<<dim3(16, 16, 4), blk, 0, stream>>>(qargs, wBuf);

    // u-bonus scalar + chunked bidirectional WKV (Mbuf overlays fs+wBuf)
    sigma_kernel<<<BT, blk, 0, stream>>>(rb, kb, u, sig);
    wkv_pass1<<<dim3(2 * B * H * NCH), dim3(64), 0, stream>>>(kb, vb, wd, Mbuf, Dbuf);
    wkv_pass2<<<dim3(2 * B * H), dim3(64), 0, stream>>>(Mbuf, Dbuf);
    wkv_pass3<<<dim3(2 * B * H * NCH), dim3(64), 0, stream>>>(rb, kb, vb, wd, Mbuf, xa, xx);

    // ya = groupnorm(yf+yb+sig*v)*g ; out = x + ya @ Wo^T
    gnmul_kernel<<<BT, dim3(1024), 0, stream>>>(xa, xx, lnx_g, lnx_b, gb, vb, sig, vb);
    wconv_kernel<<<dim3(C / 32, C / 32), tblk, 0, stream>>>(Wo, wBuf, C, C);
    bgemm_kernel<64, BEPI_RES_F><<<gNN, blk, 0, stream>>>(vb, wBuf, out, BT, C, C, x, nullptr);

    // ---- FFN branch ----
    ln_kernel<<<BT, blk, 0, stream>>>(out, ln2_g, ln2_b, wd);
    bshift_kernel<<<EW, blk, 0, stream>>>(wd, xx);
    cmix_kernel<<<EW, blk, 0, stream>>>(wd, xx, cmaa_k, cmaa_r, bf1, gb);
    wconv_kernel<<<dim3(FF / 32, C / 32), tblk, 0, stream>>>(Wck, wBuf, C, FF);
    bgemm_kernel<128, BEPI_RELUSQ_BF><<<dim3(FF / 128, BT / 128), blk, 0, stream>>>(bf1, wBuf, kk, BT, FF, C, nullptr, nullptr);
    wconv_kernel<<<dim3(C / 32, FF / 32), tblk, 0, stream>>>(Wcv, wBuf, FF, C);
    bgemm_kernel<64, BEPI_NONE_F><<<gNN, blk, 0, stream>>>(kk, wBuf, fs, BT, C, FF, nullptr, nullptr);
    wconv_kernel<<<dim3(C / 32, C / 32), tblk, 0, stream>>>(Wcr, wBuf, C, C);
    bgemm_kernel<64, BEPI_SIGRES_F><<<gNN, blk, 0, stream>>>(gb, wBuf, out, BT, C, C, out, fs);

    (void)in_sizes; (void)n_in; (void)out_size; (void)ws_size;
}

// Round 7
// 372.489 us; speedup vs baseline: 3.8721x; 1.1702x over previous
//
#include <hip/hip_runtime.h>
#include <math.h>
#include <stdint.h>

static constexpr int B  = 8;
static constexpr int T  = 256;
static constexpr int C  = 1024;
static constexpr int H  = 16;
static constexpr int HEAD = 64;
static constexpr int FF = 4096;
static constexpr int BT = B * T;
static constexpr int NCH = 8;       // time chunks
static constexpr int CS  = 32;      // chunk size (NCH*CS == T)

typedef short short8  __attribute__((ext_vector_type(8)));
typedef float floatx4 __attribute__((ext_vector_type(4)));

// ---------------- bf16 helpers ----------------
__device__ __forceinline__ float bf2f(ushort u) {
    return __uint_as_float(((uint32_t)u) << 16);
}
__device__ __forceinline__ ushort f2bf(float x) {
    uint32_t u = __float_as_uint(x);
    u += 0x7fff + ((u >> 16) & 1);          // RNE
    return (ushort)(u >> 16);
}

__device__ __forceinline__ void gload16(const void* g, void* l) {
    __builtin_amdgcn_global_load_lds(
        (const __attribute__((address_space(1))) unsigned int*)g,
        (__attribute__((address_space(3))) unsigned int*)l, 16, 0, 0);
}

// ---------------- epilogue ids ----------------
#define BEPI_NONE_BF   0
#define BEPI_SILU_BF   1
#define BEPI_RELUSQ_BF 2
#define BEPI_NONE_F    3
#define BEPI_RES_F     4
#define BEPI_SIGRES_F  5
#define BEPI_TANH_F    6
#define BEPI_TANH_BF   7
#define BEPI_DECAY_F   8

// ---------------- LayerNorm ----------------
__global__ __launch_bounds__(256) void ln_kernel(const float* __restrict__ x,
                                                 const float* __restrict__ g,
                                                 const float* __restrict__ b,
                                                 float* __restrict__ out)
{
    const int row = blockIdx.x;
    const int tid = threadIdx.x;
    const float4 v = reinterpret_cast<const float4*>(x + (size_t)row * C)[tid];
    float s = v.x + v.y + v.z + v.w;
#pragma unroll
    for (int off = 32; off > 0; off >>= 1) s += __shfl_xor(s, off);
    __shared__ float red[8];
    const int wave = tid >> 6, lane = tid & 63;
    if (lane == 0) red[wave] = s;
    __syncthreads();
    const float mean = (red[0] + red[1] + red[2] + red[3]) * (1.0f / C);
    const float d0 = v.x - mean, d1 = v.y - mean, d2 = v.z - mean, d3 = v.w - mean;
    float q = d0 * d0 + d1 * d1 + d2 * d2 + d3 * d3;
#pragma unroll
    for (int off = 32; off > 0; off >>= 1) q += __shfl_xor(q, off);
    if (lane == 0) red[4 + wave] = q;
    __syncthreads();
    const float var = (red[4] + red[5] + red[6] + red[7]) * (1.0f / C);
    const float rstd = rsqrtf(var + 1e-5f);
    const int c = tid * 4;
    float4 o;
    o.x = d0 * rstd * g[c + 0] + b[c + 0];
    o.y = d1 * rstd * g[c + 1] + b[c + 1];
    o.z = d2 * rstd * g[c + 2] + b[c + 2];
    o.w = d3 * rstd * g[c + 3] + b[c + 3];
    reinterpret_cast<float4*>(out + (size_t)row * C)[tid] = o;
}

// ---------------- bshift:  xx = bshift(xa) - xa ----------------
__global__ __launch_bounds__(256) void bshift_kernel(const float* __restrict__ xa,
                                                     float* __restrict__ xx)
{
    const int i = blockIdx.x * 256 + threadIdx.x;
    const int c = i & (C - 1);
    const int bt = i >> 10;
    const int t = bt & (T - 1);
    const int j = c & (HEAD - 1);
    float src = 0.f;
    if (j < HEAD / 2) { if (t > 0)     src = xa[i - C]; }
    else              { if (t < T - 1) src = xa[i + C]; }
    xx[i] = src - xa[i];
}

// ---------------- ax = xa + xx * maa_x  (bf16 out) ----------------
__global__ __launch_bounds__(256) void mixaxbf_kernel(const float* __restrict__ xa,
                                                      const float* __restrict__ xx,
                                                      const float* __restrict__ maa,
                                                      ushort* __restrict__ out)
{
    const int i = blockIdx.x * 256 + threadIdx.x;
    const int c = i & (C - 1);
    out[i] = f2bf(xa[i] + xx[i] * maa[c]);
}

// -------- batched mix5: 5 mixes in one launch (blockIdx.y = f) --------
struct Mix5Args { const float* maa[5]; ushort* out[5]; };
__global__ __launch_bounds__(256) void mix5b_kernel(const float* __restrict__ xa,
                                                    const float* __restrict__ xx,
                                                    const float* __restrict__ a5,
                                                    const float* __restrict__ w2,
                                                    Mix5Args args)
{
    const int bt = blockIdx.x;
    const int f  = blockIdx.y;
    const int tid = threadIdx.x;
    __shared__ float al[32];
    if (tid < 32) al[tid] = a5[(size_t)bt * 160 + f * 32 + tid];
    __syncthreads();
    const float* __restrict__ w2f = w2 + (size_t)f * 32 * C;
    const float* __restrict__ maa = args.maa[f];
    ushort* __restrict__ out = args.out[f];
    const size_t rb = (size_t)bt * C;
#pragma unroll
    for (int m = 0; m < 4; ++m) {
        const int c = tid + 256 * m;
        float acc = 0.f;
#pragma unroll 8
        for (int d = 0; d < 32; ++d) acc = fmaf(al[d], w2f[d * C + c], acc);
        out[rb + c] = f2bf(xa[rb + c] + xx[rb + c] * (maa[c] + acc));
    }
}

// -------- cmix --------
__global__ __launch_bounds__(256) void cmix_kernel(const float* __restrict__ xc,
                                                   const float* __restrict__ cxx,
                                                   const float* __restrict__ mk,
                                                   const float* __restrict__ mr,
                                                   ushort* __restrict__ ok,
                                                   ushort* __restrict__ orr)
{
    const int i = blockIdx.x * 256 + threadIdx.x;
    const int c = i & (C - 1);
    const float a = xc[i], d = cxx[i];
    ok[i]  = f2bf(a + d * mk[c]);
    orr[i] = f2bf(a + d * mr[c]);
}

// -------- sigma --------
__global__ __launch_bounds__(256) void sigma_kernel(const ushort* __restrict__ r,
                                                    const ushort* __restrict__ k,
                                                    const float* __restrict__ u,
                                                    float* __restrict__ sig)
{
    const int bt = blockIdx.x;
    const int tid = threadIdx.x;
    const int c0 = tid * 4;
    const size_t base = (size_t)bt * C + c0;
    const uint2 rv = *reinterpret_cast<const uint2*>(r + base);
    const uint2 kv = *reinterpret_cast<const uint2*>(k + base);
    float p = 0.f;
    p += bf2f((ushort)(rv.x & 0xffff)) * bf2f((ushort)(kv.x & 0xffff)) * u[c0 + 0];
    p += bf2f((ushort)(rv.x >> 16))    * bf2f((ushort)(kv.x >> 16))    * u[c0 + 1];
    p += bf2f((ushort)(rv.y & 0xffff)) * bf2f((ushort)(kv.y & 0xffff)) * u[c0 + 2];
    p += bf2f((ushort)(rv.y >> 16))    * bf2f((ushort)(kv.y >> 16))    * u[c0 + 3];
    p += __shfl_xor(p, 1);
    p += __shfl_xor(p, 2);
    p += __shfl_xor(p, 4);
    p += __shfl_xor(p, 8);
    if ((tid & 15) == 0) sig[(size_t)bt * H + (tid >> 4)] = p;
}

// -------- GroupNorm --------
__global__ __launch_bounds__(1024) void gnmul_kernel(const float* __restrict__ yf,
                                                     const float* __restrict__ yb,
                                                     const float* __restrict__ g,
                                                     const float* __restrict__ b,
                                                     const ushort* __restrict__ gate,
                                                     const ushort* __restrict__ vin,
                                                     const float* __restrict__ sig,
                                                     ushort* __restrict__ out)
{
    const int row = blockIdx.x;
    const int tid = threadIdx.x;
    const size_t idx = (size_t)row * C + tid;
    const float sg = sig[(size_t)row * H + (tid >> 6)];
    const float v = yf[idx] + yb[idx] + sg * bf2f(vin[idx]);
    float s = v;
#pragma unroll
    for (int off = 32; off > 0; off >>= 1) s += __shfl_xor(s, off);
    const float m = s * (1.0f / HEAD);
    const float d = v - m;
    float q = d * d;
#pragma unroll
    for (int off = 32; off > 0; off >>= 1) q += __shfl_xor(q, off);
    const float rstd = rsqrtf(q * (1.0f / HEAD) + 6.4e-4f);
    out[idx] = f2bf((d * rstd * g[tid] + b[tid]) * bf2f(gate[idx]));
}

// -------- weight convert+transpose: W[Kd,Nd] f32 -> Wt[Nd,Kd] bf16 --------
__global__ __launch_bounds__(256) void wconv_kernel(const float* __restrict__ W,
                                                    ushort* __restrict__ Wt,
                                                    int Kd, int Nd)
{
    __shared__ float tile[32][33];
    const int n0 = blockIdx.x * 32, k0 = blockIdx.y * 32;
    const int tx = threadIdx.x, ty = threadIdx.y;
#pragma unroll
    for (int i = 0; i < 4; ++i)
        tile[ty * 4 + i][tx] = W[(size_t)(k0 + ty * 4 + i) * Nd + n0 + tx];
    __syncthreads();
#pragma unroll
    for (int i = 0; i < 4; ++i)
        Wt[(size_t)(n0 + ty * 4 + i) * Kd + k0 + tx] = f2bf(tile[tx][ty * 4 + i]);
}

// -------- batched wconv: 4 C x C weights (blockIdx.z) --------
struct Wconv4Args { const float* W[4]; };
__global__ __launch_bounds__(256) void wconv4_kernel(Wconv4Args args, ushort* __restrict__ Wt)
{
    __shared__ float tile[32][33];
    const int z = blockIdx.z;
    const float* __restrict__ W = args.W[z];
    ushort* __restrict__ dst = Wt + (size_t)z * C * C;
    const int n0 = blockIdx.x * 32, k0 = blockIdx.y * 32;
    const int tx = threadIdx.x, ty = threadIdx.y;
#pragma unroll
    for (int i = 0; i < 4; ++i)
        tile[ty * 4 + i][tx] = W[(size_t)(k0 + ty * 4 + i) * C + n0 + tx];
    __syncthreads();
#pragma unroll
    for (int i = 0; i < 4; ++i)
        dst[(size_t)(n0 + ty * 4 + i) * C + k0 + tx] = f2bf(tile[tx][ty * 4 + i]);
}

// ================== chunked bidirectional WKV6 ==================
__global__ __launch_bounds__(64) void wkv_pass1(const ushort* __restrict__ k,
                                                const ushort* __restrict__ v,
                                                const float* __restrict__ d,
                                                ushort* __restrict__ M,
                                                float* __restrict__ D)
{
    const int uc = blockIdx.x;
    const int c = uc & (NCH - 1), unit = uc >> 3;
    const int dir = unit & 1, bh = unit >> 1;
    const int lane = threadIdx.x;
    const size_t hb = ((size_t)(bh >> 4) * T * H + (bh & 15)) * HEAD + lane;
    __shared__ __align__(16) float sbuf[2][2][64];

    float S[64];
#pragma unroll
    for (int j = 0; j < 64; ++j) S[j] = 0.f;
    float PD = 1.f;

    int s0 = c * CS;
    int t0 = dir ? (T - 1 - s0) : s0;
    size_t pb = hb + (size_t)t0 * (H * HEAD);
    float kk = bf2f(k[pb]);
    float vn = bf2f(v[pb]);
    float dd = d[pb];

    int p = 0;
    for (int ss = 0; ss < CS; ++ss) {
        const float kc = kk, vv = vn, dc = dd;
        const int sn = (ss + 1 < CS) ? (ss + 1) : 0;
        const int s = c * CS + sn;
        const int tn = dir ? (T - 1 - s) : s;
        const size_t nb = hb + (size_t)tn * (H * HEAD);
        kk = bf2f(k[nb]);
        vn = bf2f(v[nb]);
        dd = d[nb];

        PD *= dc;
        sbuf[p][0][lane] = kc;
        sbuf[p][1][lane] = dc;
        asm volatile("s_waitcnt lgkmcnt(0)" ::: "memory");
        const float* __restrict__ sk = sbuf[p][0];
        const float* __restrict__ sd = sbuf[p][1];
#pragma unroll
        for (int jj = 0; jj < 64; jj += 4) {
            const float4 k4 = *reinterpret_cast<const float4*>(&sk[jj]);
            const float4 d4 = *reinterpret_cast<const float4*>(&sd[jj]);
            S[jj + 0] = fmaf(d4.x, S[jj + 0], k4.x * vv);
            S[jj + 1] = fmaf(d4.y, S[jj + 1], k4.y * vv);
            S[jj + 2] = fmaf(d4.z, S[jj + 2], k4.z * vv);
            S[jj + 3] = fmaf(d4.w, S[jj + 3], k4.w * vv);
        }
        p ^= 1;
    }
    const size_t mb = (size_t)uc * 4096 + lane;
#pragma unroll
    for (int j = 0; j < 64; ++j) M[mb + j * 64] = f2bf(S[j]);
    D[(size_t)uc * 64 + lane] = PD;
}

// pass2 (parallel): 1024 threads/unit, thread owns 4 state elements; only the
// 8-chunk loop is serial. No barriers.
__global__ __launch_bounds__(1024) void wkv_pass2(ushort* __restrict__ M,
                                                  const float* __restrict__ D)
{
    const int unit = blockIdx.x;
    const int tid = threadIdx.x;          // 1024
    const int j = tid >> 4;               // state row (decay index)
    float S0 = 0.f, S1 = 0.f, S2 = 0.f, S3 = 0.f;
#pragma unroll
    for (int c = 0; c < NCH; ++c) {
        const int uc = unit * NCH + c;
        const float Dj = D[(size_t)uc * 64 + j];
        ushort* mp = M + (size_t)uc * 4096 + tid * 4;
        const uint2 mv = *reinterpret_cast<const uint2*>(mp);
        const float m0 = bf2f((ushort)(mv.x & 0xffff));
        const float m1 = bf2f((ushort)(mv.x >> 16));
        const float m2 = bf2f((ushort)(mv.y & 0xffff));
        const float m3 = bf2f((ushort)(mv.y >> 16));
        uint2 sv;
        sv.x = (uint32_t)f2bf(S0) | ((uint32_t)f2bf(S1) << 16);
        sv.y = (uint32_t)f2bf(S2) | ((uint32_t)f2bf(S3) << 16);
        *reinterpret_cast<uint2*>(mp) = sv;
        S0 = fmaf(Dj, S0, m0);
        S1 = fmaf(Dj, S1, m1);
        S2 = fmaf(Dj, S2, m2);
        S3 = fmaf(Dj, S3, m3);
    }
}

__global__ __launch_bounds__(64) void wkv_pass3(const ushort* __restrict__ r,
                                                const ushort* __restrict__ k,
                                                const ushort* __restrict__ v,
                                                const float* __restrict__ d,
                                                const ushort* __restrict__ Sin,
                                                float* __restrict__ yf,
                                                float* __restrict__ yb)
{
    const int uc = blockIdx.x;
    const int c = uc & (NCH - 1), unit = uc >> 3;
    const int dir = unit & 1, bh = unit >> 1;
    const int lane = threadIdx.x;
    const size_t hb = ((size_t)(bh >> 4) * T * H + (bh & 15)) * HEAD + lane;
    __shared__ __align__(16) float sbuf[2][3][64];

    float S[64];
    const size_t mb = (size_t)uc * 4096 + lane;
#pragma unroll
    for (int j = 0; j < 64; ++j) S[j] = bf2f(Sin[mb + j * 64]);
    float* __restrict__ yo = dir ? yb : yf;

    int s0 = c * CS;
    int t0 = dir ? (T - 1 - s0) : s0;
    size_t pb = hb + (size_t)t0 * (H * HEAD);
    float rr = bf2f(r[pb]);
    float kk = bf2f(k[pb]);
    float vn = bf2f(v[pb]);
    float dd = d[pb];

    int p = 0;
    for (int ss = 0; ss < CS; ++ss) {
        const int s = c * CS + ss;
        const int t = dir ? (T - 1 - s) : s;
        const size_t ob = hb + (size_t)t * (H * HEAD);
        const float rc = rr, kc = kk, vv = vn, dc = dd;

        const int sn2 = (ss + 1 < CS) ? (ss + 1) : 0;
        const int s2 = c * CS + sn2;
        const int tn = dir ? (T - 1 - s2) : s2;
        const size_t nb = hb + (size_t)tn * (H * HEAD);
        rr = bf2f(r[nb]);
        kk = bf2f(k[nb]);
        vn = bf2f(v[nb]);
        dd = d[nb];

        sbuf[p][0][lane] = rc;
        sbuf[p][1][lane] = kc;
        sbuf[p][2][lane] = dc;
        asm volatile("s_waitcnt lgkmcnt(0)" ::: "memory");
        const float* __restrict__ sr = sbuf[p][0];
        const float* __restrict__ sk = sbuf[p][1];
        const float* __restrict__ sd = sbuf[p][2];
        float y0 = 0.f, y1 = 0.f, y2 = 0.f, y3 = 0.f;
#pragma unroll
        for (int jj = 0; jj < 64; jj += 4) {
            const float4 r4 = *reinterpret_cast<const float4*>(&sr[jj]);
            const float4 k4 = *reinterpret_cast<const float4*>(&sk[jj]);
            const float4 d4 = *reinterpret_cast<const float4*>(&sd[jj]);
            y0 = fmaf(r4.x, S[jj + 0], y0);
            S[jj + 0] = fmaf(d4.x, S[jj + 0], k4.x * vv);
            y1 = fmaf(r4.y, S[jj + 1], y1);
            S[jj + 1] = fmaf(d4.y, S[jj + 1], k4.y * vv);
            y2 = fmaf(r4.z, S[jj + 2], y2);
            S[jj + 2] = fmaf(d4.z, S[jj + 2], k4.z * vv);
            y3 = fmaf(r4.w, S[jj + 3], y3);
            S[jj + 3] = fmaf(d4.w, S[jj + 3], k4.w * vv);
        }
        yo[ob] = (y0 + y1) + (y2 + y3);
        p ^= 1;
    }
}

// ======== pipelined bf16 MFMA GEMM core: BM=128, BK=64, BN in {64,128} ========
template <int BN>
struct GemmLds {
    ushort As[2][128 * 64];
    ushort Bs[2][BN * 64];
};

template <int BN>
__device__ __forceinline__ void gemm_body(const ushort* __restrict__ A,
                                          const ushort* __restrict__ Bt,
                                          int bm, int bn, int K,
                                          GemmLds<BN>& lds,
                                          floatx4 (&acc)[4][BN / 32])
{
    constexpr int NF = BN / 32;
    const int tid = threadIdx.x;
    const int wid = tid >> 6, lane = tid & 63;
    const int wr = wid >> 1, wc = wid & 1;
    const int l15 = lane & 15, lhi = lane >> 4;
    const int NT = K >> 6;

    auto stage = [&](int buf, int k0) {
#pragma unroll
        for (int p = 0; p < 4; ++p) {
            const int lin = p * 256 + tid;
            const int row = lin >> 3;
            const int cs = (lin & 7) ^ (row & 7);
            gload16(A + (size_t)(bm + row) * K + k0 + cs * 8, &lds.As[buf][lin * 8]);
        }
#pragma unroll
        for (int p = 0; p < NF; ++p) {
            const int lin = p * 256 + tid;
            const int n = lin >> 3;
            const int cs = (lin & 7) ^ (n & 7);
            gload16(Bt + (size_t)(bn + n) * K + k0 + cs * 8, &lds.Bs[buf][lin * 8]);
        }
    };

    stage(0, 0);
    __syncthreads();
    for (int t = 0; t < NT; ++t) {
        const int cur = t & 1;
        if (t + 1 < NT) stage(cur ^ 1, (t + 1) << 6);

        short8 af[4][2];
#pragma unroll
        for (int m = 0; m < 4; ++m) {
            const int row = wr * 64 + m * 16 + l15;
#pragma unroll
            for (int s = 0; s < 2; ++s) {
                const int cc = (s * 4 + lhi) ^ (row & 7);
                af[m][s] = *(const short8*)&lds.As[cur][row * 64 + cc * 8];
            }
        }
        short8 bf[NF][2];
#pragma unroll
        for (int n = 0; n < NF; ++n) {
            const int col = wc * (BN / 2) + n * 16 + l15;
#pragma unroll
            for (int s = 0; s < 2; ++s) {
                const int cc = (s * 4 + lhi) ^ (col & 7);
                bf[n][s] = *(const short8*)&lds.Bs[cur][col * 64 + cc * 8];
            }
        }
#pragma unroll
        for (int m = 0; m < 4; ++m)
#pragma unroll
            for (int n = 0; n < NF; ++n) {
                acc[m][n] = __builtin_amdgcn_mfma_f32_16x16x32_bf16(af[m][0], bf[n][0], acc[m][n], 0, 0, 0);
                acc[m][n] = __builtin_amdgcn_mfma_f32_16x16x32_bf16(af[m][1], bf[n][1], acc[m][n], 0, 0, 0);
            }
        __syncthreads();
    }
}

template <int BN, int EPI>
__global__ __launch_bounds__(256) void bgemm_kernel(const ushort* __restrict__ A,
                                                    const ushort* __restrict__ Bt,
                                                    void* __restrict__ Cm,
                                                    int M, int N, int K,
                                                    const float* __restrict__ aux1,
                                                    const float* __restrict__ aux2)
{
    constexpr int NF = BN / 32;
    __shared__ GemmLds<BN> lds;
    int w = blockIdx.y * gridDim.x + blockIdx.x;
    const int nwg = gridDim.x * gridDim.y;
    if ((nwg & 7) == 0) w = (w & 7) * (nwg >> 3) + (w >> 3);   // XCD swizzle
    const int bn = (w % gridDim.x) * BN;
    const int bm = (w / gridDim.x) * 128;
    const int tid = threadIdx.x;
    const int wid = tid >> 6, lane = tid & 63;
    const int wr = wid >> 1, wc = wid & 1;
    const int l15 = lane & 15, lhi = lane >> 4;

    floatx4 acc[4][NF];
#pragma unroll
    for (int m = 0; m < 4; ++m)
#pragma unroll
        for (int n = 0; n < NF; ++n) acc[m][n] = (floatx4){0.f, 0.f, 0.f, 0.f};

    gemm_body<BN>(A, Bt, bm, bn, K, lds, acc);

#pragma unroll
    for (int m = 0; m < 4; ++m) {
        const int row0 = bm + wr * 64 + m * 16 + lhi * 4;
#pragma unroll
        for (int n = 0; n < NF; ++n) {
            const int col = bn + wc * (BN / 2) + n * 16 + l15;
            if (col >= N) continue;
#pragma unroll
            for (int j = 0; j < 4; ++j) {
                const size_t oi = (size_t)(row0 + j) * N + col;
                const float a = acc[m][n][j];
                if constexpr (EPI == BEPI_NONE_BF) {
                    ((ushort*)Cm)[oi] = f2bf(a);
                } else if constexpr (EPI == BEPI_SILU_BF) {
                    ((ushort*)Cm)[oi] = f2bf(a / (1.f + __expf(-a)));
                } else if constexpr (EPI == BEPI_RELUSQ_BF) {
                    const float t = fmaxf(a, 0.f);
                    ((ushort*)Cm)[oi] = f2bf(t * t);
                } else if constexpr (EPI == BEPI_NONE_F) {
                    ((float*)Cm)[oi] = a;
                } else if constexpr (EPI == BEPI_RES_F) {
                    ((float*)Cm)[oi] = aux1[oi] + a;
                } else if constexpr (EPI == BEPI_SIGRES_F) {
                    ((float*)Cm)[oi] = aux1[oi] + aux2[oi] / (1.f + __expf(-a));
                } else if constexpr (EPI == BEPI_TANH_F) {
                    ((float*)Cm)[oi] = tanhf(a);
                } else if constexpr (EPI == BEPI_TANH_BF) {
                    ((ushort*)Cm)[oi] = f2bf(tanhf(a));
                } else {  // BEPI_DECAY_F
                    ((float*)Cm)[oi] = __expf(-__expf(a + aux1[col]));
                }
            }
        }
    }
}

// -------- batched QKVG GEMM (BN=128): blockIdx.z selects {k,v,r,g} --------
struct QkvgArgs { const ushort* A[4]; ushort* O[4]; };
__global__ __launch_bounds__(256) void qkvg_kernel(QkvgArgs args,
                                                   const ushort* __restrict__ Wt)
{
    __shared__ GemmLds<128> lds;
    const int z = blockIdx.z;
    int w = blockIdx.y * gridDim.x + blockIdx.x;          // 8 x 16 grid = 128
    w = (w & 7) * 16 + (w >> 3);                           // XCD swizzle
    const int bn = (w & 7) * 128;
    const int bm = (w >> 3) * 128;
    const int tid = threadIdx.x;
    const int wid = tid >> 6, lane = tid & 63;
    const int wr = wid >> 1, wc = wid & 1;
    const int l15 = lane & 15, lhi = lane >> 4;

    floatx4 acc[4][4];
#pragma unroll
    for (int m = 0; m < 4; ++m)
#pragma unroll
        for (int n = 0; n < 4; ++n) acc[m][n] = (floatx4){0.f, 0.f, 0.f, 0.f};

    gemm_body<128>(args.A[z], Wt + (size_t)z * C * C, bm, bn, C, lds, acc);

    ushort* __restrict__ O = args.O[z];
    const bool silu = (z == 3);
#pragma unroll
    for (int m = 0; m < 4; ++m) {
        const int row0 = bm + wr * 64 + m * 16 + lhi * 4;
#pragma unroll
        for (int n = 0; n < 4; ++n) {
            const int col = bn + wc * 64 + n * 16 + l15;
#pragma unroll
            for (int j = 0; j < 4; ++j) {
                float a = acc[m][n][j];
                if (silu) a = a / (1.f + __expf(-a));
                O[(size_t)(row0 + j) * C + col] = f2bf(a);
            }
        }
    }
}

// ---------------- launch ----------------
extern "C" void kernel_launch(void* const* d_in, const int* in_sizes, int n_in,
                              void* d_out, int out_size, void* d_ws, size_t ws_size,
                              hipStream_t stream)
{
    const float* x        = (const float*)d_in[0];
    const float* ln1_g    = (const float*)d_in[1];
    const float* ln1_b    = (const float*)d_in[2];
    const float* ln2_g    = (const float*)d_in[3];
    const float* ln2_b    = (const float*)d_in[4];
    const float* maa_x    = (const float*)d_in[5];
    const float* maa_w    = (const float*)d_in[6];
    const float* maa_k    = (const float*)d_in[7];
    const float* maa_v    = (const float*)d_in[8];
    const float* maa_r    = (const float*)d_in[9];
    const float* maa_g    = (const float*)d_in[10];
    const float* maa_w1   = (const float*)d_in[11];
    const float* maa_w2   = (const float*)d_in[12];
    const float* time_dec = (const float*)d_in[13];
    const float* tdw1     = (const float*)d_in[14];
    const float* tdw2     = (const float*)d_in[15];
    const float* u        = (const float*)d_in[16];
    const float* Wr       = (const float*)d_in[17];
    const float* Wk       = (const float*)d_in[18];
    const float* Wv       = (const float*)d_in[19];
    const float* Wg       = (const float*)d_in[20];
    const float* Wo       = (const float*)d_in[21];
    const float* lnx_g    = (const float*)d_in[22];
    const float* lnx_b    = (const float*)d_in[23];
    const float* cmaa_k   = (const float*)d_in[24];
    const float* cmaa_r   = (const float*)d_in[25];
    const float* Wck      = (const float*)d_in[26];
    const float* Wcv      = (const float*)d_in[27];
    const float* Wcr      = (const float*)d_in[28];
    float* out = (float*)d_out;

    // -------- workspace layout (~63 MB) --------
    float* fws = (float*)d_ws;
    const size_t E = (size_t)BT * C;            // 2,097,152
    float* xa  = fws + 0 * E;                   // xa -> yf ; (FFN) kk low half
    float* xx  = fws + 1 * E;                   // xx -> yb -> cxx ; kk high half
    float* wd  = fws + 2 * E;                   // decay d -> xc
    float* fs  = fws + 3 * E;                   // xvb/xrb (mix) ; M low ; kv
    ushort* wBuf = (ushort*)(fws + 4 * E);      // 4M ushort: weights / M high
    ushort* Mbuf = (ushort*)fs;                 // 2048*4096 bf16 = fs..wBuf (16MB)
    ushort* bf1  = wBuf + (size_t)C * FF;       // E: mixax out / xkb / ck_in
    ushort* rb   = bf1 + E;                     // r
    ushort* kb   = rb + E;                      // k
    ushort* vb   = kb + E;                      // v  -> ya
    ushort* gb   = vb + E;                      // g  -> cr_in
    ushort* t1b  = gb + E;                      // BT*64 bf16
    float* a5    = (float*)(t1b + (size_t)BT * 64);   // BT*160 f32
    float* sig   = a5 + (size_t)BT * 160;       // BT*16 f32
    float* Dbuf  = sig + (size_t)BT * H;        // 2048*64 f32
    ushort* xvb  = (ushort*)fs;                 // E (mix v input)
    ushort* xrb  = (ushort*)fs + E;             // E (mix r input)
    ushort* xgb  = (ushort*)out;                // E (mix g input; out is scratch)
    ushort* xwb  = (ushort*)out + E;            // E (mix w input)
    ushort* kk   = (ushort*)xa;                 // BT*FF bf16 == xa..xx

    const dim3 blk(256);
    const dim3 tblk(32, 8);
    const int EW = (BT * C) / 256;
    const dim3 gNN(C / 64, BT / 128);

    // ---- attention branch ----
    ln_kernel<<<BT, blk, 0, stream>>>(x, ln1_g, ln1_b, xa);
    bshift_kernel<<<EW, blk, 0, stream>>>(xa, xx);
    mixaxbf_kernel<<<EW, blk, 0, stream>>>(xa, xx, maa_x, bf1);
    wconv_kernel<<<dim3(160 / 32, C / 32), tblk, 0, stream>>>(maa_w1, wBuf, C, 160);
    bgemm_kernel<64, BEPI_TANH_F><<<dim3(3, BT / 128), blk, 0, stream>>>(bf1, wBuf, a5, BT, 160, C, nullptr, nullptr);

    // all 5 mixes in one launch
    Mix5Args margs;
    margs.maa[0] = maa_w; margs.maa[1] = maa_k; margs.maa[2] = maa_v;
    margs.maa[3] = maa_r; margs.maa[4] = maa_g;
    margs.out[0] = xwb; margs.out[1] = bf1; margs.out[2] = xvb;
    margs.out[3] = xrb; margs.out[4] = xgb;
    mix5b_kernel<<<dim3(BT, 5), blk, 0, stream>>>(xa, xx, a5, maa_w2, margs);

    // w path: tanh(xw@tdw1) -> decay d = exp(-exp(@tdw2 + time_decay))
    wconv_kernel<<<dim3(64 / 32, C / 32), tblk, 0, stream>>>(tdw1, wBuf, C, 64);
    bgemm_kernel<64, BEPI_TANH_BF><<<dim3(1, BT / 128), blk, 0, stream>>>(xwb, wBuf, t1b, BT, 64, C, nullptr, nullptr);
    wconv_kernel<<<dim3(C / 32, 64 / 32), tblk, 0, stream>>>(tdw2, wBuf, 64, C);
    bgemm_kernel<64, BEPI_DECAY_F><<<gNN, blk, 0, stream>>>(t1b, wBuf, wd, BT, C, 64, time_dec, nullptr);

    // batched QKVG
    Wconv4Args wargs;
    wargs.W[0] = Wk; wargs.W[1] = Wv; wargs.W[2] = Wr; wargs.W[3] = Wg;
    wconv4_kernel<<<dim3(C / 32, C / 32, 4), tblk, 0, stream>>>(wargs, wBuf);
    QkvgArgs qargs;
    qargs.A[0] = bf1; qargs.A[1] = xvb; qargs.A[2] = xrb; qargs.A[3] = xgb;
    qargs.O[0] = kb;  qargs.O[1] = vb;  qargs.O[2] = rb;  qargs.O[3] = gb;
    qkvg_kernel<<<dim3(8, 16, 4), blk, 0, stream>>>(qargs, wBuf);

    // u-bonus scalar + chunked bidirectional WKV (Mbuf overlays fs+wBuf)
    sigma_kernel<<<BT, blk, 0, stream>>>(rb, kb, u, sig);
    wkv_pass1<<<dim3(2 * B * H * NCH), dim3(64), 0, stream>>>(kb, vb, wd, Mbuf, Dbuf);
    wkv_pass2<<<dim3(2 * B * H), dim3(1024), 0, stream>>>(Mbuf, Dbuf);
    wkv_pass3<<<dim3(2 * B * H * NCH), dim3(64), 0, stream>>>(rb, kb, vb, wd, Mbuf, xa, xx);

    // ya = groupnorm(yf+yb+sig*v)*g ; out = x + ya @ Wo^T
    gnmul_kernel<<<BT, dim3(1024), 0, stream>>>(xa, xx, lnx_g, lnx_b, gb, vb, sig, vb);
    wconv_kernel<<<dim3(C / 32, C / 32), tblk, 0, stream>>>(Wo, wBuf, C, C);
    bgemm_kernel<64, BEPI_RES_F><<<gNN, blk, 0, stream>>>(vb, wBuf, out, BT, C, C, x, nullptr);

    // ---- FFN branch ----
    ln_kernel<<<BT, blk, 0, stream>>>(out, ln2_g, ln2_b, wd);
    bshift_kernel<<<EW, blk, 0, stream>>>(wd, xx);
    cmix_kernel<<<EW, blk, 0, stream>>>(wd, xx, cmaa_k, cmaa_r, bf1, gb);
    wconv_kernel<<<dim3(FF / 32, C / 32), tblk, 0, stream>>>(Wck, wBuf, C, FF);
    bgemm_kernel<128, BEPI_RELUSQ_BF><<<dim3(FF / 128, BT / 128), blk, 0, stream>>>(bf1, wBuf, kk, BT, FF, C, nullptr, nullptr);
    wconv_kernel<<<dim3(C / 32, FF / 32), tblk, 0, stream>>>(Wcv, wBuf, FF, C);
    bgemm_kernel<64, BEPI_NONE_F><<<gNN, blk, 0, stream>>>(kk, wBuf, fs, BT, C, FF, nullptr, nullptr);
    wconv_kernel<<<dim3(C / 32, C / 32), tblk, 0, stream>>>(Wcr, wBuf, C, C);
    bgemm_kernel<64, BEPI_SIGRES_F><<<gNN, blk, 0, stream>>>(gb, wBuf, out, BT, C, C, out, fs);

    (void)in_sizes; (void)n_in; (void)out_size; (void)ws_size;
}

// Round 8
// 335.984 us; speedup vs baseline: 4.2928x; 1.1087x over previous
//
#include <hip/hip_runtime.h>
#include <math.h>
#include <stdint.h>

static constexpr int B  = 8;
static constexpr int T  = 256;
static constexpr int C  = 1024;
static constexpr int H  = 16;
static constexpr int HEAD = 64;
static constexpr int FF = 4096;
static constexpr int BT = B * T;
static constexpr int NCH = 8;       // time chunks
static constexpr int CS  = 32;      // chunk size (NCH*CS == T)

typedef short short8  __attribute__((ext_vector_type(8)));
typedef float floatx4 __attribute__((ext_vector_type(4)));

// ---------------- bf16 helpers ----------------
__device__ __forceinline__ float bf2f(ushort u) {
    return __uint_as_float(((uint32_t)u) << 16);
}
__device__ __forceinline__ ushort f2bf(float x) {
    uint32_t u = __float_as_uint(x);
    u += 0x7fff + ((u >> 16) & 1);          // RNE
    return (ushort)(u >> 16);
}

__device__ __forceinline__ void gload16(const void* g, void* l) {
    __builtin_amdgcn_global_load_lds(
        (const __attribute__((address_space(1))) unsigned int*)g,
        (__attribute__((address_space(3))) unsigned int*)l, 16, 0, 0);
}

// ---------------- epilogue ids ----------------
#define BEPI_NONE_BF   0
#define BEPI_SILU_BF   1
#define BEPI_RELUSQ_BF 2
#define BEPI_NONE_F    3
#define BEPI_RES_F     4
#define BEPI_SIGRES_F  5
#define BEPI_TANH_F    6
#define BEPI_TANH_BF   7
#define BEPI_DECAY_F   8

// ---------------- LayerNorm ----------------
__global__ __launch_bounds__(256) void ln_kernel(const float* __restrict__ x,
                                                 const float* __restrict__ g,
                                                 const float* __restrict__ b,
                                                 float* __restrict__ out)
{
    const int row = blockIdx.x;
    const int tid = threadIdx.x;
    const float4 v = reinterpret_cast<const float4*>(x + (size_t)row * C)[tid];
    float s = v.x + v.y + v.z + v.w;
#pragma unroll
    for (int off = 32; off > 0; off >>= 1) s += __shfl_xor(s, off);
    __shared__ float red[8];
    const int wave = tid >> 6, lane = tid & 63;
    if (lane == 0) red[wave] = s;
    __syncthreads();
    const float mean = (red[0] + red[1] + red[2] + red[3]) * (1.0f / C);
    const float d0 = v.x - mean, d1 = v.y - mean, d2 = v.z - mean, d3 = v.w - mean;
    float q = d0 * d0 + d1 * d1 + d2 * d2 + d3 * d3;
#pragma unroll
    for (int off = 32; off > 0; off >>= 1) q += __shfl_xor(q, off);
    if (lane == 0) red[4 + wave] = q;
    __syncthreads();
    const float var = (red[4] + red[5] + red[6] + red[7]) * (1.0f / C);
    const float rstd = rsqrtf(var + 1e-5f);
    const int c = tid * 4;
    float4 o;
    o.x = d0 * rstd * g[c + 0] + b[c + 0];
    o.y = d1 * rstd * g[c + 1] + b[c + 1];
    o.z = d2 * rstd * g[c + 2] + b[c + 2];
    o.w = d3 * rstd * g[c + 3] + b[c + 3];
    reinterpret_cast<float4*>(out + (size_t)row * C)[tid] = o;
}

// ---- fused bshift+mixax: xx = bshift(xa)-xa (f32), ax = bf16(xa + xx*maa) ----
__global__ __launch_bounds__(256) void bshiftmix_kernel(const float* __restrict__ xa,
                                                        const float* __restrict__ maa,
                                                        float* __restrict__ xx,
                                                        ushort* __restrict__ ax)
{
    const int i = blockIdx.x * 256 + threadIdx.x;
    const int c = i & (C - 1);
    const int bt = i >> 10;
    const int t = bt & (T - 1);
    const int j = c & (HEAD - 1);
    float src = 0.f;
    if (j < HEAD / 2) { if (t > 0)     src = xa[i - C]; }
    else              { if (t < T - 1) src = xa[i + C]; }
    const float a = xa[i];
    const float xv = src - a;
    xx[i] = xv;
    ax[i] = f2bf(a + xv * maa[c]);
}

// ---- plain bshift (FFN side) ----
__global__ __launch_bounds__(256) void bshift_kernel(const float* __restrict__ xa,
                                                     float* __restrict__ xx)
{
    const int i = blockIdx.x * 256 + threadIdx.x;
    const int c = i & (C - 1);
    const int bt = i >> 10;
    const int t = bt & (T - 1);
    const int j = c & (HEAD - 1);
    float src = 0.f;
    if (j < HEAD / 2) { if (t > 0)     src = xa[i - C]; }
    else              { if (t < T - 1) src = xa[i + C]; }
    xx[i] = src - xa[i];
}

// -------- cmix --------
__global__ __launch_bounds__(256) void cmix_kernel(const float* __restrict__ xc,
                                                   const float* __restrict__ cxx,
                                                   const float* __restrict__ mk,
                                                   const float* __restrict__ mr,
                                                   ushort* __restrict__ ok,
                                                   ushort* __restrict__ orr)
{
    const int i = blockIdx.x * 256 + threadIdx.x;
    const int c = i & (C - 1);
    const float a = xc[i], d = cxx[i];
    ok[i]  = f2bf(a + d * mk[c]);
    orr[i] = f2bf(a + d * mr[c]);
}

// -------- sigma --------
__global__ __launch_bounds__(256) void sigma_kernel(const ushort* __restrict__ r,
                                                    const ushort* __restrict__ k,
                                                    const float* __restrict__ u,
                                                    float* __restrict__ sig)
{
    const int bt = blockIdx.x;
    const int tid = threadIdx.x;
    const int c0 = tid * 4;
    const size_t base = (size_t)bt * C + c0;
    const uint2 rv = *reinterpret_cast<const uint2*>(r + base);
    const uint2 kv = *reinterpret_cast<const uint2*>(k + base);
    float p = 0.f;
    p += bf2f((ushort)(rv.x & 0xffff)) * bf2f((ushort)(kv.x & 0xffff)) * u[c0 + 0];
    p += bf2f((ushort)(rv.x >> 16))    * bf2f((ushort)(kv.x >> 16))    * u[c0 + 1];
    p += bf2f((ushort)(rv.y & 0xffff)) * bf2f((ushort)(kv.y & 0xffff)) * u[c0 + 2];
    p += bf2f((ushort)(rv.y >> 16))    * bf2f((ushort)(kv.y >> 16))    * u[c0 + 3];
    p += __shfl_xor(p, 1);
    p += __shfl_xor(p, 2);
    p += __shfl_xor(p, 4);
    p += __shfl_xor(p, 8);
    if ((tid & 15) == 0) sig[(size_t)bt * H + (tid >> 4)] = p;
}

// -------- GroupNorm --------
__global__ __launch_bounds__(1024) void gnmul_kernel(const float* __restrict__ yf,
                                                     const float* __restrict__ yb,
                                                     const float* __restrict__ g,
                                                     const float* __restrict__ b,
                                                     const ushort* __restrict__ gate,
                                                     const ushort* __restrict__ vin,
                                                     const float* __restrict__ sig,
                                                     ushort* __restrict__ out)
{
    const int row = blockIdx.x;
    const int tid = threadIdx.x;
    const size_t idx = (size_t)row * C + tid;
    const float sg = sig[(size_t)row * H + (tid >> 6)];
    const float v = yf[idx] + yb[idx] + sg * bf2f(vin[idx]);
    float s = v;
#pragma unroll
    for (int off = 32; off > 0; off >>= 1) s += __shfl_xor(s, off);
    const float m = s * (1.0f / HEAD);
    const float d = v - m;
    float q = d * d;
#pragma unroll
    for (int off = 32; off > 0; off >>= 1) q += __shfl_xor(q, off);
    const float rstd = rsqrtf(q * (1.0f / HEAD) + 6.4e-4f);
    out[idx] = f2bf((d * rstd * g[tid] + b[tid]) * bf2f(gate[idx]));
}

// -------- weight convert+transpose: W[Kd,Nd] f32 -> Wt[Nd,Kd] bf16 --------
__global__ __launch_bounds__(256) void wconv_kernel(const float* __restrict__ W,
                                                    ushort* __restrict__ Wt,
                                                    int Kd, int Nd)
{
    __shared__ float tile[32][33];
    const int n0 = blockIdx.x * 32, k0 = blockIdx.y * 32;
    const int tx = threadIdx.x, ty = threadIdx.y;
#pragma unroll
    for (int i = 0; i < 4; ++i)
        tile[ty * 4 + i][tx] = W[(size_t)(k0 + ty * 4 + i) * Nd + n0 + tx];
    __syncthreads();
#pragma unroll
    for (int i = 0; i < 4; ++i)
        Wt[(size_t)(n0 + ty * 4 + i) * Kd + k0 + tx] = f2bf(tile[tx][ty * 4 + i]);
}

// -------- batched wconv: 4 C x C weights (blockIdx.z) --------
struct Wconv4Args { const float* W[4]; };
__global__ __launch_bounds__(256) void wconv4_kernel(Wconv4Args args, ushort* __restrict__ Wt)
{
    __shared__ float tile[32][33];
    const int z = blockIdx.z;
    const float* __restrict__ W = args.W[z];
    ushort* __restrict__ dst = Wt + (size_t)z * C * C;
    const int n0 = blockIdx.x * 32, k0 = blockIdx.y * 32;
    const int tx = threadIdx.x, ty = threadIdx.y;
#pragma unroll
    for (int i = 0; i < 4; ++i)
        tile[ty * 4 + i][tx] = W[(size_t)(k0 + ty * 4 + i) * C + n0 + tx];
    __syncthreads();
#pragma unroll
    for (int i = 0; i < 4; ++i)
        dst[(size_t)(n0 + ty * 4 + i) * C + k0 + tx] = f2bf(tile[tx][ty * 4 + i]);
}

// ======== mix5 as fused MFMA GEMM: out_f = bf16(xa + xx*(maa_f + a5b@w2t_f)) ====
// K=32 single step. grid (C/64, BT/128, 5). Slot-XOR LDS layout (round-2 proven).
struct Mix5Args { const float* maa[5]; ushort* out[5]; };
__global__ __launch_bounds__(256) void mix5m_kernel(const ushort* __restrict__ a5b,
                                                    const ushort* __restrict__ w2t,
                                                    const float* __restrict__ xa,
                                                    const float* __restrict__ xx,
                                                    Mix5Args args)
{
    __shared__ __align__(16) ushort As[128 * 32];
    __shared__ __align__(16) ushort Bs[64 * 32];
    const int f = blockIdx.z;
    const int bm = blockIdx.y * 128, bn = blockIdx.x * 64;
    const int tid = threadIdx.x;
    const int wid = tid >> 6, lane = tid & 63;
    const int wr = wid >> 1, wc = wid & 1;
    const int l15 = lane & 15, lhi = lane >> 4;

    // stage A: 128 rows x 32 bf16 from a5b[BT,160] (f-slice), 2 passes
#pragma unroll
    for (int p = 0; p < 2; ++p) {
        const int lin = p * 256 + tid;
        const int row = lin >> 2;
        const int sp = (lin & 3) ^ ((row >> 1) & 3);
        gload16(a5b + (size_t)(bm + row) * 160 + f * 32 + sp * 8, &As[lin * 8]);
    }
    // stage B: 64 rows x 32 bf16 from w2t[f][C][32]
    {
        const int lin = tid;
        const int n = lin >> 2;
        const int sp = (lin & 3) ^ ((n >> 1) & 3);
        gload16(w2t + ((size_t)f * C + bn + n) * 32 + sp * 8, &Bs[lin * 8]);
    }
    __syncthreads();

    short8 af[4], bfr[2];
#pragma unroll
    for (int m = 0; m < 4; ++m) {
        const int row = wr * 64 + m * 16 + l15;
        const int sp = lhi ^ ((row >> 1) & 3);
        af[m] = *(const short8*)&As[row * 32 + sp * 8];
    }
#pragma unroll
    for (int n = 0; n < 2; ++n) {
        const int col = wc * 32 + n * 16 + l15;
        const int sp = lhi ^ ((col >> 1) & 3);
        bfr[n] = *(const short8*)&Bs[col * 32 + sp * 8];
    }
    floatx4 acc[4][2];
#pragma unroll
    for (int m = 0; m < 4; ++m)
#pragma unroll
        for (int n = 0; n < 2; ++n)
            acc[m][n] = __builtin_amdgcn_mfma_f32_16x16x32_bf16(
                af[m], bfr[n], (floatx4){0.f, 0.f, 0.f, 0.f}, 0, 0, 0);

    const float* __restrict__ maa = args.maa[f];
    ushort* __restrict__ out = args.out[f];
#pragma unroll
    for (int m = 0; m < 4; ++m) {
        const int row0 = bm + wr * 64 + m * 16 + lhi * 4;
#pragma unroll
        for (int n = 0; n < 2; ++n) {
            const int col = bn + wc * 32 + n * 16 + l15;
            const float mc = maa[col];
#pragma unroll
            for (int j = 0; j < 4; ++j) {
                const size_t oi = (size_t)(row0 + j) * C + col;
                out[oi] = f2bf(xa[oi] + xx[oi] * (mc + acc[m][n][j]));
            }
        }
    }
}

// ================== chunked bidirectional WKV6 ==================
__global__ __launch_bounds__(64) void wkv_pass1(const ushort* __restrict__ k,
                                                const ushort* __restrict__ v,
                                                const float* __restrict__ d,
                                                ushort* __restrict__ M,
                                                float* __restrict__ D)
{
    const int uc = blockIdx.x;
    const int c = uc & (NCH - 1), unit = uc >> 3;
    const int dir = unit & 1, bh = unit >> 1;
    const int lane = threadIdx.x;
    const size_t hb = ((size_t)(bh >> 4) * T * H + (bh & 15)) * HEAD + lane;
    __shared__ __align__(16) float sbuf[2][2][64];

    float S[64];
#pragma unroll
    for (int j = 0; j < 64; ++j) S[j] = 0.f;
    float PD = 1.f;

    int s0 = c * CS;
    int t0 = dir ? (T - 1 - s0) : s0;
    size_t pb = hb + (size_t)t0 * (H * HEAD);
    float kk = bf2f(k[pb]);
    float vn = bf2f(v[pb]);
    float dd = d[pb];

    int p = 0;
    for (int ss = 0; ss < CS; ++ss) {
        const float kc = kk, vv = vn, dc = dd;
        const int sn = (ss + 1 < CS) ? (ss + 1) : 0;
        const int s = c * CS + sn;
        const int tn = dir ? (T - 1 - s) : s;
        const size_t nb = hb + (size_t)tn * (H * HEAD);
        kk = bf2f(k[nb]);
        vn = bf2f(v[nb]);
        dd = d[nb];

        PD *= dc;
        sbuf[p][0][lane] = kc;
        sbuf[p][1][lane] = dc;
        asm volatile("s_waitcnt lgkmcnt(0)" ::: "memory");
        const float* __restrict__ sk = sbuf[p][0];
        const float* __restrict__ sd = sbuf[p][1];
#pragma unroll
        for (int jj = 0; jj < 64; jj += 4) {
            const float4 k4 = *reinterpret_cast<const float4*>(&sk[jj]);
            const float4 d4 = *reinterpret_cast<const float4*>(&sd[jj]);
            S[jj + 0] = fmaf(d4.x, S[jj + 0], k4.x * vv);
            S[jj + 1] = fmaf(d4.y, S[jj + 1], k4.y * vv);
            S[jj + 2] = fmaf(d4.z, S[jj + 2], k4.z * vv);
            S[jj + 3] = fmaf(d4.w, S[jj + 3], k4.w * vv);
        }
        p ^= 1;
    }
    const size_t mb = (size_t)uc * 4096 + lane;
#pragma unroll
    for (int j = 0; j < 64; ++j) M[mb + j * 64] = f2bf(S[j]);
    D[(size_t)uc * 64 + lane] = PD;
}

// pass2 (parallel): 1024 threads/unit, thread owns 4 state elements
__global__ __launch_bounds__(1024) void wkv_pass2(ushort* __restrict__ M,
                                                  const float* __restrict__ D)
{
    const int unit = blockIdx.x;
    const int tid = threadIdx.x;
    const int j = tid >> 4;
    float S0 = 0.f, S1 = 0.f, S2 = 0.f, S3 = 0.f;
#pragma unroll
    for (int c = 0; c < NCH; ++c) {
        const int uc = unit * NCH + c;
        const float Dj = D[(size_t)uc * 64 + j];
        ushort* mp = M + (size_t)uc * 4096 + tid * 4;
        const uint2 mv = *reinterpret_cast<const uint2*>(mp);
        const float m0 = bf2f((ushort)(mv.x & 0xffff));
        const float m1 = bf2f((ushort)(mv.x >> 16));
        const float m2 = bf2f((ushort)(mv.y & 0xffff));
        const float m3 = bf2f((ushort)(mv.y >> 16));
        uint2 sv;
        sv.x = (uint32_t)f2bf(S0) | ((uint32_t)f2bf(S1) << 16);
        sv.y = (uint32_t)f2bf(S2) | ((uint32_t)f2bf(S3) << 16);
        *reinterpret_cast<uint2*>(mp) = sv;
        S0 = fmaf(Dj, S0, m0);
        S1 = fmaf(Dj, S1, m1);
        S2 = fmaf(Dj, S2, m2);
        S3 = fmaf(Dj, S3, m3);
    }
}

__global__ __launch_bounds__(64) void wkv_pass3(const ushort* __restrict__ r,
                                                const ushort* __restrict__ k,
                                                const ushort* __restrict__ v,
                                                const float* __restrict__ d,
                                                const ushort* __restrict__ Sin,
                                                float* __restrict__ yf,
                                                float* __restrict__ yb)
{
    const int uc = blockIdx.x;
    const int c = uc & (NCH - 1), unit = uc >> 3;
    const int dir = unit & 1, bh = unit >> 1;
    const int lane = threadIdx.x;
    const size_t hb = ((size_t)(bh >> 4) * T * H + (bh & 15)) * HEAD + lane;
    __shared__ __align__(16) float sbuf[2][3][64];

    float S[64];
    const size_t mb = (size_t)uc * 4096 + lane;
#pragma unroll
    for (int j = 0; j < 64; ++j) S[j] = bf2f(Sin[mb + j * 64]);
    float* __restrict__ yo = dir ? yb : yf;

    int s0 = c * CS;
    int t0 = dir ? (T - 1 - s0) : s0;
    size_t pb = hb + (size_t)t0 * (H * HEAD);
    float rr = bf2f(r[pb]);
    float kk = bf2f(k[pb]);
    float vn = bf2f(v[pb]);
    float dd = d[pb];

    int p = 0;
    for (int ss = 0; ss < CS; ++ss) {
        const int s = c * CS + ss;
        const int t = dir ? (T - 1 - s) : s;
        const size_t ob = hb + (size_t)t * (H * HEAD);
        const float rc = rr, kc = kk, vv = vn, dc = dd;

        const int sn2 = (ss + 1 < CS) ? (ss + 1) : 0;
        const int s2 = c * CS + sn2;
        const int tn = dir ? (T - 1 - s2) : s2;
        const size_t nb = hb + (size_t)tn * (H * HEAD);
        rr = bf2f(r[nb]);
        kk = bf2f(k[nb]);
        vn = bf2f(v[nb]);
        dd = d[nb];

        sbuf[p][0][lane] = rc;
        sbuf[p][1][lane] = kc;
        sbuf[p][2][lane] = dc;
        asm volatile("s_waitcnt lgkmcnt(0)" ::: "memory");
        const float* __restrict__ sr = sbuf[p][0];
        const float* __restrict__ sk = sbuf[p][1];
        const float* __restrict__ sd = sbuf[p][2];
        float y0 = 0.f, y1 = 0.f, y2 = 0.f, y3 = 0.f;
#pragma unroll
        for (int jj = 0; jj < 64; jj += 4) {
            const float4 r4 = *reinterpret_cast<const float4*>(&sr[jj]);
            const float4 k4 = *reinterpret_cast<const float4*>(&sk[jj]);
            const float4 d4 = *reinterpret_cast<const float4*>(&sd[jj]);
            y0 = fmaf(r4.x, S[jj + 0], y0);
            S[jj + 0] = fmaf(d4.x, S[jj + 0], k4.x * vv);
            y1 = fmaf(r4.y, S[jj + 1], y1);
            S[jj + 1] = fmaf(d4.y, S[jj + 1], k4.y * vv);
            y2 = fmaf(r4.z, S[jj + 2], y2);
            S[jj + 2] = fmaf(d4.z, S[jj + 2], k4.z * vv);
            y3 = fmaf(r4.w, S[jj + 3], y3);
            S[jj + 3] = fmaf(d4.w, S[jj + 3], k4.w * vv);
        }
        yo[ob] = (y0 + y1) + (y2 + y3);
        p ^= 1;
    }
}

// ======== pipelined bf16 MFMA GEMM core: BM=128, BK=64, BN in {64,128} ========
template <int BN>
struct GemmLds {
    ushort As[2][128 * 64];
    ushort Bs[2][BN * 64];
};

template <int BN>
__device__ __forceinline__ void gemm_body(const ushort* __restrict__ A,
                                          const ushort* __restrict__ Bt,
                                          int bm, int bn, int K,
                                          GemmLds<BN>& lds,
                                          floatx4 (&acc)[4][BN / 32])
{
    constexpr int NF = BN / 32;
    const int tid = threadIdx.x;
    const int wid = tid >> 6, lane = tid & 63;
    const int wr = wid >> 1, wc = wid & 1;
    const int l15 = lane & 15, lhi = lane >> 4;
    const int NT = K >> 6;

    auto stage = [&](int buf, int k0) {
#pragma unroll
        for (int p = 0; p < 4; ++p) {
            const int lin = p * 256 + tid;
            const int row = lin >> 3;
            const int cs = (lin & 7) ^ (row & 7);
            gload16(A + (size_t)(bm + row) * K + k0 + cs * 8, &lds.As[buf][lin * 8]);
        }
#pragma unroll
        for (int p = 0; p < NF; ++p) {
            const int lin = p * 256 + tid;
            const int n = lin >> 3;
            const int cs = (lin & 7) ^ (n & 7);
            gload16(Bt + (size_t)(bn + n) * K + k0 + cs * 8, &lds.Bs[buf][lin * 8]);
        }
    };

    stage(0, 0);
    __syncthreads();
    for (int t = 0; t < NT; ++t) {
        const int cur = t & 1;
        if (t + 1 < NT) stage(cur ^ 1, (t + 1) << 6);

        short8 af[4][2];
#pragma unroll
        for (int m = 0; m < 4; ++m) {
            const int row = wr * 64 + m * 16 + l15;
#pragma unroll
            for (int s = 0; s < 2; ++s) {
                const int cc = (s * 4 + lhi) ^ (row & 7);
                af[m][s] = *(const short8*)&lds.As[cur][row * 64 + cc * 8];
            }
        }
        short8 bf[NF][2];
#pragma unroll
        for (int n = 0; n < NF; ++n) {
            const int col = wc * (BN / 2) + n * 16 + l15;
#pragma unroll
            for (int s = 0; s < 2; ++s) {
                const int cc = (s * 4 + lhi) ^ (col & 7);
                bf[n][s] = *(const short8*)&lds.Bs[cur][col * 64 + cc * 8];
            }
        }
#pragma unroll
        for (int m = 0; m < 4; ++m)
#pragma unroll
            for (int n = 0; n < NF; ++n) {
                acc[m][n] = __builtin_amdgcn_mfma_f32_16x16x32_bf16(af[m][0], bf[n][0], acc[m][n], 0, 0, 0);
                acc[m][n] = __builtin_amdgcn_mfma_f32_16x16x32_bf16(af[m][1], bf[n][1], acc[m][n], 0, 0, 0);
            }
        __syncthreads();
    }
}

template <int BN, int EPI>
__global__ __launch_bounds__(256) void bgemm_kernel(const ushort* __restrict__ A,
                                                    const ushort* __restrict__ Bt,
                                                    void* __restrict__ Cm,
                                                    int M, int N, int K,
                                                    const float* __restrict__ aux1,
                                                    const float* __restrict__ aux2)
{
    constexpr int NF = BN / 32;
    __shared__ GemmLds<BN> lds;
    int w = blockIdx.y * gridDim.x + blockIdx.x;
    const int nwg = gridDim.x * gridDim.y;
    if ((nwg & 7) == 0) w = (w & 7) * (nwg >> 3) + (w >> 3);   // XCD swizzle
    const int bn = (w % gridDim.x) * BN;
    const int bm = (w / gridDim.x) * 128;
    const int tid = threadIdx.x;
    const int wid = tid >> 6, lane = tid & 63;
    const int wr = wid >> 1, wc = wid & 1;
    const int l15 = lane & 15, lhi = lane >> 4;

    floatx4 acc[4][NF];
#pragma unroll
    for (int m = 0; m < 4; ++m)
#pragma unroll
        for (int n = 0; n < NF; ++n) acc[m][n] = (floatx4){0.f, 0.f, 0.f, 0.f};

    gemm_body<BN>(A, Bt, bm, bn, K, lds, acc);

#pragma unroll
    for (int m = 0; m < 4; ++m) {
        const int row0 = bm + wr * 64 + m * 16 + lhi * 4;
#pragma unroll
        for (int n = 0; n < NF; ++n) {
            const int col = bn + wc * (BN / 2) + n * 16 + l15;
            if (col >= N) continue;
#pragma unroll
            for (int j = 0; j < 4; ++j) {
                const size_t oi = (size_t)(row0 + j) * N + col;
                const float a = acc[m][n][j];
                if constexpr (EPI == BEPI_NONE_BF) {
                    ((ushort*)Cm)[oi] = f2bf(a);
                } else if constexpr (EPI == BEPI_SILU_BF) {
                    ((ushort*)Cm)[oi] = f2bf(a / (1.f + __expf(-a)));
                } else if constexpr (EPI == BEPI_RELUSQ_BF) {
                    const float t = fmaxf(a, 0.f);
                    ((ushort*)Cm)[oi] = f2bf(t * t);
                } else if constexpr (EPI == BEPI_NONE_F) {
                    ((float*)Cm)[oi] = a;
                } else if constexpr (EPI == BEPI_RES_F) {
                    ((float*)Cm)[oi] = aux1[oi] + a;
                } else if constexpr (EPI == BEPI_SIGRES_F) {
                    ((float*)Cm)[oi] = aux1[oi] + aux2[oi] / (1.f + __expf(-a));
                } else if constexpr (EPI == BEPI_TANH_F) {
                    ((float*)Cm)[oi] = tanhf(a);
                } else if constexpr (EPI == BEPI_TANH_BF) {
                    ((ushort*)Cm)[oi] = f2bf(tanhf(a));
                } else {  // BEPI_DECAY_F
                    ((float*)Cm)[oi] = __expf(-__expf(a + aux1[col]));
                }
            }
        }
    }
}

// -------- batched QKVG GEMM (BN=128): blockIdx.z selects {k,v,r,g} --------
struct QkvgArgs { const ushort* A[4]; ushort* O[4]; };
__global__ __launch_bounds__(256) void qkvg_kernel(QkvgArgs args,
                                                   const ushort* __restrict__ Wt)
{
    __shared__ GemmLds<128> lds;
    const int z = blockIdx.z;
    int w = blockIdx.y * gridDim.x + blockIdx.x;          // 8 x 16 grid = 128
    w = (w & 7) * 16 + (w >> 3);                           // XCD swizzle
    const int bn = (w & 7) * 128;
    const int bm = (w >> 3) * 128;
    const int tid = threadIdx.x;
    const int wid = tid >> 6, lane = tid & 63;
    const int wr = wid >> 1, wc = wid & 1;
    const int l15 = lane & 15, lhi = lane >> 4;

    floatx4 acc[4][4];
#pragma unroll
    for (int m = 0; m < 4; ++m)
#pragma unroll
        for (int n = 0; n < 4; ++n) acc[m][n] = (floatx4){0.f, 0.f, 0.f, 0.f};

    gemm_body<128>(args.A[z], Wt + (size_t)z * C * C, bm, bn, C, lds, acc);

    ushort* __restrict__ O = args.O[z];
    const bool silu = (z == 3);
#pragma unroll
    for (int m = 0; m < 4; ++m) {
        const int row0 = bm + wr * 64 + m * 16 + lhi * 4;
#pragma unroll
        for (int n = 0; n < 4; ++n) {
            const int col = bn + wc * 64 + n * 16 + l15;
#pragma unroll
            for (int j = 0; j < 4; ++j) {
                float a = acc[m][n][j];
                if (silu) a = a / (1.f + __expf(-a));
                O[(size_t)(row0 + j) * C + col] = f2bf(a);
            }
        }
    }
}

// ---------------- launch ----------------
extern "C" void kernel_launch(void* const* d_in, const int* in_sizes, int n_in,
                              void* d_out, int out_size, void* d_ws, size_t ws_size,
                              hipStream_t stream)
{
    const float* x        = (const float*)d_in[0];
    const float* ln1_g    = (const float*)d_in[1];
    const float* ln1_b    = (const float*)d_in[2];
    const float* ln2_g    = (const float*)d_in[3];
    const float* ln2_b    = (const float*)d_in[4];
    const float* maa_x    = (const float*)d_in[5];
    const float* maa_w    = (const float*)d_in[6];
    const float* maa_k    = (const float*)d_in[7];
    const float* maa_v    = (const float*)d_in[8];
    const float* maa_r    = (const float*)d_in[9];
    const float* maa_g    = (const float*)d_in[10];
    const float* maa_w1   = (const float*)d_in[11];
    const float* maa_w2   = (const float*)d_in[12];
    const float* time_dec = (const float*)d_in[13];
    const float* tdw1     = (const float*)d_in[14];
    const float* tdw2     = (const float*)d_in[15];
    const float* u        = (const float*)d_in[16];
    const float* Wr       = (const float*)d_in[17];
    const float* Wk       = (const float*)d_in[18];
    const float* Wv       = (const float*)d_in[19];
    const float* Wg       = (const float*)d_in[20];
    const float* Wo       = (const float*)d_in[21];
    const float* lnx_g    = (const float*)d_in[22];
    const float* lnx_b    = (const float*)d_in[23];
    const float* cmaa_k   = (const float*)d_in[24];
    const float* cmaa_r   = (const float*)d_in[25];
    const float* Wck      = (const float*)d_in[26];
    const float* Wcv      = (const float*)d_in[27];
    const float* Wcr      = (const float*)d_in[28];
    float* out = (float*)d_out;

    // -------- workspace layout (~63 MB) --------
    float* fws = (float*)d_ws;
    const size_t E = (size_t)BT * C;            // 2,097,152
    float* xa  = fws + 0 * E;                   // xa -> yf ; (FFN) kk low half
    float* xx  = fws + 1 * E;                   // xx -> yb -> cxx ; kk high half
    float* wd  = fws + 2 * E;                   // decay d -> xc
    float* fs  = fws + 3 * E;                   // xvb/xrb (mix) ; M low ; kv
    ushort* wBuf = (ushort*)(fws + 4 * E);      // 4M ushort: weights / M high
    ushort* Mbuf = (ushort*)fs;                 // 2048*4096 bf16 = fs..wBuf (16MB)
    ushort* w2t  = wBuf + (size_t)C * 160;      // 5*C*32 bf16 (after maa_w1t)
    ushort* bf1  = wBuf + (size_t)C * FF;       // E: ax / xkb / ck_in
    ushort* rb   = bf1 + E;                     // r
    ushort* kb   = rb + E;                      // k
    ushort* vb   = kb + E;                      // v  -> ya
    ushort* gb   = vb + E;                      // g  -> cr_in
    ushort* t1b  = gb + E;                      // BT*64 bf16
    float* a5    = (float*)(t1b + (size_t)BT * 64);   // BT*160 (a5b bf16 inside)
    float* sig   = a5 + (size_t)BT * 160;       // BT*16 f32
    float* Dbuf  = sig + (size_t)BT * H;        // 2048*64 f32
    ushort* a5b  = (ushort*)a5;                 // BT*160 bf16
    ushort* xvb  = (ushort*)fs;                 // E (mix v input)
    ushort* xrb  = (ushort*)fs + E;             // E (mix r input)
    ushort* xgb  = (ushort*)out;                // E (mix g input; out is scratch)
    ushort* xwb  = (ushort*)out + E;            // E (mix w input)
    ushort* kk   = (ushort*)xa;                 // BT*FF bf16 == xa..xx

    const dim3 blk(256);
    const dim3 tblk(32, 8);
    const int EW = (BT * C) / 256;
    const dim3 gNN(C / 64, BT / 128);

    // ---- attention branch ----
    ln_kernel<<<BT, blk, 0, stream>>>(x, ln1_g, ln1_b, xa);
    bshiftmix_kernel<<<EW, blk, 0, stream>>>(xa, maa_x, xx, bf1);
    wconv_kernel<<<dim3(160 / 32, C / 32), tblk, 0, stream>>>(maa_w1, wBuf, C, 160);
    bgemm_kernel<64, BEPI_TANH_BF><<<dim3(3, BT / 128), blk, 0, stream>>>(bf1, wBuf, a5b, BT, 160, C, nullptr, nullptr);

    // w2 slices -> [5][C][32] bf16 transposed
    for (int f = 0; f < 5; ++f)
        wconv_kernel<<<dim3(C / 32, 1), tblk, 0, stream>>>(maa_w2 + (size_t)f * 32 * C, w2t + (size_t)f * C * 32, 32, C);

    // all 5 mixes as one fused MFMA GEMM launch
    Mix5Args margs;
    margs.maa[0] = maa_w; margs.maa[1] = maa_k; margs.maa[2] = maa_v;
    margs.maa[3] = maa_r; margs.maa[4] = maa_g;
    margs.out[0] = xwb; margs.out[1] = bf1; margs.out[2] = xvb;
    margs.out[3] = xrb; margs.out[4] = xgb;
    mix5m_kernel<<<dim3(C / 64, BT / 128, 5), blk, 0, stream>>>(a5b, w2t, xa, xx, margs);

    // w path: tanh(xw@tdw1) -> decay d = exp(-exp(@tdw2 + time_decay))
    wconv_kernel<<<dim3(64 / 32, C / 32), tblk, 0, stream>>>(tdw1, wBuf, C, 64);
    bgemm_kernel<64, BEPI_TANH_BF><<<dim3(1, BT / 128), blk, 0, stream>>>(xwb, wBuf, t1b, BT, 64, C, nullptr, nullptr);
    wconv_kernel<<<dim3(C / 32, 64 / 32), tblk, 0, stream>>>(tdw2, wBuf, 64, C);
    bgemm_kernel<64, BEPI_DECAY_F><<<gNN, blk, 0, stream>>>(t1b, wBuf, wd, BT, C, 64, time_dec, nullptr);

    // batched QKVG
    Wconv4Args wargs;
    wargs.W[0] = Wk; wargs.W[1] = Wv; wargs.W[2] = Wr; wargs.W[3] = Wg;
    wconv4_kernel<<<dim3(C / 32, C / 32, 4), tblk, 0, stream>>>(wargs, wBuf);
    QkvgArgs qargs;
    qargs.A[0] = bf1; qargs.A[1] = xvb; qargs.A[2] = xrb; qargs.A[3] = xgb;
    qargs.O[0] = kb;  qargs.O[1] = vb;  qargs.O[2] = rb;  qargs.O[3] = gb;
    qkvg_kernel<<<dim3(8, 16, 4), blk, 0, stream>>>(qargs, wBuf);

    // u-bonus scalar + chunked bidirectional WKV (Mbuf overlays fs+wBuf)
    sigma_kernel<<<BT, blk, 0, stream>>>(rb, kb, u, sig);
    wkv_pass1<<<dim3(2 * B * H * NCH), dim3(64), 0, stream>>>(kb, vb, wd, Mbuf, Dbuf);
    wkv_pass2<<<dim3(2 * B * H), dim3(1024), 0, stream>>>(Mbuf, Dbuf);
    wkv_pass3<<<dim3(2 * B * H * NCH), dim3(64), 0, stream>>>(rb, kb, vb, wd, Mbuf, xa, xx);

    // ya = groupnorm(yf+yb+sig*v)*g ; out = x + ya @ Wo^T
    gnmul_kernel<<<BT, dim3(1024), 0, stream>>>(xa, xx, lnx_g, lnx_b, gb, vb, sig, vb);
    wconv_kernel<<<dim3(C / 32, C / 32), tblk, 0, stream>>>(Wo, wBuf, C, C);
    bgemm_kernel<64, BEPI_RES_F><<<gNN, blk, 0, stream>>>(vb, wBuf, out, BT, C, C, x, nullptr);

    // ---- FFN branch ----
    ln_kernel<<<BT, blk, 0, stream>>>(out, ln2_g, ln2_b, wd);
    bshift_kernel<<<EW, blk, 0, stream>>>(wd, xx);
    cmix_kernel<<<EW, blk, 0, stream>>>(wd, xx, cmaa_k, cmaa_r, bf1, gb);
    wconv_kernel<<<dim3(FF / 32, C / 32), tblk, 0, stream>>>(Wck, wBuf, C, FF);
    bgemm_kernel<128, BEPI_RELUSQ_BF><<<dim3(FF / 128, BT / 128), blk, 0, stream>>>(bf1, wBuf, kk, BT, FF, C, nullptr, nullptr);
    wconv_kernel<<<dim3(C / 32, FF / 32), tblk, 0, stream>>>(Wcv, wBuf, FF, C);
    bgemm_kernel<64, BEPI_NONE_F><<<gNN, blk, 0, stream>>>(kk, wBuf, fs, BT, C, FF, nullptr, nullptr);
    wconv_kernel<<<dim3(C / 32, C / 32), tblk, 0, stream>>>(Wcr, wBuf, C, C);
    bgemm_kernel<64, BEPI_SIGRES_F><<<gNN, blk, 0, stream>>>(gb, wBuf, out, BT, C, C, out, fs);

    (void)in_sizes; (void)n_in; (void)out_size; (void)ws_size;
}

// Round 9
// 318.586 us; speedup vs baseline: 4.5272x; 1.0546x over previous
//
#include <hip/hip_runtime.h>
#include <math.h>
#include <stdint.h>

static constexpr int B  = 8;
static constexpr int T  = 256;
static constexpr int C  = 1024;
static constexpr int H  = 16;
static constexpr int HEAD = 64;
static constexpr int FF = 4096;
static constexpr int BT = B * T;
static constexpr int NCH = 8;       // time chunks
static constexpr int CS  = 32;      // chunk size (NCH*CS == T)

typedef short short8  __attribute__((ext_vector_type(8)));
typedef float floatx4 __attribute__((ext_vector_type(4)));

// ---------------- bf16 helpers ----------------
__device__ __forceinline__ float bf2f(ushort u) {
    return __uint_as_float(((uint32_t)u) << 16);
}
__device__ __forceinline__ ushort f2bf(float x) {
    uint32_t u = __float_as_uint(x);
    u += 0x7fff + ((u >> 16) & 1);          // RNE
    return (ushort)(u >> 16);
}

__device__ __forceinline__ void gload16(const void* g, void* l) {
    __builtin_amdgcn_global_load_lds(
        (const __attribute__((address_space(1))) unsigned int*)g,
        (__attribute__((address_space(3))) unsigned int*)l, 16, 0, 0);
}

// ---------------- epilogue ids ----------------
#define BEPI_NONE_BF   0
#define BEPI_SILU_BF   1
#define BEPI_RELUSQ_BF 2
#define BEPI_NONE_F    3
#define BEPI_RES_F     4
#define BEPI_SIGRES_F  5
#define BEPI_TANH_F    6
#define BEPI_TANH_BF   7
#define BEPI_DECAY_F   8

// ---------------- LayerNorm ----------------
__global__ __launch_bounds__(256) void ln_kernel(const float* __restrict__ x,
                                                 const float* __restrict__ g,
                                                 const float* __restrict__ b,
                                                 float* __restrict__ out)
{
    const int row = blockIdx.x;
    const int tid = threadIdx.x;
    const float4 v = reinterpret_cast<const float4*>(x + (size_t)row * C)[tid];
    float s = v.x + v.y + v.z + v.w;
#pragma unroll
    for (int off = 32; off > 0; off >>= 1) s += __shfl_xor(s, off);
    __shared__ float red[8];
    const int wave = tid >> 6, lane = tid & 63;
    if (lane == 0) red[wave] = s;
    __syncthreads();
    const float mean = (red[0] + red[1] + red[2] + red[3]) * (1.0f / C);
    const float d0 = v.x - mean, d1 = v.y - mean, d2 = v.z - mean, d3 = v.w - mean;
    float q = d0 * d0 + d1 * d1 + d2 * d2 + d3 * d3;
#pragma unroll
    for (int off = 32; off > 0; off >>= 1) q += __shfl_xor(q, off);
    if (lane == 0) red[4 + wave] = q;
    __syncthreads();
    const float var = (red[4] + red[5] + red[6] + red[7]) * (1.0f / C);
    const float rstd = rsqrtf(var + 1e-5f);
    const int c = tid * 4;
    float4 o;
    o.x = d0 * rstd * g[c + 0] + b[c + 0];
    o.y = d1 * rstd * g[c + 1] + b[c + 1];
    o.z = d2 * rstd * g[c + 2] + b[c + 2];
    o.w = d3 * rstd * g[c + 3] + b[c + 3];
    reinterpret_cast<float4*>(out + (size_t)row * C)[tid] = o;
}

// ---- fused bshift+mixax: xx = bshift(xa)-xa (f32), ax = bf16(xa + xx*maa) ----
__global__ __launch_bounds__(256) void bshiftmix_kernel(const float* __restrict__ xa,
                                                        const float* __restrict__ maa,
                                                        float* __restrict__ xx,
                                                        ushort* __restrict__ ax)
{
    const int i = blockIdx.x * 256 + threadIdx.x;
    const int c = i & (C - 1);
    const int bt = i >> 10;
    const int t = bt & (T - 1);
    const int j = c & (HEAD - 1);
    float src = 0.f;
    if (j < HEAD / 2) { if (t > 0)     src = xa[i - C]; }
    else              { if (t < T - 1) src = xa[i + C]; }
    const float a = xa[i];
    const float xv = src - a;
    xx[i] = xv;
    ax[i] = f2bf(a + xv * maa[c]);
}

// ---- plain bshift (FFN side) ----
__global__ __launch_bounds__(256) void bshift_kernel(const float* __restrict__ xa,
                                                     float* __restrict__ xx)
{
    const int i = blockIdx.x * 256 + threadIdx.x;
    const int c = i & (C - 1);
    const int bt = i >> 10;
    const int t = bt & (T - 1);
    const int j = c & (HEAD - 1);
    float src = 0.f;
    if (j < HEAD / 2) { if (t > 0)     src = xa[i - C]; }
    else              { if (t < T - 1) src = xa[i + C]; }
    xx[i] = src - xa[i];
}

// -------- cmix --------
__global__ __launch_bounds__(256) void cmix_kernel(const float* __restrict__ xc,
                                                   const float* __restrict__ cxx,
                                                   const float* __restrict__ mk,
                                                   const float* __restrict__ mr,
                                                   ushort* __restrict__ ok,
                                                   ushort* __restrict__ orr)
{
    const int i = blockIdx.x * 256 + threadIdx.x;
    const int c = i & (C - 1);
    const float a = xc[i], d = cxx[i];
    ok[i]  = f2bf(a + d * mk[c]);
    orr[i] = f2bf(a + d * mr[c]);
}

// -------- GroupNorm over (4 bf16 y-partials + fused u-bonus), * gate ---------
__global__ __launch_bounds__(1024) void gnmul_kernel(const ushort* __restrict__ yp,
                                                     const float* __restrict__ g,
                                                     const float* __restrict__ b,
                                                     const ushort* __restrict__ gate,
                                                     const ushort* __restrict__ vin,
                                                     const ushort* __restrict__ rbuf,
                                                     const ushort* __restrict__ kbuf,
                                                     const float* __restrict__ u,
                                                     ushort* __restrict__ out)
{
    const int row = blockIdx.x;
    const int tid = threadIdx.x;                 // wave == head
    const size_t idx = (size_t)row * C + tid;
    const size_t E2 = (size_t)BT * C;
    // u-bonus scalar: sg = sum_j r_j*u_j*k_j over this head
    float p = bf2f(rbuf[idx]) * bf2f(kbuf[idx]) * u[tid];
#pragma unroll
    for (int off = 32; off > 0; off >>= 1) p += __shfl_xor(p, off);
    const float v = bf2f(yp[idx]) + bf2f(yp[E2 + idx]) +
                    bf2f(yp[2 * E2 + idx]) + bf2f(yp[3 * E2 + idx]) +
                    p * bf2f(vin[idx]);
    float s = v;
#pragma unroll
    for (int off = 32; off > 0; off >>= 1) s += __shfl_xor(s, off);
    const float m = s * (1.0f / HEAD);
    const float d = v - m;
    float q = d * d;
#pragma unroll
    for (int off = 32; off > 0; off >>= 1) q += __shfl_xor(q, off);
    const float rstd = rsqrtf(q * (1.0f / HEAD) + 6.4e-4f);
    out[idx] = f2bf((d * rstd * g[tid] + b[tid]) * bf2f(gate[idx]));
}

// -------- weight convert+transpose: W[Kd,Nd] f32 -> Wt[Nd,Kd] bf16 --------
__global__ __launch_bounds__(256) void wconv_kernel(const float* __restrict__ W,
                                                    ushort* __restrict__ Wt,
                                                    int Kd, int Nd)
{
    __shared__ float tile[32][33];
    const int n0 = blockIdx.x * 32, k0 = blockIdx.y * 32;
    const int tx = threadIdx.x, ty = threadIdx.y;
#pragma unroll
    for (int i = 0; i < 4; ++i)
        tile[ty * 4 + i][tx] = W[(size_t)(k0 + ty * 4 + i) * Nd + n0 + tx];
    __syncthreads();
#pragma unroll
    for (int i = 0; i < 4; ++i)
        Wt[(size_t)(n0 + ty * 4 + i) * Kd + k0 + tx] = f2bf(tile[tx][ty * 4 + i]);
}

// -------- w2 slices: w2[5][32][C] -> w2t[5][C][32] bf16, one launch --------
__global__ __launch_bounds__(256) void w2conv_kernel(const float* __restrict__ w2,
                                                     ushort* __restrict__ w2t)
{
    __shared__ float tile[32][33];
    const int f = blockIdx.y;
    const int n0 = blockIdx.x * 32;
    const int tx = threadIdx.x, ty = threadIdx.y;
#pragma unroll
    for (int i = 0; i < 4; ++i)
        tile[ty * 4 + i][tx] = w2[(size_t)f * 32 * C + (size_t)(ty * 4 + i) * C + n0 + tx];
    __syncthreads();
#pragma unroll
    for (int i = 0; i < 4; ++i)
        w2t[(size_t)f * C * 32 + (size_t)(n0 + ty * 4 + i) * 32 + tx] = f2bf(tile[tx][ty * 4 + i]);
}

// -------- batched wconv: 4 C x C weights (blockIdx.z) --------
struct Wconv4Args { const float* W[4]; };
__global__ __launch_bounds__(256) void wconv4_kernel(Wconv4Args args, ushort* __restrict__ Wt)
{
    __shared__ float tile[32][33];
    const int z = blockIdx.z;
    const float* __restrict__ W = args.W[z];
    ushort* __restrict__ dst = Wt + (size_t)z * C * C;
    const int n0 = blockIdx.x * 32, k0 = blockIdx.y * 32;
    const int tx = threadIdx.x, ty = threadIdx.y;
#pragma unroll
    for (int i = 0; i < 4; ++i)
        tile[ty * 4 + i][tx] = W[(size_t)(k0 + ty * 4 + i) * C + n0 + tx];
    __syncthreads();
#pragma unroll
    for (int i = 0; i < 4; ++i)
        dst[(size_t)(n0 + ty * 4 + i) * C + k0 + tx] = f2bf(tile[tx][ty * 4 + i]);
}

// ======== mix5 as fused MFMA GEMM: out_f = bf16(xa + xx*(maa_f + a5b@w2t_f)) ====
struct Mix5Args { const float* maa[5]; ushort* out[5]; };
__global__ __launch_bounds__(256) void mix5m_kernel(const ushort* __restrict__ a5b,
                                                    const ushort* __restrict__ w2t,
                                                    const float* __restrict__ xa,
                                                    const float* __restrict__ xx,
                                                    Mix5Args args)
{
    __shared__ __align__(16) ushort As[128 * 32];
    __shared__ __align__(16) ushort Bs[64 * 32];
    const int f = blockIdx.z;
    const int bm = blockIdx.y * 128, bn = blockIdx.x * 64;
    const int tid = threadIdx.x;
    const int wid = tid >> 6, lane = tid & 63;
    const int wr = wid >> 1, wc = wid & 1;
    const int l15 = lane & 15, lhi = lane >> 4;

#pragma unroll
    for (int p = 0; p < 2; ++p) {
        const int lin = p * 256 + tid;
        const int row = lin >> 2;
        const int sp = (lin & 3) ^ ((row >> 1) & 3);
        gload16(a5b + (size_t)(bm + row) * 160 + f * 32 + sp * 8, &As[lin * 8]);
    }
    {
        const int lin = tid;
        const int n = lin >> 2;
        const int sp = (lin & 3) ^ ((n >> 1) & 3);
        gload16(w2t + ((size_t)f * C + bn + n) * 32 + sp * 8, &Bs[lin * 8]);
    }
    __syncthreads();

    short8 af[4], bfr[2];
#pragma unroll
    for (int m = 0; m < 4; ++m) {
        const int row = wr * 64 + m * 16 + l15;
        const int sp = lhi ^ ((row >> 1) & 3);
        af[m] = *(const short8*)&As[row * 32 + sp * 8];
    }
#pragma unroll
    for (int n = 0; n < 2; ++n) {
        const int col = wc * 32 + n * 16 + l15;
        const int sp = lhi ^ ((col >> 1) & 3);
        bfr[n] = *(const short8*)&Bs[col * 32 + sp * 8];
    }
    floatx4 acc[4][2];
#pragma unroll
    for (int m = 0; m < 4; ++m)
#pragma unroll
        for (int n = 0; n < 2; ++n)
            acc[m][n] = __builtin_amdgcn_mfma_f32_16x16x32_bf16(
                af[m], bfr[n], (floatx4){0.f, 0.f, 0.f, 0.f}, 0, 0, 0);

    const float* __restrict__ maa = args.maa[f];
    ushort* __restrict__ out = args.out[f];
#pragma unroll
    for (int m = 0; m < 4; ++m) {
        const int row0 = bm + wr * 64 + m * 16 + lhi * 4;
#pragma unroll
        for (int n = 0; n < 2; ++n) {
            const int col = bn + wc * 32 + n * 16 + l15;
            const float mc = maa[col];
#pragma unroll
            for (int j = 0; j < 4; ++j) {
                const size_t oi = (size_t)(row0 + j) * C + col;
                out[oi] = f2bf(xa[oi] + xx[oi] * (mc + acc[m][n][j]));
            }
        }
    }
}

// ================== chunked bidirectional WKV6, 2-way j-split ==================
// block = 1 wave; bidx = uc*2 + jh; wave owns state rows j in [jh*32, jh*32+32)
__global__ __launch_bounds__(64) void wkv_pass1(const ushort* __restrict__ k,
                                                const ushort* __restrict__ v,
                                                const float* __restrict__ d,
                                                ushort* __restrict__ M,
                                                float* __restrict__ D)
{
    const int bidx = blockIdx.x;
    const int jh = bidx & 1;
    const int uc = bidx >> 1;
    const int c = uc & (NCH - 1), unit = uc >> 3;
    const int dir = unit & 1, bh = unit >> 1;
    const int lane = threadIdx.x;
    const int jl = lane & 31;
    const size_t rowb = ((size_t)(bh >> 4) * T * H + (bh & 15)) * HEAD;
    __shared__ __align__(16) float sbuf[2][2][32];

    float S[32];
#pragma unroll
    for (int j = 0; j < 32; ++j) S[j] = 0.f;
    float PD = 1.f;

    const int s0 = c * CS;
    const int t0 = dir ? (T - 1 - s0) : s0;
    const size_t pb = rowb + (size_t)t0 * (H * HEAD);
    float vn = bf2f(v[pb + lane]);
    float kk = bf2f(k[pb + jh * 32 + jl]);
    float dd = d[pb + jh * 32 + jl];

    int p = 0;
    for (int ss = 0; ss < CS; ++ss) {
        const float kc = kk, vv = vn, dc = dd;
        const int sn = (ss + 1 < CS) ? (ss + 1) : 0;
        const int s = c * CS + sn;
        const int tn = dir ? (T - 1 - s) : s;
        const size_t nb = rowb + (size_t)tn * (H * HEAD);
        vn = bf2f(v[nb + lane]);
        kk = bf2f(k[nb + jh * 32 + jl]);
        dd = d[nb + jh * 32 + jl];

        if (lane < 32) {
            PD *= dc;
            sbuf[p][0][lane] = kc;
            sbuf[p][1][lane] = dc;
        }
        asm volatile("s_waitcnt lgkmcnt(0)" ::: "memory");
        const float* __restrict__ sk = sbuf[p][0];
        const float* __restrict__ sd = sbuf[p][1];
#pragma unroll
        for (int jj = 0; jj < 32; jj += 4) {
            const float4 k4 = *reinterpret_cast<const float4*>(&sk[jj]);
            const float4 d4 = *reinterpret_cast<const float4*>(&sd[jj]);
            S[jj + 0] = fmaf(d4.x, S[jj + 0], k4.x * vv);
            S[jj + 1] = fmaf(d4.y, S[jj + 1], k4.y * vv);
            S[jj + 2] = fmaf(d4.z, S[jj + 2], k4.z * vv);
            S[jj + 3] = fmaf(d4.w, S[jj + 3], k4.w * vv);
        }
        p ^= 1;
    }
    const size_t mb = (size_t)uc * 4096 + (size_t)(jh * 32) * 64 + lane;
#pragma unroll
    for (int j = 0; j < 32; ++j) M[mb + j * 64] = f2bf(S[j]);
    if (lane < 32) D[(size_t)uc * 64 + jh * 32 + lane] = PD;
}

// pass2 (parallel): 1024 threads/unit, thread owns 4 state elements
__global__ __launch_bounds__(1024) void wkv_pass2(ushort* __restrict__ M,
                                                  const float* __restrict__ D)
{
    const int unit = blockIdx.x;
    const int tid = threadIdx.x;
    const int j = tid >> 4;
    float S0 = 0.f, S1 = 0.f, S2 = 0.f, S3 = 0.f;
#pragma unroll
    for (int c = 0; c < NCH; ++c) {
        const int uc = unit * NCH + c;
        const float Dj = D[(size_t)uc * 64 + j];
        ushort* mp = M + (size_t)uc * 4096 + tid * 4;
        const uint2 mv = *reinterpret_cast<const uint2*>(mp);
        const float m0 = bf2f((ushort)(mv.x & 0xffff));
        const float m1 = bf2f((ushort)(mv.x >> 16));
        const float m2 = bf2f((ushort)(mv.y & 0xffff));
        const float m3 = bf2f((ushort)(mv.y >> 16));
        uint2 sv;
        sv.x = (uint32_t)f2bf(S0) | ((uint32_t)f2bf(S1) << 16);
        sv.y = (uint32_t)f2bf(S2) | ((uint32_t)f2bf(S3) << 16);
        *reinterpret_cast<uint2*>(mp) = sv;
        S0 = fmaf(Dj, S0, m0);
        S1 = fmaf(Dj, S1, m1);
        S2 = fmaf(Dj, S2, m2);
        S3 = fmaf(Dj, S3, m3);
    }
}

// pass3 (j-split): partial y -> bf16 buffer (dir*2+jh)
__global__ __launch_bounds__(64) void wkv_pass3(const ushort* __restrict__ r,
                                                const ushort* __restrict__ k,
                                                const ushort* __restrict__ v,
                                                const float* __restrict__ d,
                                                const ushort* __restrict__ Sin,
                                                ushort* __restrict__ yp)
{
    const int bidx = blockIdx.x;
    const int jh = bidx & 1;
    const int uc = bidx >> 1;
    const int c = uc & (NCH - 1), unit = uc >> 3;
    const int dir = unit & 1, bh = unit >> 1;
    const int lane = threadIdx.x;
    const int jl = lane & 31;
    const size_t rowb = ((size_t)(bh >> 4) * T * H + (bh & 15)) * HEAD;
    __shared__ __align__(16) float sbuf[2][3][32];

    float S[32];
    const size_t mb = (size_t)uc * 4096 + (size_t)(jh * 32) * 64 + lane;
#pragma unroll
    for (int j = 0; j < 32; ++j) S[j] = bf2f(Sin[mb + j * 64]);
    ushort* __restrict__ yo = yp + (size_t)(dir * 2 + jh) * ((size_t)BT * C);

    const int s0 = c * CS;
    const int t0 = dir ? (T - 1 - s0) : s0;
    const size_t pb = rowb + (size_t)t0 * (H * HEAD);
    float rr = bf2f(r[pb + jh * 32 + jl]);
    float kk = bf2f(k[pb + jh * 32 + jl]);
    float vn = bf2f(v[pb + lane]);
    float dd = d[pb + jh * 32 + jl];

    int p = 0;
    for (int ss = 0; ss < CS; ++ss) {
        const int s = c * CS + ss;
        const int t = dir ? (T - 1 - s) : s;
        const size_t ob = rowb + (size_t)t * (H * HEAD) + lane;
        const float rc = rr, kc = kk, vv = vn, dc = dd;

        const int sn2 = (ss + 1 < CS) ? (ss + 1) : 0;
        const int s2 = c * CS + sn2;
        const int tn = dir ? (T - 1 - s2) : s2;
        const size_t nb = rowb + (size_t)tn * (H * HEAD);
        rr = bf2f(r[nb + jh * 32 + jl]);
        kk = bf2f(k[nb + jh * 32 + jl]);
        vn = bf2f(v[nb + lane]);
        dd = d[nb + jh * 32 + jl];

        if (lane < 32) {
            sbuf[p][0][lane] = rc;
            sbuf[p][1][lane] = kc;
            sbuf[p][2][lane] = dc;
        }
        asm volatile("s_waitcnt lgkmcnt(0)" ::: "memory");
        const float* __restrict__ sr = sbuf[p][0];
        const float* __restrict__ sk = sbuf[p][1];
        const float* __restrict__ sd = sbuf[p][2];
        float y0 = 0.f, y1 = 0.f, y2 = 0.f, y3 = 0.f;
#pragma unroll
        for (int jj = 0; jj < 32; jj += 4) {
            const float4 r4 = *reinterpret_cast<const float4*>(&sr[jj]);
            const float4 k4 = *reinterpret_cast<const float4*>(&sk[jj]);
            const float4 d4 = *reinterpret_cast<const float4*>(&sd[jj]);
            y0 = fmaf(r4.x, S[jj + 0], y0);
            S[jj + 0] = fmaf(d4.x, S[jj + 0], k4.x * vv);
            y1 = fmaf(r4.y, S[jj + 1], y1);
            S[jj + 1] = fmaf(d4.y, S[jj + 1], k4.y * vv);
            y2 = fmaf(r4.z, S[jj + 2], y2);
            S[jj + 2] = fmaf(d4.z, S[jj + 2], k4.z * vv);
            y3 = fmaf(r4.w, S[jj + 3], y3);
            S[jj + 3] = fmaf(d4.w, S[jj + 3], k4.w * vv);
        }
        yo[ob] = f2bf((y0 + y1) + (y2 + y3));
        p ^= 1;
    }
}

// ======== pipelined bf16 MFMA GEMM core: BM=128, BK=64, BN in {64,128} ========
template <int BN>
struct GemmLds {
    ushort As[2][128 * 64];
    ushort Bs[2][BN * 64];
};

template <int BN>
__device__ __forceinline__ void gemm_body(const ushort* __restrict__ A,
                                          const ushort* __restrict__ Bt,
                                          int bm, int bn, int K,
                                          GemmLds<BN>& lds,
                                          floatx4 (&acc)[4][BN / 32])
{
    constexpr int NF = BN / 32;
    const int tid = threadIdx.x;
    const int wid = tid >> 6, lane = tid & 63;
    const int wr = wid >> 1, wc = wid & 1;
    const int l15 = lane & 15, lhi = lane >> 4;
    const int NT = K >> 6;

    auto stage = [&](int buf, int k0) {
#pragma unroll
        for (int p = 0; p < 4; ++p) {
            const int lin = p * 256 + tid;
            const int row = lin >> 3;
            const int cs = (lin & 7) ^ (row & 7);
            gload16(A + (size_t)(bm + row) * K + k0 + cs * 8, &lds.As[buf][lin * 8]);
        }
#pragma unroll
        for (int p = 0; p < NF; ++p) {
            const int lin = p * 256 + tid;
            const int n = lin >> 3;
            const int cs = (lin & 7) ^ (n & 7);
            gload16(Bt + (size_t)(bn + n) * K + k0 + cs * 8, &lds.Bs[buf][lin * 8]);
        }
    };

    stage(0, 0);
    __syncthreads();
    for (int t = 0; t < NT; ++t) {
        const int cur = t & 1;
        if (t + 1 < NT) stage(cur ^ 1, (t + 1) << 6);

        short8 af[4][2];
#pragma unroll
        for (int m = 0; m < 4; ++m) {
            const int row = wr * 64 + m * 16 + l15;
#pragma unroll
            for (int s = 0; s < 2; ++s) {
                const int cc = (s * 4 + lhi) ^ (row & 7);
                af[m][s] = *(const short8*)&lds.As[cur][row * 64 + cc * 8];
            }
        }
        short8 bf[NF][2];
#pragma unroll
        for (int n = 0; n < NF; ++n) {
            const int col = wc * (BN / 2) + n * 16 + l15;
#pragma unroll
            for (int s = 0; s < 2; ++s) {
                const int cc = (s * 4 + lhi) ^ (col & 7);
                bf[n][s] = *(const short8*)&lds.Bs[cur][col * 64 + cc * 8];
            }
        }
#pragma unroll
        for (int m = 0; m < 4; ++m)
#pragma unroll
            for (int n = 0; n < NF; ++n) {
                acc[m][n] = __builtin_amdgcn_mfma_f32_16x16x32_bf16(af[m][0], bf[n][0], acc[m][n], 0, 0, 0);
                acc[m][n] = __builtin_amdgcn_mfma_f32_16x16x32_bf16(af[m][1], bf[n][1], acc[m][n], 0, 0, 0);
            }
        __syncthreads();
    }
}

template <int BN, int EPI>
__global__ __launch_bounds__(256) void bgemm_kernel(const ushort* __restrict__ A,
                                                    const ushort* __restrict__ Bt,
                                                    void* __restrict__ Cm,
                                                    int M, int N, int K,
                                                    const float* __restrict__ aux1,
                                                    const float* __restrict__ aux2)
{
    constexpr int NF = BN / 32;
    __shared__ GemmLds<BN> lds;
    int w = blockIdx.y * gridDim.x + blockIdx.x;
    const int nwg = gridDim.x * gridDim.y;
    if ((nwg & 7) == 0) w = (w & 7) * (nwg >> 3) + (w >> 3);   // XCD swizzle
    const int bn = (w % gridDim.x) * BN;
    const int bm = (w / gridDim.x) * 128;
    const int tid = threadIdx.x;
    const int wid = tid >> 6, lane = tid & 63;
    const int wr = wid >> 1, wc = wid & 1;
    const int l15 = lane & 15, lhi = lane >> 4;

    floatx4 acc[4][NF];
#pragma unroll
    for (int m = 0; m < 4; ++m)
#pragma unroll
        for (int n = 0; n < NF; ++n) acc[m][n] = (floatx4){0.f, 0.f, 0.f, 0.f};

    gemm_body<BN>(A, Bt, bm, bn, K, lds, acc);

#pragma unroll
    for (int m = 0; m < 4; ++m) {
        const int row0 = bm + wr * 64 + m * 16 + lhi * 4;
#pragma unroll
        for (int n = 0; n < NF; ++n) {
            const int col = bn + wc * (BN / 2) + n * 16 + l15;
            if (col >= N) continue;
#pragma unroll
            for (int j = 0; j < 4; ++j) {
                const size_t oi = (size_t)(row0 + j) * N + col;
                const float a = acc[m][n][j];
                if constexpr (EPI == BEPI_NONE_BF) {
                    ((ushort*)Cm)[oi] = f2bf(a);
                } else if constexpr (EPI == BEPI_SILU_BF) {
                    ((ushort*)Cm)[oi] = f2bf(a / (1.f + __expf(-a)));
                } else if constexpr (EPI == BEPI_RELUSQ_BF) {
                    const float t = fmaxf(a, 0.f);
                    ((ushort*)Cm)[oi] = f2bf(t * t);
                } else if constexpr (EPI == BEPI_NONE_F) {
                    ((float*)Cm)[oi] = a;
                } else if constexpr (EPI == BEPI_RES_F) {
                    ((float*)Cm)[oi] = aux1[oi] + a;
                } else if constexpr (EPI == BEPI_SIGRES_F) {
                    ((float*)Cm)[oi] = aux1[oi] + aux2[oi] / (1.f + __expf(-a));
                } else if constexpr (EPI == BEPI_TANH_F) {
                    ((float*)Cm)[oi] = tanhf(a);
                } else if constexpr (EPI == BEPI_TANH_BF) {
                    ((ushort*)Cm)[oi] = f2bf(tanhf(a));
                } else {  // BEPI_DECAY_F
                    ((float*)Cm)[oi] = __expf(-__expf(a + aux1[col]));
                }
            }
        }
    }
}

// -------- batched QKVG GEMM (BN=128): blockIdx.z selects {k,v,r,g} --------
struct QkvgArgs { const ushort* A[4]; ushort* O[4]; };
__global__ __launch_bounds__(256) void qkvg_kernel(QkvgArgs args,
                                                   const ushort* __restrict__ Wt)
{
    __shared__ GemmLds<128> lds;
    const int z = blockIdx.z;
    int w = blockIdx.y * gridDim.x + blockIdx.x;          // 8 x 16 grid = 128
    w = (w & 7) * 16 + (w >> 3);                           // XCD swizzle
    const int bn = (w & 7) * 128;
    const int bm = (w >> 3) * 128;
    const int tid = threadIdx.x;
    const int wid = tid >> 6, lane = tid & 63;
    const int wr = wid >> 1, wc = wid & 1;
    const int l15 = lane & 15, lhi = lane >> 4;

    floatx4 acc[4][4];
#pragma unroll
    for (int m = 0; m < 4; ++m)
#pragma unroll
        for (int n = 0; n < 4; ++n) acc[m][n] = (floatx4){0.f, 0.f, 0.f, 0.f};

    gemm_body<128>(args.A[z], Wt + (size_t)z * C * C, bm, bn, C, lds, acc);

    ushort* __restrict__ O = args.O[z];
    const bool silu = (z == 3);
#pragma unroll
    for (int m = 0; m < 4; ++m) {
        const int row0 = bm + wr * 64 + m * 16 + lhi * 4;
#pragma unroll
        for (int n = 0; n < 4; ++n) {
            const int col = bn + wc * 64 + n * 16 + l15;
#pragma unroll
            for (int j = 0; j < 4; ++j) {
                float a = acc[m][n][j];
                if (silu) a = a / (1.f + __expf(-a));
                O[(size_t)(row0 + j) * C + col] = f2bf(a);
            }
        }
    }
}

// ---------------- launch ----------------
extern "C" void kernel_launch(void* const* d_in, const int* in_sizes, int n_in,
                              void* d_out, int out_size, void* d_ws, size_t ws_size,
                              hipStream_t stream)
{
    const float* x        = (const float*)d_in[0];
    const float* ln1_g    = (const float*)d_in[1];
    const float* ln1_b    = (const float*)d_in[2];
    const float* ln2_g    = (const float*)d_in[3];
    const float* ln2_b    = (const float*)d_in[4];
    const float* maa_x    = (const float*)d_in[5];
    const float* maa_w    = (const float*)d_in[6];
    const float* maa_k    = (const float*)d_in[7];
    const float* maa_v    = (const float*)d_in[8];
    const float* maa_r    = (const float*)d_in[9];
    const float* maa_g    = (const float*)d_in[10];
    const float* maa_w1   = (const float*)d_in[11];
    const float* maa_w2   = (const float*)d_in[12];
    const float* time_dec = (const float*)d_in[13];
    const float* tdw1     = (const float*)d_in[14];
    const float* tdw2     = (const float*)d_in[15];
    const float* u        = (const float*)d_in[16];
    const float* Wr       = (const float*)d_in[17];
    const float* Wk       = (const float*)d_in[18];
    const float* Wv       = (const float*)d_in[19];
    const float* Wg       = (const float*)d_in[20];
    const float* Wo       = (const float*)d_in[21];
    const float* lnx_g    = (const float*)d_in[22];
    const float* lnx_b    = (const float*)d_in[23];
    const float* cmaa_k   = (const float*)d_in[24];
    const float* cmaa_r   = (const float*)d_in[25];
    const float* Wck      = (const float*)d_in[26];
    const float* Wcv      = (const float*)d_in[27];
    const float* Wcr      = (const float*)d_in[28];
    float* out = (float*)d_out;

    // -------- workspace layout (~63 MB) --------
    float* fws = (float*)d_ws;
    const size_t E = (size_t)BT * C;            // 2,097,152
    float* xa  = fws + 0 * E;                   // xa ; ypart (4xE bf16) ; kk low
    float* xx  = fws + 1 * E;                   // xx -> cxx ; ypart hi ; kk high
    float* wd  = fws + 2 * E;                   // decay d -> xc
    float* fs  = fws + 3 * E;                   // xvb/xrb (mix) ; M low ; kv
    ushort* wBuf = (ushort*)(fws + 4 * E);      // 4M ushort: weights / M high
    ushort* Mbuf = (ushort*)fs;                 // 2048*4096 bf16 = fs..wBuf (16MB)
    ushort* w2t  = wBuf + (size_t)C * 160;      // 5*C*32 bf16 (after maa_w1t)
    ushort* bf1  = wBuf + (size_t)C * FF;       // E: ax / xkb / ck_in
    ushort* rb   = bf1 + E;                     // r
    ushort* kb   = rb + E;                      // k
    ushort* vb   = kb + E;                      // v  -> ya
    ushort* gb   = vb + E;                      // g  -> cr_in
    ushort* t1b  = gb + E;                      // BT*64 bf16
    float* a5    = (float*)(t1b + (size_t)BT * 64);   // BT*160 (a5b bf16 inside)
    float* sig   = a5 + (size_t)BT * 160;       // (unused)
    float* Dbuf  = sig + (size_t)BT * H;        // 2048*64 f32
    ushort* a5b  = (ushort*)a5;                 // BT*160 bf16
    ushort* xvb  = (ushort*)fs;                 // E (mix v input)
    ushort* xrb  = (ushort*)fs + E;             // E (mix r input)
    ushort* xgb  = (ushort*)out;                // E (mix g input; out is scratch)
    ushort* xwb  = (ushort*)out + E;            // E (mix w input)
    ushort* ypart = (ushort*)xa;                // 4 x E bf16 == xa..xx
    ushort* kk   = (ushort*)xa;                 // BT*FF bf16 == xa..xx

    const dim3 blk(256);
    const dim3 tblk(32, 8);
    const int EW = (BT * C) / 256;
    const dim3 gNN(C / 64, BT / 128);

    // ---- attention branch ----
    ln_kernel<<<BT, blk, 0, stream>>>(x, ln1_g, ln1_b, xa);
    bshiftmix_kernel<<<EW, blk, 0, stream>>>(xa, maa_x, xx, bf1);
    wconv_kernel<<<dim3(160 / 32, C / 32), tblk, 0, stream>>>(maa_w1, wBuf, C, 160);
    bgemm_kernel<64, BEPI_TANH_BF><<<dim3(3, BT / 128), blk, 0, stream>>>(bf1, wBuf, a5b, BT, 160, C, nullptr, nullptr);

    // w2 slices -> [5][C][32] bf16 transposed (one launch)
    w2conv_kernel<<<dim3(C / 32, 5), tblk, 0, stream>>>(maa_w2, w2t);

    // all 5 mixes as one fused MFMA GEMM launch
    Mix5Args margs;
    margs.maa[0] = maa_w; margs.maa[1] = maa_k; margs.maa[2] = maa_v;
    margs.maa[3] = maa_r; margs.maa[4] = maa_g;
    margs.out[0] = xwb; margs.out[1] = bf1; margs.out[2] = xvb;
    margs.out[3] = xrb; margs.out[4] = xgb;
    mix5m_kernel<<<dim3(C / 64, BT / 128, 5), blk, 0, stream>>>(a5b, w2t, xa, xx, margs);

    // w path: tanh(xw@tdw1) -> decay d = exp(-exp(@tdw2 + time_decay))
    wconv_kernel<<<dim3(64 / 32, C / 32), tblk, 0, stream>>>(tdw1, wBuf, C, 64);
    bgemm_kernel<64, BEPI_TANH_BF><<<dim3(1, BT / 128), blk, 0, stream>>>(xwb, wBuf, t1b, BT, 64, C, nullptr, nullptr);
    wconv_kernel<<<dim3(C / 32, 64 / 32), tblk, 0, stream>>>(tdw2, wBuf, 64, C);
    bgemm_kernel<64, BEPI_DECAY_F><<<gNN, blk, 0, stream>>>(t1b, wBuf, wd, BT, C, 64, time_dec, nullptr);

    // batched QKVG
    Wconv4Args wargs;
    wargs.W[0] = Wk; wargs.W[1] = Wv; wargs.W[2] = Wr; wargs.W[3] = Wg;
    wconv4_kernel<<<dim3(C / 32, C / 32, 4), tblk, 0, stream>>>(wargs, wBuf);
    QkvgArgs qargs;
    qargs.A[0] = bf1; qargs.A[1] = xvb; qargs.A[2] = xrb; qargs.A[3] = xgb;
    qargs.O[0] = kb;  qargs.O[1] = vb;  qargs.O[2] = rb;  qargs.O[3] = gb;
    qkvg_kernel<<<dim3(8, 16, 4), blk, 0, stream>>>(qargs, wBuf);

    // chunked bidirectional WKV (Mbuf overlays fs+wBuf; ypart overlays xa..xx)
    wkv_pass1<<<dim3(2 * B * H * NCH * 2), dim3(64), 0, stream>>>(kb, vb, wd, Mbuf, Dbuf);
    wkv_pass2<<<dim3(2 * B * H), dim3(1024), 0, stream>>>(Mbuf, Dbuf);
    wkv_pass3<<<dim3(2 * B * H * NCH * 2), dim3(64), 0, stream>>>(rb, kb, vb, wd, Mbuf, ypart);

    // ya = groupnorm(sum ypart + sig*v)*g ; out = x + ya @ Wo^T
    gnmul_kernel<<<BT, dim3(1024), 0, stream>>>(ypart, lnx_g, lnx_b, gb, vb, rb, kb, u, vb);
    wconv_kernel<<<dim3(C / 32, C / 32), tblk, 0, stream>>>(Wo, wBuf, C, C);
    bgemm_kernel<64, BEPI_RES_F><<<gNN, blk, 0, stream>>>(vb, wBuf, out, BT, C, C, x, nullptr);

    // ---- FFN branch ----
    ln_kernel<<<BT, blk, 0, stream>>>(out, ln2_g, ln2_b, wd);
    bshift_kernel<<<EW, blk, 0, stream>>>(wd, xx);
    cmix_kernel<<<EW, blk, 0, stream>>>(wd, xx, cmaa_k, cmaa_r, bf1, gb);
    wconv_kernel<<<dim3(FF / 32, C / 32), tblk, 0, stream>>>(Wck, wBuf, C, FF);
    bgemm_kernel<128, BEPI_RELUSQ_BF><<<dim3(FF / 128, BT / 128), blk, 0, stream>>>(bf1, wBuf, kk, BT, FF, C, nullptr, nullptr);
    wconv_kernel<<<dim3(C / 32, FF / 32), tblk, 0, stream>>>(Wcv, wBuf, FF, C);
    bgemm_kernel<64, BEPI_NONE_F><<<gNN, blk, 0, stream>>>(kk, wBuf, fs, BT, C, FF, nullptr, nullptr);
    wconv_kernel<<<dim3(C / 32, C / 32), tblk, 0, stream>>>(Wcr, wBuf, C, C);
    bgemm_kernel<64, BEPI_SIGRES_F><<<gNN, blk, 0, stream>>>(gb, wBuf, out, BT, C, C, out, fs);

    (void)in_sizes; (void)n_in; (void)out_size; (void)ws_size;
}

// Round 11
// 299.014 us; speedup vs baseline: 4.8235x; 1.0655x over previous
//
#include <hip/hip_runtime.h>
#include <math.h>
#include <stdint.h>

static constexpr int B  = 8;
static constexpr int T  = 256;
static constexpr int C  = 1024;
static constexpr int H  = 16;
static constexpr int HEAD = 64;
static constexpr int FF = 4096;
static constexpr int BT = B * T;
static constexpr int NCH = 8;       // time chunks
static constexpr int CS  = 32;      // chunk size (NCH*CS == T)

typedef short short8  __attribute__((ext_vector_type(8)));
typedef float floatx4 __attribute__((ext_vector_type(4)));

// ---------------- bf16 helpers ----------------
__device__ __forceinline__ float bf2f(ushort u) {
    return __uint_as_float(((uint32_t)u) << 16);
}
__device__ __forceinline__ ushort f2bf(float x) {
    uint32_t u = __float_as_uint(x);
    u += 0x7fff + ((u >> 16) & 1);          // RNE
    return (ushort)(u >> 16);
}

__device__ __forceinline__ void gload16(const void* g, void* l) {
    __builtin_amdgcn_global_load_lds(
        (const __attribute__((address_space(1))) unsigned int*)g,
        (__attribute__((address_space(3))) unsigned int*)l, 16, 0, 0);
}

// ---------------- epilogue ids ----------------
#define BEPI_NONE_BF   0
#define BEPI_SILU_BF   1
#define BEPI_RELUSQ_BF 2
#define BEPI_NONE_F    3
#define BEPI_RES_F     4
#define BEPI_SIGRES_F  5
#define BEPI_TANH_F    6
#define BEPI_TANH_BF   7
#define BEPI_DECAY_F   8
#define BEPI_SIGRES2_F 9

// ---------------- LayerNorm ----------------
__global__ __launch_bounds__(256) void ln_kernel(const float* __restrict__ x,
                                                 const float* __restrict__ g,
                                                 const float* __restrict__ b,
                                                 float* __restrict__ out)
{
    const int row = blockIdx.x;
    const int tid = threadIdx.x;
    const float4 v = reinterpret_cast<const float4*>(x + (size_t)row * C)[tid];
    float s = v.x + v.y + v.z + v.w;
#pragma unroll
    for (int off = 32; off > 0; off >>= 1) s += __shfl_xor(s, off);
    __shared__ float red[8];
    const int wave = tid >> 6, lane = tid & 63;
    if (lane == 0) red[wave] = s;
    __syncthreads();
    const float mean = (red[0] + red[1] + red[2] + red[3]) * (1.0f / C);
    const float d0 = v.x - mean, d1 = v.y - mean, d2 = v.z - mean, d3 = v.w - mean;
    float q = d0 * d0 + d1 * d1 + d2 * d2 + d3 * d3;
#pragma unroll
    for (int off = 32; off > 0; off >>= 1) q += __shfl_xor(q, off);
    if (lane == 0) red[4 + wave] = q;
    __syncthreads();
    const float var = (red[4] + red[5] + red[6] + red[7]) * (1.0f / C);
    const float rstd = rsqrtf(var + 1e-5f);
    const int c = tid * 4;
    float4 o;
    o.x = d0 * rstd * g[c + 0] + b[c + 0];
    o.y = d1 * rstd * g[c + 1] + b[c + 1];
    o.z = d2 * rstd * g[c + 2] + b[c + 2];
    o.w = d3 * rstd * g[c + 3] + b[c + 3];
    reinterpret_cast<float4*>(out + (size_t)row * C)[tid] = o;
}

// ---- fused bshift+mixax: xx = bshift(xa)-xa (f32), ax = bf16(xa + xx*maa) ----
__global__ __launch_bounds__(256) void bshiftmix_kernel(const float* __restrict__ xa,
                                                        const float* __restrict__ maa,
                                                        float* __restrict__ xx,
                                                        ushort* __restrict__ ax)
{
    const int i = blockIdx.x * 256 + threadIdx.x;
    const int c = i & (C - 1);
    const int bt = i >> 10;
    const int t = bt & (T - 1);
    const int j = c & (HEAD - 1);
    float src = 0.f;
    if (j < HEAD / 2) { if (t > 0)     src = xa[i - C]; }
    else              { if (t < T - 1) src = xa[i + C]; }
    const float a = xa[i];
    const float xv = src - a;
    xx[i] = xv;
    ax[i] = f2bf(a + xv * maa[c]);
}

// ---- fused FFN bshift+cmix: two bf16 mixed outputs, no xx materialization ----
__global__ __launch_bounds__(256) void bshiftcmix_kernel(const float* __restrict__ xc,
                                                         const float* __restrict__ mk,
                                                         const float* __restrict__ mr,
                                                         ushort* __restrict__ ok,
                                                         ushort* __restrict__ orr)
{
    const int i = blockIdx.x * 256 + threadIdx.x;
    const int c = i & (C - 1);
    const int bt = i >> 10;
    const int t = bt & (T - 1);
    const int j = c & (HEAD - 1);
    float src = 0.f;
    if (j < HEAD / 2) { if (t > 0)     src = xc[i - C]; }
    else              { if (t < T - 1) src = xc[i + C]; }
    const float a = xc[i];
    const float cxx = src - a;
    ok[i]  = f2bf(a + cxx * mk[c]);
    orr[i] = f2bf(a + cxx * mr[c]);
}

// -------- GroupNorm(yf+yb+sig*v)*g+b, * gate; u-bonus scalar fused ---------
__global__ __launch_bounds__(1024) void gnmul_kernel(const float* __restrict__ yf,
                                                     const float* __restrict__ yb,
                                                     const float* __restrict__ g,
                                                     const float* __restrict__ b,
                                                     const ushort* __restrict__ gate,
                                                     const ushort* __restrict__ vin,
                                                     const ushort* __restrict__ rbuf,
                                                     const ushort* __restrict__ kbuf,
                                                     const float* __restrict__ u,
                                                     ushort* __restrict__ out)
{
    const int row = blockIdx.x;
    const int tid = threadIdx.x;                 // wave == head
    const size_t idx = (size_t)row * C + tid;
    float p = bf2f(rbuf[idx]) * bf2f(kbuf[idx]) * u[tid];
#pragma unroll
    for (int off = 32; off > 0; off >>= 1) p += __shfl_xor(p, off);
    const float v = yf[idx] + yb[idx] + p * bf2f(vin[idx]);
    float s = v;
#pragma unroll
    for (int off = 32; off > 0; off >>= 1) s += __shfl_xor(s, off);
    const float m = s * (1.0f / HEAD);
    const float d = v - m;
    float q = d * d;
#pragma unroll
    for (int off = 32; off > 0; off >>= 1) q += __shfl_xor(q, off);
    const float rstd = rsqrtf(q * (1.0f / HEAD) + 6.4e-4f);
    out[idx] = f2bf((d * rstd * g[tid] + b[tid]) * bf2f(gate[idx]));
}

// -------- weight convert+transpose: W[Kd,Nd] f32 -> Wt[Nd,Kd] bf16 --------
__global__ __launch_bounds__(256) void wconv_kernel(const float* __restrict__ W,
                                                    ushort* __restrict__ Wt,
                                                    int Kd, int Nd)
{
    __shared__ float tile[32][33];
    const int n0 = blockIdx.x * 32, k0 = blockIdx.y * 32;
    const int tx = threadIdx.x, ty = threadIdx.y;
#pragma unroll
    for (int i = 0; i < 4; ++i)
        tile[ty * 4 + i][tx] = W[(size_t)(k0 + ty * 4 + i) * Nd + n0 + tx];
    __syncthreads();
#pragma unroll
    for (int i = 0; i < 4; ++i)
        Wt[(size_t)(n0 + ty * 4 + i) * Kd + k0 + tx] = f2bf(tile[tx][ty * 4 + i]);
}

// -------- w2 slices: w2[5][32][C] -> w2t[5][C][32] bf16, one launch --------
__global__ __launch_bounds__(256) void w2conv_kernel(const float* __restrict__ w2,
                                                     ushort* __restrict__ w2t)
{
    __shared__ float tile[32][33];
    const int f = blockIdx.y;
    const int n0 = blockIdx.x * 32;
    const int tx = threadIdx.x, ty = threadIdx.y;
#pragma unroll
    for (int i = 0; i < 4; ++i)
        tile[ty * 4 + i][tx] = w2[(size_t)f * 32 * C + (size_t)(ty * 4 + i) * C + n0 + tx];
    __syncthreads();
#pragma unroll
    for (int i = 0; i < 4; ++i)
        w2t[(size_t)f * C * 32 + (size_t)(n0 + ty * 4 + i) * 32 + tx] = f2bf(tile[tx][ty * 4 + i]);
}

// -------- batched wconv: 4 C x C weights (blockIdx.z) --------
struct Wconv4Args { const float* W[4]; };
__global__ __launch_bounds__(256) void wconv4_kernel(Wconv4Args args, ushort* __restrict__ Wt)
{
    __shared__ float tile[32][33];
    const int z = blockIdx.z;
    const float* __restrict__ W = args.W[z];
    ushort* __restrict__ dst = Wt + (size_t)z * C * C;
    const int n0 = blockIdx.x * 32, k0 = blockIdx.y * 32;
    const int tx = threadIdx.x, ty = threadIdx.y;
#pragma unroll
    for (int i = 0; i < 4; ++i)
        tile[ty * 4 + i][tx] = W[(size_t)(k0 + ty * 4 + i) * C + n0 + tx];
    __syncthreads();
#pragma unroll
    for (int i = 0; i < 4; ++i)
        dst[(size_t)(n0 + ty * 4 + i) * C + k0 + tx] = f2bf(tile[tx][ty * 4 + i]);
}

// ======== mix5 as fused MFMA GEMM: out_f = bf16(xa + xx*(maa_f + a5b@w2t_f)) ====
struct Mix5Args { const float* maa[5]; ushort* out[5]; };
__global__ __launch_bounds__(256) void mix5m_kernel(const ushort* __restrict__ a5b,
                                                    const ushort* __restrict__ w2t,
                                                    const float* __restrict__ xa,
                                                    const float* __restrict__ xx,
                                                    Mix5Args args)
{
    __shared__ __align__(16) ushort As[128 * 32];
    __shared__ __align__(16) ushort Bs[64 * 32];
    const int f = blockIdx.z;
    const int bm = blockIdx.y * 128, bn = blockIdx.x * 64;
    const int tid = threadIdx.x;
    const int wid = tid >> 6, lane = tid & 63;
    const int wr = wid >> 1, wc = wid & 1;
    const int l15 = lane & 15, lhi = lane >> 4;

#pragma unroll
    for (int p = 0; p < 2; ++p) {
        const int lin = p * 256 + tid;
        const int row = lin >> 2;
        const int sp = (lin & 3) ^ ((row >> 1) & 3);
        gload16(a5b + (size_t)(bm + row) * 160 + f * 32 + sp * 8, &As[lin * 8]);
    }
    {
        const int lin = tid;
        const int n = lin >> 2;
        const int sp = (lin & 3) ^ ((n >> 1) & 3);
        gload16(w2t + ((size_t)f * C + bn + n) * 32 + sp * 8, &Bs[lin * 8]);
    }
    __syncthreads();

    short8 af[4], bfr[2];
#pragma unroll
    for (int m = 0; m < 4; ++m) {
        const int row = wr * 64 + m * 16 + l15;
        const int sp = lhi ^ ((row >> 1) & 3);
        af[m] = *(const short8*)&As[row * 32 + sp * 8];
    }
#pragma unroll
    for (int n = 0; n < 2; ++n) {
        const int col = wc * 32 + n * 16 + l15;
        const int sp = lhi ^ ((col >> 1) & 3);
        bfr[n] = *(const short8*)&Bs[col * 32 + sp * 8];
    }
    floatx4 acc[4][2];
#pragma unroll
    for (int m = 0; m < 4; ++m)
#pragma unroll
        for (int n = 0; n < 2; ++n)
            acc[m][n] = __builtin_amdgcn_mfma_f32_16x16x32_bf16(
                af[m], bfr[n], (floatx4){0.f, 0.f, 0.f, 0.f}, 0, 0, 0);

    const float* __restrict__ maa = args.maa[f];
    ushort* __restrict__ out = args.out[f];
#pragma unroll
    for (int m = 0; m < 4; ++m) {
        const int row0 = bm + wr * 64 + m * 16 + lhi * 4;
#pragma unroll
        for (int n = 0; n < 2; ++n) {
            const int col = bn + wc * 32 + n * 16 + l15;
            const float mc = maa[col];
#pragma unroll
            for (int j = 0; j < 4; ++j) {
                const size_t oi = (size_t)(row0 + j) * C + col;
                out[oi] = f2bf(xa[oi] + xx[oi] * (mc + acc[m][n][j]));
            }
        }
    }
}

// ================== chunked bidirectional WKV6, 4-way j-split ==================
// pass1: 4 independent wave-units per block; gw = blk*4+wave; jh=gw&3; uc=gw>>2
__global__ __launch_bounds__(256) void wkv_pass1(const ushort* __restrict__ k,
                                                 const ushort* __restrict__ v,
                                                 const float* __restrict__ d,
                                                 ushort* __restrict__ M,
                                                 float* __restrict__ D)
{
    const int w = threadIdx.x >> 6, lane = threadIdx.x & 63;
    const int gw = blockIdx.x * 4 + w;
    const int jh = gw & 3;
    const int uc = gw >> 2;
    const int c = uc & (NCH - 1), unit = uc >> 3;
    const int dir = unit & 1, bh = unit >> 1;
    const int jb = jh * 16, jl = lane & 15;
    const size_t rowb = ((size_t)(bh >> 4) * T * H + (bh & 15)) * HEAD;
    __shared__ __align__(16) float sb[4][2][2][16];

    float S[16];
#pragma unroll
    for (int j = 0; j < 16; ++j) S[j] = 0.f;
    float PD = 1.f;

    const int s0 = c * CS;
    const int t0 = dir ? (T - 1 - s0) : s0;
    const size_t pb = rowb + (size_t)t0 * (H * HEAD);
    float vn = bf2f(v[pb + lane]);
    float kk = bf2f(k[pb + jb + jl]);
    float dd = d[pb + jb + jl];

    int p = 0;
    for (int ss = 0; ss < CS; ++ss) {
        const float kc = kk, vv = vn, dc = dd;
        const int sn = (ss + 1 < CS) ? (ss + 1) : 0;
        const int s = c * CS + sn;
        const int tn = dir ? (T - 1 - s) : s;
        const size_t nb = rowb + (size_t)tn * (H * HEAD);
        vn = bf2f(v[nb + lane]);
        kk = bf2f(k[nb + jb + jl]);
        dd = d[nb + jb + jl];

        PD *= dc;
        if (lane < 16) {
            sb[w][p][0][lane] = kc;
            sb[w][p][1][lane] = dc;
        }
        asm volatile("s_waitcnt lgkmcnt(0)" ::: "memory");
        const float* __restrict__ sk = sb[w][p][0];
        const float* __restrict__ sd = sb[w][p][1];
#pragma unroll
        for (int jj = 0; jj < 16; jj += 4) {
            const float4 k4 = *reinterpret_cast<const float4*>(&sk[jj]);
            const float4 d4 = *reinterpret_cast<const float4*>(&sd[jj]);
            S[jj + 0] = fmaf(d4.x, S[jj + 0], k4.x * vv);
            S[jj + 1] = fmaf(d4.y, S[jj + 1], k4.y * vv);
            S[jj + 2] = fmaf(d4.z, S[jj + 2], k4.z * vv);
            S[jj + 3] = fmaf(d4.w, S[jj + 3], k4.w * vv);
        }
        p ^= 1;
    }
    const size_t mb = (size_t)uc * 4096 + (size_t)jb * 64 + lane;
#pragma unroll
    for (int j = 0; j < 16; ++j) M[mb + j * 64] = f2bf(S[j]);
    if (lane < 16) D[(size_t)uc * 64 + jb + lane] = PD;
}

// pass2 (parallel): 1024 threads/unit, thread owns 4 state elements
__global__ __launch_bounds__(1024) void wkv_pass2(ushort* __restrict__ M,
                                                  const float* __restrict__ D)
{
    const int unit = blockIdx.x;
    const int tid = threadIdx.x;
    const int j = tid >> 4;
    float S0 = 0.f, S1 = 0.f, S2 = 0.f, S3 = 0.f;
#pragma unroll
    for (int c = 0; c < NCH; ++c) {
        const int uc = unit * NCH + c;
        const float Dj = D[(size_t)uc * 64 + j];
        ushort* mp = M + (size_t)uc * 4096 + tid * 4;
        const uint2 mv = *reinterpret_cast<const uint2*>(mp);
        const float m0 = bf2f((ushort)(mv.x & 0xffff));
        const float m1 = bf2f((ushort)(mv.x >> 16));
        const float m2 = bf2f((ushort)(mv.y & 0xffff));
        const float m3 = bf2f((ushort)(mv.y >> 16));
        uint2 sv;
        sv.x = (uint32_t)f2bf(S0) | ((uint32_t)f2bf(S1) << 16);
        sv.y = (uint32_t)f2bf(S2) | ((uint32_t)f2bf(S3) << 16);
        *reinterpret_cast<uint2*>(mp) = sv;
        S0 = fmaf(Dj, S0, m0);
        S1 = fmaf(Dj, S1, m1);
        S2 = fmaf(Dj, S2, m2);
        S3 = fmaf(Dj, S3, m3);
    }
}

// pass3: block = one (unit,chunk); 4 waves = 4 j-slices; psum in LDS;
// single end-of-loop barrier, cooperative coalesced f32 y store.
__global__ __launch_bounds__(256) void wkv_pass3(const ushort* __restrict__ r,
                                                 const ushort* __restrict__ k,
                                                 const ushort* __restrict__ v,
                                                 const float* __restrict__ d,
                                                 const ushort* __restrict__ Sin,
                                                 float* __restrict__ yf,
                                                 float* __restrict__ yb)
{
    const int uc = blockIdx.x;
    const int w = threadIdx.x >> 6, lane = threadIdx.x & 63;
    const int c = uc & (NCH - 1), unit = uc >> 3;
    const int dir = unit & 1, bh = unit >> 1;
    const int jb = w * 16, jl = lane & 15;
    const size_t rowb = ((size_t)(bh >> 4) * T * H + (bh & 15)) * HEAD;
    __shared__ __align__(16) float sb[4][2][3][16];
    __shared__ ushort psum[4][CS][64];

    float S[16];
    const size_t mb = (size_t)uc * 4096 + (size_t)jb * 64 + lane;
#pragma unroll
    for (int j = 0; j < 16; ++j) S[j] = bf2f(Sin[mb + j * 64]);

    const int s0 = c * CS;
    const int t0 = dir ? (T - 1 - s0) : s0;
    const size_t pb = rowb + (size_t)t0 * (H * HEAD);
    float rr = bf2f(r[pb + jb + jl]);
    float kk = bf2f(k[pb + jb + jl]);
    float vn = bf2f(v[pb + lane]);
    float dd = d[pb + jb + jl];

    int p = 0;
    for (int ss = 0; ss < CS; ++ss) {
        const float rc = rr, kc = kk, vv = vn, dc = dd;
        const int sn2 = (ss + 1 < CS) ? (ss + 1) : 0;
        const int s2 = c * CS + sn2;
        const int tn = dir ? (T - 1 - s2) : s2;
        const size_t nb = rowb + (size_t)tn * (H * HEAD);
        rr = bf2f(r[nb + jb + jl]);
        kk = bf2f(k[nb + jb + jl]);
        vn = bf2f(v[nb + lane]);
        dd = d[nb + jb + jl];

        if (lane < 16) {
            sb[w][p][0][lane] = rc;
            sb[w][p][1][lane] = kc;
            sb[w][p][2][lane] = dc;
        }
        asm volatile("s_waitcnt lgkmcnt(0)" ::: "memory");
        const float* __restrict__ sr = sb[w][p][0];
        const float* __restrict__ sk = sb[w][p][1];
        const float* __restrict__ sd = sb[w][p][2];
        float y0 = 0.f, y1 = 0.f, y2 = 0.f, y3 = 0.f;
#pragma unroll
        for (int jj = 0; jj < 16; jj += 4) {
            const float4 r4 = *reinterpret_cast<const float4*>(&sr[jj]);
            const float4 k4 = *reinterpret_cast<const float4*>(&sk[jj]);
            const float4 d4 = *reinterpret_cast<const float4*>(&sd[jj]);
            y0 = fmaf(r4.x, S[jj + 0], y0);
            S[jj + 0] = fmaf(d4.x, S[jj + 0], k4.x * vv);
            y1 = fmaf(r4.y, S[jj + 1], y1);
            S[jj + 1] = fmaf(d4.y, S[jj + 1], k4.y * vv);
            y2 = fmaf(r4.z, S[jj + 2], y2);
            S[jj + 2] = fmaf(d4.z, S[jj + 2], k4.z * vv);
            y3 = fmaf(r4.w, S[jj + 3], y3);
            S[jj + 3] = fmaf(d4.w, S[jj + 3], k4.w * vv);
        }
        psum[w][ss][lane] = f2bf((y0 + y1) + (y2 + y3));
        p ^= 1;
    }
    __syncthreads();
    float* __restrict__ yo = dir ? yb : yf;
    for (int idx = threadIdx.x; idx < CS * 64; idx += 256) {
        const int s = idx >> 6, i = idx & 63;
        const float sum = bf2f(psum[0][s][i]) + bf2f(psum[1][s][i]) +
                          bf2f(psum[2][s][i]) + bf2f(psum[3][s][i]);
        const int sg = c * CS + s;
        const int t = dir ? (T - 1 - sg) : sg;
        yo[rowb + (size_t)t * (H * HEAD) + i] = sum;
    }
}

// ======== pipelined bf16 MFMA GEMM core: BM=128, BK=64, BN in {64,128} ========
template <int BN>
struct GemmLds {
    ushort As[2][128 * 64];
    ushort Bs[2][BN * 64];
};

template <int BN>
__device__ __forceinline__ void gemm_body(const ushort* __restrict__ A,
                                          const ushort* __restrict__ Bt,
                                          int bm, int bn, int K, int lda, int ldb,
                                          GemmLds<BN>& lds,
                                          floatx4 (&acc)[4][BN / 32])
{
    constexpr int NF = BN / 32;
    const int tid = threadIdx.x;
    const int wid = tid >> 6, lane = tid & 63;
    const int wr = wid >> 1, wc = wid & 1;
    const int l15 = lane & 15, lhi = lane >> 4;
    const int NT = K >> 6;

    auto stage = [&](int buf, int k0) {
#pragma unroll
        for (int p = 0; p < 4; ++p) {
            const int lin = p * 256 + tid;
            const int row = lin >> 3;
            const int cs = (lin & 7) ^ (row & 7);
            gload16(A + (size_t)(bm + row) * lda + k0 + cs * 8, &lds.As[buf][lin * 8]);
        }
#pragma unroll
        for (int p = 0; p < NF; ++p) {
            const int lin = p * 256 + tid;
            const int n = lin >> 3;
            const int cs = (lin & 7) ^ (n & 7);
            gload16(Bt + (size_t)(bn + n) * ldb + k0 + cs * 8, &lds.Bs[buf][lin * 8]);
        }
    };

    stage(0, 0);
    __syncthreads();
    for (int t = 0; t < NT; ++t) {
        const int cur = t & 1;
        if (t + 1 < NT) stage(cur ^ 1, (t + 1) << 6);

        short8 af[4][2];
#pragma unroll
        for (int m = 0; m < 4; ++m) {
            const int row = wr * 64 + m * 16 + l15;
#pragma unroll
            for (int s = 0; s < 2; ++s) {
                const int cc = (s * 4 + lhi) ^ (row & 7);
                af[m][s] = *(const short8*)&lds.As[cur][row * 64 + cc * 8];
            }
        }
        short8 bf[NF][2];
#pragma unroll
        for (int n = 0; n < NF; ++n) {
            const int col = wc * (BN / 2) + n * 16 + l15;
#pragma unroll
            for (int s = 0; s < 2; ++s) {
                const int cc = (s * 4 + lhi) ^ (col & 7);
                bf[n][s] = *(const short8*)&lds.Bs[cur][col * 64 + cc * 8];
            }
        }
#pragma unroll
        for (int m = 0; m < 4; ++m)
#pragma unroll
            for (int n = 0; n < NF; ++n) {
                acc[m][n] = __builtin_amdgcn_mfma_f32_16x16x32_bf16(af[m][0], bf[n][0], acc[m][n], 0, 0, 0);
                acc[m][n] = __builtin_amdgcn_mfma_f32_16x16x32_bf16(af[m][1], bf[n][1], acc[m][n], 0, 0, 0);
            }
        __syncthreads();
    }
}

template <int BN, int EPI>
__global__ __launch_bounds__(256) void bgemm_kernel(const ushort* __restrict__ A,
                                                    const ushort* __restrict__ Bt,
                                                    void* __restrict__ Cm,
                                                    int M, int N, int K,
                                                    const float* __restrict__ aux1,
                                                    const float* __restrict__ aux2,
                                                    const float* __restrict__ aux3)
{
    constexpr int NF = BN / 32;
    __shared__ GemmLds<BN> lds;
    int w = blockIdx.y * gridDim.x + blockIdx.x;
    const int nwg = gridDim.x * gridDim.y;
    if ((nwg & 7) == 0) w = (w & 7) * (nwg >> 3) + (w >> 3);   // XCD swizzle
    const int bn = (w % gridDim.x) * BN;
    const int bm = (w / gridDim.x) * 128;
    const int tid = threadIdx.x;
    const int wid = tid >> 6, lane = tid & 63;
    const int wr = wid >> 1, wc = wid & 1;
    const int l15 = lane & 15, lhi = lane >> 4;

    floatx4 acc[4][NF];
#pragma unroll
    for (int m = 0; m < 4; ++m)
#pragma unroll
        for (int n = 0; n < NF; ++n) acc[m][n] = (floatx4){0.f, 0.f, 0.f, 0.f};

    gemm_body<BN>(A, Bt, bm, bn, K, K, K, lds, acc);

#pragma unroll
    for (int m = 0; m < 4; ++m) {
        const int row0 = bm + wr * 64 + m * 16 + lhi * 4;
#pragma unroll
        for (int n = 0; n < NF; ++n) {
            const int col = bn + wc * (BN / 2) + n * 16 + l15;
            if (col >= N) continue;
#pragma unroll
            for (int j = 0; j < 4; ++j) {
                const size_t oi = (size_t)(row0 + j) * N + col;
                const float a = acc[m][n][j];
                if constexpr (EPI == BEPI_NONE_BF) {
                    ((ushort*)Cm)[oi] = f2bf(a);
                } else if constexpr (EPI == BEPI_SILU_BF) {
                    ((ushort*)Cm)[oi] = f2bf(a / (1.f + __expf(-a)));
                } else if constexpr (EPI == BEPI_RELUSQ_BF) {
                    const float t = fmaxf(a, 0.f);
                    ((ushort*)Cm)[oi] = f2bf(t * t);
                } else if constexpr (EPI == BEPI_NONE_F) {
                    ((float*)Cm)[oi] = a;
                } else if constexpr (EPI == BEPI_RES_F) {
                    ((float*)Cm)[oi] = aux1[oi] + a;
                } else if constexpr (EPI == BEPI_SIGRES_F) {
                    ((float*)Cm)[oi] = aux1[oi] + aux2[oi] / (1.f + __expf(-a));
                } else if constexpr (EPI == BEPI_SIGRES2_F) {
                    ((float*)Cm)[oi] = aux1[oi] + (aux2[oi] + aux3[oi]) / (1.f + __expf(-a));
                } else if constexpr (EPI == BEPI_TANH_F) {
                    ((float*)Cm)[oi] = tanhf(a);
                } else if constexpr (EPI == BEPI_TANH_BF) {
                    ((ushort*)Cm)[oi] = f2bf(tanhf(a));
                } else {  // BEPI_DECAY_F
                    ((float*)Cm)[oi] = __expf(-__expf(a + aux1[col]));
                }
            }
        }
    }
}

// -------- Wcv split-K=2: z = K-half; f32 partials to P0/P1 --------
__global__ __launch_bounds__(256) void wcv_kernel(const ushort* __restrict__ A,
                                                  const ushort* __restrict__ Bt,
                                                  float* __restrict__ P0,
                                                  float* __restrict__ P1)
{
    __shared__ GemmLds<64> lds;
    const int z = blockIdx.z;
    int w = blockIdx.y * gridDim.x + blockIdx.x;   // 16x16 = 256
    w = (w & 7) * 32 + (w >> 3);                    // XCD swizzle
    const int bn = (w % 16) * 64;
    const int bm = (w / 16) * 128;
    const int tid = threadIdx.x;
    const int wid = tid >> 6, lane = tid & 63;
    const int wr = wid >> 1, wc = wid & 1;
    const int l15 = lane & 15, lhi = lane >> 4;

    floatx4 acc[4][2];
#pragma unroll
    for (int m = 0; m < 4; ++m)
#pragma unroll
        for (int n = 0; n < 2; ++n) acc[m][n] = (floatx4){0.f, 0.f, 0.f, 0.f};

    gemm_body<64>(A + z * (FF / 2), Bt + z * (FF / 2), bm, bn, FF / 2, FF, FF, lds, acc);

    float* __restrict__ P = z ? P1 : P0;
#pragma unroll
    for (int m = 0; m < 4; ++m) {
        const int row0 = bm + wr * 64 + m * 16 + lhi * 4;
#pragma unroll
        for (int n = 0; n < 2; ++n) {
            const int col = bn + wc * 32 + n * 16 + l15;
#pragma unroll
            for (int j = 0; j < 4; ++j)
                P[(size_t)(row0 + j) * C + col] = acc[m][n][j];
        }
    }
}

// -------- batched QKVG GEMM (BN=128): blockIdx.z selects {k,v,r,g} --------
struct QkvgArgs { const ushort* A[4]; ushort* O[4]; };
__global__ __launch_bounds__(256) void qkvg_kernel(QkvgArgs args,
                                                   const ushort* __restrict__ Wt)
{
    __shared__ GemmLds<128> lds;
    const int z = blockIdx.z;
    int w = blockIdx.y * gridDim.x + blockIdx.x;          // 8 x 16 grid = 128
    w = (w & 7) * 16 + (w >> 3);                           // XCD swizzle
    const int bn = (w & 7) * 128;
    const int bm = (w >> 3) * 128;
    const int tid = threadIdx.x;
    const int wid = tid >> 6, lane = tid & 63;
    const int wr = wid >> 1, wc = wid & 1;
    const int l15 = lane & 15, lhi = lane >> 4;

    floatx4 acc[4][4];
#pragma unroll
    for (int m = 0; m < 4; ++m)
#pragma unroll
        for (int n = 0; n < 4; ++n) acc[m][n] = (floatx4){0.f, 0.f, 0.f, 0.f};

    gemm_body<128>(args.A[z], Wt + (size_t)z * C * C, bm, bn, C, C, C, lds, acc);

    ushort* __restrict__ O = args.O[z];
    const bool silu = (z == 3);
#pragma unroll
    for (int m = 0; m < 4; ++m) {
        const int row0 = bm + wr * 64 + m * 16 + lhi * 4;
#pragma unroll
        for (int n = 0; n < 4; ++n) {
            const int col = bn + wc * 64 + n * 16 + l15;
#pragma unroll
            for (int j = 0; j < 4; ++j) {
                float a = acc[m][n][j];
                if (silu) a = a / (1.f + __expf(-a));
                O[(size_t)(row0 + j) * C + col] = f2bf(a);
            }
        }
    }
}

// ---------------- launch ----------------
extern "C" void kernel_launch(void* const* d_in, const int* in_sizes, int n_in,
                              void* d_out, int out_size, void* d_ws, size_t ws_size,
                              hipStream_t stream)
{
    const float* x        = (const float*)d_in[0];
    const float* ln1_g    = (const float*)d_in[1];
    const float* ln1_b    = (const float*)d_in[2];
    const float* ln2_g    = (const float*)d_in[3];
    const float* ln2_b    = (const float*)d_in[4];
    const float* maa_x    = (const float*)d_in[5];
    const float* maa_w    = (const float*)d_in[6];
    const float* maa_k    = (const float*)d_in[7];
    const float* maa_v    = (const float*)d_in[8];
    const float* maa_r    = (const float*)d_in[9];
    const float* maa_g    = (const float*)d_in[10];
    const float* maa_w1   = (const float*)d_in[11];
    const float* maa_w2   = (const float*)d_in[12];
    const float* time_dec = (const float*)d_in[13];
    const float* tdw1     = (const float*)d_in[14];
    const float* tdw2     = (const float*)d_in[15];
    const float* u        = (const float*)d_in[16];
    const float* Wr       = (const float*)d_in[17];
    const float* Wk       = (const float*)d_in[18];
    const float* Wv       = (const float*)d_in[19];
    const float* Wg       = (const float*)d_in[20];
    const float* Wo       = (const float*)d_in[21];
    const float* lnx_g    = (const float*)d_in[22];
    const float* lnx_b    = (const float*)d_in[23];
    const float* cmaa_k   = (const float*)d_in[24];
    const float* cmaa_r   = (const float*)d_in[25];
    const float* Wck      = (const float*)d_in[26];
    const float* Wcv      = (const float*)d_in[27];
    const float* Wcr      = (const float*)d_in[28];
    float* out = (float*)d_out;

    // -------- workspace layout (~63 MB) --------
    float* fws = (float*)d_ws;
    const size_t E = (size_t)BT * C;            // 2,097,152
    float* xa  = fws + 0 * E;                   // xa -> yf ; (FFN) kk low half
    float* xx  = fws + 1 * E;                   // xx -> yb ; kk high half
    float* wd  = fws + 2 * E;                   // decay d -> xc -> kvB partial
    float* fs  = fws + 3 * E;                   // xvb/xrb ; M low ; kvA partial
    ushort* wBuf = (ushort*)(fws + 4 * E);      // 4M ushort: weights / M high
    ushort* Mbuf = (ushort*)fs;                 // 2048*4096 bf16 = fs..wBuf (16MB)
    ushort* w2t  = wBuf + (size_t)C * 160;      // 5*C*32 bf16 (after maa_w1t)
    ushort* bf1  = wBuf + (size_t)C * FF;       // E: ax / xkb / ck_in
    ushort* rb   = bf1 + E;                     // r
    ushort* kb   = rb + E;                      // k
    ushort* vb   = kb + E;                      // v  -> ya
    ushort* gb   = vb + E;                      // g  -> cr_in
    ushort* t1b  = gb + E;                      // BT*64 bf16
    float* a5    = (float*)(t1b + (size_t)BT * 64);   // BT*160 (a5b bf16 inside)
    float* sig   = a5 + (size_t)BT * 160;       // (unused)
    float* Dbuf  = sig + (size_t)BT * H;        // 2048*64 f32
    ushort* a5b  = (ushort*)a5;                 // BT*160 bf16
    ushort* xvb  = (ushort*)fs;                 // E (mix v input)
    ushort* xrb  = (ushort*)fs + E;             // E (mix r input)
    ushort* xgb  = (ushort*)out;                // E (mix g input; out is scratch)
    ushort* xwb  = (ushort*)out + E;            // E (mix w input)
    ushort* kk   = (ushort*)xa;                 // BT*FF bf16 == xa..xx

    const dim3 blk(256);
    const dim3 tblk(32, 8);
    const int EW = (BT * C) / 256;
    const dim3 gNN(C / 64, BT / 128);

    // ---- attention branch ----
    ln_kernel<<<BT, blk, 0, stream>>>(x, ln1_g, ln1_b, xa);
    bshiftmix_kernel<<<EW, blk, 0, stream>>>(xa, maa_x, xx, bf1);
    wconv_kernel<<<dim3(160 / 32, C / 32), tblk, 0, stream>>>(maa_w1, wBuf, C, 160);
    bgemm_kernel<64, BEPI_TANH_BF><<<dim3(3, BT / 128), blk, 0, stream>>>(bf1, wBuf, a5b, BT, 160, C, nullptr, nullptr, nullptr);

    // w2 slices -> [5][C][32] bf16 transposed (one launch)
    w2conv_kernel<<<dim3(C / 32, 5), tblk, 0, stream>>>(maa_w2, w2t);

    // all 5 mixes as one fused MFMA GEMM launch
    Mix5Args margs;
    margs.maa[0] = maa_w; margs.maa[1] = maa_k; margs.maa[2] = maa_v;
    margs.maa[3] = maa_r; margs.maa[4] = maa_g;
    margs.out[0] = xwb; margs.out[1] = bf1; margs.out[2] = xvb;
    margs.out[3] = xrb; margs.out[4] = xgb;
    mix5m_kernel<<<dim3(C / 64, BT / 128, 5), blk, 0, stream>>>(a5b, w2t, xa, xx, margs);

    // w path: tanh(xw@tdw1) -> decay d = exp(-exp(@tdw2 + time_decay))
    wconv_kernel<<<dim3(64 / 32, C / 32), tblk, 0, stream>>>(tdw1, wBuf, C, 64);
    bgemm_kernel<64, BEPI_TANH_BF><<<dim3(1, BT / 128), blk, 0, stream>>>(xwb, wBuf, t1b, BT, 64, C, nullptr, nullptr, nullptr);
    wconv_kernel<<<dim3(C / 32, 64 / 32), tblk, 0, stream>>>(tdw2, wBuf, 64, C);
    bgemm_kernel<64, BEPI_DECAY_F><<<gNN, blk, 0, stream>>>(t1b, wBuf, wd, BT, C, 64, time_dec, nullptr, nullptr);

    // batched QKVG
    Wconv4Args wargs;
    wargs.W[0] = Wk; wargs.W[1] = Wv; wargs.W[2] = Wr; wargs.W[3] = Wg;
    wconv4_kernel<<<dim3(C / 32, C / 32, 4), tblk, 0, stream>>>(wargs, wBuf);
    QkvgArgs qargs;
    qargs.A[0] = bf1; qargs.A[1] = xvb; qargs.A[2] = xrb; qargs.A[3] = xgb;
    qargs.O[0] = kb;  qargs.O[1] = vb;  qargs.O[2] = rb;  qargs.O[3] = gb;
    qkvg_kernel<<<dim3(8, 16, 4), blk, 0, stream>>>(qargs, wBuf);

    // chunked bidirectional WKV (Mbuf overlays fs+wBuf; yf/yb = xa/xx f32)
    wkv_pass1<<<dim3(2 * B * H * NCH), blk, 0, stream>>>(kb, vb, wd, Mbuf, Dbuf);
    wkv_pass2<<<dim3(2 * B * H), dim3(1024), 0, stream>>>(Mbuf, Dbuf);
    wkv_pass3<<<dim3(2 * B * H * NCH), blk, 0, stream>>>(rb, kb, vb, wd, Mbuf, xa, xx);

    // ya = groupnorm(yf+yb+sig*v)*g ; out = x + ya @ Wo^T
    gnmul_kernel<<<BT, dim3(1024), 0, stream>>>(xa, xx, lnx_g, lnx_b, gb, vb, rb, kb, u, vb);
    wconv_kernel<<<dim3(C / 32, C / 32), tblk, 0, stream>>>(Wo, wBuf, C, C);
    bgemm_kernel<64, BEPI_RES_F><<<gNN, blk, 0, stream>>>(vb, wBuf, out, BT, C, C, x, nullptr, nullptr);

    // ---- FFN branch ----
    ln_kernel<<<BT, blk, 0, stream>>>(out, ln2_g, ln2_b, wd);
    bshiftcmix_kernel<<<EW, blk, 0, stream>>>(wd, cmaa_k, cmaa_r, bf1, gb);
    wconv_kernel<<<dim3(FF / 32, C / 32), tblk, 0, stream>>>(Wck, wBuf, C, FF);
    bgemm_kernel<128, BEPI_RELUSQ_BF><<<dim3(FF / 128, BT / 128), blk, 0, stream>>>(bf1, wBuf, kk, BT, FF, C, nullptr, nullptr, nullptr);
    wconv_kernel<<<dim3(C / 32, FF / 32), tblk, 0, stream>>>(Wcv, wBuf, FF, C);
    wcv_kernel<<<dim3(16, 16, 2), blk, 0, stream>>>(kk, wBuf, fs, wd);
    wconv_kernel<<<dim3(C / 32, C / 32), tblk, 0, stream>>>(Wcr, wBuf, C, C);
    bgemm_kernel<64, BEPI_SIGRES2_F><<<gNN, blk, 0, stream>>>(gb, wBuf, out, BT, C, C, out, fs, wd);

    (void)in_sizes; (void)n_in; (void)out_size; (void)ws_size;
}

// Round 12
// 293.901 us; speedup vs baseline: 4.9075x; 1.0174x over previous
//
#include <hip/hip_runtime.h>
#include <math.h>
#include <stdint.h>

static constexpr int B  = 8;
static constexpr int T  = 256;
static constexpr int C  = 1024;
static constexpr int H  = 16;
static constexpr int HEAD = 64;
static constexpr int FF = 4096;
static constexpr int BT = B * T;
static constexpr int NCH = 8;       // time chunks
static constexpr int CS  = 32;      // chunk size (NCH*CS == T)

typedef short short8  __attribute__((ext_vector_type(8)));
typedef float floatx4 __attribute__((ext_vector_type(4)));

// ---------------- bf16 helpers ----------------
__device__ __forceinline__ float bf2f(ushort u) {
    return __uint_as_float(((uint32_t)u) << 16);
}
__device__ __forceinline__ ushort f2bf(float x) {
    uint32_t u = __float_as_uint(x);
    u += 0x7fff + ((u >> 16) & 1);          // RNE
    return (ushort)(u >> 16);
}

__device__ __forceinline__ void gload16(const void* g, void* l) {
    __builtin_amdgcn_global_load_lds(
        (const __attribute__((address_space(1))) unsigned int*)g,
        (__attribute__((address_space(3))) unsigned int*)l, 16, 0, 0);
}

// ---------------- epilogue ids ----------------
#define BEPI_NONE_BF   0
#define BEPI_SILU_BF   1
#define BEPI_RELUSQ_BF 2
#define BEPI_NONE_F    3
#define BEPI_RES_F     4
#define BEPI_SIGRES_F  5
#define BEPI_TANH_F    6
#define BEPI_TANH_BF   7
#define BEPI_DECAY_F   8
#define BEPI_SIGRES2_F 9

// ---------------- LayerNorm ----------------
__global__ __launch_bounds__(256) void ln_kernel(const float* __restrict__ x,
                                                 const float* __restrict__ g,
                                                 const float* __restrict__ b,
                                                 float* __restrict__ out)
{
    const int row = blockIdx.x;
    const int tid = threadIdx.x;
    const float4 v = reinterpret_cast<const float4*>(x + (size_t)row * C)[tid];
    float s = v.x + v.y + v.z + v.w;
#pragma unroll
    for (int off = 32; off > 0; off >>= 1) s += __shfl_xor(s, off);
    __shared__ float red[8];
    const int wave = tid >> 6, lane = tid & 63;
    if (lane == 0) red[wave] = s;
    __syncthreads();
    const float mean = (red[0] + red[1] + red[2] + red[3]) * (1.0f / C);
    const float d0 = v.x - mean, d1 = v.y - mean, d2 = v.z - mean, d3 = v.w - mean;
    float q = d0 * d0 + d1 * d1 + d2 * d2 + d3 * d3;
#pragma unroll
    for (int off = 32; off > 0; off >>= 1) q += __shfl_xor(q, off);
    if (lane == 0) red[4 + wave] = q;
    __syncthreads();
    const float var = (red[4] + red[5] + red[6] + red[7]) * (1.0f / C);
    const float rstd = rsqrtf(var + 1e-5f);
    const int c = tid * 4;
    float4 o;
    o.x = d0 * rstd * g[c + 0] + b[c + 0];
    o.y = d1 * rstd * g[c + 1] + b[c + 1];
    o.z = d2 * rstd * g[c + 2] + b[c + 2];
    o.w = d3 * rstd * g[c + 3] + b[c + 3];
    reinterpret_cast<float4*>(out + (size_t)row * C)[tid] = o;
}

// ---- fused bshift+mixax: xx = bshift(xa)-xa (f32), ax = bf16(xa + xx*maa) ----
__global__ __launch_bounds__(256) void bshiftmix_kernel(const float* __restrict__ xa,
                                                        const float* __restrict__ maa,
                                                        float* __restrict__ xx,
                                                        ushort* __restrict__ ax)
{
    const int i = blockIdx.x * 256 + threadIdx.x;
    const int c = i & (C - 1);
    const int bt = i >> 10;
    const int t = bt & (T - 1);
    const int j = c & (HEAD - 1);
    float src = 0.f;
    if (j < HEAD / 2) { if (t > 0)     src = xa[i - C]; }
    else              { if (t < T - 1) src = xa[i + C]; }
    const float a = xa[i];
    const float xv = src - a;
    xx[i] = xv;
    ax[i] = f2bf(a + xv * maa[c]);
}

// ---- fused FFN bshift+cmix: two bf16 mixed outputs, no xx materialization ----
__global__ __launch_bounds__(256) void bshiftcmix_kernel(const float* __restrict__ xc,
                                                         const float* __restrict__ mk,
                                                         const float* __restrict__ mr,
                                                         ushort* __restrict__ ok,
                                                         ushort* __restrict__ orr)
{
    const int i = blockIdx.x * 256 + threadIdx.x;
    const int c = i & (C - 1);
    const int bt = i >> 10;
    const int t = bt & (T - 1);
    const int j = c & (HEAD - 1);
    float src = 0.f;
    if (j < HEAD / 2) { if (t > 0)     src = xc[i - C]; }
    else              { if (t < T - 1) src = xc[i + C]; }
    const float a = xc[i];
    const float cxx = src - a;
    ok[i]  = f2bf(a + cxx * mk[c]);
    orr[i] = f2bf(a + cxx * mr[c]);
}

// -------- GroupNorm(yf+yb+sig*v)*g+b, * gate; u-bonus scalar fused ---------
__global__ __launch_bounds__(1024) void gnmul_kernel(const float* __restrict__ yf,
                                                     const float* __restrict__ yb,
                                                     const float* __restrict__ g,
                                                     const float* __restrict__ b,
                                                     const ushort* __restrict__ gate,
                                                     const ushort* __restrict__ vin,
                                                     const ushort* __restrict__ rbuf,
                                                     const ushort* __restrict__ kbuf,
                                                     const float* __restrict__ u,
                                                     ushort* __restrict__ out)
{
    const int row = blockIdx.x;
    const int tid = threadIdx.x;                 // wave == head
    const size_t idx = (size_t)row * C + tid;
    float p = bf2f(rbuf[idx]) * bf2f(kbuf[idx]) * u[tid];
#pragma unroll
    for (int off = 32; off > 0; off >>= 1) p += __shfl_xor(p, off);
    const float v = yf[idx] + yb[idx] + p * bf2f(vin[idx]);
    float s = v;
#pragma unroll
    for (int off = 32; off > 0; off >>= 1) s += __shfl_xor(s, off);
    const float m = s * (1.0f / HEAD);
    const float d = v - m;
    float q = d * d;
#pragma unroll
    for (int off = 32; off > 0; off >>= 1) q += __shfl_xor(q, off);
    const float rstd = rsqrtf(q * (1.0f / HEAD) + 6.4e-4f);
    out[idx] = f2bf((d * rstd * g[tid] + b[tid]) * bf2f(gate[idx]));
}

// -------- weight convert+transpose: W[Kd,Nd] f32 -> Wt[Nd,Kd] bf16 --------
__global__ __launch_bounds__(256) void wconv_kernel(const float* __restrict__ W,
                                                    ushort* __restrict__ Wt,
                                                    int Kd, int Nd)
{
    __shared__ float tile[32][33];
    const int n0 = blockIdx.x * 32, k0 = blockIdx.y * 32;
    const int tx = threadIdx.x, ty = threadIdx.y;
#pragma unroll
    for (int i = 0; i < 4; ++i)
        tile[ty * 4 + i][tx] = W[(size_t)(k0 + ty * 4 + i) * Nd + n0 + tx];
    __syncthreads();
#pragma unroll
    for (int i = 0; i < 4; ++i)
        Wt[(size_t)(n0 + ty * 4 + i) * Kd + k0 + tx] = f2bf(tile[tx][ty * 4 + i]);
}

// -------- w2 slices: w2[5][32][C] -> w2t[5][C][32] bf16, one launch --------
__global__ __launch_bounds__(256) void w2conv_kernel(const float* __restrict__ w2,
                                                     ushort* __restrict__ w2t)
{
    __shared__ float tile[32][33];
    const int f = blockIdx.y;
    const int n0 = blockIdx.x * 32;
    const int tx = threadIdx.x, ty = threadIdx.y;
#pragma unroll
    for (int i = 0; i < 4; ++i)
        tile[ty * 4 + i][tx] = w2[(size_t)f * 32 * C + (size_t)(ty * 4 + i) * C + n0 + tx];
    __syncthreads();
#pragma unroll
    for (int i = 0; i < 4; ++i)
        w2t[(size_t)f * C * 32 + (size_t)(n0 + ty * 4 + i) * 32 + tx] = f2bf(tile[tx][ty * 4 + i]);
}

// -------- batched wconv: 4 C x C weights (blockIdx.z) --------
struct Wconv4Args { const float* W[4]; };
__global__ __launch_bounds__(256) void wconv4_kernel(Wconv4Args args, ushort* __restrict__ Wt)
{
    __shared__ float tile[32][33];
    const int z = blockIdx.z;
    const float* __restrict__ W = args.W[z];
    ushort* __restrict__ dst = Wt + (size_t)z * C * C;
    const int n0 = blockIdx.x * 32, k0 = blockIdx.y * 32;
    const int tx = threadIdx.x, ty = threadIdx.y;
#pragma unroll
    for (int i = 0; i < 4; ++i)
        tile[ty * 4 + i][tx] = W[(size_t)(k0 + ty * 4 + i) * C + n0 + tx];
    __syncthreads();
#pragma unroll
    for (int i = 0; i < 4; ++i)
        dst[(size_t)(n0 + ty * 4 + i) * C + k0 + tx] = f2bf(tile[tx][ty * 4 + i]);
}

// ======== mix5 as fused MFMA GEMM: out_f = bf16(xa + xx*(maa_f + a5b@w2t_f)) ====
struct Mix5Args { const float* maa[5]; ushort* out[5]; };
__global__ __launch_bounds__(256) void mix5m_kernel(const ushort* __restrict__ a5b,
                                                    const ushort* __restrict__ w2t,
                                                    const float* __restrict__ xa,
                                                    const float* __restrict__ xx,
                                                    Mix5Args args)
{
    __shared__ __align__(16) ushort As[128 * 32];
    __shared__ __align__(16) ushort Bs[64 * 32];
    const int f = blockIdx.z;
    const int bm = blockIdx.y * 128, bn = blockIdx.x * 64;
    const int tid = threadIdx.x;
    const int wid = tid >> 6, lane = tid & 63;
    const int wr = wid >> 1, wc = wid & 1;
    const int l15 = lane & 15, lhi = lane >> 4;

#pragma unroll
    for (int p = 0; p < 2; ++p) {
        const int lin = p * 256 + tid;
        const int row = lin >> 2;
        const int sp = (lin & 3) ^ ((row >> 1) & 3);
        gload16(a5b + (size_t)(bm + row) * 160 + f * 32 + sp * 8, &As[lin * 8]);
    }
    {
        const int lin = tid;
        const int n = lin >> 2;
        const int sp = (lin & 3) ^ ((n >> 1) & 3);
        gload16(w2t + ((size_t)f * C + bn + n) * 32 + sp * 8, &Bs[lin * 8]);
    }
    __syncthreads();

    short8 af[4], bfr[2];
#pragma unroll
    for (int m = 0; m < 4; ++m) {
        const int row = wr * 64 + m * 16 + l15;
        const int sp = lhi ^ ((row >> 1) & 3);
        af[m] = *(const short8*)&As[row * 32 + sp * 8];
    }
#pragma unroll
    for (int n = 0; n < 2; ++n) {
        const int col = wc * 32 + n * 16 + l15;
        const int sp = lhi ^ ((col >> 1) & 3);
        bfr[n] = *(const short8*)&Bs[col * 32 + sp * 8];
    }
    floatx4 acc[4][2];
#pragma unroll
    for (int m = 0; m < 4; ++m)
#pragma unroll
        for (int n = 0; n < 2; ++n)
            acc[m][n] = __builtin_amdgcn_mfma_f32_16x16x32_bf16(
                af[m], bfr[n], (floatx4){0.f, 0.f, 0.f, 0.f}, 0, 0, 0);

    const float* __restrict__ maa = args.maa[f];
    ushort* __restrict__ out = args.out[f];
#pragma unroll
    for (int m = 0; m < 4; ++m) {
        const int row0 = bm + wr * 64 + m * 16 + lhi * 4;
#pragma unroll
        for (int n = 0; n < 2; ++n) {
            const int col = bn + wc * 32 + n * 16 + l15;
            const float mc = maa[col];
#pragma unroll
            for (int j = 0; j < 4; ++j) {
                const size_t oi = (size_t)(row0 + j) * C + col;
                out[oi] = f2bf(xa[oi] + xx[oi] * (mc + acc[m][n][j]));
            }
        }
    }
}

// ================== chunked bidirectional WKV6, LDS-staged ==================
// pass1: block = one (unit,chunk); 4 waves = 4 j-slices; chunk operands staged
// in LDS once, v column in registers; pure FMA loop.
__global__ __launch_bounds__(256) void wkv_pass1(const ushort* __restrict__ k,
                                                 const ushort* __restrict__ v,
                                                 const float* __restrict__ d,
                                                 ushort* __restrict__ M,
                                                 float* __restrict__ D)
{
    const int uc = blockIdx.x;
    const int w = threadIdx.x >> 6, lane = threadIdx.x & 63;
    const int c = uc & (NCH - 1), unit = uc >> 3;
    const int dir = unit & 1, bh = unit >> 1;
    const int jb = w * 16;
    const size_t rowb = ((size_t)(bh >> 4) * T * H + (bh & 15)) * HEAD;
    __shared__ float Lk[4][CS][16], Ld[4][CS][16];      // 16 KB

    const int s0 = c * CS;
    for (int idx = lane; idx < CS * 16; idx += 64) {
        const int s = idx >> 4, jj = idx & 15;
        const int t = dir ? (T - 1 - (s0 + s)) : (s0 + s);
        const size_t g = rowb + (size_t)t * (H * HEAD) + jb + jj;
        Lk[w][s][jj] = bf2f(k[g]);
        Ld[w][s][jj] = d[g];
    }
    float vr[CS];
#pragma unroll
    for (int s = 0; s < CS; ++s) {
        const int t = dir ? (T - 1 - (s0 + s)) : (s0 + s);
        vr[s] = bf2f(v[rowb + (size_t)t * (H * HEAD) + lane]);
    }
    __syncthreads();

    float S[16];
#pragma unroll
    for (int j = 0; j < 16; ++j) S[j] = 0.f;

    for (int ss = 0; ss < CS; ++ss) {
        const float vv = vr[ss];
        const float* __restrict__ sk = Lk[w][ss];
        const float* __restrict__ sd = Ld[w][ss];
#pragma unroll
        for (int jj = 0; jj < 16; jj += 4) {
            const float4 k4 = *reinterpret_cast<const float4*>(&sk[jj]);
            const float4 d4 = *reinterpret_cast<const float4*>(&sd[jj]);
            S[jj + 0] = fmaf(d4.x, S[jj + 0], k4.x * vv);
            S[jj + 1] = fmaf(d4.y, S[jj + 1], k4.y * vv);
            S[jj + 2] = fmaf(d4.z, S[jj + 2], k4.z * vv);
            S[jj + 3] = fmaf(d4.w, S[jj + 3], k4.w * vv);
        }
    }
    const size_t mb = (size_t)uc * 4096 + (size_t)jb * 64 + lane;
#pragma unroll
    for (int j = 0; j < 16; ++j) M[mb + j * 64] = f2bf(S[j]);
    if (lane < 16) {
        float PD = 1.f;
#pragma unroll
        for (int s = 0; s < CS; ++s) PD *= Ld[w][s][lane];
        D[(size_t)uc * 64 + jb + lane] = PD;
    }
}

// pass2 (parallel): 1024 threads/unit, thread owns 4 state elements
__global__ __launch_bounds__(1024) void wkv_pass2(ushort* __restrict__ M,
                                                  const float* __restrict__ D)
{
    const int unit = blockIdx.x;
    const int tid = threadIdx.x;
    const int j = tid >> 4;
    float S0 = 0.f, S1 = 0.f, S2 = 0.f, S3 = 0.f;
#pragma unroll
    for (int c = 0; c < NCH; ++c) {
        const int uc = unit * NCH + c;
        const float Dj = D[(size_t)uc * 64 + j];
        ushort* mp = M + (size_t)uc * 4096 + tid * 4;
        const uint2 mv = *reinterpret_cast<const uint2*>(mp);
        const float m0 = bf2f((ushort)(mv.x & 0xffff));
        const float m1 = bf2f((ushort)(mv.x >> 16));
        const float m2 = bf2f((ushort)(mv.y & 0xffff));
        const float m3 = bf2f((ushort)(mv.y >> 16));
        uint2 sv;
        sv.x = (uint32_t)f2bf(S0) | ((uint32_t)f2bf(S1) << 16);
        sv.y = (uint32_t)f2bf(S2) | ((uint32_t)f2bf(S3) << 16);
        *reinterpret_cast<uint2*>(mp) = sv;
        S0 = fmaf(Dj, S0, m0);
        S1 = fmaf(Dj, S1, m1);
        S2 = fmaf(Dj, S2, m2);
        S3 = fmaf(Dj, S3, m3);
    }
}

// pass3: block = one (unit,chunk); 4 waves = 4 j-slices; LDS-staged r/k/d,
// v column in regs; psum in LDS; one barrier; cooperative coalesced f32 store.
__global__ __launch_bounds__(256) void wkv_pass3(const ushort* __restrict__ r,
                                                 const ushort* __restrict__ k,
                                                 const ushort* __restrict__ v,
                                                 const float* __restrict__ d,
                                                 const ushort* __restrict__ Sin,
                                                 float* __restrict__ yf,
                                                 float* __restrict__ yb)
{
    const int uc = blockIdx.x;
    const int w = threadIdx.x >> 6, lane = threadIdx.x & 63;
    const int c = uc & (NCH - 1), unit = uc >> 3;
    const int dir = unit & 1, bh = unit >> 1;
    const int jb = w * 16;
    const size_t rowb = ((size_t)(bh >> 4) * T * H + (bh & 15)) * HEAD;
    __shared__ float Lr[4][CS][16], Lk[4][CS][16], Ld[4][CS][16];   // 24 KB
    __shared__ ushort psum[4][CS][64];                              // 4 KB

    const int s0 = c * CS;
    for (int idx = lane; idx < CS * 16; idx += 64) {
        const int s = idx >> 4, jj = idx & 15;
        const int t = dir ? (T - 1 - (s0 + s)) : (s0 + s);
        const size_t g = rowb + (size_t)t * (H * HEAD) + jb + jj;
        Lr[w][s][jj] = bf2f(r[g]);
        Lk[w][s][jj] = bf2f(k[g]);
        Ld[w][s][jj] = d[g];
    }
    float vr[CS];
#pragma unroll
    for (int s = 0; s < CS; ++s) {
        const int t = dir ? (T - 1 - (s0 + s)) : (s0 + s);
        vr[s] = bf2f(v[rowb + (size_t)t * (H * HEAD) + lane]);
    }
    __syncthreads();

    float S[16];
    const size_t mb = (size_t)uc * 4096 + (size_t)jb * 64 + lane;
#pragma unroll
    for (int j = 0; j < 16; ++j) S[j] = bf2f(Sin[mb + j * 64]);

    for (int ss = 0; ss < CS; ++ss) {
        const float vv = vr[ss];
        const float* __restrict__ sr = Lr[w][ss];
        const float* __restrict__ sk = Lk[w][ss];
        const float* __restrict__ sd = Ld[w][ss];
        float y0 = 0.f, y1 = 0.f, y2 = 0.f, y3 = 0.f;
#pragma unroll
        for (int jj = 0; jj < 16; jj += 4) {
            const float4 r4 = *reinterpret_cast<const float4*>(&sr[jj]);
            const float4 k4 = *reinterpret_cast<const float4*>(&sk[jj]);
            const float4 d4 = *reinterpret_cast<const float4*>(&sd[jj]);
            y0 = fmaf(r4.x, S[jj + 0], y0);
            S[jj + 0] = fmaf(d4.x, S[jj + 0], k4.x * vv);
            y1 = fmaf(r4.y, S[jj + 1], y1);
            S[jj + 1] = fmaf(d4.y, S[jj + 1], k4.y * vv);
            y2 = fmaf(r4.z, S[jj + 2], y2);
            S[jj + 2] = fmaf(d4.z, S[jj + 2], k4.z * vv);
            y3 = fmaf(r4.w, S[jj + 3], y3);
            S[jj + 3] = fmaf(d4.w, S[jj + 3], k4.w * vv);
        }
        psum[w][ss][lane] = f2bf((y0 + y1) + (y2 + y3));
    }
    __syncthreads();
    float* __restrict__ yo = dir ? yb : yf;
    for (int idx = threadIdx.x; idx < CS * 64; idx += 256) {
        const int s = idx >> 6, i = idx & 63;
        const float sum = bf2f(psum[0][s][i]) + bf2f(psum[1][s][i]) +
                          bf2f(psum[2][s][i]) + bf2f(psum[3][s][i]);
        const int sg = c * CS + s;
        const int t = dir ? (T - 1 - sg) : sg;
        yo[rowb + (size_t)t * (H * HEAD) + i] = sum;
    }
}

// ======== pipelined bf16 MFMA GEMM core: BM=128, BK=64, BN in {64,128} ========
template <int BN>
struct GemmLds {
    ushort As[2][128 * 64];
    ushort Bs[2][BN * 64];
};

template <int BN>
__device__ __forceinline__ void gemm_body(const ushort* __restrict__ A,
                                          const ushort* __restrict__ Bt,
                                          int bm, int bn, int K, int lda, int ldb,
                                          GemmLds<BN>& lds,
                                          floatx4 (&acc)[4][BN / 32])
{
    constexpr int NF = BN / 32;
    const int tid = threadIdx.x;
    const int wid = tid >> 6, lane = tid & 63;
    const int wr = wid >> 1, wc = wid & 1;
    const int l15 = lane & 15, lhi = lane >> 4;
    const int NT = K >> 6;

    auto stage = [&](int buf, int k0) {
#pragma unroll
        for (int p = 0; p < 4; ++p) {
            const int lin = p * 256 + tid;
            const int row = lin >> 3;
            const int cs = (lin & 7) ^ (row & 7);
            gload16(A + (size_t)(bm + row) * lda + k0 + cs * 8, &lds.As[buf][lin * 8]);
        }
#pragma unroll
        for (int p = 0; p < NF; ++p) {
            const int lin = p * 256 + tid;
            const int n = lin >> 3;
            const int cs = (lin & 7) ^ (n & 7);
            gload16(Bt + (size_t)(bn + n) * ldb + k0 + cs * 8, &lds.Bs[buf][lin * 8]);
        }
    };

    stage(0, 0);
    __syncthreads();
    for (int t = 0; t < NT; ++t) {
        const int cur = t & 1;
        if (t + 1 < NT) stage(cur ^ 1, (t + 1) << 6);

        short8 af[4][2];
#pragma unroll
        for (int m = 0; m < 4; ++m) {
            const int row = wr * 64 + m * 16 + l15;
#pragma unroll
            for (int s = 0; s < 2; ++s) {
                const int cc = (s * 4 + lhi) ^ (row & 7);
                af[m][s] = *(const short8*)&lds.As[cur][row * 64 + cc * 8];
            }
        }
        short8 bf[NF][2];
#pragma unroll
        for (int n = 0; n < NF; ++n) {
            const int col = wc * (BN / 2) + n * 16 + l15;
#pragma unroll
            for (int s = 0; s < 2; ++s) {
                const int cc = (s * 4 + lhi) ^ (col & 7);
                bf[n][s] = *(const short8*)&lds.Bs[cur][col * 64 + cc * 8];
            }
        }
#pragma unroll
        for (int m = 0; m < 4; ++m)
#pragma unroll
            for (int n = 0; n < NF; ++n) {
                acc[m][n] = __builtin_amdgcn_mfma_f32_16x16x32_bf16(af[m][0], bf[n][0], acc[m][n], 0, 0, 0);
                acc[m][n] = __builtin_amdgcn_mfma_f32_16x16x32_bf16(af[m][1], bf[n][1], acc[m][n], 0, 0, 0);
            }
        __syncthreads();
    }
}

template <int BN, int EPI>
__global__ __launch_bounds__(256) void bgemm_kernel(const ushort* __restrict__ A,
                                                    const ushort* __restrict__ Bt,
                                                    void* __restrict__ Cm,
                                                    int M, int N, int K,
                                                    const float* __restrict__ aux1,
                                                    const float* __restrict__ aux2,
                                                    const float* __restrict__ aux3)
{
    constexpr int NF = BN / 32;
    __shared__ GemmLds<BN> lds;
    int w = blockIdx.y * gridDim.x + blockIdx.x;
    const int nwg = gridDim.x * gridDim.y;
    if ((nwg & 7) == 0) w = (w & 7) * (nwg >> 3) + (w >> 3);   // XCD swizzle
    const int bn = (w % gridDim.x) * BN;
    const int bm = (w / gridDim.x) * 128;
    const int tid = threadIdx.x;
    const int wid = tid >> 6, lane = tid & 63;
    const int wr = wid >> 1, wc = wid & 1;
    const int l15 = lane & 15, lhi = lane >> 4;

    floatx4 acc[4][NF];
#pragma unroll
    for (int m = 0; m < 4; ++m)
#pragma unroll
        for (int n = 0; n < NF; ++n) acc[m][n] = (floatx4){0.f, 0.f, 0.f, 0.f};

    gemm_body<BN>(A, Bt, bm, bn, K, K, K, lds, acc);

#pragma unroll
    for (int m = 0; m < 4; ++m) {
        const int row0 = bm + wr * 64 + m * 16 + lhi * 4;
#pragma unroll
        for (int n = 0; n < NF; ++n) {
            const int col = bn + wc * (BN / 2) + n * 16 + l15;
            if (col >= N) continue;
#pragma unroll
            for (int j = 0; j < 4; ++j) {
                const size_t oi = (size_t)(row0 + j) * N + col;
                const float a = acc[m][n][j];
                if constexpr (EPI == BEPI_NONE_BF) {
                    ((ushort*)Cm)[oi] = f2bf(a);
                } else if constexpr (EPI == BEPI_SILU_BF) {
                    ((ushort*)Cm)[oi] = f2bf(a / (1.f + __expf(-a)));
                } else if constexpr (EPI == BEPI_RELUSQ_BF) {
                    const float t = fmaxf(a, 0.f);
                    ((ushort*)Cm)[oi] = f2bf(t * t);
                } else if constexpr (EPI == BEPI_NONE_F) {
                    ((float*)Cm)[oi] = a;
                } else if constexpr (EPI == BEPI_RES_F) {
                    ((float*)Cm)[oi] = aux1[oi] + a;
                } else if constexpr (EPI == BEPI_SIGRES_F) {
                    ((float*)Cm)[oi] = aux1[oi] + aux2[oi] / (1.f + __expf(-a));
                } else if constexpr (EPI == BEPI_SIGRES2_F) {
                    ((float*)Cm)[oi] = aux1[oi] + (aux2[oi] + aux3[oi]) / (1.f + __expf(-a));
                } else if constexpr (EPI == BEPI_TANH_F) {
                    ((float*)Cm)[oi] = tanhf(a);
                } else if constexpr (EPI == BEPI_TANH_BF) {
                    ((ushort*)Cm)[oi] = f2bf(tanhf(a));
                } else {  // BEPI_DECAY_F
                    ((float*)Cm)[oi] = __expf(-__expf(a + aux1[col]));
                }
            }
        }
    }
}

// -------- Wcv split-K=2: z = K-half; f32 partials to P0/P1 --------
__global__ __launch_bounds__(256) void wcv_kernel(const ushort* __restrict__ A,
                                                  const ushort* __restrict__ Bt,
                                                  float* __restrict__ P0,
                                                  float* __restrict__ P1)
{
    __shared__ GemmLds<64> lds;
    const int z = blockIdx.z;
    int w = blockIdx.y * gridDim.x + blockIdx.x;   // 16x16 = 256
    w = (w & 7) * 32 + (w >> 3);                    // XCD swizzle
    const int bn = (w % 16) * 64;
    const int bm = (w / 16) * 128;
    const int tid = threadIdx.x;
    const int wid = tid >> 6, lane = tid & 63;
    const int wr = wid >> 1, wc = wid & 1;
    const int l15 = lane & 15, lhi = lane >> 4;

    floatx4 acc[4][2];
#pragma unroll
    for (int m = 0; m < 4; ++m)
#pragma unroll
        for (int n = 0; n < 2; ++n) acc[m][n] = (floatx4){0.f, 0.f, 0.f, 0.f};

    gemm_body<64>(A + z * (FF / 2), Bt + z * (FF / 2), bm, bn, FF / 2, FF, FF, lds, acc);

    float* __restrict__ P = z ? P1 : P0;
#pragma unroll
    for (int m = 0; m < 4; ++m) {
        const int row0 = bm + wr * 64 + m * 16 + lhi * 4;
#pragma unroll
        for (int n = 0; n < 2; ++n) {
            const int col = bn + wc * 32 + n * 16 + l15;
#pragma unroll
            for (int j = 0; j < 4; ++j)
                P[(size_t)(row0 + j) * C + col] = acc[m][n][j];
        }
    }
}

// -------- batched QKVG GEMM (BN=128): blockIdx.z selects {k,v,r,g} --------
struct QkvgArgs { const ushort* A[4]; ushort* O[4]; };
__global__ __launch_bounds__(256) void qkvg_kernel(QkvgArgs args,
                                                   const ushort* __restrict__ Wt)
{
    __shared__ GemmLds<128> lds;
    const int z = blockIdx.z;
    int w = blockIdx.y * gridDim.x + blockIdx.x;          // 8 x 16 grid = 128
    w = (w & 7) * 16 + (w >> 3);                           // XCD swizzle
    const int bn = (w & 7) * 128;
    const int bm = (w >> 3) * 128;
    const int tid = threadIdx.x;
    const int wid = tid >> 6, lane = tid & 63;
    const int wr = wid >> 1, wc = wid & 1;
    const int l15 = lane & 15, lhi = lane >> 4;

    floatx4 acc[4][4];
#pragma unroll
    for (int m = 0; m < 4; ++m)
#pragma unroll
        for (int n = 0; n < 4; ++n) acc[m][n] = (floatx4){0.f, 0.f, 0.f, 0.f};

    gemm_body<128>(args.A[z], Wt + (size_t)z * C * C, bm, bn, C, C, C, lds, acc);

    ushort* __restrict__ O = args.O[z];
    const bool silu = (z == 3);
#pragma unroll
    for (int m = 0; m < 4; ++m) {
        const int row0 = bm + wr * 64 + m * 16 + lhi * 4;
#pragma unroll
        for (int n = 0; n < 4; ++n) {
            const int col = bn + wc * 64 + n * 16 + l15;
#pragma unroll
            for (int j = 0; j < 4; ++j) {
                float a = acc[m][n][j];
                if (silu) a = a / (1.f + __expf(-a));
                O[(size_t)(row0 + j) * C + col] = f2bf(a);
            }
        }
    }
}

// ---------------- launch ----------------
extern "C" void kernel_launch(void* const* d_in, const int* in_sizes, int n_in,
                              void* d_out, int out_size, void* d_ws, size_t ws_size,
                              hipStream_t stream)
{
    const float* x        = (const float*)d_in[0];
    const float* ln1_g    = (const float*)d_in[1];
    const float* ln1_b    = (const float*)d_in[2];
    const float* ln2_g    = (const float*)d_in[3];
    const float* ln2_b    = (const float*)d_in[4];
    const float* maa_x    = (const float*)d_in[5];
    const float* maa_w    = (const float*)d_in[6];
    const float* maa_k    = (const float*)d_in[7];
    const float* maa_v    = (const float*)d_in[8];
    const float* maa_r    = (const float*)d_in[9];
    const float* maa_g    = (const float*)d_in[10];
    const float* maa_w1   = (const float*)d_in[11];
    const float* maa_w2   = (const float*)d_in[12];
    const float* time_dec = (const float*)d_in[13];
    const float* tdw1     = (const float*)d_in[14];
    const float* tdw2     = (const float*)d_in[15];
    const float* u        = (const float*)d_in[16];
    const float* Wr       = (const float*)d_in[17];
    const float* Wk       = (const float*)d_in[18];
    const float* Wv       = (const float*)d_in[19];
    const float* Wg       = (const float*)d_in[20];
    const float* Wo       = (const float*)d_in[21];
    const float* lnx_g    = (const float*)d_in[22];
    const float* lnx_b    = (const float*)d_in[23];
    const float* cmaa_k   = (const float*)d_in[24];
    const float* cmaa_r   = (const float*)d_in[25];
    const float* Wck      = (const float*)d_in[26];
    const float* Wcv      = (const float*)d_in[27];
    const float* Wcr      = (const float*)d_in[28];
    float* out = (float*)d_out;

    // -------- workspace layout (~63 MB) --------
    float* fws = (float*)d_ws;
    const size_t E = (size_t)BT * C;            // 2,097,152
    float* xa  = fws + 0 * E;                   // xa -> yf ; (FFN) kk low half
    float* xx  = fws + 1 * E;                   // xx -> yb ; kk high half
    float* wd  = fws + 2 * E;                   // decay d -> xc -> kvB partial
    float* fs  = fws + 3 * E;                   // xvb/xrb ; M low ; kvA partial
    ushort* wBuf = (ushort*)(fws + 4 * E);      // 4M ushort: weights / M high
    ushort* Mbuf = (ushort*)fs;                 // 2048*4096 bf16 = fs..wBuf (16MB)
    ushort* w2t  = wBuf + (size_t)C * 160;      // 5*C*32 bf16 (after maa_w1t)
    ushort* bf1  = wBuf + (size_t)C * FF;       // E: ax / xkb / ck_in
    ushort* rb   = bf1 + E;                     // r
    ushort* kb   = rb + E;                      // k
    ushort* vb   = kb + E;                      // v  -> ya
    ushort* gb   = vb + E;                      // g  -> cr_in
    ushort* t1b  = gb + E;                      // BT*64 bf16
    float* a5    = (float*)(t1b + (size_t)BT * 64);   // BT*160 (a5b bf16 inside)
    float* sig   = a5 + (size_t)BT * 160;       // (unused)
    float* Dbuf  = sig + (size_t)BT * H;        // 2048*64 f32
    ushort* a5b  = (ushort*)a5;                 // BT*160 bf16
    ushort* xvb  = (ushort*)fs;                 // E (mix v input)
    ushort* xrb  = (ushort*)fs + E;             // E (mix r input)
    ushort* xgb  = (ushort*)out;                // E (mix g input; out is scratch)
    ushort* xwb  = (ushort*)out + E;            // E (mix w input)
    ushort* kk   = (ushort*)xa;                 // BT*FF bf16 == xa..xx

    const dim3 blk(256);
    const dim3 tblk(32, 8);
    const int EW = (BT * C) / 256;
    const dim3 gNN(C / 64, BT / 128);

    // ---- attention branch ----
    ln_kernel<<<BT, blk, 0, stream>>>(x, ln1_g, ln1_b, xa);
    bshiftmix_kernel<<<EW, blk, 0, stream>>>(xa, maa_x, xx, bf1);
    wconv_kernel<<<dim3(160 / 32, C / 32), tblk, 0, stream>>>(maa_w1, wBuf, C, 160);
    bgemm_kernel<64, BEPI_TANH_BF><<<dim3(3, BT / 128), blk, 0, stream>>>(bf1, wBuf, a5b, BT, 160, C, nullptr, nullptr, nullptr);

    // w2 slices -> [5][C][32] bf16 transposed (one launch)
    w2conv_kernel<<<dim3(C / 32, 5), tblk, 0, stream>>>(maa_w2, w2t);

    // all 5 mixes as one fused MFMA GEMM launch
    Mix5Args margs;
    margs.maa[0] = maa_w; margs.maa[1] = maa_k; margs.maa[2] = maa_v;
    margs.maa[3] = maa_r; margs.maa[4] = maa_g;
    margs.out[0] = xwb; margs.out[1] = bf1; margs.out[2] = xvb;
    margs.out[3] = xrb; margs.out[4] = xgb;
    mix5m_kernel<<<dim3(C / 64, BT / 128, 5), blk, 0, stream>>>(a5b, w2t, xa, xx, margs);

    // w path: tanh(xw@tdw1) -> decay d = exp(-exp(@tdw2 + time_decay))
    wconv_kernel<<<dim3(64 / 32, C / 32), tblk, 0, stream>>>(tdw1, wBuf, C, 64);
    bgemm_kernel<64, BEPI_TANH_BF><<<dim3(1, BT / 128), blk, 0, stream>>>(xwb, wBuf, t1b, BT, 64, C, nullptr, nullptr, nullptr);
    wconv_kernel<<<dim3(C / 32, 64 / 32), tblk, 0, stream>>>(tdw2, wBuf, 64, C);
    bgemm_kernel<64, BEPI_DECAY_F><<<gNN, blk, 0, stream>>>(t1b, wBuf, wd, BT, C, 64, time_dec, nullptr, nullptr);

    // batched QKVG
    Wconv4Args wargs;
    wargs.W[0] = Wk; wargs.W[1] = Wv; wargs.W[2] = Wr; wargs.W[3] = Wg;
    wconv4_kernel<<<dim3(C / 32, C / 32, 4), tblk, 0, stream>>>(wargs, wBuf);
    QkvgArgs qargs;
    qargs.A[0] = bf1; qargs.A[1] = xvb; qargs.A[2] = xrb; qargs.A[3] = xgb;
    qargs.O[0] = kb;  qargs.O[1] = vb;  qargs.O[2] = rb;  qargs.O[3] = gb;
    qkvg_kernel<<<dim3(8, 16, 4), blk, 0, stream>>>(qargs, wBuf);

    // chunked bidirectional WKV (Mbuf overlays fs+wBuf; yf/yb = xa/xx f32)
    wkv_pass1<<<dim3(2 * B * H * NCH), blk, 0, stream>>>(kb, vb, wd, Mbuf, Dbuf);
    wkv_pass2<<<dim3(2 * B * H), dim3(1024), 0, stream>>>(Mbuf, Dbuf);
    wkv_pass3<<<dim3(2 * B * H * NCH), blk, 0, stream>>>(rb, kb, vb, wd, Mbuf, xa, xx);

    // ya = groupnorm(yf+yb+sig*v)*g ; out = x + ya @ Wo^T
    gnmul_kernel<<<BT, dim3(1024), 0, stream>>>(xa, xx, lnx_g, lnx_b, gb, vb, rb, kb, u, vb);
    wconv_kernel<<<dim3(C / 32, C / 32), tblk, 0, stream>>>(Wo, wBuf, C, C);
    bgemm_kernel<64, BEPI_RES_F><<<gNN, blk, 0, stream>>>(vb, wBuf, out, BT, C, C, x, nullptr, nullptr);

    // ---- FFN branch ----
    ln_kernel<<<BT, blk, 0, stream>>>(out, ln2_g, ln2_b, wd);
    bshiftcmix_kernel<<<EW, blk, 0, stream>>>(wd, cmaa_k, cmaa_r, bf1, gb);
    wconv_kernel<<<dim3(FF / 32, C / 32), tblk, 0, stream>>>(Wck, wBuf, C, FF);
    bgemm_kernel<128, BEPI_RELUSQ_BF><<<dim3(FF / 128, BT / 128), blk, 0, stream>>>(bf1, wBuf, kk, BT, FF, C, nullptr, nullptr, nullptr);
    wconv_kernel<<<dim3(C / 32, FF / 32), tblk, 0, stream>>>(Wcv, wBuf, FF, C);
    wcv_kernel<<<dim3(16, 16, 2), blk, 0, stream>>>(kk, wBuf, fs, wd);
    wconv_kernel<<<dim3(C / 32, C / 32), tblk, 0, stream>>>(Wcr, wBuf, C, C);
    bgemm_kernel<64, BEPI_SIGRES2_F><<<gNN, blk, 0, stream>>>(gb, wBuf, out, BT, C, C, out, fs, wd);

    (void)in_sizes; (void)n_in; (void)out_size; (void)ws_size;
}

// Round 13
// 268.544 us; speedup vs baseline: 5.3708x; 1.0944x over previous
//
#include <hip/hip_runtime.h>
#include <math.h>
#include <stdint.h>

static constexpr int B  = 8;
static constexpr int T  = 256;
static constexpr int C  = 1024;
static constexpr int H  = 16;
static constexpr int HEAD = 64;
static constexpr int FF = 4096;
static constexpr int BT = B * T;
static constexpr int NCH = 8;       // time chunks
static constexpr int CS  = 32;      // chunk size (NCH*CS == T)

typedef short short8  __attribute__((ext_vector_type(8)));
typedef float floatx4 __attribute__((ext_vector_type(4)));

// ---------------- bf16 helpers ----------------
__device__ __forceinline__ float bf2f(ushort u) {
    return __uint_as_float(((uint32_t)u) << 16);
}
__device__ __forceinline__ ushort f2bf(float x) {
    uint32_t u = __float_as_uint(x);
    u += 0x7fff + ((u >> 16) & 1);          // RNE
    return (ushort)(u >> 16);
}

__device__ __forceinline__ void gload16(const void* g, void* l) {
    __builtin_amdgcn_global_load_lds(
        (const __attribute__((address_space(1))) unsigned int*)g,
        (__attribute__((address_space(3))) unsigned int*)l, 16, 0, 0);
}

// ---------------- epilogue ids ----------------
#define BEPI_NONE_BF   0
#define BEPI_SILU_BF   1
#define BEPI_RELUSQ_BF 2
#define BEPI_NONE_F    3
#define BEPI_RES_F     4
#define BEPI_SIGRES_F  5
#define BEPI_TANH_F    6
#define BEPI_TANH_BF   7
#define BEPI_DECAY_F   8
#define BEPI_SIGRES2_F 9

// ---------------- LayerNorm ----------------
__global__ __launch_bounds__(256) void ln_kernel(const float* __restrict__ x,
                                                 const float* __restrict__ g,
                                                 const float* __restrict__ b,
                                                 float* __restrict__ out)
{
    const int row = blockIdx.x;
    const int tid = threadIdx.x;
    const float4 v = reinterpret_cast<const float4*>(x + (size_t)row * C)[tid];
    float s = v.x + v.y + v.z + v.w;
#pragma unroll
    for (int off = 32; off > 0; off >>= 1) s += __shfl_xor(s, off);
    __shared__ float red[8];
    const int wave = tid >> 6, lane = tid & 63;
    if (lane == 0) red[wave] = s;
    __syncthreads();
    const float mean = (red[0] + red[1] + red[2] + red[3]) * (1.0f / C);
    const float d0 = v.x - mean, d1 = v.y - mean, d2 = v.z - mean, d3 = v.w - mean;
    float q = d0 * d0 + d1 * d1 + d2 * d2 + d3 * d3;
#pragma unroll
    for (int off = 32; off > 0; off >>= 1) q += __shfl_xor(q, off);
    if (lane == 0) red[4 + wave] = q;
    __syncthreads();
    const float var = (red[4] + red[5] + red[6] + red[7]) * (1.0f / C);
    const float rstd = rsqrtf(var + 1e-5f);
    const int c = tid * 4;
    float4 o;
    o.x = d0 * rstd * g[c + 0] + b[c + 0];
    o.y = d1 * rstd * g[c + 1] + b[c + 1];
    o.z = d2 * rstd * g[c + 2] + b[c + 2];
    o.w = d3 * rstd * g[c + 3] + b[c + 3];
    reinterpret_cast<float4*>(out + (size_t)row * C)[tid] = o;
}

// ---- fused bshift+mixax: xx = bshift(xa)-xa (f32), ax = bf16(xa + xx*maa) ----
__global__ __launch_bounds__(256) void bshiftmix_kernel(const float* __restrict__ xa,
                                                        const float* __restrict__ maa,
                                                        float* __restrict__ xx,
                                                        ushort* __restrict__ ax)
{
    const int i = blockIdx.x * 256 + threadIdx.x;
    const int c = i & (C - 1);
    const int bt = i >> 10;
    const int t = bt & (T - 1);
    const int j = c & (HEAD - 1);
    float src = 0.f;
    if (j < HEAD / 2) { if (t > 0)     src = xa[i - C]; }
    else              { if (t < T - 1) src = xa[i + C]; }
    const float a = xa[i];
    const float xv = src - a;
    xx[i] = xv;
    ax[i] = f2bf(a + xv * maa[c]);
}

// ---- fused FFN bshift+cmix: two bf16 mixed outputs, no xx materialization ----
__global__ __launch_bounds__(256) void bshiftcmix_kernel(const float* __restrict__ xc,
                                                         const float* __restrict__ mk,
                                                         const float* __restrict__ mr,
                                                         ushort* __restrict__ ok,
                                                         ushort* __restrict__ orr)
{
    const int i = blockIdx.x * 256 + threadIdx.x;
    const int c = i & (C - 1);
    const int bt = i >> 10;
    const int t = bt & (T - 1);
    const int j = c & (HEAD - 1);
    float src = 0.f;
    if (j < HEAD / 2) { if (t > 0)     src = xc[i - C]; }
    else              { if (t < T - 1) src = xc[i + C]; }
    const float a = xc[i];
    const float cxx = src - a;
    ok[i]  = f2bf(a + cxx * mk[c]);
    orr[i] = f2bf(a + cxx * mr[c]);
}

// -------- GroupNorm(yf+yb+sig*v)*g+b, * gate; u-bonus scalar fused ---------
__global__ __launch_bounds__(1024) void gnmul_kernel(const float* __restrict__ yf,
                                                     const float* __restrict__ yb,
                                                     const float* __restrict__ g,
                                                     const float* __restrict__ b,
                                                     const ushort* __restrict__ gate,
                                                     const ushort* __restrict__ vin,
                                                     const ushort* __restrict__ rbuf,
                                                     const ushort* __restrict__ kbuf,
                                                     const float* __restrict__ u,
                                                     ushort* __restrict__ out)
{
    const int row = blockIdx.x;
    const int tid = threadIdx.x;                 // wave == head
    const size_t idx = (size_t)row * C + tid;
    float p = bf2f(rbuf[idx]) * bf2f(kbuf[idx]) * u[tid];
#pragma unroll
    for (int off = 32; off > 0; off >>= 1) p += __shfl_xor(p, off);
    const float v = yf[idx] + yb[idx] + p * bf2f(vin[idx]);
    float s = v;
#pragma unroll
    for (int off = 32; off > 0; off >>= 1) s += __shfl_xor(s, off);
    const float m = s * (1.0f / HEAD);
    const float d = v - m;
    float q = d * d;
#pragma unroll
    for (int off = 32; off > 0; off >>= 1) q += __shfl_xor(q, off);
    const float rstd = rsqrtf(q * (1.0f / HEAD) + 6.4e-4f);
    out[idx] = f2bf((d * rstd * g[tid] + b[tid]) * bf2f(gate[idx]));
}

// -------- weight convert+transpose: W[Kd,Nd] f32 -> Wt[Nd,Kd] bf16 --------
__global__ __launch_bounds__(256) void wconv_kernel(const float* __restrict__ W,
                                                    ushort* __restrict__ Wt,
                                                    int Kd, int Nd)
{
    __shared__ float tile[32][33];
    const int n0 = blockIdx.x * 32, k0 = blockIdx.y * 32;
    const int tx = threadIdx.x, ty = threadIdx.y;
#pragma unroll
    for (int i = 0; i < 4; ++i)
        tile[ty * 4 + i][tx] = W[(size_t)(k0 + ty * 4 + i) * Nd + n0 + tx];
    __syncthreads();
#pragma unroll
    for (int i = 0; i < 4; ++i)
        Wt[(size_t)(n0 + ty * 4 + i) * Kd + k0 + tx] = f2bf(tile[tx][ty * 4 + i]);
}

// -------- w2 slices: w2[5][32][C] -> w2t[5][C][32] bf16, one launch --------
__global__ __launch_bounds__(256) void w2conv_kernel(const float* __restrict__ w2,
                                                     ushort* __restrict__ w2t)
{
    __shared__ float tile[32][33];
    const int f = blockIdx.y;
    const int n0 = blockIdx.x * 32;
    const int tx = threadIdx.x, ty = threadIdx.y;
#pragma unroll
    for (int i = 0; i < 4; ++i)
        tile[ty * 4 + i][tx] = w2[(size_t)f * 32 * C + (size_t)(ty * 4 + i) * C + n0 + tx];
    __syncthreads();
#pragma unroll
    for (int i = 0; i < 4; ++i)
        w2t[(size_t)f * C * 32 + (size_t)(n0 + ty * 4 + i) * 32 + tx] = f2bf(tile[tx][ty * 4 + i]);
}

// -------- batched wconv: 4 C x C weights (blockIdx.z) --------
struct Wconv4Args { const float* W[4]; };
__global__ __launch_bounds__(256) void wconv4_kernel(Wconv4Args args, ushort* __restrict__ Wt)
{
    __shared__ float tile[32][33];
    const int z = blockIdx.z;
    const float* __restrict__ W = args.W[z];
    ushort* __restrict__ dst = Wt + (size_t)z * C * C;
    const int n0 = blockIdx.x * 32, k0 = blockIdx.y * 32;
    const int tx = threadIdx.x, ty = threadIdx.y;
#pragma unroll
    for (int i = 0; i < 4; ++i)
        tile[ty * 4 + i][tx] = W[(size_t)(k0 + ty * 4 + i) * C + n0 + tx];
    __syncthreads();
#pragma unroll
    for (int i = 0; i < 4; ++i)
        dst[(size_t)(n0 + ty * 4 + i) * C + k0 + tx] = f2bf(tile[tx][ty * 4 + i]);
}

// ======== mix5 as fused MFMA GEMM: out_f = bf16(xa + xx*(maa_f + a5b@w2t_f)) ====
struct Mix5Args { const float* maa[5]; ushort* out[5]; };
__global__ __launch_bounds__(256) void mix5m_kernel(const ushort* __restrict__ a5b,
                                                    const ushort* __restrict__ w2t,
                                                    const float* __restrict__ xa,
                                                    const float* __restrict__ xx,
                                                    Mix5Args args)
{
    __shared__ __align__(16) ushort As[128 * 32];
    __shared__ __align__(16) ushort Bs[64 * 32];
    const int f = blockIdx.z;
    const int bm = blockIdx.y * 128, bn = blockIdx.x * 64;
    const int tid = threadIdx.x;
    const int wid = tid >> 6, lane = tid & 63;
    const int wr = wid >> 1, wc = wid & 1;
    const int l15 = lane & 15, lhi = lane >> 4;

#pragma unroll
    for (int p = 0; p < 2; ++p) {
        const int lin = p * 256 + tid;
        const int row = lin >> 2;
        const int sp = (lin & 3) ^ ((row >> 1) & 3);
        gload16(a5b + (size_t)(bm + row) * 160 + f * 32 + sp * 8, &As[lin * 8]);
    }
    {
        const int lin = tid;
        const int n = lin >> 2;
        const int sp = (lin & 3) ^ ((n >> 1) & 3);
        gload16(w2t + ((size_t)f * C + bn + n) * 32 + sp * 8, &Bs[lin * 8]);
    }
    __syncthreads();

    short8 af[4], bfr[2];
#pragma unroll
    for (int m = 0; m < 4; ++m) {
        const int row = wr * 64 + m * 16 + l15;
        const int sp = lhi ^ ((row >> 1) & 3);
        af[m] = *(const short8*)&As[row * 32 + sp * 8];
    }
#pragma unroll
    for (int n = 0; n < 2; ++n) {
        const int col = wc * 32 + n * 16 + l15;
        const int sp = lhi ^ ((col >> 1) & 3);
        bfr[n] = *(const short8*)&Bs[col * 32 + sp * 8];
    }
    floatx4 acc[4][2];
#pragma unroll
    for (int m = 0; m < 4; ++m)
#pragma unroll
        for (int n = 0; n < 2; ++n)
            acc[m][n] = __builtin_amdgcn_mfma_f32_16x16x32_bf16(
                af[m], bfr[n], (floatx4){0.f, 0.f, 0.f, 0.f}, 0, 0, 0);

    const float* __restrict__ maa = args.maa[f];
    ushort* __restrict__ out = args.out[f];
#pragma unroll
    for (int m = 0; m < 4; ++m) {
        const int row0 = bm + wr * 64 + m * 16 + lhi * 4;
#pragma unroll
        for (int n = 0; n < 2; ++n) {
            const int col = bn + wc * 32 + n * 16 + l15;
            const float mc = maa[col];
#pragma unroll
            for (int j = 0; j < 4; ++j) {
                const size_t oi = (size_t)(row0 + j) * C + col;
                out[oi] = f2bf(xa[oi] + xx[oi] * (mc + acc[m][n][j]));
            }
        }
    }
}

// ================== chunked bidirectional WKV6 ==================
// pass1: block = one (unit,chunk); 4 waves = 4 j-slices; LDS-staged k/d,
// v column in regs; writes M TRANSPOSED: M[uc][i][j] (bf16), D[uc][j].
__global__ __launch_bounds__(256) void wkv_pass1(const ushort* __restrict__ k,
                                                 const ushort* __restrict__ v,
                                                 const float* __restrict__ d,
                                                 ushort* __restrict__ M,
                                                 float* __restrict__ D)
{
    const int uc = blockIdx.x;
    const int w = threadIdx.x >> 6, lane = threadIdx.x & 63;
    const int c = uc & (NCH - 1), unit = uc >> 3;
    const int dir = unit & 1, bh = unit >> 1;
    const int jb = w * 16;
    const size_t rowb = ((size_t)(bh >> 4) * T * H + (bh & 15)) * HEAD;
    __shared__ float Lk[4][CS][16], Ld[4][CS][16];      // 16 KB

    const int s0 = c * CS;
    for (int idx = lane; idx < CS * 16; idx += 64) {
        const int s = idx >> 4, jj = idx & 15;
        const int t = dir ? (T - 1 - (s0 + s)) : (s0 + s);
        const size_t g = rowb + (size_t)t * (H * HEAD) + jb + jj;
        Lk[w][s][jj] = bf2f(k[g]);
        Ld[w][s][jj] = d[g];
    }
    float vr[CS];
#pragma unroll
    for (int s = 0; s < CS; ++s) {
        const int t = dir ? (T - 1 - (s0 + s)) : (s0 + s);
        vr[s] = bf2f(v[rowb + (size_t)t * (H * HEAD) + lane]);
    }
    __syncthreads();

    float S[16];
#pragma unroll
    for (int j = 0; j < 16; ++j) S[j] = 0.f;

    for (int ss = 0; ss < CS; ++ss) {
        const float vv = vr[ss];
        const float* __restrict__ sk = Lk[w][ss];
        const float* __restrict__ sd = Ld[w][ss];
#pragma unroll
        for (int jj = 0; jj < 16; jj += 4) {
            const float4 k4 = *reinterpret_cast<const float4*>(&sk[jj]);
            const float4 d4 = *reinterpret_cast<const float4*>(&sd[jj]);
            S[jj + 0] = fmaf(d4.x, S[jj + 0], k4.x * vv);
            S[jj + 1] = fmaf(d4.y, S[jj + 1], k4.y * vv);
            S[jj + 2] = fmaf(d4.z, S[jj + 2], k4.z * vv);
            S[jj + 3] = fmaf(d4.w, S[jj + 3], k4.w * vv);
        }
    }
    // store transposed: M[uc][i=lane][jb+j]
    const size_t mb = (size_t)uc * 4096 + (size_t)lane * 64 + jb;
#pragma unroll
    for (int j = 0; j < 16; ++j) M[mb + j] = f2bf(S[j]);
    if (lane < 16) {
        float PD = 1.f;
#pragma unroll
        for (int s = 0; s < CS; ++s) PD *= Ld[w][s][lane];
        D[(size_t)uc * 64 + jb + lane] = PD;
    }
}

// pass2 (parallel): 1024 threads/unit, thread owns 4 state elements of M^T.
// element e = i*64 + j -> for tid: i = tid>>4, j = (tid&15)*4 .. +3
__global__ __launch_bounds__(1024) void wkv_pass2(ushort* __restrict__ M,
                                                  const float* __restrict__ D)
{
    const int unit = blockIdx.x;
    const int tid = threadIdx.x;
    const int j0 = (tid & 15) * 4;
    float S0 = 0.f, S1 = 0.f, S2 = 0.f, S3 = 0.f;
#pragma unroll
    for (int c = 0; c < NCH; ++c) {
        const int uc = unit * NCH + c;
        const float4 Dv = *reinterpret_cast<const float4*>(D + (size_t)uc * 64 + j0);
        ushort* mp = M + (size_t)uc * 4096 + tid * 4;
        const uint2 mv = *reinterpret_cast<const uint2*>(mp);
        const float m0 = bf2f((ushort)(mv.x & 0xffff));
        const float m1 = bf2f((ushort)(mv.x >> 16));
        const float m2 = bf2f((ushort)(mv.y & 0xffff));
        const float m3 = bf2f((ushort)(mv.y >> 16));
        uint2 sv;
        sv.x = (uint32_t)f2bf(S0) | ((uint32_t)f2bf(S1) << 16);
        sv.y = (uint32_t)f2bf(S2) | ((uint32_t)f2bf(S3) << 16);
        *reinterpret_cast<uint2*>(mp) = sv;
        S0 = fmaf(Dv.x, S0, m0);
        S1 = fmaf(Dv.y, S1, m1);
        S2 = fmaf(Dv.z, S2, m2);
        S3 = fmaf(Dv.w, S3, m3);
    }
}

// ======= y via MFMA: y = r' @ S_in + tril(r' @ k'^T, -1) @ v  ================
// r'[s][j] = r*Q[s], k'[u][j] = k/Q[u+1], Q = cumprod of d within chunk.
// block = one (unit,chunk), 4 waves; wave w: s-tile st=w&1, i-tiles 2*(w>>1)+{0,1}
__global__ __launch_bounds__(256) void wkv_ymfma(const ushort* __restrict__ r,
                                                 const ushort* __restrict__ k,
                                                 const ushort* __restrict__ v,
                                                 const float* __restrict__ d,
                                                 const ushort* __restrict__ Sin,
                                                 float* __restrict__ yf,
                                                 float* __restrict__ yb)
{
    const int uc = blockIdx.x;
    const int c = uc & (NCH - 1), unit = uc >> 3;
    const int dir = unit & 1, bh = unit >> 1;
    const int tid = threadIdx.x;
    const int wv = tid >> 6, lane = tid & 63;
    const int l15 = lane & 15, lhi = lane >> 4;
    const size_t rowb = ((size_t)(bh >> 4) * T * H + (bh & 15)) * HEAD;
    const int s0 = c * CS;

    __shared__ ushort rp[32][64];    // raw r -> r' (chunk-XOR swizzled rows)
    __shared__ ushort kp[32][64];    // raw k -> k'
    __shared__ ushort vt[64][40];    // v^T, padded
    __shared__ ushort Pl[32][32];    // masked attention, bf16

    // stage raw r,k (swizzled) and v^T
    for (int idx = tid; idx < 32 * 64; idx += 256) {
        const int s = idx >> 6, j = idx & 63;
        const int t = dir ? (T - 1 - (s0 + s)) : (s0 + s);
        const size_t g = rowb + (size_t)t * (H * HEAD) + j;
        const int cs = (j >> 3) ^ (s & 7);
        rp[s][cs * 8 + (j & 7)] = r[g];
        kp[s][cs * 8 + (j & 7)] = k[g];
        vt[j][s] = v[g];
    }
    __syncthreads();

    // cumprod rewrite (threads 0..63 = j)
    if (tid < 64) {
        const int j = tid;
        float Q = 1.f, iQ = 1.f;
        for (int s = 0; s < 32; ++s) {
            const int t = dir ? (T - 1 - (s0 + s)) : (s0 + s);
            const float dd = d[rowb + (size_t)t * (H * HEAD) + j];
            const int a = ((j >> 3) ^ (s & 7)) * 8 + (j & 7);
            rp[s][a] = f2bf(bf2f(rp[s][a]) * Q);
            Q *= dd;
            iQ *= (1.0f / dd);
            kp[s][a] = f2bf(bf2f(kp[s][a]) * iQ);
        }
    }
    __syncthreads();

    const int st = wv & 1;           // s-tile
    const int ip = wv >> 1;          // i-tile pair

    // A-fragments from r'
    short8 ar[2];
#pragma unroll
    for (int ks = 0; ks < 2; ++ks) {
        const int row = st * 16 + l15;
        const int ch = (ks * 4 + lhi) ^ (row & 7);
        ar[ks] = *(const short8*)&rp[row][ch * 8];
    }

    // y1 = r' @ S_in  (B-fragments straight from global Sin^T rows)
    floatx4 acc[2];
#pragma unroll
    for (int n = 0; n < 2; ++n) {
        const int i = ip * 32 + n * 16 + l15;
        const ushort* sp = Sin + (size_t)uc * 4096 + (size_t)i * 64;
        const short8 b0 = *(const short8*)&sp[lhi * 8];
        const short8 b1 = *(const short8*)&sp[32 + lhi * 8];
        acc[n] = __builtin_amdgcn_mfma_f32_16x16x32_bf16(ar[0], b0, (floatx4){0.f, 0.f, 0.f, 0.f}, 0, 0, 0);
        acc[n] = __builtin_amdgcn_mfma_f32_16x16x32_bf16(ar[1], b1, acc[n], 0, 0, 0);
    }

    // P = tril(r' @ k'^T, -1): waves 0,1 compute & write their s-tile rows
    if (wv < 2) {
#pragma unroll
        for (int ut = 0; ut < 2; ++ut) {
            const int urow = ut * 16 + l15;
            const short8 bk0 = *(const short8*)&kp[urow][((0 + lhi) ^ (urow & 7)) * 8];
            const short8 bk1 = *(const short8*)&kp[urow][((4 + lhi) ^ (urow & 7)) * 8];
            floatx4 pa = __builtin_amdgcn_mfma_f32_16x16x32_bf16(ar[0], bk0, (floatx4){0.f, 0.f, 0.f, 0.f}, 0, 0, 0);
            pa = __builtin_amdgcn_mfma_f32_16x16x32_bf16(ar[1], bk1, pa, 0, 0, 0);
            const int sg0 = st * 16 + lhi * 4;
            const int ug = ut * 16 + l15;
#pragma unroll
            for (int jr = 0; jr < 4; ++jr) {
                const float val = (ug < sg0 + jr) ? pa[jr] : 0.f;
                Pl[sg0 + jr][ug] = f2bf(val);
            }
        }
    }
    __syncthreads();

    // y2 += P @ v  (K=32, single MFMA per tile)
    short8 ap;
    {
        const int row = st * 16 + l15;
        ap = *(const short8*)&Pl[row][lhi * 8];
    }
#pragma unroll
    for (int n = 0; n < 2; ++n) {
        const int i = ip * 32 + n * 16 + l15;
        const short8 bv = *(const short8*)&vt[i][lhi * 8];
        acc[n] = __builtin_amdgcn_mfma_f32_16x16x32_bf16(ap, bv, acc[n], 0, 0, 0);
    }

    // store y (f32)
    float* __restrict__ yo = dir ? yb : yf;
#pragma unroll
    for (int n = 0; n < 2; ++n) {
        const int i = ip * 32 + n * 16 + l15;
#pragma unroll
        for (int jr = 0; jr < 4; ++jr) {
            const int sg = st * 16 + lhi * 4 + jr;
            const int t = dir ? (T - 1 - (s0 + sg)) : (s0 + sg);
            yo[rowb + (size_t)t * (H * HEAD) + i] = acc[n][jr];
        }
    }
}

// ======== pipelined bf16 MFMA GEMM core: BM=128, BK=64, BN in {64,128} ========
template <int BN>
struct GemmLds {
    ushort As[2][128 * 64];
    ushort Bs[2][BN * 64];
};

template <int BN>
__device__ __forceinline__ void gemm_body(const ushort* __restrict__ A,
                                          const ushort* __restrict__ Bt,
                                          int bm, int bn, int K, int lda, int ldb,
                                          GemmLds<BN>& lds,
                                          floatx4 (&acc)[4][BN / 32])
{
    constexpr int NF = BN / 32;
    const int tid = threadIdx.x;
    const int wid = tid >> 6, lane = tid & 63;
    const int wr = wid >> 1, wc = wid & 1;
    const int l15 = lane & 15, lhi = lane >> 4;
    const int NT = K >> 6;

    auto stage = [&](int buf, int k0) {
#pragma unroll
        for (int p = 0; p < 4; ++p) {
            const int lin = p * 256 + tid;
            const int row = lin >> 3;
            const int cs = (lin & 7) ^ (row & 7);
            gload16(A + (size_t)(bm + row) * lda + k0 + cs * 8, &lds.As[buf][lin * 8]);
        }
#pragma unroll
        for (int p = 0; p < NF; ++p) {
            const int lin = p * 256 + tid;
            const int n = lin >> 3;
            const int cs = (lin & 7) ^ (n & 7);
            gload16(Bt + (size_t)(bn + n) * ldb + k0 + cs * 8, &lds.Bs[buf][lin * 8]);
        }
    };

    stage(0, 0);
    __syncthreads();
    for (int t = 0; t < NT; ++t) {
        const int cur = t & 1;
        if (t + 1 < NT) stage(cur ^ 1, (t + 1) << 6);

        short8 af[4][2];
#pragma unroll
        for (int m = 0; m < 4; ++m) {
            const int row = wr * 64 + m * 16 + l15;
#pragma unroll
            for (int s = 0; s < 2; ++s) {
                const int cc = (s * 4 + lhi) ^ (row & 7);
                af[m][s] = *(const short8*)&lds.As[cur][row * 64 + cc * 8];
            }
        }
        short8 bf[NF][2];
#pragma unroll
        for (int n = 0; n < NF; ++n) {
            const int col = wc * (BN / 2) + n * 16 + l15;
#pragma unroll
            for (int s = 0; s < 2; ++s) {
                const int cc = (s * 4 + lhi) ^ (col & 7);
                bf[n][s] = *(const short8*)&lds.Bs[cur][col * 64 + cc * 8];
            }
        }
#pragma unroll
        for (int m = 0; m < 4; ++m)
#pragma unroll
            for (int n = 0; n < NF; ++n) {
                acc[m][n] = __builtin_amdgcn_mfma_f32_16x16x32_bf16(af[m][0], bf[n][0], acc[m][n], 0, 0, 0);
                acc[m][n] = __builtin_amdgcn_mfma_f32_16x16x32_bf16(af[m][1], bf[n][1], acc[m][n], 0, 0, 0);
            }
        __syncthreads();
    }
}

template <int BN, int EPI>
__global__ __launch_bounds__(256) void bgemm_kernel(const ushort* __restrict__ A,
                                                    const ushort* __restrict__ Bt,
                                                    void* __restrict__ Cm,
                                                    int M, int N, int K,
                                                    const float* __restrict__ aux1,
                                                    const float* __restrict__ aux2,
                                                    const float* __restrict__ aux3)
{
    constexpr int NF = BN / 32;
    __shared__ GemmLds<BN> lds;
    int w = blockIdx.y * gridDim.x + blockIdx.x;
    const int nwg = gridDim.x * gridDim.y;
    if ((nwg & 7) == 0) w = (w & 7) * (nwg >> 3) + (w >> 3);   // XCD swizzle
    const int bn = (w % gridDim.x) * BN;
    const int bm = (w / gridDim.x) * 128;
    const int tid = threadIdx.x;
    const int wid = tid >> 6, lane = tid & 63;
    const int wr = wid >> 1, wc = wid & 1;
    const int l15 = lane & 15, lhi = lane >> 4;

    floatx4 acc[4][NF];
#pragma unroll
    for (int m = 0; m < 4; ++m)
#pragma unroll
        for (int n = 0; n < NF; ++n) acc[m][n] = (floatx4){0.f, 0.f, 0.f, 0.f};

    gemm_body<BN>(A, Bt, bm, bn, K, K, K, lds, acc);

#pragma unroll
    for (int m = 0; m < 4; ++m) {
        const int row0 = bm + wr * 64 + m * 16 + lhi * 4;
#pragma unroll
        for (int n = 0; n < NF; ++n) {
            const int col = bn + wc * (BN / 2) + n * 16 + l15;
            if (col >= N) continue;
#pragma unroll
            for (int j = 0; j < 4; ++j) {
                const size_t oi = (size_t)(row0 + j) * N + col;
                const float a = acc[m][n][j];
                if constexpr (EPI == BEPI_NONE_BF) {
                    ((ushort*)Cm)[oi] = f2bf(a);
                } else if constexpr (EPI == BEPI_SILU_BF) {
                    ((ushort*)Cm)[oi] = f2bf(a / (1.f + __expf(-a)));
                } else if constexpr (EPI == BEPI_RELUSQ_BF) {
                    const float t = fmaxf(a, 0.f);
                    ((ushort*)Cm)[oi] = f2bf(t * t);
                } else if constexpr (EPI == BEPI_NONE_F) {
                    ((float*)Cm)[oi] = a;
                } else if constexpr (EPI == BEPI_RES_F) {
                    ((float*)Cm)[oi] = aux1[oi] + a;
                } else if constexpr (EPI == BEPI_SIGRES_F) {
                    ((float*)Cm)[oi] = aux1[oi] + aux2[oi] / (1.f + __expf(-a));
                } else if constexpr (EPI == BEPI_SIGRES2_F) {
                    ((float*)Cm)[oi] = aux1[oi] + (aux2[oi] + aux3[oi]) / (1.f + __expf(-a));
                } else if constexpr (EPI == BEPI_TANH_F) {
                    ((float*)Cm)[oi] = tanhf(a);
                } else if constexpr (EPI == BEPI_TANH_BF) {
                    ((ushort*)Cm)[oi] = f2bf(tanhf(a));
                } else {  // BEPI_DECAY_F
                    ((float*)Cm)[oi] = __expf(-__expf(a + aux1[col]));
                }
            }
        }
    }
}

// -------- Wcv split-K=2: z = K-half; f32 partials to P0/P1 --------
__global__ __launch_bounds__(256) void wcv_kernel(const ushort* __restrict__ A,
                                                  const ushort* __restrict__ Bt,
                                                  float* __restrict__ P0,
                                                  float* __restrict__ P1)
{
    __shared__ GemmLds<64> lds;
    const int z = blockIdx.z;
    int w = blockIdx.y * gridDim.x + blockIdx.x;   // 16x16 = 256
    w = (w & 7) * 32 + (w >> 3);                    // XCD swizzle
    const int bn = (w % 16) * 64;
    const int bm = (w / 16) * 128;
    const int tid = threadIdx.x;
    const int wid = tid >> 6, lane = tid & 63;
    const int wr = wid >> 1, wc = wid & 1;
    const int l15 = lane & 15, lhi = lane >> 4;

    floatx4 acc[4][2];
#pragma unroll
    for (int m = 0; m < 4; ++m)
#pragma unroll
        for (int n = 0; n < 2; ++n) acc[m][n] = (floatx4){0.f, 0.f, 0.f, 0.f};

    gemm_body<64>(A + z * (FF / 2), Bt + z * (FF / 2), bm, bn, FF / 2, FF, FF, lds, acc);

    float* __restrict__ P = z ? P1 : P0;
#pragma unroll
    for (int m = 0; m < 4; ++m) {
        const int row0 = bm + wr * 64 + m * 16 + lhi * 4;
#pragma unroll
        for (int n = 0; n < 2; ++n) {
            const int col = bn + wc * 32 + n * 16 + l15;
#pragma unroll
            for (int j = 0; j < 4; ++j)
                P[(size_t)(row0 + j) * C + col] = acc[m][n][j];
        }
    }
}

// -------- batched QKVG GEMM (BN=128): blockIdx.z selects {k,v,r,g} --------
struct QkvgArgs { const ushort* A[4]; ushort* O[4]; };
__global__ __launch_bounds__(256) void qkvg_kernel(QkvgArgs args,
                                                   const ushort* __restrict__ Wt)
{
    __shared__ GemmLds<128> lds;
    const int z = blockIdx.z;
    int w = blockIdx.y * gridDim.x + blockIdx.x;          // 8 x 16 grid = 128
    w = (w & 7) * 16 + (w >> 3);                           // XCD swizzle
    const int bn = (w & 7) * 128;
    const int bm = (w >> 3) * 128;
    const int tid = threadIdx.x;
    const int wid = tid >> 6, lane = tid & 63;
    const int wr = wid >> 1, wc = wid & 1;
    const int l15 = lane & 15, lhi = lane >> 4;

    floatx4 acc[4][4];
#pragma unroll
    for (int m = 0; m < 4; ++m)
#pragma unroll
        for (int n = 0; n < 4; ++n) acc[m][n] = (floatx4){0.f, 0.f, 0.f, 0.f};

    gemm_body<128>(args.A[z], Wt + (size_t)z * C * C, bm, bn, C, C, C, lds, acc);

    ushort* __restrict__ O = args.O[z];
    const bool silu = (z == 3);
#pragma unroll
    for (int m = 0; m < 4; ++m) {
        const int row0 = bm + wr * 64 + m * 16 + lhi * 4;
#pragma unroll
        for (int n = 0; n < 4; ++n) {
            const int col = bn + wc * 64 + n * 16 + l15;
#pragma unroll
            for (int j = 0; j < 4; ++j) {
                float a = acc[m][n][j];
                if (silu) a = a / (1.f + __expf(-a));
                O[(size_t)(row0 + j) * C + col] = f2bf(a);
            }
        }
    }
}

// ---------------- launch ----------------
extern "C" void kernel_launch(void* const* d_in, const int* in_sizes, int n_in,
                              void* d_out, int out_size, void* d_ws, size_t ws_size,
                              hipStream_t stream)
{
    const float* x        = (const float*)d_in[0];
    const float* ln1_g    = (const float*)d_in[1];
    const float* ln1_b    = (const float*)d_in[2];
    const float* ln2_g    = (const float*)d_in[3];
    const float* ln2_b    = (const float*)d_in[4];
    const float* maa_x    = (const float*)d_in[5];
    const float* maa_w    = (const float*)d_in[6];
    const float* maa_k    = (const float*)d_in[7];
    const float* maa_v    = (const float*)d_in[8];
    const float* maa_r    = (const float*)d_in[9];
    const float* maa_g    = (const float*)d_in[10];
    const float* maa_w1   = (const float*)d_in[11];
    const float* maa_w2   = (const float*)d_in[12];
    const float* time_dec = (const float*)d_in[13];
    const float* tdw1     = (const float*)d_in[14];
    const float* tdw2     = (const float*)d_in[15];
    const float* u        = (const float*)d_in[16];
    const float* Wr       = (const float*)d_in[17];
    const float* Wk       = (const float*)d_in[18];
    const float* Wv       = (const float*)d_in[19];
    const float* Wg       = (const float*)d_in[20];
    const float* Wo       = (const float*)d_in[21];
    const float* lnx_g    = (const float*)d_in[22];
    const float* lnx_b    = (const float*)d_in[23];
    const float* cmaa_k   = (const float*)d_in[24];
    const float* cmaa_r   = (const float*)d_in[25];
    const float* Wck      = (const float*)d_in[26];
    const float* Wcv      = (const float*)d_in[27];
    const float* Wcr      = (const float*)d_in[28];
    float* out = (float*)d_out;

    // -------- workspace layout (~63 MB) --------
    float* fws = (float*)d_ws;
    const size_t E = (size_t)BT * C;            // 2,097,152
    float* xa  = fws + 0 * E;                   // xa -> yf ; (FFN) kk low half
    float* xx  = fws + 1 * E;                   // xx -> yb ; kk high half
    float* wd  = fws + 2 * E;                   // decay d -> xc -> kvB partial
    float* fs  = fws + 3 * E;                   // xvb/xrb ; M low ; kvA partial
    ushort* wBuf = (ushort*)(fws + 4 * E);      // 4M ushort: weights / M high
    ushort* Mbuf = (ushort*)fs;                 // 2048*4096 bf16 = fs..wBuf (16MB)
    ushort* w2t  = wBuf + (size_t)C * 160;      // 5*C*32 bf16 (after maa_w1t)
    ushort* bf1  = wBuf + (size_t)C * FF;       // E: ax / xkb / ck_in
    ushort* rb   = bf1 + E;                     // r
    ushort* kb   = rb + E;                      // k
    ushort* vb   = kb + E;                      // v  -> ya
    ushort* gb   = vb + E;                      // g  -> cr_in
    ushort* t1b  = gb + E;                      // BT*64 bf16
    float* a5    = (float*)(t1b + (size_t)BT * 64);   // BT*160 (a5b bf16 inside)
    float* sig   = a5 + (size_t)BT * 160;       // (unused)
    float* Dbuf  = sig + (size_t)BT * H;        // 2048*64 f32
    ushort* a5b  = (ushort*)a5;                 // BT*160 bf16
    ushort* xvb  = (ushort*)fs;                 // E (mix v input)
    ushort* xrb  = (ushort*)fs + E;             // E (mix r input)
    ushort* xgb  = (ushort*)out;                // E (mix g input; out is scratch)
    ushort* xwb  = (ushort*)out + E;            // E (mix w input)
    ushort* kk   = (ushort*)xa;                 // BT*FF bf16 == xa..xx

    const dim3 blk(256);
    const dim3 tblk(32, 8);
    const int EW = (BT * C) / 256;
    const dim3 gNN(C / 64, BT / 128);

    // ---- attention branch ----
    ln_kernel<<<BT, blk, 0, stream>>>(x, ln1_g, ln1_b, xa);
    bshiftmix_kernel<<<EW, blk, 0, stream>>>(xa, maa_x, xx, bf1);
    wconv_kernel<<<dim3(160 / 32, C / 32), tblk, 0, stream>>>(maa_w1, wBuf, C, 160);
    bgemm_kernel<64, BEPI_TANH_BF><<<dim3(3, BT / 128), blk, 0, stream>>>(bf1, wBuf, a5b, BT, 160, C, nullptr, nullptr, nullptr);

    // w2 slices -> [5][C][32] bf16 transposed (one launch)
    w2conv_kernel<<<dim3(C / 32, 5), tblk, 0, stream>>>(maa_w2, w2t);

    // all 5 mixes as one fused MFMA GEMM launch
    Mix5Args margs;
    margs.maa[0] = maa_w; margs.maa[1] = maa_k; margs.maa[2] = maa_v;
    margs.maa[3] = maa_r; margs.maa[4] = maa_g;
    margs.out[0] = xwb; margs.out[1] = bf1; margs.out[2] = xvb;
    margs.out[3] = xrb; margs.out[4] = xgb;
    mix5m_kernel<<<dim3(C / 64, BT / 128, 5), blk, 0, stream>>>(a5b, w2t, xa, xx, margs);

    // w path: tanh(xw@tdw1) -> decay d = exp(-exp(@tdw2 + time_decay))
    wconv_kernel<<<dim3(64 / 32, C / 32), tblk, 0, stream>>>(tdw1, wBuf, C, 64);
    bgemm_kernel<64, BEPI_TANH_BF><<<dim3(1, BT / 128), blk, 0, stream>>>(xwb, wBuf, t1b, BT, 64, C, nullptr, nullptr, nullptr);
    wconv_kernel<<<dim3(C / 32, 64 / 32), tblk, 0, stream>>>(tdw2, wBuf, 64, C);
    bgemm_kernel<64, BEPI_DECAY_F><<<gNN, blk, 0, stream>>>(t1b, wBuf, wd, BT, C, 64, time_dec, nullptr, nullptr);

    // batched QKVG
    Wconv4Args wargs;
    wargs.W[0] = Wk; wargs.W[1] = Wv; wargs.W[2] = Wr; wargs.W[3] = Wg;
    wconv4_kernel<<<dim3(C / 32, C / 32, 4), tblk, 0, stream>>>(wargs, wBuf);
    QkvgArgs qargs;
    qargs.A[0] = bf1; qargs.A[1] = xvb; qargs.A[2] = xrb; qargs.A[3] = xgb;
    qargs.O[0] = kb;  qargs.O[1] = vb;  qargs.O[2] = rb;  qargs.O[3] = gb;
    qkvg_kernel<<<dim3(8, 16, 4), blk, 0, stream>>>(qargs, wBuf);

    // chunked bidirectional WKV (Mbuf overlays fs+wBuf; yf/yb = xa/xx f32)
    wkv_pass1<<<dim3(2 * B * H * NCH), blk, 0, stream>>>(kb, vb, wd, Mbuf, Dbuf);
    wkv_pass2<<<dim3(2 * B * H), dim3(1024), 0, stream>>>(Mbuf, Dbuf);
    wkv_ymfma<<<dim3(2 * B * H * NCH), blk, 0, stream>>>(rb, kb, vb, wd, Mbuf, xa, xx);

    // ya = groupnorm(yf+yb+sig*v)*g ; out = x + ya @ Wo^T
    gnmul_kernel<<<BT, dim3(1024), 0, stream>>>(xa, xx, lnx_g, lnx_b, gb, vb, rb, kb, u, vb);
    wconv_kernel<<<dim3(C / 32, C / 32), tblk, 0, stream>>>(Wo, wBuf, C, C);
    bgemm_kernel<64, BEPI_RES_F><<<gNN, blk, 0, stream>>>(vb, wBuf, out, BT, C, C, x, nullptr, nullptr);

    // ---- FFN branch ----
    ln_kernel<<<BT, blk, 0, stream>>>(out, ln2_g, ln2_b, wd);
    bshiftcmix_kernel<<<EW, blk, 0, stream>>>(wd, cmaa_k, cmaa_r, bf1, gb);
    wconv_kernel<<<dim3(FF / 32, C / 32), tblk, 0, stream>>>(Wck, wBuf, C, FF);
    bgemm_kernel<128, BEPI_RELUSQ_BF><<<dim3(FF / 128, BT / 128), blk, 0, stream>>>(bf1, wBuf, kk, BT, FF, C, nullptr, nullptr, nullptr);
    wconv_kernel<<<dim3(C / 32, FF / 32), tblk, 0, stream>>>(Wcv, wBuf, FF, C);
    wcv_kernel<<<dim3(16, 16, 2), blk, 0, stream>>>(kk, wBuf, fs, wd);
    wconv_kernel<<<dim3(C / 32, C / 32), tblk, 0, stream>>>(Wcr, wBuf, C, C);
    bgemm_kernel<64, BEPI_SIGRES2_F><<<gNN, blk, 0, stream>>>(gb, wBuf, out, BT, C, C, out, fs, wd);

    (void)in_sizes; (void)n_in; (void)out_size; (void)ws_size;
}

// Round 14
// 255.587 us; speedup vs baseline: 5.6431x; 1.0507x over previous
//
#include <hip/hip_runtime.h>
#include <math.h>
#include <stdint.h>

static constexpr int B  = 8;
static constexpr int T  = 256;
static constexpr int C  = 1024;
static constexpr int H  = 16;
static constexpr int HEAD = 64;
static constexpr int FF = 4096;
static constexpr int BT = B * T;
static constexpr int NCH = 8;       // time chunks
static constexpr int CS  = 32;      // chunk size (NCH*CS == T)

typedef short short8  __attribute__((ext_vector_type(8)));
typedef float floatx4 __attribute__((ext_vector_type(4)));

// ---------------- bf16 helpers ----------------
__device__ __forceinline__ float bf2f(ushort u) {
    return __uint_as_float(((uint32_t)u) << 16);
}
__device__ __forceinline__ ushort f2bf(float x) {
    uint32_t u = __float_as_uint(x);
    u += 0x7fff + ((u >> 16) & 1);          // RNE
    return (ushort)(u >> 16);
}

__device__ __forceinline__ void gload16(const void* g, void* l) {
    __builtin_amdgcn_global_load_lds(
        (const __attribute__((address_space(1))) unsigned int*)g,
        (__attribute__((address_space(3))) unsigned int*)l, 16, 0, 0);
}

// ---------------- epilogue ids ----------------
#define BEPI_NONE_BF   0
#define BEPI_SILU_BF   1
#define BEPI_RELUSQ_BF 2
#define BEPI_NONE_F    3
#define BEPI_RES_F     4
#define BEPI_SIGRES_F  5
#define BEPI_TANH_F    6
#define BEPI_TANH_BF   7
#define BEPI_DECAY_F   8
#define BEPI_SIGRES2_F 9

// ---------------- LayerNorm ----------------
__global__ __launch_bounds__(256) void ln_kernel(const float* __restrict__ x,
                                                 const float* __restrict__ g,
                                                 const float* __restrict__ b,
                                                 float* __restrict__ out)
{
    const int row = blockIdx.x;
    const int tid = threadIdx.x;
    const float4 v = reinterpret_cast<const float4*>(x + (size_t)row * C)[tid];
    float s = v.x + v.y + v.z + v.w;
#pragma unroll
    for (int off = 32; off > 0; off >>= 1) s += __shfl_xor(s, off);
    __shared__ float red[8];
    const int wave = tid >> 6, lane = tid & 63;
    if (lane == 0) red[wave] = s;
    __syncthreads();
    const float mean = (red[0] + red[1] + red[2] + red[3]) * (1.0f / C);
    const float d0 = v.x - mean, d1 = v.y - mean, d2 = v.z - mean, d3 = v.w - mean;
    float q = d0 * d0 + d1 * d1 + d2 * d2 + d3 * d3;
#pragma unroll
    for (int off = 32; off > 0; off >>= 1) q += __shfl_xor(q, off);
    if (lane == 0) red[4 + wave] = q;
    __syncthreads();
    const float var = (red[4] + red[5] + red[6] + red[7]) * (1.0f / C);
    const float rstd = rsqrtf(var + 1e-5f);
    const int c = tid * 4;
    float4 o;
    o.x = d0 * rstd * g[c + 0] + b[c + 0];
    o.y = d1 * rstd * g[c + 1] + b[c + 1];
    o.z = d2 * rstd * g[c + 2] + b[c + 2];
    o.w = d3 * rstd * g[c + 3] + b[c + 3];
    reinterpret_cast<float4*>(out + (size_t)row * C)[tid] = o;
}

// ---- fused bshift+mixax: xx = bshift(xa)-xa (f32), ax = bf16(xa + xx*maa) ----
__global__ __launch_bounds__(256) void bshiftmix_kernel(const float* __restrict__ xa,
                                                        const float* __restrict__ maa,
                                                        float* __restrict__ xx,
                                                        ushort* __restrict__ ax)
{
    const int i = blockIdx.x * 256 + threadIdx.x;
    const int c = i & (C - 1);
    const int bt = i >> 10;
    const int t = bt & (T - 1);
    const int j = c & (HEAD - 1);
    float src = 0.f;
    if (j < HEAD / 2) { if (t > 0)     src = xa[i - C]; }
    else              { if (t < T - 1) src = xa[i + C]; }
    const float a = xa[i];
    const float xv = src - a;
    xx[i] = xv;
    ax[i] = f2bf(a + xv * maa[c]);
}

// ---- fused FFN bshift+cmix: two bf16 mixed outputs, no xx materialization ----
__global__ __launch_bounds__(256) void bshiftcmix_kernel(const float* __restrict__ xc,
                                                         const float* __restrict__ mk,
                                                         const float* __restrict__ mr,
                                                         ushort* __restrict__ ok,
                                                         ushort* __restrict__ orr)
{
    const int i = blockIdx.x * 256 + threadIdx.x;
    const int c = i & (C - 1);
    const int bt = i >> 10;
    const int t = bt & (T - 1);
    const int j = c & (HEAD - 1);
    float src = 0.f;
    if (j < HEAD / 2) { if (t > 0)     src = xc[i - C]; }
    else              { if (t < T - 1) src = xc[i + C]; }
    const float a = xc[i];
    const float cxx = src - a;
    ok[i]  = f2bf(a + cxx * mk[c]);
    orr[i] = f2bf(a + cxx * mr[c]);
}

// -------- GroupNorm(yf+yb+sig*v)*g+b, * gate; u-bonus scalar fused ---------
__global__ __launch_bounds__(1024) void gnmul_kernel(const float* __restrict__ yf,
                                                     const float* __restrict__ yb,
                                                     const float* __restrict__ g,
                                                     const float* __restrict__ b,
                                                     const ushort* __restrict__ gate,
                                                     const ushort* __restrict__ vin,
                                                     const ushort* __restrict__ rbuf,
                                                     const ushort* __restrict__ kbuf,
                                                     const float* __restrict__ u,
                                                     ushort* __restrict__ out)
{
    const int row = blockIdx.x;
    const int tid = threadIdx.x;                 // wave == head
    const size_t idx = (size_t)row * C + tid;
    float p = bf2f(rbuf[idx]) * bf2f(kbuf[idx]) * u[tid];
#pragma unroll
    for (int off = 32; off > 0; off >>= 1) p += __shfl_xor(p, off);
    const float v = yf[idx] + yb[idx] + p * bf2f(vin[idx]);
    float s = v;
#pragma unroll
    for (int off = 32; off > 0; off >>= 1) s += __shfl_xor(s, off);
    const float m = s * (1.0f / HEAD);
    const float d = v - m;
    float q = d * d;
#pragma unroll
    for (int off = 32; off > 0; off >>= 1) q += __shfl_xor(q, off);
    const float rstd = rsqrtf(q * (1.0f / HEAD) + 6.4e-4f);
    out[idx] = f2bf((d * rstd * g[tid] + b[tid]) * bf2f(gate[idx]));
}

// -------- weight convert+transpose: W[Kd,Nd] f32 -> Wt[Nd,Kd] bf16 --------
__global__ __launch_bounds__(256) void wconv_kernel(const float* __restrict__ W,
                                                    ushort* __restrict__ Wt,
                                                    int Kd, int Nd)
{
    __shared__ float tile[32][33];
    const int n0 = blockIdx.x * 32, k0 = blockIdx.y * 32;
    const int tx = threadIdx.x, ty = threadIdx.y;
#pragma unroll
    for (int i = 0; i < 4; ++i)
        tile[ty * 4 + i][tx] = W[(size_t)(k0 + ty * 4 + i) * Nd + n0 + tx];
    __syncthreads();
#pragma unroll
    for (int i = 0; i < 4; ++i)
        Wt[(size_t)(n0 + ty * 4 + i) * Kd + k0 + tx] = f2bf(tile[tx][ty * 4 + i]);
}

// -------- w2 slices: w2[5][32][C] -> w2t[5][C][32] bf16, one launch --------
__global__ __launch_bounds__(256) void w2conv_kernel(const float* __restrict__ w2,
                                                     ushort* __restrict__ w2t)
{
    __shared__ float tile[32][33];
    const int f = blockIdx.y;
    const int n0 = blockIdx.x * 32;
    const int tx = threadIdx.x, ty = threadIdx.y;
#pragma unroll
    for (int i = 0; i < 4; ++i)
        tile[ty * 4 + i][tx] = w2[(size_t)f * 32 * C + (size_t)(ty * 4 + i) * C + n0 + tx];
    __syncthreads();
#pragma unroll
    for (int i = 0; i < 4; ++i)
        w2t[(size_t)f * C * 32 + (size_t)(n0 + ty * 4 + i) * 32 + tx] = f2bf(tile[tx][ty * 4 + i]);
}

// -------- batched wconv: 4 C x C weights (blockIdx.z) --------
struct Wconv4Args { const float* W[4]; };
__global__ __launch_bounds__(256) void wconv4_kernel(Wconv4Args args, ushort* __restrict__ Wt)
{
    __shared__ float tile[32][33];
    const int z = blockIdx.z;
    const float* __restrict__ W = args.W[z];
    ushort* __restrict__ dst = Wt + (size_t)z * C * C;
    const int n0 = blockIdx.x * 32, k0 = blockIdx.y * 32;
    const int tx = threadIdx.x, ty = threadIdx.y;
#pragma unroll
    for (int i = 0; i < 4; ++i)
        tile[ty * 4 + i][tx] = W[(size_t)(k0 + ty * 4 + i) * C + n0 + tx];
    __syncthreads();
#pragma unroll
    for (int i = 0; i < 4; ++i)
        dst[(size_t)(n0 + ty * 4 + i) * C + k0 + tx] = f2bf(tile[tx][ty * 4 + i]);
}

// ======== mix5 as fused MFMA GEMM: out_f = bf16(xa + xx*(maa_f + a5b@w2t_f)) ====
struct Mix5Args { const float* maa[5]; ushort* out[5]; };
__global__ __launch_bounds__(256) void mix5m_kernel(const ushort* __restrict__ a5b,
                                                    const ushort* __restrict__ w2t,
                                                    const float* __restrict__ xa,
                                                    const float* __restrict__ xx,
                                                    Mix5Args args)
{
    __shared__ __align__(16) ushort As[128 * 32];
    __shared__ __align__(16) ushort Bs[64 * 32];
    const int f = blockIdx.z;
    const int bm = blockIdx.y * 128, bn = blockIdx.x * 64;
    const int tid = threadIdx.x;
    const int wid = tid >> 6, lane = tid & 63;
    const int wr = wid >> 1, wc = wid & 1;
    const int l15 = lane & 15, lhi = lane >> 4;

#pragma unroll
    for (int p = 0; p < 2; ++p) {
        const int lin = p * 256 + tid;
        const int row = lin >> 2;
        const int sp = (lin & 3) ^ ((row >> 1) & 3);
        gload16(a5b + (size_t)(bm + row) * 160 + f * 32 + sp * 8, &As[lin * 8]);
    }
    {
        const int lin = tid;
        const int n = lin >> 2;
        const int sp = (lin & 3) ^ ((n >> 1) & 3);
        gload16(w2t + ((size_t)f * C + bn + n) * 32 + sp * 8, &Bs[lin * 8]);
    }
    __syncthreads();

    short8 af[4], bfr[2];
#pragma unroll
    for (int m = 0; m < 4; ++m) {
        const int row = wr * 64 + m * 16 + l15;
        const int sp = lhi ^ ((row >> 1) & 3);
        af[m] = *(const short8*)&As[row * 32 + sp * 8];
    }
#pragma unroll
    for (int n = 0; n < 2; ++n) {
        const int col = wc * 32 + n * 16 + l15;
        const int sp = lhi ^ ((col >> 1) & 3);
        bfr[n] = *(const short8*)&Bs[col * 32 + sp * 8];
    }
    floatx4 acc[4][2];
#pragma unroll
    for (int m = 0; m < 4; ++m)
#pragma unroll
        for (int n = 0; n < 2; ++n)
            acc[m][n] = __builtin_amdgcn_mfma_f32_16x16x32_bf16(
                af[m], bfr[n], (floatx4){0.f, 0.f, 0.f, 0.f}, 0, 0, 0);

    const float* __restrict__ maa = args.maa[f];
    ushort* __restrict__ out = args.out[f];
#pragma unroll
    for (int m = 0; m < 4; ++m) {
        const int row0 = bm + wr * 64 + m * 16 + lhi * 4;
#pragma unroll
        for (int n = 0; n < 2; ++n) {
            const int col = bn + wc * 32 + n * 16 + l15;
            const float mc = maa[col];
#pragma unroll
            for (int j = 0; j < 4; ++j) {
                const size_t oi = (size_t)(row0 + j) * C + col;
                out[oi] = f2bf(xa[oi] + xx[oi] * (mc + acc[m][n][j]));
            }
        }
    }
}

// ================== chunked bidirectional WKV6 (MFMA) ==================
// pass1: M^T[i][j] = sum_s v[s][i] * (k[s][j] * G_s[j]),  G_s = prod_{u>s} d_u
// (division-free backward cumprod). 16 MFMAs/block; D[uc][j] = G_{-1} = PD.
__global__ __launch_bounds__(256) void wkv_pass1(const ushort* __restrict__ k,
                                                 const ushort* __restrict__ v,
                                                 const float* __restrict__ d,
                                                 ushort* __restrict__ M,
                                                 float* __restrict__ D)
{
    const int uc = blockIdx.x;
    const int c = uc & (NCH - 1), unit = uc >> 3;
    const int dir = unit & 1, bh = unit >> 1;
    const int tid = threadIdx.x;
    const int wv = tid >> 6, lane = tid & 63;
    const int l15 = lane & 15, lhi = lane >> 4;
    const size_t rowb = ((size_t)(bh >> 4) * T * H + (bh & 15)) * HEAD;
    const int s0 = c * CS;

    __shared__ ushort kT[64][40];    // k'' transposed [j][s]
    __shared__ ushort vt[64][40];    // v^T [i][s]
    __shared__ float  Ldd[CS][64];   // d staged [s][j]

    for (int idx = tid; idx < CS * 64; idx += 256) {
        const int s = idx >> 6, j = idx & 63;
        const int t = dir ? (T - 1 - (s0 + s)) : (s0 + s);
        const size_t g = rowb + (size_t)t * (H * HEAD) + j;
        kT[j][s] = k[g];
        vt[j][s] = v[g];
        Ldd[s][j] = d[g];
    }
    __syncthreads();

    // backward cumprod rewrite: kT[j][s] *= G, G *= d[s][j]
    if (tid < 64) {
        const int j = tid;
        float G = 1.f;
#pragma unroll
        for (int s = CS - 1; s >= 0; --s) {
            kT[j][s] = f2bf(bf2f(kT[j][s]) * G);
            G *= Ldd[s][j];
        }
        D[(size_t)uc * 64 + j] = G;
    }
    __syncthreads();

    // M^T = v^T @ k''  (A rows = i, B rows = j, K = 32)
    const short8 av = *(const short8*)&vt[wv * 16 + l15][lhi * 8];
    ushort* __restrict__ mrow = M + (size_t)uc * 4096;
#pragma unroll
    for (int n = 0; n < 4; ++n) {
        const short8 bk = *(const short8*)&kT[n * 16 + l15][lhi * 8];
        const floatx4 acc = __builtin_amdgcn_mfma_f32_16x16x32_bf16(
            av, bk, (floatx4){0.f, 0.f, 0.f, 0.f}, 0, 0, 0);
#pragma unroll
        for (int jr = 0; jr < 4; ++jr) {
            const int i = wv * 16 + lhi * 4 + jr;
            mrow[(size_t)i * 64 + n * 16 + l15] = f2bf(acc[jr]);
        }
    }
}

// pass2 (parallel): 1024 threads/unit, thread owns 4 state elements of M^T.
__global__ __launch_bounds__(1024) void wkv_pass2(ushort* __restrict__ M,
                                                  const float* __restrict__ D)
{
    const int unit = blockIdx.x;
    const int tid = threadIdx.x;
    const int j0 = (tid & 15) * 4;
    float S0 = 0.f, S1 = 0.f, S2 = 0.f, S3 = 0.f;
#pragma unroll
    for (int c = 0; c < NCH; ++c) {
        const int uc = unit * NCH + c;
        const float4 Dv = *reinterpret_cast<const float4*>(D + (size_t)uc * 64 + j0);
        ushort* mp = M + (size_t)uc * 4096 + tid * 4;
        const uint2 mv = *reinterpret_cast<const uint2*>(mp);
        const float m0 = bf2f((ushort)(mv.x & 0xffff));
        const float m1 = bf2f((ushort)(mv.x >> 16));
        const float m2 = bf2f((ushort)(mv.y & 0xffff));
        const float m3 = bf2f((ushort)(mv.y >> 16));
        uint2 sv;
        sv.x = (uint32_t)f2bf(S0) | ((uint32_t)f2bf(S1) << 16);
        sv.y = (uint32_t)f2bf(S2) | ((uint32_t)f2bf(S3) << 16);
        *reinterpret_cast<uint2*>(mp) = sv;
        S0 = fmaf(Dv.x, S0, m0);
        S1 = fmaf(Dv.y, S1, m1);
        S2 = fmaf(Dv.z, S2, m2);
        S3 = fmaf(Dv.w, S3, m3);
    }
}

// ======= y via MFMA: y = r' @ S_in + tril(r' @ k'^T, -1) @ v  ================
__global__ __launch_bounds__(256) void wkv_ymfma(const ushort* __restrict__ r,
                                                 const ushort* __restrict__ k,
                                                 const ushort* __restrict__ v,
                                                 const float* __restrict__ d,
                                                 const ushort* __restrict__ Sin,
                                                 float* __restrict__ yf,
                                                 float* __restrict__ yb)
{
    const int uc = blockIdx.x;
    const int c = uc & (NCH - 1), unit = uc >> 3;
    const int dir = unit & 1, bh = unit >> 1;
    const int tid = threadIdx.x;
    const int wv = tid >> 6, lane = tid & 63;
    const int l15 = lane & 15, lhi = lane >> 4;
    const size_t rowb = ((size_t)(bh >> 4) * T * H + (bh & 15)) * HEAD;
    const int s0 = c * CS;

    __shared__ ushort rp[32][64];    // raw r -> r' (chunk-XOR swizzled rows)
    __shared__ ushort kp[32][64];    // raw k -> k'
    __shared__ ushort vt[64][40];    // v^T, padded
    __shared__ ushort Pl[32][32];    // masked attention, bf16
    __shared__ float  Ldd[CS][64];   // d staged [s][j]

    for (int idx = tid; idx < 32 * 64; idx += 256) {
        const int s = idx >> 6, j = idx & 63;
        const int t = dir ? (T - 1 - (s0 + s)) : (s0 + s);
        const size_t g = rowb + (size_t)t * (H * HEAD) + j;
        const int cs = (j >> 3) ^ (s & 7);
        rp[s][cs * 8 + (j & 7)] = r[g];
        kp[s][cs * 8 + (j & 7)] = k[g];
        vt[j][s] = v[g];
        Ldd[s][j] = d[g];
    }
    __syncthreads();

    // cumprod rewrite, split across two waves (independent chains)
    if (wv == 0) {                   // r' = r * Q[s]
        const int j = lane;
        float Q = 1.f;
#pragma unroll
        for (int s = 0; s < 32; ++s) {
            const int a = ((j >> 3) ^ (s & 7)) * 8 + (j & 7);
            rp[s][a] = f2bf(bf2f(rp[s][a]) * Q);
            Q *= Ldd[s][j];
        }
    } else if (wv == 1) {            // k' = k / Q[s+1]
        const int j = lane;
        float iQ = 1.f;
#pragma unroll
        for (int s = 0; s < 32; ++s) {
            iQ *= (1.0f / Ldd[s][j]);
            const int a = ((j >> 3) ^ (s & 7)) * 8 + (j & 7);
            kp[s][a] = f2bf(bf2f(kp[s][a]) * iQ);
        }
    }
    __syncthreads();

    const int st = wv & 1;           // s-tile
    const int ip = wv >> 1;          // i-tile pair

    short8 ar[2];
#pragma unroll
    for (int ks = 0; ks < 2; ++ks) {
        const int row = st * 16 + l15;
        const int ch = (ks * 4 + lhi) ^ (row & 7);
        ar[ks] = *(const short8*)&rp[row][ch * 8];
    }

    // y1 = r' @ S_in
    floatx4 acc[2];
#pragma unroll
    for (int n = 0; n < 2; ++n) {
        const int i = ip * 32 + n * 16 + l15;
        const ushort* sp = Sin + (size_t)uc * 4096 + (size_t)i * 64;
        const short8 b0 = *(const short8*)&sp[lhi * 8];
        const short8 b1 = *(const short8*)&sp[32 + lhi * 8];
        acc[n] = __builtin_amdgcn_mfma_f32_16x16x32_bf16(ar[0], b0, (floatx4){0.f, 0.f, 0.f, 0.f}, 0, 0, 0);
        acc[n] = __builtin_amdgcn_mfma_f32_16x16x32_bf16(ar[1], b1, acc[n], 0, 0, 0);
    }

    // P = tril(r' @ k'^T, -1)
    if (wv < 2) {
#pragma unroll
        for (int ut = 0; ut < 2; ++ut) {
            const int urow = ut * 16 + l15;
            const short8 bk0 = *(const short8*)&kp[urow][((0 + lhi) ^ (urow & 7)) * 8];
            const short8 bk1 = *(const short8*)&kp[urow][((4 + lhi) ^ (urow & 7)) * 8];
            floatx4 pa = __builtin_amdgcn_mfma_f32_16x16x32_bf16(ar[0], bk0, (floatx4){0.f, 0.f, 0.f, 0.f}, 0, 0, 0);
            pa = __builtin_amdgcn_mfma_f32_16x16x32_bf16(ar[1], bk1, pa, 0, 0, 0);
            const int sg0 = st * 16 + lhi * 4;
            const int ug = ut * 16 + l15;
#pragma unroll
            for (int jr = 0; jr < 4; ++jr) {
                const float val = (ug < sg0 + jr) ? pa[jr] : 0.f;
                Pl[sg0 + jr][ug] = f2bf(val);
            }
        }
    }
    __syncthreads();

    // y2 += P @ v
    short8 ap;
    {
        const int row = st * 16 + l15;
        ap = *(const short8*)&Pl[row][lhi * 8];
    }
#pragma unroll
    for (int n = 0; n < 2; ++n) {
        const int i = ip * 32 + n * 16 + l15;
        const short8 bv = *(const short8*)&vt[i][lhi * 8];
        acc[n] = __builtin_amdgcn_mfma_f32_16x16x32_bf16(ap, bv, acc[n], 0, 0, 0);
    }

    float* __restrict__ yo = dir ? yb : yf;
#pragma unroll
    for (int n = 0; n < 2; ++n) {
        const int i = ip * 32 + n * 16 + l15;
#pragma unroll
        for (int jr = 0; jr < 4; ++jr) {
            const int sg = st * 16 + lhi * 4 + jr;
            const int t = dir ? (T - 1 - (s0 + sg)) : (s0 + sg);
            yo[rowb + (size_t)t * (H * HEAD) + i] = acc[n][jr];
        }
    }
}

// ======== pipelined bf16 MFMA GEMM core: BM=128, BK=64, BN in {64,128} ========
template <int BN>
struct GemmLds {
    ushort As[2][128 * 64];
    ushort Bs[2][BN * 64];
};

template <int BN>
__device__ __forceinline__ void gemm_body(const ushort* __restrict__ A,
                                          const ushort* __restrict__ Bt,
                                          int bm, int bn, int K, int lda, int ldb,
                                          GemmLds<BN>& lds,
                                          floatx4 (&acc)[4][BN / 32])
{
    constexpr int NF = BN / 32;
    const int tid = threadIdx.x;
    const int wid = tid >> 6, lane = tid & 63;
    const int wr = wid >> 1, wc = wid & 1;
    const int l15 = lane & 15, lhi = lane >> 4;
    const int NT = K >> 6;

    auto stage = [&](int buf, int k0) {
#pragma unroll
        for (int p = 0; p < 4; ++p) {
            const int lin = p * 256 + tid;
            const int row = lin >> 3;
            const int cs = (lin & 7) ^ (row & 7);
            gload16(A + (size_t)(bm + row) * lda + k0 + cs * 8, &lds.As[buf][lin * 8]);
        }
#pragma unroll
        for (int p = 0; p < NF; ++p) {
            const int lin = p * 256 + tid;
            const int n = lin >> 3;
            const int cs = (lin & 7) ^ (n & 7);
            gload16(Bt + (size_t)(bn + n) * ldb + k0 + cs * 8, &lds.Bs[buf][lin * 8]);
        }
    };

    stage(0, 0);
    __syncthreads();
    for (int t = 0; t < NT; ++t) {
        const int cur = t & 1;
        if (t + 1 < NT) stage(cur ^ 1, (t + 1) << 6);

        short8 af[4][2];
#pragma unroll
        for (int m = 0; m < 4; ++m) {
            const int row = wr * 64 + m * 16 + l15;
#pragma unroll
            for (int s = 0; s < 2; ++s) {
                const int cc = (s * 4 + lhi) ^ (row & 7);
                af[m][s] = *(const short8*)&lds.As[cur][row * 64 + cc * 8];
            }
        }
        short8 bf[NF][2];
#pragma unroll
        for (int n = 0; n < NF; ++n) {
            const int col = wc * (BN / 2) + n * 16 + l15;
#pragma unroll
            for (int s = 0; s < 2; ++s) {
                const int cc = (s * 4 + lhi) ^ (col & 7);
                bf[n][s] = *(const short8*)&lds.Bs[cur][col * 64 + cc * 8];
            }
        }
#pragma unroll
        for (int m = 0; m < 4; ++m)
#pragma unroll
            for (int n = 0; n < NF; ++n) {
                acc[m][n] = __builtin_amdgcn_mfma_f32_16x16x32_bf16(af[m][0], bf[n][0], acc[m][n], 0, 0, 0);
                acc[m][n] = __builtin_amdgcn_mfma_f32_16x16x32_bf16(af[m][1], bf[n][1], acc[m][n], 0, 0, 0);
            }
        __syncthreads();
    }
}

template <int BN, int EPI>
__global__ __launch_bounds__(256) void bgemm_kernel(const ushort* __restrict__ A,
                                                    const ushort* __restrict__ Bt,
                                                    void* __restrict__ Cm,
                                                    int M, int N, int K,
                                                    const float* __restrict__ aux1,
                                                    const float* __restrict__ aux2,
                                                    const float* __restrict__ aux3)
{
    constexpr int NF = BN / 32;
    __shared__ GemmLds<BN> lds;
    int w = blockIdx.y * gridDim.x + blockIdx.x;
    const int nwg = gridDim.x * gridDim.y;
    if ((nwg & 7) == 0) w = (w & 7) * (nwg >> 3) + (w >> 3);   // XCD swizzle
    const int bn = (w % gridDim.x) * BN;
    const int bm = (w / gridDim.x) * 128;
    const int tid = threadIdx.x;
    const int wid = tid >> 6, lane = tid & 63;
    const int wr = wid >> 1, wc = wid & 1;
    const int l15 = lane & 15, lhi = lane >> 4;

    floatx4 acc[4][NF];
#pragma unroll
    for (int m = 0; m < 4; ++m)
#pragma unroll
        for (int n = 0; n < NF; ++n) acc[m][n] = (floatx4){0.f, 0.f, 0.f, 0.f};

    gemm_body<BN>(A, Bt, bm, bn, K, K, K, lds, acc);

#pragma unroll
    for (int m = 0; m < 4; ++m) {
        const int row0 = bm + wr * 64 + m * 16 + lhi * 4;
#pragma unroll
        for (int n = 0; n < NF; ++n) {
            const int col = bn + wc * (BN / 2) + n * 16 + l15;
            if (col >= N) continue;
#pragma unroll
            for (int j = 0; j < 4; ++j) {
                const size_t oi = (size_t)(row0 + j) * N + col;
                const float a = acc[m][n][j];
                if constexpr (EPI == BEPI_NONE_BF) {
                    ((ushort*)Cm)[oi] = f2bf(a);
                } else if constexpr (EPI == BEPI_SILU_BF) {
                    ((ushort*)Cm)[oi] = f2bf(a / (1.f + __expf(-a)));
                } else if constexpr (EPI == BEPI_RELUSQ_BF) {
                    const float t = fmaxf(a, 0.f);
                    ((ushort*)Cm)[oi] = f2bf(t * t);
                } else if constexpr (EPI == BEPI_NONE_F) {
                    ((float*)Cm)[oi] = a;
                } else if constexpr (EPI == BEPI_RES_F) {
                    ((float*)Cm)[oi] = aux1[oi] + a;
                } else if constexpr (EPI == BEPI_SIGRES_F) {
                    ((float*)Cm)[oi] = aux1[oi] + aux2[oi] / (1.f + __expf(-a));
                } else if constexpr (EPI == BEPI_SIGRES2_F) {
                    ((float*)Cm)[oi] = aux1[oi] + (aux2[oi] + aux3[oi]) / (1.f + __expf(-a));
                } else if constexpr (EPI == BEPI_TANH_F) {
                    ((float*)Cm)[oi] = tanhf(a);
                } else if constexpr (EPI == BEPI_TANH_BF) {
                    ((ushort*)Cm)[oi] = f2bf(tanhf(a));
                } else {  // BEPI_DECAY_F
                    ((float*)Cm)[oi] = __expf(-__expf(a + aux1[col]));
                }
            }
        }
    }
}

// -------- Wcv split-K=2: z = K-half; f32 partials to P0/P1 --------
__global__ __launch_bounds__(256) void wcv_kernel(const ushort* __restrict__ A,
                                                  const ushort* __restrict__ Bt,
                                                  float* __restrict__ P0,
                                                  float* __restrict__ P1)
{
    __shared__ GemmLds<64> lds;
    const int z = blockIdx.z;
    int w = blockIdx.y * gridDim.x + blockIdx.x;   // 16x16 = 256
    w = (w & 7) * 32 + (w >> 3);                    // XCD swizzle
    const int bn = (w % 16) * 64;
    const int bm = (w / 16) * 128;
    const int tid = threadIdx.x;
    const int wid = tid >> 6, lane = tid & 63;
    const int wr = wid >> 1, wc = wid & 1;
    const int l15 = lane & 15, lhi = lane >> 4;

    floatx4 acc[4][2];
#pragma unroll
    for (int m = 0; m < 4; ++m)
#pragma unroll
        for (int n = 0; n < 2; ++n) acc[m][n] = (floatx4){0.f, 0.f, 0.f, 0.f};

    gemm_body<64>(A + z * (FF / 2), Bt + z * (FF / 2), bm, bn, FF / 2, FF, FF, lds, acc);

    float* __restrict__ P = z ? P1 : P0;
#pragma unroll
    for (int m = 0; m < 4; ++m) {
        const int row0 = bm + wr * 64 + m * 16 + lhi * 4;
#pragma unroll
        for (int n = 0; n < 2; ++n) {
            const int col = bn + wc * 32 + n * 16 + l15;
#pragma unroll
            for (int j = 0; j < 4; ++j)
                P[(size_t)(row0 + j) * C + col] = acc[m][n][j];
        }
    }
}

// -------- batched QKVG GEMM (BN=128): blockIdx.z selects {k,v,r,g} --------
struct QkvgArgs { const ushort* A[4]; ushort* O[4]; };
__global__ __launch_bounds__(256) void qkvg_kernel(QkvgArgs args,
                                                   const ushort* __restrict__ Wt)
{
    __shared__ GemmLds<128> lds;
    const int z = blockIdx.z;
    int w = blockIdx.y * gridDim.x + blockIdx.x;          // 8 x 16 grid = 128
    w = (w & 7) * 16 + (w >> 3);                           // XCD swizzle
    const int bn = (w & 7) * 128;
    const int bm = (w >> 3) * 128;
    const int tid = threadIdx.x;
    const int wid = tid >> 6, lane = tid & 63;
    const int wr = wid >> 1, wc = wid & 1;
    const int l15 = lane & 15, lhi = lane >> 4;

    floatx4 acc[4][4];
#pragma unroll
    for (int m = 0; m < 4; ++m)
#pragma unroll
        for (int n = 0; n < 4; ++n) acc[m][n] = (floatx4){0.f, 0.f, 0.f, 0.f};

    gemm_body<128>(args.A[z], Wt + (size_t)z * C * C, bm, bn, C, C, C, lds, acc);

    ushort* __restrict__ O = args.O[z];
    const bool silu = (z == 3);
#pragma unroll
    for (int m = 0; m < 4; ++m) {
        const int row0 = bm + wr * 64 + m * 16 + lhi * 4;
#pragma unroll
        for (int n = 0; n < 4; ++n) {
            const int col = bn + wc * 64 + n * 16 + l15;
#pragma unroll
            for (int j = 0; j < 4; ++j) {
                float a = acc[m][n][j];
                if (silu) a = a / (1.f + __expf(-a));
                O[(size_t)(row0 + j) * C + col] = f2bf(a);
            }
        }
    }
}

// ---------------- launch ----------------
extern "C" void kernel_launch(void* const* d_in, const int* in_sizes, int n_in,
                              void* d_out, int out_size, void* d_ws, size_t ws_size,
                              hipStream_t stream)
{
    const float* x        = (const float*)d_in[0];
    const float* ln1_g    = (const float*)d_in[1];
    const float* ln1_b    = (const float*)d_in[2];
    const float* ln2_g    = (const float*)d_in[3];
    const float* ln2_b    = (const float*)d_in[4];
    const float* maa_x    = (const float*)d_in[5];
    const float* maa_w    = (const float*)d_in[6];
    const float* maa_k    = (const float*)d_in[7];
    const float* maa_v    = (const float*)d_in[8];
    const float* maa_r    = (const float*)d_in[9];
    const float* maa_g    = (const float*)d_in[10];
    const float* maa_w1   = (const float*)d_in[11];
    const float* maa_w2   = (const float*)d_in[12];
    const float* time_dec = (const float*)d_in[13];
    const float* tdw1     = (const float*)d_in[14];
    const float* tdw2     = (const float*)d_in[15];
    const float* u        = (const float*)d_in[16];
    const float* Wr       = (const float*)d_in[17];
    const float* Wk       = (const float*)d_in[18];
    const float* Wv       = (const float*)d_in[19];
    const float* Wg       = (const float*)d_in[20];
    const float* Wo       = (const float*)d_in[21];
    const float* lnx_g    = (const float*)d_in[22];
    const float* lnx_b    = (const float*)d_in[23];
    const float* cmaa_k   = (const float*)d_in[24];
    const float* cmaa_r   = (const float*)d_in[25];
    const float* Wck      = (const float*)d_in[26];
    const float* Wcv      = (const float*)d_in[27];
    const float* Wcr      = (const float*)d_in[28];
    float* out = (float*)d_out;

    // -------- workspace layout (~63 MB) --------
    float* fws = (float*)d_ws;
    const size_t E = (size_t)BT * C;            // 2,097,152
    float* xa  = fws + 0 * E;                   // xa -> yf ; (FFN) kk low half
    float* xx  = fws + 1 * E;                   // xx -> yb ; kk high half
    float* wd  = fws + 2 * E;                   // decay d -> xc -> kvB partial
    float* fs  = fws + 3 * E;                   // xvb/xrb ; M low ; kvA partial
    ushort* wBuf = (ushort*)(fws + 4 * E);      // 4M ushort: weights / M high
    ushort* Mbuf = (ushort*)fs;                 // 2048*4096 bf16 = fs..wBuf (16MB)
    ushort* w2t  = wBuf + (size_t)C * 160;      // 5*C*32 bf16 (after maa_w1t)
    ushort* bf1  = wBuf + (size_t)C * FF;       // E: ax / xkb / ck_in
    ushort* rb   = bf1 + E;                     // r
    ushort* kb   = rb + E;                      // k
    ushort* vb   = kb + E;                      // v  -> ya
    ushort* gb   = vb + E;                      // g  -> cr_in
    ushort* t1b  = gb + E;                      // BT*64 bf16
    float* a5    = (float*)(t1b + (size_t)BT * 64);   // BT*160 (a5b bf16 inside)
    float* sig   = a5 + (size_t)BT * 160;       // (unused)
    float* Dbuf  = sig + (size_t)BT * H;        // 2048*64 f32
    ushort* a5b  = (ushort*)a5;                 // BT*160 bf16
    ushort* xvb  = (ushort*)fs;                 // E (mix v input)
    ushort* xrb  = (ushort*)fs + E;             // E (mix r input)
    ushort* xgb  = (ushort*)out;                // E (mix g input; out is scratch)
    ushort* xwb  = (ushort*)out + E;            // E (mix w input)
    ushort* kk   = (ushort*)xa;                 // BT*FF bf16 == xa..xx

    const dim3 blk(256);
    const dim3 tblk(32, 8);
    const int EW = (BT * C) / 256;
    const dim3 gNN(C / 64, BT / 128);

    // ---- attention branch ----
    ln_kernel<<<BT, blk, 0, stream>>>(x, ln1_g, ln1_b, xa);
    bshiftmix_kernel<<<EW, blk, 0, stream>>>(xa, maa_x, xx, bf1);
    wconv_kernel<<<dim3(160 / 32, C / 32), tblk, 0, stream>>>(maa_w1, wBuf, C, 160);
    bgemm_kernel<64, BEPI_TANH_BF><<<dim3(3, BT / 128), blk, 0, stream>>>(bf1, wBuf, a5b, BT, 160, C, nullptr, nullptr, nullptr);

    // w2 slices -> [5][C][32] bf16 transposed (one launch)
    w2conv_kernel<<<dim3(C / 32, 5), tblk, 0, stream>>>(maa_w2, w2t);

    // all 5 mixes as one fused MFMA GEMM launch
    Mix5Args margs;
    margs.maa[0] = maa_w; margs.maa[1] = maa_k; margs.maa[2] = maa_v;
    margs.maa[3] = maa_r; margs.maa[4] = maa_g;
    margs.out[0] = xwb; margs.out[1] = bf1; margs.out[2] = xvb;
    margs.out[3] = xrb; margs.out[4] = xgb;
    mix5m_kernel<<<dim3(C / 64, BT / 128, 5), blk, 0, stream>>>(a5b, w2t, xa, xx, margs);

    // w path: tanh(xw@tdw1) -> decay d = exp(-exp(@tdw2 + time_decay))
    wconv_kernel<<<dim3(64 / 32, C / 32), tblk, 0, stream>>>(tdw1, wBuf, C, 64);
    bgemm_kernel<64, BEPI_TANH_BF><<<dim3(1, BT / 128), blk, 0, stream>>>(xwb, wBuf, t1b, BT, 64, C, nullptr, nullptr, nullptr);
    wconv_kernel<<<dim3(C / 32, 64 / 32), tblk, 0, stream>>>(tdw2, wBuf, 64, C);
    bgemm_kernel<64, BEPI_DECAY_F><<<gNN, blk, 0, stream>>>(t1b, wBuf, wd, BT, C, 64, time_dec, nullptr, nullptr);

    // batched QKVG
    Wconv4Args wargs;
    wargs.W[0] = Wk; wargs.W[1] = Wv; wargs.W[2] = Wr; wargs.W[3] = Wg;
    wconv4_kernel<<<dim3(C / 32, C / 32, 4), tblk, 0, stream>>>(wargs, wBuf);
    QkvgArgs qargs;
    qargs.A[0] = bf1; qargs.A[1] = xvb; qargs.A[2] = xrb; qargs.A[3] = xgb;
    qargs.O[0] = kb;  qargs.O[1] = vb;  qargs.O[2] = rb;  qargs.O[3] = gb;
    qkvg_kernel<<<dim3(8, 16, 4), blk, 0, stream>>>(qargs, wBuf);

    // chunked bidirectional WKV (Mbuf overlays fs+wBuf; yf/yb = xa/xx f32)
    wkv_pass1<<<dim3(2 * B * H * NCH), blk, 0, stream>>>(kb, vb, wd, Mbuf, Dbuf);
    wkv_pass2<<<dim3(2 * B * H), dim3(1024), 0, stream>>>(Mbuf, Dbuf);
    wkv_ymfma<<<dim3(2 * B * H * NCH), blk, 0, stream>>>(rb, kb, vb, wd, Mbuf, xa, xx);

    // ya = groupnorm(yf+yb+sig*v)*g ; out = x + ya @ Wo^T
    gnmul_kernel<<<BT, dim3(1024), 0, stream>>>(xa, xx, lnx_g, lnx_b, gb, vb, rb, kb, u, vb);
    wconv_kernel<<<dim3(C / 32, C / 32), tblk, 0, stream>>>(Wo, wBuf, C, C);
    bgemm_kernel<64, BEPI_RES_F><<<gNN, blk, 0, stream>>>(vb, wBuf, out, BT, C, C, x, nullptr, nullptr);

    // ---- FFN branch ----
    ln_kernel<<<BT, blk, 0, stream>>>(out, ln2_g, ln2_b, wd);
    bshiftcmix_kernel<<<EW, blk, 0, stream>>>(wd, cmaa_k, cmaa_r, bf1, gb);
    wconv_kernel<<<dim3(FF / 32, C / 32), tblk, 0, stream>>>(Wck, wBuf, C, FF);
    bgemm_kernel<128, BEPI_RELUSQ_BF><<<dim3(FF / 128, BT / 128), blk, 0, stream>>>(bf1, wBuf, kk, BT, FF, C, nullptr, nullptr, nullptr);
    wconv_kernel<<<dim3(C / 32, FF / 32), tblk, 0, stream>>>(Wcv, wBuf, FF, C);
    wcv_kernel<<<dim3(16, 16, 2), blk, 0, stream>>>(kk, wBuf, fs, wd);
    wconv_kernel<<<dim3(C / 32, C / 32), tblk, 0, stream>>>(Wcr, wBuf, C, C);
    bgemm_kernel<64, BEPI_SIGRES2_F><<<gNN, blk, 0, stream>>>(gb, wBuf, out, BT, C, C, out, fs, wd);

    (void)in_sizes; (void)n_in; (void)out_size; (void)ws_size;
}

// Round 15
// 251.251 us; speedup vs baseline: 5.7405x; 1.0173x over previous
//
#include <hip/hip_runtime.h>
#include <math.h>
#include <stdint.h>

static constexpr int B  = 8;
static constexpr int T  = 256;
static constexpr int C  = 1024;
static constexpr int H  = 16;
static constexpr int HEAD = 64;
static constexpr int FF = 4096;
static constexpr int BT = B * T;
static constexpr int NCH = 8;       // time chunks
static constexpr int CS  = 32;      // chunk size (NCH*CS == T)

typedef short short8  __attribute__((ext_vector_type(8)));
typedef float floatx4 __attribute__((ext_vector_type(4)));

// ---------------- bf16 helpers ----------------
__device__ __forceinline__ float bf2f(ushort u) {
    return __uint_as_float(((uint32_t)u) << 16);
}
__device__ __forceinline__ ushort f2bf(float x) {
    uint32_t u = __float_as_uint(x);
    u += 0x7fff + ((u >> 16) & 1);          // RNE
    return (ushort)(u >> 16);
}

__device__ __forceinline__ void gload16(const void* g, void* l) {
    __builtin_amdgcn_global_load_lds(
        (const __attribute__((address_space(1))) unsigned int*)g,
        (__attribute__((address_space(3))) unsigned int*)l, 16, 0, 0);
}

// ---------------- epilogue ids ----------------
#define BEPI_NONE_BF   0
#define BEPI_SILU_BF   1
#define BEPI_RELUSQ_BF 2
#define BEPI_NONE_F    3
#define BEPI_RES_F     4
#define BEPI_SIGRES_F  5
#define BEPI_TANH_F    6
#define BEPI_TANH_BF   7
#define BEPI_DECAY_F   8
#define BEPI_SIGRES2_F 9

// ---- 3-row LN helper: reduce 6 partial sums across block ----
__device__ __forceinline__ void red6(float (&vals)[6], float* red)
{
    const int wave = threadIdx.x >> 6, lane = threadIdx.x & 63;
#pragma unroll
    for (int i = 0; i < 6; ++i) {
        float v = vals[i];
#pragma unroll
        for (int off = 32; off > 0; off >>= 1) v += __shfl_xor(v, off);
        if (lane == 0) red[i * 4 + wave] = v;
    }
    __syncthreads();
#pragma unroll
    for (int i = 0; i < 6; ++i)
        vals[i] = red[i * 4 + 0] + red[i * 4 + 1] + red[i * 4 + 2] + red[i * 4 + 3];
}

// ---- fused LN + bshift + mixax (attention) ----
// xa = LN(x) f32 ; xx = bshift(xa)-xa f32 ; ax = bf16(xa + xx*maa)
__global__ __launch_bounds__(256) void lnshiftmix_kernel(const float* __restrict__ x,
                                                         const float* __restrict__ g,
                                                         const float* __restrict__ b,
                                                         const float* __restrict__ maa,
                                                         float* __restrict__ xa,
                                                         float* __restrict__ xx,
                                                         ushort* __restrict__ ax)
{
    const int row = blockIdx.x;
    const int t = row & (T - 1);
    const int tid = threadIdx.x;
    __shared__ float red[24];
    const float4 vc = reinterpret_cast<const float4*>(x + (size_t)row * C)[tid];
    float4 vp = make_float4(0.f, 0.f, 0.f, 0.f), vn = make_float4(0.f, 0.f, 0.f, 0.f);
    if (t > 0)     vp = reinterpret_cast<const float4*>(x + (size_t)(row - 1) * C)[tid];
    if (t < T - 1) vn = reinterpret_cast<const float4*>(x + (size_t)(row + 1) * C)[tid];
    float vals[6];
    vals[0] = vc.x + vc.y + vc.z + vc.w;
    vals[1] = vc.x * vc.x + vc.y * vc.y + vc.z * vc.z + vc.w * vc.w;
    vals[2] = vp.x + vp.y + vp.z + vp.w;
    vals[3] = vp.x * vp.x + vp.y * vp.y + vp.z * vp.z + vp.w * vp.w;
    vals[4] = vn.x + vn.y + vn.z + vn.w;
    vals[5] = vn.x * vn.x + vn.y * vn.y + vn.z * vn.z + vn.w * vn.w;
    red6(vals, red);
    const float mc = vals[0] * (1.f / C);
    const float rc = rsqrtf(fmaxf(vals[1] * (1.f / C) - mc * mc, 0.f) + 1e-5f);
    const float mp = vals[2] * (1.f / C);
    const float rp = rsqrtf(fmaxf(vals[3] * (1.f / C) - mp * mp, 0.f) + 1e-5f);
    const float mn = vals[4] * (1.f / C);
    const float rn = rsqrtf(fmaxf(vals[5] * (1.f / C) - mn * mn, 0.f) + 1e-5f);

    const int c = tid * 4;
    const bool fh = ((c & 63) < 32);
    const float cur[4] = {vc.x, vc.y, vc.z, vc.w};
    const float nbr[4] = {fh ? vp.x : vn.x, fh ? vp.y : vn.y,
                          fh ? vp.z : vn.z, fh ? vp.w : vn.w};
    const float mN = fh ? mp : mn, rN = fh ? rp : rn;
    const bool nvalid = fh ? (t > 0) : (t < T - 1);
    const size_t rb = (size_t)row * C;
#pragma unroll
    for (int e = 0; e < 4; ++e) {
        const float gg = g[c + e], bb = b[c + e];
        const float av = (cur[e] - mc) * rc * gg + bb;
        const float sv = nvalid ? ((nbr[e] - mN) * rN * gg + bb) : 0.f;
        const float xv = sv - av;
        xa[rb + c + e] = av;
        xx[rb + c + e] = xv;
        ax[rb + c + e] = f2bf(av + xv * maa[c + e]);
    }
}

// ---- fused LN + bshift + cmix (FFN): two bf16 mixed outputs, no intermediates
__global__ __launch_bounds__(256) void lnshiftcmix_kernel(const float* __restrict__ x,
                                                          const float* __restrict__ g,
                                                          const float* __restrict__ b,
                                                          const float* __restrict__ mk,
                                                          const float* __restrict__ mr,
                                                          ushort* __restrict__ ok,
                                                          ushort* __restrict__ orr)
{
    const int row = blockIdx.x;
    const int t = row & (T - 1);
    const int tid = threadIdx.x;
    __shared__ float red[24];
    const float4 vc = reinterpret_cast<const float4*>(x + (size_t)row * C)[tid];
    float4 vp = make_float4(0.f, 0.f, 0.f, 0.f), vn = make_float4(0.f, 0.f, 0.f, 0.f);
    if (t > 0)     vp = reinterpret_cast<const float4*>(x + (size_t)(row - 1) * C)[tid];
    if (t < T - 1) vn = reinterpret_cast<const float4*>(x + (size_t)(row + 1) * C)[tid];
    float vals[6];
    vals[0] = vc.x + vc.y + vc.z + vc.w;
    vals[1] = vc.x * vc.x + vc.y * vc.y + vc.z * vc.z + vc.w * vc.w;
    vals[2] = vp.x + vp.y + vp.z + vp.w;
    vals[3] = vp.x * vp.x + vp.y * vp.y + vp.z * vp.z + vp.w * vp.w;
    vals[4] = vn.x + vn.y + vn.z + vn.w;
    vals[5] = vn.x * vn.x + vn.y * vn.y + vn.z * vn.z + vn.w * vn.w;
    red6(vals, red);
    const float mc = vals[0] * (1.f / C);
    const float rc = rsqrtf(fmaxf(vals[1] * (1.f / C) - mc * mc, 0.f) + 1e-5f);
    const float mp = vals[2] * (1.f / C);
    const float rp = rsqrtf(fmaxf(vals[3] * (1.f / C) - mp * mp, 0.f) + 1e-5f);
    const float mn = vals[4] * (1.f / C);
    const float rn = rsqrtf(fmaxf(vals[5] * (1.f / C) - mn * mn, 0.f) + 1e-5f);

    const int c = tid * 4;
    const bool fh = ((c & 63) < 32);
    const float cur[4] = {vc.x, vc.y, vc.z, vc.w};
    const float nbr[4] = {fh ? vp.x : vn.x, fh ? vp.y : vn.y,
                          fh ? vp.z : vn.z, fh ? vp.w : vn.w};
    const float mN = fh ? mp : mn, rN = fh ? rp : rn;
    const bool nvalid = fh ? (t > 0) : (t < T - 1);
    const size_t rb = (size_t)row * C;
#pragma unroll
    for (int e = 0; e < 4; ++e) {
        const float gg = g[c + e], bb = b[c + e];
        const float av = (cur[e] - mc) * rc * gg + bb;
        const float sv = nvalid ? ((nbr[e] - mN) * rN * gg + bb) : 0.f;
        const float xv = sv - av;
        ok[rb + c + e]  = f2bf(av + xv * mk[c + e]);
        orr[rb + c + e] = f2bf(av + xv * mr[c + e]);
    }
}

// -------- GroupNorm(yf+yb+sig*v)*g+b, * gate; u-bonus scalar fused ---------
__global__ __launch_bounds__(1024) void gnmul_kernel(const ushort* __restrict__ yf,
                                                     const ushort* __restrict__ yb,
                                                     const float* __restrict__ g,
                                                     const float* __restrict__ b,
                                                     const ushort* __restrict__ gate,
                                                     const ushort* __restrict__ vin,
                                                     const ushort* __restrict__ rbuf,
                                                     const ushort* __restrict__ kbuf,
                                                     const float* __restrict__ u,
                                                     ushort* __restrict__ out)
{
    const int row = blockIdx.x;
    const int tid = threadIdx.x;                 // wave == head
    const size_t idx = (size_t)row * C + tid;
    float p = bf2f(rbuf[idx]) * bf2f(kbuf[idx]) * u[tid];
#pragma unroll
    for (int off = 32; off > 0; off >>= 1) p += __shfl_xor(p, off);
    const float v = bf2f(yf[idx]) + bf2f(yb[idx]) + p * bf2f(vin[idx]);
    float s = v;
#pragma unroll
    for (int off = 32; off > 0; off >>= 1) s += __shfl_xor(s, off);
    const float m = s * (1.0f / HEAD);
    const float d = v - m;
    float q = d * d;
#pragma unroll
    for (int off = 32; off > 0; off >>= 1) q += __shfl_xor(q, off);
    const float rstd = rsqrtf(q * (1.0f / HEAD) + 6.4e-4f);
    out[idx] = f2bf((d * rstd * g[tid] + b[tid]) * bf2f(gate[idx]));
}

// -------- weight convert+transpose: W[Kd,Nd] f32 -> Wt[Nd,Kd] bf16 --------
__global__ __launch_bounds__(256) void wconv_kernel(const float* __restrict__ W,
                                                    ushort* __restrict__ Wt,
                                                    int Kd, int Nd)
{
    __shared__ float tile[32][33];
    const int n0 = blockIdx.x * 32, k0 = blockIdx.y * 32;
    const int tx = threadIdx.x, ty = threadIdx.y;
#pragma unroll
    for (int i = 0; i < 4; ++i)
        tile[ty * 4 + i][tx] = W[(size_t)(k0 + ty * 4 + i) * Nd + n0 + tx];
    __syncthreads();
#pragma unroll
    for (int i = 0; i < 4; ++i)
        Wt[(size_t)(n0 + ty * 4 + i) * Kd + k0 + tx] = f2bf(tile[tx][ty * 4 + i]);
}

// -------- w2 slices: w2[5][32][C] -> w2t[5][C][32] bf16, one launch --------
__global__ __launch_bounds__(256) void w2conv_kernel(const float* __restrict__ w2,
                                                     ushort* __restrict__ w2t)
{
    __shared__ float tile[32][33];
    const int f = blockIdx.y;
    const int n0 = blockIdx.x * 32;
    const int tx = threadIdx.x, ty = threadIdx.y;
#pragma unroll
    for (int i = 0; i < 4; ++i)
        tile[ty * 4 + i][tx] = w2[(size_t)f * 32 * C + (size_t)(ty * 4 + i) * C + n0 + tx];
    __syncthreads();
#pragma unroll
    for (int i = 0; i < 4; ++i)
        w2t[(size_t)f * C * 32 + (size_t)(n0 + ty * 4 + i) * 32 + tx] = f2bf(tile[tx][ty * 4 + i]);
}

// -------- batched wconv: 4 C x C weights (blockIdx.z) --------
struct Wconv4Args { const float* W[4]; };
__global__ __launch_bounds__(256) void wconv4_kernel(Wconv4Args args, ushort* __restrict__ Wt)
{
    __shared__ float tile[32][33];
    const int z = blockIdx.z;
    const float* __restrict__ W = args.W[z];
    ushort* __restrict__ dst = Wt + (size_t)z * C * C;
    const int n0 = blockIdx.x * 32, k0 = blockIdx.y * 32;
    const int tx = threadIdx.x, ty = threadIdx.y;
#pragma unroll
    for (int i = 0; i < 4; ++i)
        tile[ty * 4 + i][tx] = W[(size_t)(k0 + ty * 4 + i) * C + n0 + tx];
    __syncthreads();
#pragma unroll
    for (int i = 0; i < 4; ++i)
        dst[(size_t)(n0 + ty * 4 + i) * C + k0 + tx] = f2bf(tile[tx][ty * 4 + i]);
}

// ======== mix5 as fused MFMA GEMM: out_f = bf16(xa + xx*(maa_f + a5b@w2t_f)) ====
struct Mix5Args { const float* maa[5]; ushort* out[5]; };
__global__ __launch_bounds__(256) void mix5m_kernel(const ushort* __restrict__ a5b,
                                                    const ushort* __restrict__ w2t,
                                                    const float* __restrict__ xa,
                                                    const float* __restrict__ xx,
                                                    Mix5Args args)
{
    __shared__ __align__(16) ushort As[128 * 32];
    __shared__ __align__(16) ushort Bs[64 * 32];
    const int f = blockIdx.z;
    const int bm = blockIdx.y * 128, bn = blockIdx.x * 64;
    const int tid = threadIdx.x;
    const int wid = tid >> 6, lane = tid & 63;
    const int wr = wid >> 1, wc = wid & 1;
    const int l15 = lane & 15, lhi = lane >> 4;

#pragma unroll
    for (int p = 0; p < 2; ++p) {
        const int lin = p * 256 + tid;
        const int row = lin >> 2;
        const int sp = (lin & 3) ^ ((row >> 1) & 3);
        gload16(a5b + (size_t)(bm + row) * 160 + f * 32 + sp * 8, &As[lin * 8]);
    }
    {
        const int lin = tid;
        const int n = lin >> 2;
        const int sp = (lin & 3) ^ ((n >> 1) & 3);
        gload16(w2t + ((size_t)f * C + bn + n) * 32 + sp * 8, &Bs[lin * 8]);
    }
    __syncthreads();

    short8 af[4], bfr[2];
#pragma unroll
    for (int m = 0; m < 4; ++m) {
        const int row = wr * 64 + m * 16 + l15;
        const int sp = lhi ^ ((row >> 1) & 3);
        af[m] = *(const short8*)&As[row * 32 + sp * 8];
    }
#pragma unroll
    for (int n = 0; n < 2; ++n) {
        const int col = wc * 32 + n * 16 + l15;
        const int sp = lhi ^ ((col >> 1) & 3);
        bfr[n] = *(const short8*)&Bs[col * 32 + sp * 8];
    }
    floatx4 acc[4][2];
#pragma unroll
    for (int m = 0; m < 4; ++m)
#pragma unroll
        for (int n = 0; n < 2; ++n)
            acc[m][n] = __builtin_amdgcn_mfma_f32_16x16x32_bf16(
                af[m], bfr[n], (floatx4){0.f, 0.f, 0.f, 0.f}, 0, 0, 0);

    const float* __restrict__ maa = args.maa[f];
    ushort* __restrict__ out = args.out[f];
#pragma unroll
    for (int m = 0; m < 4; ++m) {
        const int row0 = bm + wr * 64 + m * 16 + lhi * 4;
#pragma unroll
        for (int n = 0; n < 2; ++n) {
            const int col = bn + wc * 32 + n * 16 + l15;
            const float mc = maa[col];
#pragma unroll
            for (int j = 0; j < 4; ++j) {
                const size_t oi = (size_t)(row0 + j) * C + col;
                out[oi] = f2bf(xa[oi] + xx[oi] * (mc + acc[m][n][j]));
            }
        }
    }
}

// ================== chunked bidirectional WKV6 (MFMA) ==================
// pass1: M^T[i][j] = sum_s v[s][i] * (k[s][j] * G_s[j]),  G_s = prod_{u>s} d_u
__global__ __launch_bounds__(256) void wkv_pass1(const ushort* __restrict__ k,
                                                 const ushort* __restrict__ v,
                                                 const float* __restrict__ d,
                                                 ushort* __restrict__ M,
                                                 float* __restrict__ D)
{
    const int uc = blockIdx.x;
    const int c = uc & (NCH - 1), unit = uc >> 3;
    const int dir = unit & 1, bh = unit >> 1;
    const int tid = threadIdx.x;
    const int wv = tid >> 6, lane = tid & 63;
    const int l15 = lane & 15, lhi = lane >> 4;
    const size_t rowb = ((size_t)(bh >> 4) * T * H + (bh & 15)) * HEAD;
    const int s0 = c * CS;

    __shared__ ushort kT[64][40];    // k'' transposed [j][s]
    __shared__ ushort vt[64][40];    // v^T [i][s]
    __shared__ float  Ldd[CS][64];   // d staged [s][j]

    for (int idx = tid; idx < CS * 64; idx += 256) {
        const int s = idx >> 6, j = idx & 63;
        const int t = dir ? (T - 1 - (s0 + s)) : (s0 + s);
        const size_t g = rowb + (size_t)t * (H * HEAD) + j;
        kT[j][s] = k[g];
        vt[j][s] = v[g];
        Ldd[s][j] = d[g];
    }
    __syncthreads();

    if (tid < 64) {
        const int j = tid;
        float G = 1.f;
#pragma unroll
        for (int s = CS - 1; s >= 0; --s) {
            kT[j][s] = f2bf(bf2f(kT[j][s]) * G);
            G *= Ldd[s][j];
        }
        D[(size_t)uc * 64 + j] = G;
    }
    __syncthreads();

    const short8 av = *(const short8*)&vt[wv * 16 + l15][lhi * 8];
    ushort* __restrict__ mrow = M + (size_t)uc * 4096;
#pragma unroll
    for (int n = 0; n < 4; ++n) {
        const short8 bk = *(const short8*)&kT[n * 16 + l15][lhi * 8];
        const floatx4 acc = __builtin_amdgcn_mfma_f32_16x16x32_bf16(
            av, bk, (floatx4){0.f, 0.f, 0.f, 0.f}, 0, 0, 0);
#pragma unroll
        for (int jr = 0; jr < 4; ++jr) {
            const int i = wv * 16 + lhi * 4 + jr;
            mrow[(size_t)i * 64 + n * 16 + l15] = f2bf(acc[jr]);
        }
    }
}

// pass2 (parallel): 1024 threads/unit, thread owns 4 state elements of M^T.
__global__ __launch_bounds__(1024) void wkv_pass2(ushort* __restrict__ M,
                                                  const float* __restrict__ D)
{
    const int unit = blockIdx.x;
    const int tid = threadIdx.x;
    const int j0 = (tid & 15) * 4;
    float S0 = 0.f, S1 = 0.f, S2 = 0.f, S3 = 0.f;
#pragma unroll
    for (int c = 0; c < NCH; ++c) {
        const int uc = unit * NCH + c;
        const float4 Dv = *reinterpret_cast<const float4*>(D + (size_t)uc * 64 + j0);
        ushort* mp = M + (size_t)uc * 4096 + tid * 4;
        const uint2 mv = *reinterpret_cast<const uint2*>(mp);
        const float m0 = bf2f((ushort)(mv.x & 0xffff));
        const float m1 = bf2f((ushort)(mv.x >> 16));
        const float m2 = bf2f((ushort)(mv.y & 0xffff));
        const float m3 = bf2f((ushort)(mv.y >> 16));
        uint2 sv;
        sv.x = (uint32_t)f2bf(S0) | ((uint32_t)f2bf(S1) << 16);
        sv.y = (uint32_t)f2bf(S2) | ((uint32_t)f2bf(S3) << 16);
        *reinterpret_cast<uint2*>(mp) = sv;
        S0 = fmaf(Dv.x, S0, m0);
        S1 = fmaf(Dv.y, S1, m1);
        S2 = fmaf(Dv.z, S2, m2);
        S3 = fmaf(Dv.w, S3, m3);
    }
}

// ======= y via MFMA: y = r' @ S_in + tril(r' @ k'^T, -1) @ v (bf16 y out) ====
__global__ __launch_bounds__(256) void wkv_ymfma(const ushort* __restrict__ r,
                                                 const ushort* __restrict__ k,
                                                 const ushort* __restrict__ v,
                                                 const float* __restrict__ d,
                                                 const ushort* __restrict__ Sin,
                                                 ushort* __restrict__ yf,
                                                 ushort* __restrict__ yb)
{
    const int uc = blockIdx.x;
    const int c = uc & (NCH - 1), unit = uc >> 3;
    const int dir = unit & 1, bh = unit >> 1;
    const int tid = threadIdx.x;
    const int wv = tid >> 6, lane = tid & 63;
    const int l15 = lane & 15, lhi = lane >> 4;
    const size_t rowb = ((size_t)(bh >> 4) * T * H + (bh & 15)) * HEAD;
    const int s0 = c * CS;

    __shared__ ushort rp[32][64];
    __shared__ ushort kp[32][64];
    __shared__ ushort vt[64][40];
    __shared__ ushort Pl[32][32];
    __shared__ float  Ldd[CS][64];

    for (int idx = tid; idx < 32 * 64; idx += 256) {
        const int s = idx >> 6, j = idx & 63;
        const int t = dir ? (T - 1 - (s0 + s)) : (s0 + s);
        const size_t g = rowb + (size_t)t * (H * HEAD) + j;
        const int cs = (j >> 3) ^ (s & 7);
        rp[s][cs * 8 + (j & 7)] = r[g];
        kp[s][cs * 8 + (j & 7)] = k[g];
        vt[j][s] = v[g];
        Ldd[s][j] = d[g];
    }
    __syncthreads();

    if (wv == 0) {                   // r' = r * Q[s]
        const int j = lane;
        float Q = 1.f;
#pragma unroll
        for (int s = 0; s < 32; ++s) {
            const int a = ((j >> 3) ^ (s & 7)) * 8 + (j & 7);
            rp[s][a] = f2bf(bf2f(rp[s][a]) * Q);
            Q *= Ldd[s][j];
        }
    } else if (wv == 1) {            // k' = k / Q[s+1]
        const int j = lane;
        float iQ = 1.f;
#pragma unroll
        for (int s = 0; s < 32; ++s) {
            iQ *= (1.0f / Ldd[s][j]);
            const int a = ((j >> 3) ^ (s & 7)) * 8 + (j & 7);
            kp[s][a] = f2bf(bf2f(kp[s][a]) * iQ);
        }
    }
    __syncthreads();

    const int st = wv & 1;
    const int ip = wv >> 1;

    short8 ar[2];
#pragma unroll
    for (int ks = 0; ks < 2; ++ks) {
        const int row = st * 16 + l15;
        const int ch = (ks * 4 + lhi) ^ (row & 7);
        ar[ks] = *(const short8*)&rp[row][ch * 8];
    }

    floatx4 acc[2];
#pragma unroll
    for (int n = 0; n < 2; ++n) {
        const int i = ip * 32 + n * 16 + l15;
        const ushort* sp = Sin + (size_t)uc * 4096 + (size_t)i * 64;
        const short8 b0 = *(const short8*)&sp[lhi * 8];
        const short8 b1 = *(const short8*)&sp[32 + lhi * 8];
        acc[n] = __builtin_amdgcn_mfma_f32_16x16x32_bf16(ar[0], b0, (floatx4){0.f, 0.f, 0.f, 0.f}, 0, 0, 0);
        acc[n] = __builtin_amdgcn_mfma_f32_16x16x32_bf16(ar[1], b1, acc[n], 0, 0, 0);
    }

    if (wv < 2) {
#pragma unroll
        for (int ut = 0; ut < 2; ++ut) {
            const int urow = ut * 16 + l15;
            const short8 bk0 = *(const short8*)&kp[urow][((0 + lhi) ^ (urow & 7)) * 8];
            const short8 bk1 = *(const short8*)&kp[urow][((4 + lhi) ^ (urow & 7)) * 8];
            floatx4 pa = __builtin_amdgcn_mfma_f32_16x16x32_bf16(ar[0], bk0, (floatx4){0.f, 0.f, 0.f, 0.f}, 0, 0, 0);
            pa = __builtin_amdgcn_mfma_f32_16x16x32_bf16(ar[1], bk1, pa, 0, 0, 0);
            const int sg0 = st * 16 + lhi * 4;
            const int ug = ut * 16 + l15;
#pragma unroll
            for (int jr = 0; jr < 4; ++jr) {
                const float val = (ug < sg0 + jr) ? pa[jr] : 0.f;
                Pl[sg0 + jr][ug] = f2bf(val);
            }
        }
    }
    __syncthreads();

    short8 ap;
    {
        const int row = st * 16 + l15;
        ap = *(const short8*)&Pl[row][lhi * 8];
    }
#pragma unroll
    for (int n = 0; n < 2; ++n) {
        const int i = ip * 32 + n * 16 + l15;
        const short8 bv = *(const short8*)&vt[i][lhi * 8];
        acc[n] = __builtin_amdgcn_mfma_f32_16x16x32_bf16(ap, bv, acc[n], 0, 0, 0);
    }

    ushort* __restrict__ yo = dir ? yb : yf;
#pragma unroll
    for (int n = 0; n < 2; ++n) {
        const int i = ip * 32 + n * 16 + l15;
#pragma unroll
        for (int jr = 0; jr < 4; ++jr) {
            const int sg = st * 16 + lhi * 4 + jr;
            const int t = dir ? (T - 1 - (s0 + sg)) : (s0 + sg);
            yo[rowb + (size_t)t * (H * HEAD) + i] = f2bf(acc[n][jr]);
        }
    }
}

// ======== pipelined bf16 MFMA GEMM core: BM=128, BK=64, BN in {64,128} ========
template <int BN>
struct GemmLds {
    ushort As[2][128 * 64];
    ushort Bs[2][BN * 64];
};

template <int BN>
__device__ __forceinline__ void gemm_body(const ushort* __restrict__ A,
                                          const ushort* __restrict__ Bt,
                                          int bm, int bn, int K, int lda, int ldb,
                                          GemmLds<BN>& lds,
                                          floatx4 (&acc)[4][BN / 32])
{
    constexpr int NF = BN / 32;
    const int tid = threadIdx.x;
    const int wid = tid >> 6, lane = tid & 63;
    const int wr = wid >> 1, wc = wid & 1;
    const int l15 = lane & 15, lhi = lane >> 4;
    const int NT = K >> 6;

    auto stage = [&](int buf, int k0) {
#pragma unroll
        for (int p = 0; p < 4; ++p) {
            const int lin = p * 256 + tid;
            const int row = lin >> 3;
            const int cs = (lin & 7) ^ (row & 7);
            gload16(A + (size_t)(bm + row) * lda + k0 + cs * 8, &lds.As[buf][lin * 8]);
        }
#pragma unroll
        for (int p = 0; p < NF; ++p) {
            const int lin = p * 256 + tid;
            const int n = lin >> 3;
            const int cs = (lin & 7) ^ (n & 7);
            gload16(Bt + (size_t)(bn + n) * ldb + k0 + cs * 8, &lds.Bs[buf][lin * 8]);
        }
    };

    stage(0, 0);
    __syncthreads();
    for (int t = 0; t < NT; ++t) {
        const int cur = t & 1;
        if (t + 1 < NT) stage(cur ^ 1, (t + 1) << 6);

        short8 af[4][2];
#pragma unroll
        for (int m = 0; m < 4; ++m) {
            const int row = wr * 64 + m * 16 + l15;
#pragma unroll
            for (int s = 0; s < 2; ++s) {
                const int cc = (s * 4 + lhi) ^ (row & 7);
                af[m][s] = *(const short8*)&lds.As[cur][row * 64 + cc * 8];
            }
        }
        short8 bf[NF][2];
#pragma unroll
        for (int n = 0; n < NF; ++n) {
            const int col = wc * (BN / 2) + n * 16 + l15;
#pragma unroll
            for (int s = 0; s < 2; ++s) {
                const int cc = (s * 4 + lhi) ^ (col & 7);
                bf[n][s] = *(const short8*)&lds.Bs[cur][col * 64 + cc * 8];
            }
        }
#pragma unroll
        for (int m = 0; m < 4; ++m)
#pragma unroll
            for (int n = 0; n < NF; ++n) {
                acc[m][n] = __builtin_amdgcn_mfma_f32_16x16x32_bf16(af[m][0], bf[n][0], acc[m][n], 0, 0, 0);
                acc[m][n] = __builtin_amdgcn_mfma_f32_16x16x32_bf16(af[m][1], bf[n][1], acc[m][n], 0, 0, 0);
            }
        __syncthreads();
    }
}

template <int BN, int EPI>
__global__ __launch_bounds__(256) void bgemm_kernel(const ushort* __restrict__ A,
                                                    const ushort* __restrict__ Bt,
                                                    void* __restrict__ Cm,
                                                    int M, int N, int K,
                                                    const float* __restrict__ aux1,
                                                    const float* __restrict__ aux2,
                                                    const float* __restrict__ aux3)
{
    constexpr int NF = BN / 32;
    __shared__ GemmLds<BN> lds;
    int w = blockIdx.y * gridDim.x + blockIdx.x;
    const int nwg = gridDim.x * gridDim.y;
    if ((nwg & 7) == 0) w = (w & 7) * (nwg >> 3) + (w >> 3);   // XCD swizzle
    const int bn = (w % gridDim.x) * BN;
    const int bm = (w / gridDim.x) * 128;
    const int tid = threadIdx.x;
    const int wid = tid >> 6, lane = tid & 63;
    const int wr = wid >> 1, wc = wid & 1;
    const int l15 = lane & 15, lhi = lane >> 4;

    floatx4 acc[4][NF];
#pragma unroll
    for (int m = 0; m < 4; ++m)
#pragma unroll
        for (int n = 0; n < NF; ++n) acc[m][n] = (floatx4){0.f, 0.f, 0.f, 0.f};

    gemm_body<BN>(A, Bt, bm, bn, K, K, K, lds, acc);

#pragma unroll
    for (int m = 0; m < 4; ++m) {
        const int row0 = bm + wr * 64 + m * 16 + lhi * 4;
#pragma unroll
        for (int n = 0; n < NF; ++n) {
            const int col = bn + wc * (BN / 2) + n * 16 + l15;
            if (col >= N) continue;
#pragma unroll
            for (int j = 0; j < 4; ++j) {
                const size_t oi = (size_t)(row0 + j) * N + col;
                const float a = acc[m][n][j];
                if constexpr (EPI == BEPI_NONE_BF) {
                    ((ushort*)Cm)[oi] = f2bf(a);
                } else if constexpr (EPI == BEPI_SILU_BF) {
                    ((ushort*)Cm)[oi] = f2bf(a / (1.f + __expf(-a)));
                } else if constexpr (EPI == BEPI_RELUSQ_BF) {
                    const float t = fmaxf(a, 0.f);
                    ((ushort*)Cm)[oi] = f2bf(t * t);
                } else if constexpr (EPI == BEPI_NONE_F) {
                    ((float*)Cm)[oi] = a;
                } else if constexpr (EPI == BEPI_RES_F) {
                    ((float*)Cm)[oi] = aux1[oi] + a;
                } else if constexpr (EPI == BEPI_SIGRES_F) {
                    ((float*)Cm)[oi] = aux1[oi] + aux2[oi] / (1.f + __expf(-a));
                } else if constexpr (EPI == BEPI_SIGRES2_F) {
                    const float kv = bf2f(((const ushort*)aux2)[oi]) +
                                     bf2f(((const ushort*)aux3)[oi]);
                    ((float*)Cm)[oi] = aux1[oi] + kv / (1.f + __expf(-a));
                } else if constexpr (EPI == BEPI_TANH_F) {
                    ((float*)Cm)[oi] = tanhf(a);
                } else if constexpr (EPI == BEPI_TANH_BF) {
                    ((ushort*)Cm)[oi] = f2bf(tanhf(a));
                } else {  // BEPI_DECAY_F
                    ((float*)Cm)[oi] = __expf(-__expf(a + aux1[col]));
                }
            }
        }
    }
}

// -------- Wcv split-K=2: z = K-half; bf16 partials to P0/P1 --------
__global__ __launch_bounds__(256) void wcv_kernel(const ushort* __restrict__ A,
                                                  const ushort* __restrict__ Bt,
                                                  ushort* __restrict__ P0,
                                                  ushort* __restrict__ P1)
{
    __shared__ GemmLds<64> lds;
    const int z = blockIdx.z;
    int w = blockIdx.y * gridDim.x + blockIdx.x;   // 16x16 = 256
    w = (w & 7) * 32 + (w >> 3);                    // XCD swizzle
    const int bn = (w % 16) * 64;
    const int bm = (w / 16) * 128;
    const int tid = threadIdx.x;
    const int wid = tid >> 6, lane = tid & 63;
    const int wr = wid >> 1, wc = wid & 1;
    const int l15 = lane & 15, lhi = lane >> 4;

    floatx4 acc[4][2];
#pragma unroll
    for (int m = 0; m < 4; ++m)
#pragma unroll
        for (int n = 0; n < 2; ++n) acc[m][n] = (floatx4){0.f, 0.f, 0.f, 0.f};

    gemm_body<64>(A + z * (FF / 2), Bt + z * (FF / 2), bm, bn, FF / 2, FF, FF, lds, acc);

    ushort* __restrict__ P = z ? P1 : P0;
#pragma unroll
    for (int m = 0; m < 4; ++m) {
        const int row0 = bm + wr * 64 + m * 16 + lhi * 4;
#pragma unroll
        for (int n = 0; n < 2; ++n) {
            const int col = bn + wc * 32 + n * 16 + l15;
#pragma unroll
            for (int j = 0; j < 4; ++j)
                P[(size_t)(row0 + j) * C + col] = f2bf(acc[m][n][j]);
        }
    }
}

// -------- batched QKVG GEMM (BN=128): blockIdx.z selects {k,v,r,g} --------
struct QkvgArgs { const ushort* A[4]; ushort* O[4]; };
__global__ __launch_bounds__(256) void qkvg_kernel(QkvgArgs args,
                                                   const ushort* __restrict__ Wt)
{
    __shared__ GemmLds<128> lds;
    const int z = blockIdx.z;
    int w = blockIdx.y * gridDim.x + blockIdx.x;          // 8 x 16 grid = 128
    w = (w & 7) * 16 + (w >> 3);                           // XCD swizzle
    const int bn = (w & 7) * 128;
    const int bm = (w >> 3) * 128;
    const int tid = threadIdx.x;
    const int wid = tid >> 6, lane = tid & 63;
    const int wr = wid >> 1, wc = wid & 1;
    const int l15 = lane & 15, lhi = lane >> 4;

    floatx4 acc[4][4];
#pragma unroll
    for (int m = 0; m < 4; ++m)
#pragma unroll
        for (int n = 0; n < 4; ++n) acc[m][n] = (floatx4){0.f, 0.f, 0.f, 0.f};

    gemm_body<128>(args.A[z], Wt + (size_t)z * C * C, bm, bn, C, C, C, lds, acc);

    ushort* __restrict__ O = args.O[z];
    const bool silu = (z == 3);
#pragma unroll
    for (int m = 0; m < 4; ++m) {
        const int row0 = bm + wr * 64 + m * 16 + lhi * 4;
#pragma unroll
        for (int n = 0; n < 4; ++n) {
            const int col = bn + wc * 64 + n * 16 + l15;
#pragma unroll
            for (int j = 0; j < 4; ++j) {
                float a = acc[m][n][j];
                if (silu) a = a / (1.f + __expf(-a));
                O[(size_t)(row0 + j) * C + col] = f2bf(a);
            }
        }
    }
}

// ---------------- launch ----------------
extern "C" void kernel_launch(void* const* d_in, const int* in_sizes, int n_in,
                              void* d_out, int out_size, void* d_ws, size_t ws_size,
                              hipStream_t stream)
{
    const float* x        = (const float*)d_in[0];
    const float* ln1_g    = (const float*)d_in[1];
    const float* ln1_b    = (const float*)d_in[2];
    const float* ln2_g    = (const float*)d_in[3];
    const float* ln2_b    = (const float*)d_in[4];
    const float* maa_x    = (const float*)d_in[5];
    const float* maa_w    = (const float*)d_in[6];
    const float* maa_k    = (const float*)d_in[7];
    const float* maa_v    = (const float*)d_in[8];
    const float* maa_r    = (const float*)d_in[9];
    const float* maa_g    = (const float*)d_in[10];
    const float* maa_w1   = (const float*)d_in[11];
    const float* maa_w2   = (const float*)d_in[12];
    const float* time_dec = (const float*)d_in[13];
    const float* tdw1     = (const float*)d_in[14];
    const float* tdw2     = (const float*)d_in[15];
    const float* u        = (const float*)d_in[16];
    const float* Wr       = (const float*)d_in[17];
    const float* Wk       = (const float*)d_in[18];
    const float* Wv       = (const float*)d_in[19];
    const float* Wg       = (const float*)d_in[20];
    const float* Wo       = (const float*)d_in[21];
    const float* lnx_g    = (const float*)d_in[22];
    const float* lnx_b    = (const float*)d_in[23];
    const float* cmaa_k   = (const float*)d_in[24];
    const float* cmaa_r   = (const float*)d_in[25];
    const float* Wck      = (const float*)d_in[26];
    const float* Wcv      = (const float*)d_in[27];
    const float* Wcr      = (const float*)d_in[28];
    float* out = (float*)d_out;

    // -------- workspace layout (~63 MB) --------
    float* fws = (float*)d_ws;
    const size_t E = (size_t)BT * C;            // 2,097,152
    float* xa  = fws + 0 * E;                   // xa ; yfb/ybb (bf16) ; kk low
    float* xx  = fws + 1 * E;                   // xx ; kk high half
    float* wd  = fws + 2 * E;                   // decay d
    float* fs  = fws + 3 * E;                   // xvb/xrb ; M low ; kv partials
    ushort* wBuf = (ushort*)(fws + 4 * E);      // 4M ushort: weights / M high
    ushort* Mbuf = (ushort*)fs;                 // 2048*4096 bf16 = fs..wBuf (16MB)
    ushort* w2t  = wBuf + (size_t)C * 160;      // 5*C*32 bf16 (after maa_w1t)
    ushort* bf1  = wBuf + (size_t)C * FF;       // E: ax / xkb / ck_in
    ushort* rb   = bf1 + E;                     // r
    ushort* kb   = rb + E;                      // k
    ushort* vb   = kb + E;                      // v  -> ya
    ushort* gb   = vb + E;                      // g  -> cr_in
    ushort* t1b  = gb + E;                      // BT*64 bf16
    float* a5    = (float*)(t1b + (size_t)BT * 64);   // BT*160 (a5b bf16 inside)
    float* sig   = a5 + (size_t)BT * 160;       // (unused)
    float* Dbuf  = sig + (size_t)BT * H;        // 2048*64 f32
    ushort* a5b  = (ushort*)a5;                 // BT*160 bf16
    ushort* xvb  = (ushort*)fs;                 // E (mix v input)
    ushort* xrb  = (ushort*)fs + E;             // E (mix r input)
    ushort* xgb  = (ushort*)out;                // E (mix g input; out is scratch)
    ushort* xwb  = (ushort*)out + E;            // E (mix w input)
    ushort* yfb  = (ushort*)xa;                 // E bf16 (forward y)
    ushort* ybb  = (ushort*)xa + E;             // E bf16 (backward y)
    ushort* p0b  = (ushort*)fs;                 // E bf16 (kv partial 0)
    ushort* p1b  = (ushort*)fs + E;             // E bf16 (kv partial 1)
    ushort* kk   = (ushort*)xa;                 // BT*FF bf16 == xa..xx

    const dim3 blk(256);
    const dim3 tblk(32, 8);
    const dim3 gNN(C / 64, BT / 128);

    // ---- attention branch ----
    lnshiftmix_kernel<<<BT, blk, 0, stream>>>(x, ln1_g, ln1_b, maa_x, xa, xx, bf1);
    wconv_kernel<<<dim3(160 / 32, C / 32), tblk, 0, stream>>>(maa_w1, wBuf, C, 160);
    bgemm_kernel<64, BEPI_TANH_BF><<<dim3(3, BT / 128), blk, 0, stream>>>(bf1, wBuf, a5b, BT, 160, C, nullptr, nullptr, nullptr);

    // w2 slices -> [5][C][32] bf16 transposed (one launch)
    w2conv_kernel<<<dim3(C / 32, 5), tblk, 0, stream>>>(maa_w2, w2t);

    // all 5 mixes as one fused MFMA GEMM launch
    Mix5Args margs;
    margs.maa[0] = maa_w; margs.maa[1] = maa_k; margs.maa[2] = maa_v;
    margs.maa[3] = maa_r; margs.maa[4] = maa_g;
    margs.out[0] = xwb; margs.out[1] = bf1; margs.out[2] = xvb;
    margs.out[3] = xrb; margs.out[4] = xgb;
    mix5m_kernel<<<dim3(C / 64, BT / 128, 5), blk, 0, stream>>>(a5b, w2t, xa, xx, margs);

    // w path: tanh(xw@tdw1) -> decay d = exp(-exp(@tdw2 + time_decay))
    wconv_kernel<<<dim3(64 / 32, C / 32), tblk, 0, stream>>>(tdw1, wBuf, C, 64);
    bgemm_kernel<64, BEPI_TANH_BF><<<dim3(1, BT / 128), blk, 0, stream>>>(xwb, wBuf, t1b, BT, 64, C, nullptr, nullptr, nullptr);
    wconv_kernel<<<dim3(C / 32, 64 / 32), tblk, 0, stream>>>(tdw2, wBuf, 64, C);
    bgemm_kernel<64, BEPI_DECAY_F><<<gNN, blk, 0, stream>>>(t1b, wBuf, wd, BT, C, 64, time_dec, nullptr, nullptr);

    // batched QKVG
    Wconv4Args wargs;
    wargs.W[0] = Wk; wargs.W[1] = Wv; wargs.W[2] = Wr; wargs.W[3] = Wg;
    wconv4_kernel<<<dim3(C / 32, C / 32, 4), tblk, 0, stream>>>(wargs, wBuf);
    QkvgArgs qargs;
    qargs.A[0] = bf1; qargs.A[1] = xvb; qargs.A[2] = xrb; qargs.A[3] = xgb;
    qargs.O[0] = kb;  qargs.O[1] = vb;  qargs.O[2] = rb;  qargs.O[3] = gb;
    qkvg_kernel<<<dim3(8, 16, 4), blk, 0, stream>>>(qargs, wBuf);

    // chunked bidirectional WKV (Mbuf overlays fs+wBuf; yfb/ybb overlay xa)
    wkv_pass1<<<dim3(2 * B * H * NCH), blk, 0, stream>>>(kb, vb, wd, Mbuf, Dbuf);
    wkv_pass2<<<dim3(2 * B * H), dim3(1024), 0, stream>>>(Mbuf, Dbuf);
    wkv_ymfma<<<dim3(2 * B * H * NCH), blk, 0, stream>>>(rb, kb, vb, wd, Mbuf, yfb, ybb);

    // ya = groupnorm(yf+yb+sig*v)*g ; out = x + ya @ Wo^T
    gnmul_kernel<<<BT, dim3(1024), 0, stream>>>(yfb, ybb, lnx_g, lnx_b, gb, vb, rb, kb, u, vb);
    wconv_kernel<<<dim3(C / 32, C / 32), tblk, 0, stream>>>(Wo, wBuf, C, C);
    bgemm_kernel<64, BEPI_RES_F><<<gNN, blk, 0, stream>>>(vb, wBuf, out, BT, C, C, x, nullptr, nullptr);

    // ---- FFN branch ----
    lnshiftcmix_kernel<<<BT, blk, 0, stream>>>(out, ln2_g, ln2_b, cmaa_k, cmaa_r, bf1, gb);
    wconv_kernel<<<dim3(FF / 32, C / 32), tblk, 0, stream>>>(Wck, wBuf, C, FF);
    bgemm_kernel<128, BEPI_RELUSQ_BF><<<dim3(FF / 128, BT / 128), blk, 0, stream>>>(bf1, wBuf, kk, BT, FF, C, nullptr, nullptr, nullptr);
    wconv_kernel<<<dim3(C / 32, FF / 32), tblk, 0, stream>>>(Wcv, wBuf, FF, C);
    wcv_kernel<<<dim3(16, 16, 2), blk, 0, stream>>>(kk, wBuf, p0b, p1b);
    wconv_kernel<<<dim3(C / 32, C / 32), tblk, 0, stream>>>(Wcr, wBuf, C, C);
    bgemm_kernel<64, BEPI_SIGRES2_F><<<gNN, blk, 0, stream>>>(gb, wBuf, out, BT, C, C, out, (const float*)p0b, (const float*)p1b);

    (void)in_sizes; (void)n_in; (void)out_size; (void)ws_size;
}